// Round 1
// baseline (2938.407 us; speedup 1.0000x reference)
//
#include <hip/hip_runtime.h>
#include <hip/hip_bf16.h>

// ---------------------------------------------------------------------------
// Model: ProteinGraphConv (3x CustomConv edge-attention) + GCN diff branch +
// GRU/MLP head. f32 correctness-first baseline.
// N=6000 nodes, E=200000 edges, HID=256, GH=64, H=8, B=8.
// ---------------------------------------------------------------------------

static inline int cdiv_h(int a, int b) { return (a + b - 1) / b; }

// ---------------- fill ----------------
__global__ void fill_kernel(float* __restrict__ p, float v, int n) {
  int stride = gridDim.x * blockDim.x;
  for (int i = blockIdx.x * blockDim.x + threadIdx.x; i < n; i += stride) p[i] = v;
}

// ---------------- relu (copy or in-place) ----------------
__global__ void relu_kernel(const float* __restrict__ in, float* __restrict__ out, int n) {
  int stride = gridDim.x * blockDim.x;
  for (int i = blockIdx.x * blockDim.x + threadIdx.x; i < n; i += stride)
    out[i] = fmaxf(in[i], 0.0f);
}

// ---------------- GEMM: C = [relu](A(MxK) @ W(KxN) [+ bias]) ----------------
// 64x64 tile, 256 threads, 4x4 per thread, K-step 16. K multiple of 16,
// N multiple of 64, rows of A/W 16B-aligned (K,N multiples of 4).
template <bool RELU, bool BIAS>
__global__ void gemm_kernel(const float* __restrict__ A, const float* __restrict__ W,
                            const float* __restrict__ bias, float* __restrict__ C,
                            int M, int K, int N) {
  __shared__ float As[16][64];
  __shared__ float Bs[16][64];
  const int tx = threadIdx.x;
  const int m0 = blockIdx.x * 64, n0 = blockIdx.y * 64;
  const int tm = (tx & 15) * 4, tn = (tx >> 4) * 4;
  float acc[4][4] = {};
  for (int k0 = 0; k0 < K; k0 += 16) {
    {
      int m = tx >> 2, kq = (tx & 3) * 4;
      float4 av = make_float4(0.f, 0.f, 0.f, 0.f);
      if (m0 + m < M) av = *(const float4*)(A + (size_t)(m0 + m) * K + (k0 + kq));
      As[kq + 0][m] = av.x; As[kq + 1][m] = av.y;
      As[kq + 2][m] = av.z; As[kq + 3][m] = av.w;
      int kk = tx >> 4, nq = (tx & 15) * 4;
      *(float4*)&Bs[kk][nq] = *(const float4*)(W + (size_t)(k0 + kk) * N + (n0 + nq));
    }
    __syncthreads();
#pragma unroll
    for (int k = 0; k < 16; ++k) {
      float4 a4 = *(const float4*)&As[k][tm];
      float4 b4 = *(const float4*)&Bs[k][tn];
      float av[4] = {a4.x, a4.y, a4.z, a4.w};
      float bv[4] = {b4.x, b4.y, b4.z, b4.w};
#pragma unroll
      for (int i = 0; i < 4; ++i)
#pragma unroll
        for (int j = 0; j < 4; ++j) acc[i][j] += av[i] * bv[j];
    }
    __syncthreads();
  }
#pragma unroll
  for (int i = 0; i < 4; ++i) {
    int m = m0 + tm + i;
    if (m >= M) continue;
#pragma unroll
    for (int j = 0; j < 4; ++j) {
      float v = acc[i][j];
      int n = n0 + tn + j;
      if (BIAS) v += bias[n];
      if (RELU) v = fmaxf(v, 0.f);
      C[(size_t)m * N + n] = v;
    }
  }
}

// ---------------- per-edge multi-head attention (CustomConv core) -----------
// One 64-lane wave per edge. Lane (h,g) = (lane>>3, lane&7).
// s[h][g] = dot(q[h], k[g]) * inv_sqrt_d + bias[h]; softmax over g (8-lane
// group shfl_xor); out[h][:] = sum_g a[h][g] * v[g][:]; atomicAdd into AGG[dst].
template <int D>  // head dim: 32 (HID=256) or 8 (GH=64)
__global__ void edge_attn_kernel(const float* __restrict__ Qn, const float* __restrict__ Kn,
                                 const float* __restrict__ Vn, const int* __restrict__ src,
                                 const int* __restrict__ dst, const float* __restrict__ abias,
                                 float* __restrict__ AGG, int E, float inv_sqrt_d) {
  constexpr int C = 8 * D;
  constexpr int WPB = 4;  // waves per 256-thread block
  __shared__ float sQ[WPB][C], sK[WPB][C], sV[WPB][C];
  const int wave = threadIdx.x >> 6, lane = threadIdx.x & 63;
  const int e = blockIdx.x * WPB + wave;
  const bool valid = (e < E);
  int vs = 0, vd = 0;
  if (valid) { vs = src[e]; vd = dst[e]; }
  if (valid) {
    const float4* q4 = (const float4*)(Qn + (size_t)vd * C);
    const float4* k4 = (const float4*)(Kn + (size_t)vs * C);
    const float4* v4 = (const float4*)(Vn + (size_t)vs * C);
    for (int t = lane; t < C / 4; t += 64) {
      ((float4*)sQ[wave])[t] = q4[t];
      ((float4*)sK[wave])[t] = k4[t];
      ((float4*)sV[wave])[t] = v4[t];
    }
  }
  __syncthreads();

  const int h = lane >> 3, g = lane & 7;
  float s = 0.f;
  if (valid) {
    const float* qr = sQ[wave] + h * D;
    const float* kr = sK[wave] + g * D;
#pragma unroll
    for (int d = 0; d < D; ++d) s += qr[d] * kr[d];
    s = s * inv_sqrt_d + abias[h];
  }
  // softmax over g within each 8-lane group
  float m = s;
  m = fmaxf(m, __shfl_xor(m, 1));
  m = fmaxf(m, __shfl_xor(m, 2));
  m = fmaxf(m, __shfl_xor(m, 4));
  float ex = expf(s - m);
  float sum = ex;
  sum += __shfl_xor(sum, 1);
  sum += __shfl_xor(sum, 2);
  sum += __shfl_xor(sum, 4);
  float a = ex / sum;

  // out[h][g + 8*t] = sum_g2 a[h][g2] * v[g2][g + 8*t]
  float acc[D / 8] = {};
#pragma unroll
  for (int g2 = 0; g2 < 8; ++g2) {
    float ag = __shfl(a, (h << 3) + g2);
    const float* vr = sV[wave] + g2 * D;
#pragma unroll
    for (int t = 0; t < D / 8; ++t) acc[t] += ag * vr[g + 8 * t];
  }
  if (valid) {
#pragma unroll
    for (int t = 0; t < D / 8; ++t)
      atomicAdd(&AGG[(size_t)vd * C + h * D + g + 8 * t], acc[t]);
  }
}

// ---------------- GCN ----------------
__global__ void deg_kernel(const int* __restrict__ dst, float* __restrict__ deg, int E) {
  int i = blockIdx.x * blockDim.x + threadIdx.x;
  if (i < E) atomicAdd(&deg[dst[i]], 1.0f);
}

__global__ void rsqrt_kernel(float* __restrict__ p, int n) {
  int i = blockIdx.x * blockDim.x + threadIdx.x;
  if (i < n) p[i] = rsqrtf(p[i]);
}

// O[n][c] = bias[c] + H[n][c]*dis[n]^2   (self-loop + bias init)
__global__ void gcn_init_kernel(const float* __restrict__ H, const float* __restrict__ dis,
                                const float* __restrict__ bias, float* __restrict__ O,
                                int N, int C) {
  int i = blockIdx.x * blockDim.x + threadIdx.x;
  if (i < N * C) {
    int n = i / C, c = i % C;
    float d = dis[n];
    O[i] = bias[c] + H[i] * d * d;
  }
}

// per-edge: O[dst] += H[src] * dis[src]*dis[dst]; one wave per edge
__global__ void gcn_scatter_kernel(const float* __restrict__ H, const int* __restrict__ src,
                                   const int* __restrict__ dst, const float* __restrict__ dis,
                                   float* __restrict__ O, int E, int C) {
  const int wave = threadIdx.x >> 6, lane = threadIdx.x & 63;
  const int e = blockIdx.x * 4 + wave;
  if (e >= E) return;
  const int sN = src[e], tN = dst[e];
  const float coef = dis[sN] * dis[tN];
  const float4* h4 = (const float4*)(H + (size_t)sN * C);
  float* op = O + (size_t)tN * C;
  for (int t = lane; t < C / 4; t += 64) {
    float4 hv = h4[t];
    atomicAdd(op + t * 4 + 0, hv.x * coef);
    atomicAdd(op + t * 4 + 1, hv.y * coef);
    atomicAdd(op + t * 4 + 2, hv.z * coef);
    atomicAdd(op + t * 4 + 3, hv.w * coef);
  }
}

// ---------------- segment sums ----------------
// X3 (N,64) -> sum_x3 (8,64); also positional-encoding sums and counts.
__global__ void segsum_x3_pe_kernel(const float* __restrict__ X3, const int* __restrict__ batch,
                                    float* __restrict__ sum_x3, float* __restrict__ sum_pe,
                                    float* __restrict__ cnt, int N) {
  int i = blockIdx.x * blockDim.x + threadIdx.x;
  if (i >= N * 64) return;
  int n = i >> 6, c = i & 63;
  int b = batch[n];
  atomicAdd(&sum_x3[(b << 6) + c], X3[i]);
  const float F = -0.14391156831f;  // -ln(10000)/64
  float arg = (float)n * expf(F * (float)(c & ~1));
  float pev = (c & 1) ? cosf(arg) : sinf(arg);
  atomicAdd(&sum_pe[(b << 6) + c], pev);
  if (c == 0) atomicAdd(&cnt[b], 1.0f);
}

__global__ void segsum_vfd_kernel(const float* __restrict__ VFD, const int* __restrict__ batch,
                                  float* __restrict__ sum_vfd, float* __restrict__ cnt, int N) {
  int i = blockIdx.x * blockDim.x + threadIdx.x;
  if (i >= N * 128) return;
  int n = i >> 7, c = i & 127;
  int b = batch[n];
  atomicAdd(&sum_vfd[(b << 7) + c], VFD[i]);
  if (c == 0) atomicAdd(&cnt[b], 1.0f);
}

// ---------------- head: segmean -> sft -> GRU -> concat -> MLP -> pred ------
__global__ void head_kernel(const float* __restrict__ sum_x3, const float* __restrict__ sum_pe,
                            const float* __restrict__ cnt_wt, const float* __restrict__ sum_vfd,
                            const float* __restrict__ cnt_df, const float* __restrict__ sft_w,
                            const float* __restrict__ sft_b, const float* __restrict__ gru_wih,
                            const float* __restrict__ gru_bih, const float* __restrict__ gru_bhh,
                            const float* __restrict__ mlp_w1, const float* __restrict__ mlp_b1,
                            const float* __restrict__ mlp_w2, const float* __restrict__ mlp_b2,
                            const float* __restrict__ mlp_w3, const float* __restrict__ mlp_b3,
                            const float* __restrict__ pred_w, const float* __restrict__ pred_b,
                            float* __restrict__ out) {
  __shared__ float sA[512];   // sf (8x64)
  __shared__ float sB[1536];  // sf1 then m2
  __shared__ float sC[2048];  // gi then hcat
  __shared__ float sD[1024];  // m1 then m3
  __shared__ float sE[1024];  // m2
  const int tid = threadIdx.x;

  // sf0 = segmean(X3)
  for (int i = tid; i < 512; i += 256) {
    int b = i >> 6;
    sA[i] = sum_x3[i] / fmaxf(cnt_wt[b], 1.f);
  }
  __syncthreads();
  // sf1 = relu(sf0 @ sft_w + sft_b)
  for (int i = tid; i < 512; i += 256) {
    int b = i >> 6, c = i & 63;
    float acc = sft_b[c];
    for (int k = 0; k < 64; ++k) acc += sA[(b << 6) + k] * sft_w[k * 64 + c];
    sB[i] = fmaxf(acc, 0.f);
  }
  __syncthreads();
  // gi = sf1 @ wih^T + bih  (8 x 192)
  for (int i = tid; i < 1536; i += 256) {
    int b = i / 192, r = i % 192;
    float acc = gru_bih[r];
    for (int k = 0; k < 64; ++k) acc += sB[(b << 6) + k] * gru_wih[r * 64 + k];
    sC[i] = acc;
  }
  __syncthreads();
  // GRU (h0 = 0): gh = bhh
  for (int i = tid; i < 512; i += 256) {
    int b = i >> 6, c = i & 63;
    const float* gi = sC + b * 192;
    float r = 1.f / (1.f + expf(-(gi[c] + gru_bhh[c])));
    float z = 1.f / (1.f + expf(-(gi[64 + c] + gru_bhh[64 + c])));
    float ng = tanhf(gi[128 + c] + r * gru_bhh[128 + c]);
    sA[i] = (1.f - z) * ng;  // sf final
  }
  __syncthreads();
  // hcat (8 x 256) = [segmean(X3)+segmean(pe), sf, segmean(vf_diff)]
  for (int i = tid; i < 2048; i += 256) {
    int b = i >> 8, c = i & 255;
    float v;
    if (c < 64)
      v = (sum_x3[(b << 6) + c] + sum_pe[(b << 6) + c]) / fmaxf(cnt_wt[b], 1.f);
    else if (c < 128)
      v = sA[(b << 6) + (c - 64)];
    else
      v = sum_vfd[(b << 7) + (c - 128)] / fmaxf(cnt_df[b], 1.f);
    sC[i] = v;
  }
  __syncthreads();
  // m1 = relu(hcat @ w1 + b1)  (8 x 128)
  for (int i = tid; i < 1024; i += 256) {
    int b = i >> 7, c = i & 127;
    float acc = mlp_b1[c];
    for (int k = 0; k < 256; ++k) acc += sC[(b << 8) + k] * mlp_w1[k * 128 + c];
    sD[i] = fmaxf(acc, 0.f);
  }
  __syncthreads();
  // m2 = relu(m1 @ w2 + b2)
  for (int i = tid; i < 1024; i += 256) {
    int b = i >> 7, c = i & 127;
    float acc = mlp_b2[c];
    for (int k = 0; k < 128; ++k) acc += sD[(b << 7) + k] * mlp_w2[k * 128 + c];
    sE[i] = fmaxf(acc, 0.f);
  }
  __syncthreads();
  // m3 = m2 @ w3 + b3
  for (int i = tid; i < 1024; i += 256) {
    int b = i >> 7, c = i & 127;
    float acc = mlp_b3[c];
    for (int k = 0; k < 128; ++k) acc += sE[(b << 7) + k] * mlp_w3[k * 128 + c];
    sD[i] = acc;
  }
  __syncthreads();
  // out[b] = m3[b] . pred_w + pred_b
  for (int b = tid; b < 8; b += 256) {
    float acc = pred_b[0];
    for (int k = 0; k < 128; ++k) acc += sD[(b << 7) + k] * pred_w[k];
    out[b] = acc;
  }
}

// ---------------------------------------------------------------------------
extern "C" void kernel_launch(void* const* d_in, const int* in_sizes, int n_in,
                              void* d_out, int out_size, void* d_ws, size_t ws_size,
                              hipStream_t stream) {
  const float* x_wt = (const float*)d_in[0];
  const float* x_diff = (const float*)d_in[1];
  const int* ei_wt = (const int*)d_in[2];
  const int* ei_df = (const int*)d_in[3];
  const int* b_wt = (const int*)d_in[4];
  const int* b_df = (const int*)d_in[5];
  const float* emb_w = (const float*)d_in[6];
  const float* emb_b = (const float*)d_in[7];
  const float* cw_lin_w = (const float*)d_in[8];
  const float* cw_lin_b = (const float*)d_in[9];
  const float* cw_q_w = (const float*)d_in[10];
  const float* cw_q_b = (const float*)d_in[11];
  const float* cw_k_w = (const float*)d_in[12];
  const float* cw_k_b = (const float*)d_in[13];
  const float* cw_v_w = (const float*)d_in[14];
  const float* cw_v_b = (const float*)d_in[15];
  const float* cw_bias = (const float*)d_in[16];
  const float* c3_lin_w = (const float*)d_in[17];
  const float* c3_lin_b = (const float*)d_in[18];
  const float* c3_q_w = (const float*)d_in[19];
  const float* c3_q_b = (const float*)d_in[20];
  const float* c3_k_w = (const float*)d_in[21];
  const float* c3_k_b = (const float*)d_in[22];
  const float* c3_v_w = (const float*)d_in[23];
  const float* c3_v_b = (const float*)d_in[24];
  const float* c3_bias = (const float*)d_in[25];
  const float* sft_w = (const float*)d_in[26];
  const float* sft_b = (const float*)d_in[27];
  const float* gru_wih = (const float*)d_in[28];
  // d_in[29] = gru_whh: unused (h0 = 0 -> gh = bhh)
  const float* gru_bih = (const float*)d_in[30];
  const float* gru_bhh = (const float*)d_in[31];
  const float* gcn_w1 = (const float*)d_in[32];
  const float* gcn_b1 = (const float*)d_in[33];
  const float* gcn_w2 = (const float*)d_in[34];
  const float* gcn_b2 = (const float*)d_in[35];
  const float* gcn_w3 = (const float*)d_in[36];
  const float* gcn_b3 = (const float*)d_in[37];
  const float* mlp_w1 = (const float*)d_in[38];
  const float* mlp_b1 = (const float*)d_in[39];
  const float* mlp_w2 = (const float*)d_in[40];
  const float* mlp_b2 = (const float*)d_in[41];
  const float* mlp_w3 = (const float*)d_in[42];
  const float* mlp_b3 = (const float*)d_in[43];
  const float* pred_w = (const float*)d_in[44];
  const float* pred_b = (const float*)d_in[45];

  const int N = in_sizes[0] / 64;   // 6000
  const int E = in_sizes[2] / 2;    // 200000
  const int* src_wt = ei_wt;
  const int* dst_wt = ei_wt + E;
  const int* src_df = ei_df;
  const int* dst_df = ei_df + E;

  // workspace layout (floats)
  float* ws = (float*)d_ws;
  const size_t fN256 = (size_t)N * 256;
  float* X = ws;                    // node features (N,256)
  float* L = ws + 1 * fN256;        // lin out / gcn H
  float* Qb = ws + 2 * fN256;       // Q / gcn O1
  float* Kb = ws + 3 * fN256;       // K / gcn O2
  float* Vb = ws + 4 * fN256;       // V / gcn VFD
  float* AGG = ws + 5 * fN256;      // conv aggregation
  float* X3 = ws + 6 * fN256;       // (N,64)
  float* DIS = X3 + (size_t)N * 64; // (N)
  float* SEG = DIS + (((size_t)N + 63) / 64) * 64;
  float* sum_x3 = SEG;              // 512
  float* sum_pe = SEG + 512;        // 512
  float* cnt_wt = SEG + 1024;       // 8
  float* sum_vfd = SEG + 1032;      // 1024
  float* cnt_df = SEG + 2056;       // 8  (total 2064)

  const int TB = 256;
  auto gemm = [&](const float* A, const float* W, const float* bias, float* C,
                  int M, int K, int Nn, bool relu) {
    dim3 g(cdiv_h(M, 64), Nn / 64);
    if (relu)
      gemm_kernel<true, true><<<g, TB, 0, stream>>>(A, W, bias, C, M, K, Nn);
    else if (bias)
      gemm_kernel<false, true><<<g, TB, 0, stream>>>(A, W, bias, C, M, K, Nn);
    else
      gemm_kernel<false, false><<<g, TB, 0, stream>>>(A, W, nullptr, C, M, K, Nn);
  };

  // ---- WT branch ----
  gemm(x_wt, emb_w, emb_b, X, N, 64, 256, true);
  const float isd32 = 0.17677669529663687f;  // 1/sqrt(32)
  const float isd8 = 0.35355339059327373f;   // 1/sqrt(8)
  for (int l = 0; l < 2; ++l) {
    const float* lw = cw_lin_w + (size_t)l * 256 * 256;
    const float* lb = cw_lin_b + l * 256;
    const float* qw = cw_q_w + (size_t)l * 256 * 256;
    const float* qb = cw_q_b + l * 256;
    const float* kw = cw_k_w + (size_t)l * 256 * 256;
    const float* kb = cw_k_b + l * 256;
    const float* vw = cw_v_w + (size_t)l * 256 * 256;
    const float* vb = cw_v_b + l * 256;
    const float* ab = cw_bias + l * 8;
    gemm(X, lw, lb, L, N, 256, 256, false);
    gemm(L, qw, qb, Qb, N, 256, 256, false);
    gemm(L, kw, kb, Kb, N, 256, 256, false);
    gemm(L, vw, vb, Vb, N, 256, 256, false);
    fill_kernel<<<2048, TB, 0, stream>>>(AGG, 0.f, N * 256);
    edge_attn_kernel<32><<<cdiv_h(E, 4), TB, 0, stream>>>(Qb, Kb, Vb, src_wt, dst_wt, ab,
                                                          AGG, E, isd32);
    relu_kernel<<<2048, TB, 0, stream>>>(AGG, X, N * 256);
  }
  // conv3 (HID -> 64)
  gemm(X, c3_lin_w, c3_lin_b, L, N, 256, 64, false);
  gemm(L, c3_q_w, c3_q_b, Qb, N, 64, 64, false);
  gemm(L, c3_k_w, c3_k_b, Kb, N, 64, 64, false);
  gemm(L, c3_v_w, c3_v_b, Vb, N, 64, 64, false);
  fill_kernel<<<512, TB, 0, stream>>>(AGG, 0.f, N * 64);
  edge_attn_kernel<8><<<cdiv_h(E, 4), TB, 0, stream>>>(Qb, Kb, Vb, src_wt, dst_wt, c3_bias,
                                                       AGG, E, isd8);
  relu_kernel<<<512, TB, 0, stream>>>(AGG, X3, N * 64);

  // segment sums for WT head
  fill_kernel<<<8, TB, 0, stream>>>(SEG, 0.f, 2064);
  segsum_x3_pe_kernel<<<cdiv_h(N * 64, TB), TB, 0, stream>>>(X3, b_wt, sum_x3, sum_pe,
                                                             cnt_wt, N);

  // ---- diff branch (GCN) ----
  fill_kernel<<<32, TB, 0, stream>>>(DIS, 1.f, N);  // self-loop degree
  deg_kernel<<<cdiv_h(E, TB), TB, 0, stream>>>(dst_df, DIS, E);
  rsqrt_kernel<<<cdiv_h(N, TB), TB, 0, stream>>>(DIS, N);
  // layer 1: x_diff (N,64) -> (N,256)
  gemm(x_diff, gcn_w1, nullptr, L, N, 64, 256, false);
  gcn_init_kernel<<<cdiv_h(N * 256, TB), TB, 0, stream>>>(L, DIS, gcn_b1, Qb, N, 256);
  gcn_scatter_kernel<<<cdiv_h(E, 4), TB, 0, stream>>>(L, src_df, dst_df, DIS, Qb, E, 256);
  relu_kernel<<<2048, TB, 0, stream>>>(Qb, Qb, N * 256);
  // layer 2: (N,256) -> (N,256)
  gemm(Qb, gcn_w2, nullptr, L, N, 256, 256, false);
  gcn_init_kernel<<<cdiv_h(N * 256, TB), TB, 0, stream>>>(L, DIS, gcn_b2, Kb, N, 256);
  gcn_scatter_kernel<<<cdiv_h(E, 4), TB, 0, stream>>>(L, src_df, dst_df, DIS, Kb, E, 256);
  relu_kernel<<<2048, TB, 0, stream>>>(Kb, Kb, N * 256);
  // layer 3: (N,256) -> (N,128), no relu
  gemm(Kb, gcn_w3, nullptr, L, N, 256, 128, false);
  gcn_init_kernel<<<cdiv_h(N * 128, TB), TB, 0, stream>>>(L, DIS, gcn_b3, Vb, N, 128);
  gcn_scatter_kernel<<<cdiv_h(E, 4), TB, 0, stream>>>(L, src_df, dst_df, DIS, Vb, E, 128);
  segsum_vfd_kernel<<<cdiv_h(N * 128, TB), TB, 0, stream>>>(Vb, b_df, sum_vfd, cnt_df, N);

  // ---- head ----
  head_kernel<<<1, TB, 0, stream>>>(sum_x3, sum_pe, cnt_wt, sum_vfd, cnt_df, sft_w, sft_b,
                                    gru_wih, gru_bih, gru_bhh, mlp_w1, mlp_b1, mlp_w2,
                                    mlp_b2, mlp_w3, mlp_b3, pred_w, pred_b, (float*)d_out);
}

// Round 2
// 808.299 us; speedup vs baseline: 3.6353x; 3.6353x over previous
//
#include <hip/hip_runtime.h>
#include <hip/hip_bf16.h>

// ---------------------------------------------------------------------------
// ProteinGraphConv (3x CustomConv edge-attention) + GCN diff branch + GRU/MLP
// head. Round 2: CSR-gather everywhere (no f32 scatter atomics).
// N=6000, E=200000, HID=256, GH=64, H=8, B=8.
// ---------------------------------------------------------------------------

static inline int cdiv_h(int a, int b) { return (a + b - 1) / b; }

__global__ void fill_f_kernel(float* __restrict__ p, float v, int n) {
  int stride = gridDim.x * blockDim.x;
  for (int i = blockIdx.x * blockDim.x + threadIdx.x; i < n; i += stride) p[i] = v;
}
__global__ void fill_i_kernel(int* __restrict__ p, int v, int n) {
  int stride = gridDim.x * blockDim.x;
  for (int i = blockIdx.x * blockDim.x + threadIdx.x; i < n; i += stride) p[i] = v;
}

// ---------------- CSR build ----------------
__global__ void hist_kernel(const int* __restrict__ dst, int* __restrict__ deg, int E) {
  int i = blockIdx.x * blockDim.x + threadIdx.x;
  if (i < E) atomicAdd(&deg[dst[i]], 1);
}

// single-block exclusive scan (N <= 1024*chunk), writes rowptr[N]=total and cursor
__global__ void scan_kernel(const int* __restrict__ deg, int* __restrict__ rowptr,
                            int* __restrict__ cursor, int N) {
  __shared__ int part[1024];
  const int t = threadIdx.x;
  const int chunk = (N + 1023) / 1024;
  const int base0 = t * chunk;
  int s = 0;
  for (int i = 0; i < chunk; ++i) {
    int idx = base0 + i;
    if (idx < N) s += deg[idx];
  }
  part[t] = s;
  __syncthreads();
  for (int off = 1; off < 1024; off <<= 1) {
    int v = (t >= off) ? part[t - off] : 0;
    __syncthreads();
    part[t] += v;
    __syncthreads();
  }
  int run = (t == 0) ? 0 : part[t - 1];
  for (int i = 0; i < chunk; ++i) {
    int idx = base0 + i;
    if (idx < N) {
      rowptr[idx] = run;
      cursor[idx] = run;
      run += deg[idx];
    }
  }
  if (t == 1023) rowptr[N] = part[1023];
}

// adj[pos] = src node id, bucketed by dst
__global__ void fill_adj_kernel(const int* __restrict__ src, const int* __restrict__ dst,
                                int* __restrict__ cursor, int* __restrict__ adj, int E) {
  int i = blockIdx.x * blockDim.x + threadIdx.x;
  if (i < E) {
    int p = atomicAdd(&cursor[dst[i]], 1);
    adj[p] = src[i];
  }
}

__global__ void dis_kernel(const int* __restrict__ rowptr, float* __restrict__ dis, int N) {
  int i = blockIdx.x * blockDim.x + threadIdx.x;
  if (i < N) dis[i] = rsqrtf((float)(rowptr[i + 1] - rowptr[i] + 1));
}

// ---------------- GEMM: C = [relu](A(MxK) @ W(KxN) [+ bias]) ----------------
template <bool RELU, bool BIAS>
__global__ void gemm_kernel(const float* __restrict__ A, const float* __restrict__ W,
                            const float* __restrict__ bias, float* __restrict__ C,
                            int M, int K, int N) {
  __shared__ float As[16][64];
  __shared__ float Bs[16][64];
  const int tx = threadIdx.x;
  const int m0 = blockIdx.x * 64, n0 = blockIdx.y * 64;
  const int tm = (tx & 15) * 4, tn = (tx >> 4) * 4;
  float acc[4][4] = {};
  for (int k0 = 0; k0 < K; k0 += 16) {
    {
      int m = tx >> 2, kq = (tx & 3) * 4;
      float4 av = make_float4(0.f, 0.f, 0.f, 0.f);
      if (m0 + m < M) av = *(const float4*)(A + (size_t)(m0 + m) * K + (k0 + kq));
      As[kq + 0][m] = av.x; As[kq + 1][m] = av.y;
      As[kq + 2][m] = av.z; As[kq + 3][m] = av.w;
      int kk = tx >> 4, nq = (tx & 15) * 4;
      *(float4*)&Bs[kk][nq] = *(const float4*)(W + (size_t)(k0 + kk) * N + (n0 + nq));
    }
    __syncthreads();
#pragma unroll
    for (int k = 0; k < 16; ++k) {
      float4 a4 = *(const float4*)&As[k][tm];
      float4 b4 = *(const float4*)&Bs[k][tn];
      float av[4] = {a4.x, a4.y, a4.z, a4.w};
      float bv[4] = {b4.x, b4.y, b4.z, b4.w};
#pragma unroll
      for (int i = 0; i < 4; ++i)
#pragma unroll
        for (int j = 0; j < 4; ++j) acc[i][j] += av[i] * bv[j];
    }
    __syncthreads();
  }
#pragma unroll
  for (int i = 0; i < 4; ++i) {
    int m = m0 + tm + i;
    if (m >= M) continue;
#pragma unroll
    for (int j = 0; j < 4; ++j) {
      float v = acc[i][j];
      int n = n0 + tn + j;
      if (BIAS) v += bias[n];
      if (RELU) v = fmaxf(v, 0.f);
      C[(size_t)m * N + n] = v;
    }
  }
}

// ---------------- CustomConv via dst-CSR gather ----------------
// One 64-lane wave (= one block) per dst node. Lane (h,g)=(lane>>3, lane&7).
// Per incoming edge: stage k,v in LDS; s[h][g]=q[h].k[g]*isd+bias[h]; softmax
// over g (8-lane shfl group); acc[h][:] += a*v. Fused relu store.
template <int D>  // head dim: 32 (C=256) or 8 (C=64)
__global__ void conv_gather_kernel(const float* __restrict__ Qn, const float* __restrict__ Kn,
                                   const float* __restrict__ Vn, const int* __restrict__ rowptr,
                                   const int* __restrict__ adj, const float* __restrict__ abias,
                                   float* __restrict__ Xout, float inv_sqrt_d) {
  constexpr int C = 8 * D;
  constexpr int KS = D + 4;   // padded row stride for sQ/sK (bank-conflict-free)
  constexpr int NF4 = C / 4;  // float4s per node row
  constexpr int F4R = D / 4;  // float4s per head row
  __shared__ float sQ[8 * KS];
  __shared__ float sK[8 * KS];
  __shared__ float sV[C];
  const int lane = threadIdx.x;  // blockDim = 64
  const int n = blockIdx.x;
  const int h = lane >> 3, g = lane & 7;

  if (lane < NF4) {
    int r = lane / F4R, c4 = lane % F4R;
    *(float4*)&sQ[r * KS + c4 * 4] =
        *(const float4*)(Qn + (size_t)n * C + r * D + c4 * 4);
  }
  const float bh = abias[h];
  float acc[D / 8] = {};
  const int s = rowptr[n], t = rowptr[n + 1];
  for (int i = s; i < t; ++i) {
    const int vs = adj[i];
    if (lane < NF4) {
      int r = lane / F4R, c4 = lane % F4R;
      *(float4*)&sK[r * KS + c4 * 4] =
          *(const float4*)(Kn + (size_t)vs * C + r * D + c4 * 4);
      *(float4*)&sV[lane * 4] = *(const float4*)(Vn + (size_t)vs * C + lane * 4);
    }
    __syncthreads();
    float sc = 0.f;
    const float* qr = sQ + h * KS;
    const float* kr = sK + g * KS;
#pragma unroll
    for (int d4 = 0; d4 < D / 4; ++d4) {
      float4 q4 = *(const float4*)(qr + d4 * 4);
      float4 k4 = *(const float4*)(kr + d4 * 4);
      sc += q4.x * k4.x + q4.y * k4.y + q4.z * k4.z + q4.w * k4.w;
    }
    sc = sc * inv_sqrt_d + bh;
    float m = sc;
    m = fmaxf(m, __shfl_xor(m, 1));
    m = fmaxf(m, __shfl_xor(m, 2));
    m = fmaxf(m, __shfl_xor(m, 4));
    float ex = __expf(sc - m);
    float sum = ex;
    sum += __shfl_xor(sum, 1);
    sum += __shfl_xor(sum, 2);
    sum += __shfl_xor(sum, 4);
    float a = ex / sum;
#pragma unroll
    for (int g2 = 0; g2 < 8; ++g2) {
      float ag = __shfl(a, (h << 3) + g2);
      const float* vr = sV + g2 * D;
#pragma unroll
      for (int t4 = 0; t4 < D / 8; ++t4) acc[t4] += ag * vr[g + 8 * t4];
    }
    __syncthreads();
  }
  float* on = Xout + (size_t)n * C + h * D;
#pragma unroll
  for (int t4 = 0; t4 < D / 8; ++t4) on[g + 8 * t4] = fmaxf(acc[t4], 0.f);
}

// ---------------- GCN propagate via dst-CSR gather ----------------
// out[n] = [relu]( dis[n]^2*H[n] + sum_e dis[src]*dis[n]*H[src] [+ bias] )
template <int C, bool BIAS, bool RELU>
__global__ void gcn_gather_kernel(const float* __restrict__ H, const int* __restrict__ rowptr,
                                  const int* __restrict__ adj, const float* __restrict__ dis,
                                  const float* __restrict__ bias, float* __restrict__ O,
                                  int Nn) {
  constexpr int EPL = C / 64;  // elements per lane: 4, 2, 1
  const int wave = threadIdx.x >> 6, lane = threadIdx.x & 63;
  const int n = blockIdx.x * 4 + wave;
  if (n >= Nn) return;
  const float dn = dis[n];
  float acc[EPL];
  const float* hn = H + (size_t)n * C;
#pragma unroll
  for (int j = 0; j < EPL; ++j) acc[j] = hn[lane * EPL + j] * dn * dn;
  const int s = rowptr[n], t = rowptr[n + 1];
  for (int i = s; i < t; ++i) {
    const int vs = adj[i];
    const float coef = dis[vs] * dn;
    const float* hs = H + (size_t)vs * C;
    if constexpr (EPL == 4) {
      float4 hv = *(const float4*)(hs + lane * 4);
      acc[0] += hv.x * coef; acc[1] += hv.y * coef;
      acc[2] += hv.z * coef; acc[3] += hv.w * coef;
    } else if constexpr (EPL == 2) {
      float2 hv = *(const float2*)(hs + lane * 2);
      acc[0] += hv.x * coef; acc[1] += hv.y * coef;
    } else {
      acc[0] += hs[lane] * coef;
    }
  }
  float* on = O + (size_t)n * C;
#pragma unroll
  for (int j = 0; j < EPL; ++j) {
    float v = acc[j];
    if (BIAS) v += bias[lane * EPL + j];
    if (RELU) v = fmaxf(v, 0.f);
    on[lane * EPL + j] = v;
  }
}

// ---------------- segment sums (LDS pre-reduction) ----------------
__global__ void segsum_x3_pe_kernel(const float* __restrict__ X3, const int* __restrict__ batch,
                                    float* __restrict__ sum_x3, float* __restrict__ sum_pe,
                                    float* __restrict__ cnt, int N) {
  __shared__ float lx[512], lp[512], lc[8];
  const int tid = threadIdx.x;
  for (int i = tid; i < 512; i += 256) { lx[i] = 0.f; lp[i] = 0.f; }
  if (tid < 8) lc[tid] = 0.f;
  __syncthreads();
  int i = blockIdx.x * 256 + tid;
  if (i < N * 64) {
    int n = i >> 6, c = i & 63;
    int b = batch[n];
    atomicAdd(&lx[(b << 6) + c], X3[i]);
    const float F = -0.14391156831f;  // -ln(10000)/64
    float arg = (float)n * expf(F * (float)(c & ~1));
    atomicAdd(&lp[(b << 6) + c], (c & 1) ? cosf(arg) : sinf(arg));
    if (c == 0) atomicAdd(&lc[b], 1.f);
  }
  __syncthreads();
  for (int j = tid; j < 512; j += 256) {
    if (lx[j] != 0.f) atomicAdd(&sum_x3[j], lx[j]);
    if (lp[j] != 0.f) atomicAdd(&sum_pe[j], lp[j]);
  }
  if (tid < 8 && lc[tid] != 0.f) atomicAdd(&cnt[tid], lc[tid]);
}

__global__ void segsum_vfd_kernel(const float* __restrict__ VFD, const int* __restrict__ batch,
                                  float* __restrict__ sum_vfd, float* __restrict__ cnt, int N) {
  __shared__ float lv[1024], lc[8];
  const int tid = threadIdx.x;
  for (int i = tid; i < 1024; i += 256) lv[i] = 0.f;
  if (tid < 8) lc[tid] = 0.f;
  __syncthreads();
  int i = blockIdx.x * 256 + tid;
  if (i < N * 128) {
    int n = i >> 7, c = i & 127;
    int b = batch[n];
    atomicAdd(&lv[(b << 7) + c], VFD[i]);
    if (c == 0) atomicAdd(&lc[b], 1.f);
  }
  __syncthreads();
  for (int j = tid; j < 1024; j += 256) {
    if (lv[j] != 0.f) atomicAdd(&sum_vfd[j], lv[j]);
  }
  if (tid < 8 && lc[tid] != 0.f) atomicAdd(&cnt[tid], lc[tid]);
}

// ---------------- head ----------------
__global__ void head_kernel(const float* __restrict__ sum_x3, const float* __restrict__ sum_pe,
                            const float* __restrict__ cnt_wt, const float* __restrict__ sum_vfd,
                            const float* __restrict__ cnt_df, const float* __restrict__ sft_w,
                            const float* __restrict__ sft_b, const float* __restrict__ gru_wih,
                            const float* __restrict__ gru_bih, const float* __restrict__ gru_bhh,
                            const float* __restrict__ mlp_w1, const float* __restrict__ mlp_b1,
                            const float* __restrict__ mlp_w2, const float* __restrict__ mlp_b2,
                            const float* __restrict__ mlp_w3, const float* __restrict__ mlp_b3,
                            const float* __restrict__ pred_w, const float* __restrict__ pred_b,
                            float* __restrict__ out) {
  __shared__ float sA[512];
  __shared__ float sB[1536];
  __shared__ float sC[2048];
  __shared__ float sD[1024];
  __shared__ float sE[1024];
  const int tid = threadIdx.x;
  for (int i = tid; i < 512; i += 256) {
    int b = i >> 6;
    sA[i] = sum_x3[i] / fmaxf(cnt_wt[b], 1.f);
  }
  __syncthreads();
  for (int i = tid; i < 512; i += 256) {
    int b = i >> 6, c = i & 63;
    float acc = sft_b[c];
    for (int k = 0; k < 64; ++k) acc += sA[(b << 6) + k] * sft_w[k * 64 + c];
    sB[i] = fmaxf(acc, 0.f);
  }
  __syncthreads();
  for (int i = tid; i < 1536; i += 256) {
    int b = i / 192, r = i % 192;
    float acc = gru_bih[r];
    for (int k = 0; k < 64; ++k) acc += sB[(b << 6) + k] * gru_wih[r * 64 + k];
    sC[i] = acc;
  }
  __syncthreads();
  for (int i = tid; i < 512; i += 256) {
    int b = i >> 6, c = i & 63;
    const float* gi = sC + b * 192;
    float r = 1.f / (1.f + expf(-(gi[c] + gru_bhh[c])));
    float z = 1.f / (1.f + expf(-(gi[64 + c] + gru_bhh[64 + c])));
    float ng = tanhf(gi[128 + c] + r * gru_bhh[128 + c]);
    sA[i] = (1.f - z) * ng;
  }
  __syncthreads();
  for (int i = tid; i < 2048; i += 256) {
    int b = i >> 8, c = i & 255;
    float v;
    if (c < 64)
      v = (sum_x3[(b << 6) + c] + sum_pe[(b << 6) + c]) / fmaxf(cnt_wt[b], 1.f);
    else if (c < 128)
      v = sA[(b << 6) + (c - 64)];
    else
      v = sum_vfd[(b << 7) + (c - 128)] / fmaxf(cnt_df[b], 1.f);
    sC[i] = v;
  }
  __syncthreads();
  for (int i = tid; i < 1024; i += 256) {
    int b = i >> 7, c = i & 127;
    float acc = mlp_b1[c];
    for (int k = 0; k < 256; ++k) acc += sC[(b << 8) + k] * mlp_w1[k * 128 + c];
    sD[i] = fmaxf(acc, 0.f);
  }
  __syncthreads();
  for (int i = tid; i < 1024; i += 256) {
    int b = i >> 7, c = i & 127;
    float acc = mlp_b2[c];
    for (int k = 0; k < 128; ++k) acc += sD[(b << 7) + k] * mlp_w2[k * 128 + c];
    sE[i] = fmaxf(acc, 0.f);
  }
  __syncthreads();
  for (int i = tid; i < 1024; i += 256) {
    int b = i >> 7, c = i & 127;
    float acc = mlp_b3[c];
    for (int k = 0; k < 128; ++k) acc += sE[(b << 7) + k] * mlp_w3[k * 128 + c];
    sD[i] = acc;
  }
  __syncthreads();
  for (int b = tid; b < 8; b += 256) {
    float acc = pred_b[0];
    for (int k = 0; k < 128; ++k) acc += sD[(b << 7) + k] * pred_w[k];
    out[b] = acc;
  }
}

// ---------------------------------------------------------------------------
extern "C" void kernel_launch(void* const* d_in, const int* in_sizes, int n_in,
                              void* d_out, int out_size, void* d_ws, size_t ws_size,
                              hipStream_t stream) {
  const float* x_wt = (const float*)d_in[0];
  const float* x_diff = (const float*)d_in[1];
  const int* ei_wt = (const int*)d_in[2];
  const int* ei_df = (const int*)d_in[3];
  const int* b_wt = (const int*)d_in[4];
  const int* b_df = (const int*)d_in[5];
  const float* emb_w = (const float*)d_in[6];
  const float* emb_b = (const float*)d_in[7];
  const float* cw_lin_w = (const float*)d_in[8];
  const float* cw_lin_b = (const float*)d_in[9];
  const float* cw_q_w = (const float*)d_in[10];
  const float* cw_q_b = (const float*)d_in[11];
  const float* cw_k_w = (const float*)d_in[12];
  const float* cw_k_b = (const float*)d_in[13];
  const float* cw_v_w = (const float*)d_in[14];
  const float* cw_v_b = (const float*)d_in[15];
  const float* cw_bias = (const float*)d_in[16];
  const float* c3_lin_w = (const float*)d_in[17];
  const float* c3_lin_b = (const float*)d_in[18];
  const float* c3_q_w = (const float*)d_in[19];
  const float* c3_q_b = (const float*)d_in[20];
  const float* c3_k_w = (const float*)d_in[21];
  const float* c3_k_b = (const float*)d_in[22];
  const float* c3_v_w = (const float*)d_in[23];
  const float* c3_v_b = (const float*)d_in[24];
  const float* c3_bias = (const float*)d_in[25];
  const float* sft_w = (const float*)d_in[26];
  const float* sft_b = (const float*)d_in[27];
  const float* gru_wih = (const float*)d_in[28];
  const float* gru_bih = (const float*)d_in[30];
  const float* gru_bhh = (const float*)d_in[31];
  const float* gcn_w1 = (const float*)d_in[32];
  const float* gcn_b1 = (const float*)d_in[33];
  const float* gcn_w2 = (const float*)d_in[34];
  const float* gcn_b2 = (const float*)d_in[35];
  const float* gcn_w3 = (const float*)d_in[36];
  const float* gcn_b3 = (const float*)d_in[37];
  const float* mlp_w1 = (const float*)d_in[38];
  const float* mlp_b1 = (const float*)d_in[39];
  const float* mlp_w2 = (const float*)d_in[40];
  const float* mlp_b2 = (const float*)d_in[41];
  const float* mlp_w3 = (const float*)d_in[42];
  const float* mlp_b3 = (const float*)d_in[43];
  const float* pred_w = (const float*)d_in[44];
  const float* pred_b = (const float*)d_in[45];

  const int N = in_sizes[0] / 64;  // 6000
  const int E = in_sizes[2] / 2;   // 200000
  const int* src_wt = ei_wt;
  const int* dst_wt = ei_wt + E;
  const int* src_df = ei_df;
  const int* dst_df = ei_df + E;

  // ---- workspace layout ----
  float* ws = (float*)d_ws;
  const size_t fN256 = (size_t)N * 256;
  float* X = ws;
  float* L = ws + 1 * fN256;
  float* Qb = ws + 2 * fN256;
  float* Kb = ws + 3 * fN256;
  float* Vb = ws + 4 * fN256;
  float* X3 = ws + 5 * fN256;          // (N,64)
  float* DIS = X3 + (size_t)N * 64;    // (N)
  float* SEG = DIS + (((size_t)N + 63) / 64) * 64;
  float* sum_x3 = SEG;                 // 512
  float* sum_pe = SEG + 512;           // 512
  float* cnt_wt = SEG + 1024;          // 8
  float* sum_vfd = SEG + 1032;         // 1024
  float* cnt_df = SEG + 2056;          // 8
  int* ip = (int*)(SEG + 2064 + 16);
  int* rp_wt = ip;                     // N+1
  int* cur_wt = rp_wt + (N + 1);       // N
  int* adj_wt = cur_wt + N;            // E
  int* rp_df = adj_wt + E;             // N+1
  int* cur_df = rp_df + (N + 1);       // N
  int* adj_df = cur_df + N;            // E

  const int TB = 256;
  auto gemm = [&](const float* A, const float* W, const float* bias, float* C,
                  int M, int K, int Nn, bool relu) {
    dim3 g(cdiv_h(M, 64), Nn / 64);
    if (relu)
      gemm_kernel<true, true><<<g, TB, 0, stream>>>(A, W, bias, C, M, K, Nn);
    else if (bias)
      gemm_kernel<false, true><<<g, TB, 0, stream>>>(A, W, bias, C, M, K, Nn);
    else
      gemm_kernel<false, false><<<g, TB, 0, stream>>>(A, W, nullptr, C, M, K, Nn);
  };

  // ---- CSR build (both graphs); reuse cur_* as temporary deg ----
  fill_i_kernel<<<32, TB, 0, stream>>>(cur_wt, 0, N);
  fill_i_kernel<<<32, TB, 0, stream>>>(cur_df, 0, N);
  hist_kernel<<<cdiv_h(E, TB), TB, 0, stream>>>(dst_wt, cur_wt, E);
  hist_kernel<<<cdiv_h(E, TB), TB, 0, stream>>>(dst_df, cur_df, E);
  scan_kernel<<<1, 1024, 0, stream>>>(cur_wt, rp_wt, cur_wt, N);
  scan_kernel<<<1, 1024, 0, stream>>>(cur_df, rp_df, cur_df, N);
  fill_adj_kernel<<<cdiv_h(E, TB), TB, 0, stream>>>(src_wt, dst_wt, cur_wt, adj_wt, E);
  fill_adj_kernel<<<cdiv_h(E, TB), TB, 0, stream>>>(src_df, dst_df, cur_df, adj_df, E);
  dis_kernel<<<cdiv_h(N, TB), TB, 0, stream>>>(rp_df, DIS, N);

  // ---- WT branch ----
  gemm(x_wt, emb_w, emb_b, X, N, 64, 256, true);
  const float isd32 = 0.17677669529663687f;  // 1/sqrt(32)
  const float isd8 = 0.35355339059327373f;   // 1/sqrt(8)
  for (int l = 0; l < 2; ++l) {
    const float* lw = cw_lin_w + (size_t)l * 256 * 256;
    const float* lb = cw_lin_b + l * 256;
    const float* qw = cw_q_w + (size_t)l * 256 * 256;
    const float* qb = cw_q_b + l * 256;
    const float* kw = cw_k_w + (size_t)l * 256 * 256;
    const float* kb = cw_k_b + l * 256;
    const float* vw = cw_v_w + (size_t)l * 256 * 256;
    const float* vb = cw_v_b + l * 256;
    const float* ab = cw_bias + l * 8;
    gemm(X, lw, lb, L, N, 256, 256, false);
    gemm(L, qw, qb, Qb, N, 256, 256, false);
    gemm(L, kw, kb, Kb, N, 256, 256, false);
    gemm(L, vw, vb, Vb, N, 256, 256, false);
    conv_gather_kernel<32><<<N, 64, 0, stream>>>(Qb, Kb, Vb, rp_wt, adj_wt, ab, X, isd32);
  }
  gemm(X, c3_lin_w, c3_lin_b, L, N, 256, 64, false);
  gemm(L, c3_q_w, c3_q_b, Qb, N, 64, 64, false);
  gemm(L, c3_k_w, c3_k_b, Kb, N, 64, 64, false);
  gemm(L, c3_v_w, c3_v_b, Vb, N, 64, 64, false);
  conv_gather_kernel<8><<<N, 64, 0, stream>>>(Qb, Kb, Vb, rp_wt, adj_wt, c3_bias, X3, isd8);

  fill_f_kernel<<<8, TB, 0, stream>>>(SEG, 0.f, 2064);
  segsum_x3_pe_kernel<<<cdiv_h(N * 64, TB), TB, 0, stream>>>(X3, b_wt, sum_x3, sum_pe,
                                                             cnt_wt, N);

  // ---- diff branch (GCN), propagate-first / transform-first reordering ----
  // layer 1: P = prop(x_diff) (64-wide), Y1 = relu(P@W1 + b1)
  gcn_gather_kernel<64, false, false><<<cdiv_h(N, 4), TB, 0, stream>>>(
      x_diff, rp_df, adj_df, DIS, nullptr, L, N);
  gemm(L, gcn_w1, gcn_b1, Qb, N, 64, 256, true);
  // layer 2: H2 = Y1@W2, Y2 = relu(prop(H2) + b2)
  gemm(Qb, gcn_w2, nullptr, Kb, N, 256, 256, false);
  gcn_gather_kernel<256, true, true><<<cdiv_h(N, 4), TB, 0, stream>>>(
      Kb, rp_df, adj_df, DIS, gcn_b2, L, N);
  // layer 3: H3 = Y2@W3 (128-wide), VFD = prop(H3) + b3
  gemm(L, gcn_w3, nullptr, Qb, N, 256, 128, false);
  gcn_gather_kernel<128, true, false><<<cdiv_h(N, 4), TB, 0, stream>>>(
      Qb, rp_df, adj_df, DIS, gcn_b3, Kb, N);
  segsum_vfd_kernel<<<cdiv_h(N * 128, TB), TB, 0, stream>>>(Kb, b_df, sum_vfd, cnt_df, N);

  // ---- head ----
  head_kernel<<<1, TB, 0, stream>>>(sum_x3, sum_pe, cnt_wt, sum_vfd, cnt_df, sft_w, sft_b,
                                    gru_wih, gru_bih, gru_bhh, mlp_w1, mlp_b1, mlp_w2,
                                    mlp_b2, mlp_w3, mlp_b3, pred_w, pred_b, (float*)d_out);
}

// Round 3
// 704.506 us; speedup vs baseline: 4.1709x; 1.1473x over previous
//
#include <hip/hip_runtime.h>
#include <hip/hip_bf16.h>

// ---------------------------------------------------------------------------
// ProteinGraphConv (3x CustomConv edge-attention) + GCN diff branch + GRU/MLP
// head. Round 3: 4-wave node-parallel gathers, folded QKV weights, batched
// QKV GEMMs. N=6000, E=200000, HID=256, GH=64, H=8, B=8.
// ---------------------------------------------------------------------------

static inline int cdiv_h(int a, int b) { return (a + b - 1) / b; }

__global__ void fill_f_kernel(float* __restrict__ p, float v, int n) {
  int stride = gridDim.x * blockDim.x;
  for (int i = blockIdx.x * blockDim.x + threadIdx.x; i < n; i += stride) p[i] = v;
}
__global__ void fill_i_kernel(int* __restrict__ p, int v, int n) {
  int stride = gridDim.x * blockDim.x;
  for (int i = blockIdx.x * blockDim.x + threadIdx.x; i < n; i += stride) p[i] = v;
}

// ---------------- CSR build ----------------
__global__ void hist_kernel(const int* __restrict__ dst, int* __restrict__ deg, int E) {
  int i = blockIdx.x * blockDim.x + threadIdx.x;
  if (i < E) atomicAdd(&deg[dst[i]], 1);
}

__global__ void scan_kernel(const int* __restrict__ deg, int* __restrict__ rowptr,
                            int* __restrict__ cursor, int N) {
  __shared__ int part[1024];
  const int t = threadIdx.x;
  const int chunk = (N + 1023) / 1024;
  const int base0 = t * chunk;
  int s = 0;
  for (int i = 0; i < chunk; ++i) {
    int idx = base0 + i;
    if (idx < N) s += deg[idx];
  }
  part[t] = s;
  __syncthreads();
  for (int off = 1; off < 1024; off <<= 1) {
    int v = (t >= off) ? part[t - off] : 0;
    __syncthreads();
    part[t] += v;
    __syncthreads();
  }
  int run = (t == 0) ? 0 : part[t - 1];
  for (int i = 0; i < chunk; ++i) {
    int idx = base0 + i;
    if (idx < N) {
      rowptr[idx] = run;
      cursor[idx] = run;
      run += deg[idx];
    }
  }
  if (t == 1023) rowptr[N] = part[1023];
}

__global__ void fill_adj_kernel(const int* __restrict__ src, const int* __restrict__ dst,
                                int* __restrict__ cursor, int* __restrict__ adj, int E) {
  int i = blockIdx.x * blockDim.x + threadIdx.x;
  if (i < E) {
    int p = atomicAdd(&cursor[dst[i]], 1);
    adj[p] = src[i];
  }
}

__global__ void dis_kernel(const int* __restrict__ rowptr, float* __restrict__ dis, int N) {
  int i = blockIdx.x * blockDim.x + threadIdx.x;
  if (i < N) dis[i] = rsqrtf((float)(rowptr[i + 1] - rowptr[i] + 1));
}

// ---------------- GEMM: C = [relu](A(MxK) @ W(KxN) [+ bias]) ----------------
template <bool RELU, bool BIAS>
__global__ void gemm_kernel(const float* __restrict__ A, const float* __restrict__ W,
                            const float* __restrict__ bias, float* __restrict__ C,
                            int M, int K, int N) {
  __shared__ float As[16][64];
  __shared__ float Bs[16][64];
  const int tx = threadIdx.x;
  const int m0 = blockIdx.x * 64, n0 = blockIdx.y * 64;
  const int tm = (tx & 15) * 4, tn = (tx >> 4) * 4;
  float acc[4][4] = {};
  for (int k0 = 0; k0 < K; k0 += 16) {
    {
      int m = tx >> 2, kq = (tx & 3) * 4;
      float4 av = make_float4(0.f, 0.f, 0.f, 0.f);
      if (m0 + m < M) av = *(const float4*)(A + (size_t)(m0 + m) * K + (k0 + kq));
      As[kq + 0][m] = av.x; As[kq + 1][m] = av.y;
      As[kq + 2][m] = av.z; As[kq + 3][m] = av.w;
      int kk = tx >> 4, nq = (tx & 15) * 4;
      *(float4*)&Bs[kk][nq] = *(const float4*)(W + (size_t)(k0 + kk) * N + (n0 + nq));
    }
    __syncthreads();
#pragma unroll
    for (int k = 0; k < 16; ++k) {
      float4 a4 = *(const float4*)&As[k][tm];
      float4 b4 = *(const float4*)&Bs[k][tn];
      float av[4] = {a4.x, a4.y, a4.z, a4.w};
      float bv[4] = {b4.x, b4.y, b4.z, b4.w};
#pragma unroll
      for (int i = 0; i < 4; ++i)
#pragma unroll
        for (int j = 0; j < 4; ++j) acc[i][j] += av[i] * bv[j];
    }
    __syncthreads();
  }
#pragma unroll
  for (int i = 0; i < 4; ++i) {
    int m = m0 + tm + i;
    if (m >= M) continue;
#pragma unroll
    for (int j = 0; j < 4; ++j) {
      float v = acc[i][j];
      int n = n0 + tn + j;
      if (BIAS) v += bias[n];
      if (RELU) v = fmaxf(v, 0.f);
      C[(size_t)m * N + n] = v;
    }
  }
}

// ---------------- batched 3-way GEMM (blockIdx.z selects W/bias/C) ----------
template <bool BIAS>
__global__ void gemm3_kernel(const float* __restrict__ A, const float* __restrict__ W0,
                             const float* __restrict__ W1, const float* __restrict__ W2,
                             const float* __restrict__ b0, const float* __restrict__ b1,
                             const float* __restrict__ b2, float* __restrict__ C0,
                             float* __restrict__ C1, float* __restrict__ C2,
                             int M, int K, int N) {
  const int z = blockIdx.z;
  const float* W = (z == 0) ? W0 : (z == 1) ? W1 : W2;
  const float* bias = (z == 0) ? b0 : (z == 1) ? b1 : b2;
  float* C = (z == 0) ? C0 : (z == 1) ? C1 : C2;
  __shared__ float As[16][64];
  __shared__ float Bs[16][64];
  const int tx = threadIdx.x;
  const int m0 = blockIdx.x * 64, n0 = blockIdx.y * 64;
  const int tm = (tx & 15) * 4, tn = (tx >> 4) * 4;
  float acc[4][4] = {};
  for (int k0 = 0; k0 < K; k0 += 16) {
    {
      int m = tx >> 2, kq = (tx & 3) * 4;
      float4 av = make_float4(0.f, 0.f, 0.f, 0.f);
      if (m0 + m < M) av = *(const float4*)(A + (size_t)(m0 + m) * K + (k0 + kq));
      As[kq + 0][m] = av.x; As[kq + 1][m] = av.y;
      As[kq + 2][m] = av.z; As[kq + 3][m] = av.w;
      int kk = tx >> 4, nq = (tx & 15) * 4;
      *(float4*)&Bs[kk][nq] = *(const float4*)(W + (size_t)(k0 + kk) * N + (n0 + nq));
    }
    __syncthreads();
#pragma unroll
    for (int k = 0; k < 16; ++k) {
      float4 a4 = *(const float4*)&As[k][tm];
      float4 b4 = *(const float4*)&Bs[k][tn];
      float av[4] = {a4.x, a4.y, a4.z, a4.w};
      float bv[4] = {b4.x, b4.y, b4.z, b4.w};
#pragma unroll
      for (int i = 0; i < 4; ++i)
#pragma unroll
        for (int j = 0; j < 4; ++j) acc[i][j] += av[i] * bv[j];
    }
    __syncthreads();
  }
#pragma unroll
  for (int i = 0; i < 4; ++i) {
    int m = m0 + tm + i;
    if (m >= M) continue;
#pragma unroll
    for (int j = 0; j < 4; ++j) {
      float v = acc[i][j];
      int n = n0 + tn + j;
      if (BIAS) v += bias[n];
      C[(size_t)m * N + n] = v;
    }
  }
}

// bias' = b + lb @ W  (one block per z)
__global__ void bias_fold_kernel(const float* __restrict__ lb, const float* __restrict__ W0,
                                 const float* __restrict__ W1, const float* __restrict__ W2,
                                 const float* __restrict__ b0, const float* __restrict__ b1,
                                 const float* __restrict__ b2, float* __restrict__ bf) {
  const int z = blockIdx.x, c = threadIdx.x;
  const float* W = (z == 0) ? W0 : (z == 1) ? W1 : W2;
  const float* b = (z == 0) ? b0 : (z == 1) ? b1 : b2;
  float acc = b[c];
  for (int k = 0; k < 256; ++k) acc += lb[k] * W[k * 256 + c];
  bf[z * 256 + c] = acc;
}

// ---------------- CustomConv via dst-CSR gather, 4 waves/node ---------------
// Block = 256 threads = 4 waves, one block per dst node. Each wave processes
// edges i = s+w, s+w+4, ... with wave-private LDS staging (no block barriers
// in the loop; wave-lockstep LDS is in-order). Lane (h,g)=(lane>>3,lane&7).
template <int D>  // 32 (C=256) or 8 (C=64)
__global__ void conv_gather4_kernel(const float* __restrict__ Qn, const float* __restrict__ Kn,
                                    const float* __restrict__ Vn, const int* __restrict__ rowptr,
                                    const int* __restrict__ adj, const float* __restrict__ abias,
                                    float* __restrict__ Xout, float inv_sqrt_d) {
  constexpr int C = 8 * D;
  constexpr int KS = D + 4;
  constexpr int NF4 = C / 4;   // 64 or 16 float4 per node row
  constexpr int F4R = D / 4;   // float4 per head row
  constexpr int EPL = D / 8;   // output elements per lane
  __shared__ float sQ[8 * KS];
  __shared__ float sK[4][8 * KS];
  __shared__ float sV[4][C];
  __shared__ float sR[4][C];
  const int tid = threadIdx.x;
  const int w = tid >> 6, lane = tid & 63;
  const int n = blockIdx.x;
  const int h = lane >> 3, g = lane & 7;

  if (tid < NF4) {
    int r = tid / F4R, c4 = tid % F4R;
    *(float4*)&sQ[r * KS + c4 * 4] = *(const float4*)(Qn + (size_t)n * C + tid * 4);
  }
  __syncthreads();

  const float bh = abias[h];
  float acc[EPL] = {};
  const int s = rowptr[n], t = rowptr[n + 1];
  for (int i = s + w; i < t; i += 4) {
    const int vs = adj[i];
    const float* kp = Kn + (size_t)vs * C;
    const float* vp = Vn + (size_t)vs * C;
    if (D == 32) {  // 64 float4 per row: every lane stages one K-f4 and one V-f4
      int r = lane / F4R, c4 = lane % F4R;
      *(float4*)&sK[w][r * KS + c4 * 4] = *(const float4*)(kp + lane * 4);
      *(float4*)&sV[w][lane * 4] = *(const float4*)(vp + lane * 4);
    } else {  // 16 float4 per row: lanes 0-15 stage K, lanes 16-31 stage V
      if (lane < NF4) {
        int r = lane / F4R, c4 = lane % F4R;
        *(float4*)&sK[w][r * KS + c4 * 4] = *(const float4*)(kp + lane * 4);
      } else if (lane < 2 * NF4) {
        int j = lane - NF4;
        *(float4*)&sV[w][j * 4] = *(const float4*)(vp + j * 4);
      }
    }
    __builtin_amdgcn_wave_barrier();
    float sc = 0.f;
    const float* qr = sQ + h * KS;
    const float* kr = sK[w] + g * KS;
#pragma unroll
    for (int d4 = 0; d4 < D / 4; ++d4) {
      float4 q4 = *(const float4*)(qr + d4 * 4);
      float4 k4 = *(const float4*)(kr + d4 * 4);
      sc += q4.x * k4.x + q4.y * k4.y + q4.z * k4.z + q4.w * k4.w;
    }
    sc = sc * inv_sqrt_d + bh;
    float m = fmaxf(sc, __shfl_xor(sc, 1));
    m = fmaxf(m, __shfl_xor(m, 2));
    m = fmaxf(m, __shfl_xor(m, 4));
    float ex = __expf(sc - m);
    float sum = ex;
    sum += __shfl_xor(sum, 1);
    sum += __shfl_xor(sum, 2);
    sum += __shfl_xor(sum, 4);
    float a = ex / sum;
#pragma unroll
    for (int g2 = 0; g2 < 8; ++g2) {
      float ag = __shfl(a, (h << 3) + g2);
      const float* vr = sV[w] + g2 * D;
#pragma unroll
      for (int t4 = 0; t4 < EPL; ++t4) acc[t4] += ag * vr[g + 8 * t4];
    }
    __builtin_amdgcn_wave_barrier();
  }
#pragma unroll
  for (int t4 = 0; t4 < EPL; ++t4) sR[w][h * D + g + 8 * t4] = acc[t4];
  __syncthreads();
  for (int c = tid; c < C; c += 256) {
    float v = sR[0][c] + sR[1][c] + sR[2][c] + sR[3][c];
    Xout[(size_t)n * C + c] = fmaxf(v, 0.f);
  }
}

// ---------------- GCN propagate via dst-CSR gather, 4 waves/node ------------
template <int C, bool BIAS, bool RELU>
__global__ void gcn_gather4_kernel(const float* __restrict__ H, const int* __restrict__ rowptr,
                                   const int* __restrict__ adj, const float* __restrict__ dis,
                                   const float* __restrict__ bias, float* __restrict__ O,
                                   int Nn) {
  constexpr int EPL = C / 64;  // 4, 2, 1
  __shared__ float sR[4][C];
  const int tid = threadIdx.x, w = tid >> 6, lane = tid & 63;
  const int n = blockIdx.x;
  const float dn = dis[n];
  float acc[EPL] = {};
  const int s = rowptr[n], t = rowptr[n + 1];
  for (int i = s + w; i < t; i += 4) {
    const int vs = adj[i];
    const float coef = dis[vs] * dn;
    const float* hs = H + (size_t)vs * C;
    if constexpr (EPL == 4) {
      float4 hv = *(const float4*)(hs + lane * 4);
      acc[0] += hv.x * coef; acc[1] += hv.y * coef;
      acc[2] += hv.z * coef; acc[3] += hv.w * coef;
    } else if constexpr (EPL == 2) {
      float2 hv = *(const float2*)(hs + lane * 2);
      acc[0] += hv.x * coef; acc[1] += hv.y * coef;
    } else {
      acc[0] += hs[lane] * coef;
    }
  }
  if (w == 0) {  // self-loop
    const float* hn = H + (size_t)n * C;
#pragma unroll
    for (int j = 0; j < EPL; ++j) acc[j] += hn[lane * EPL + j] * dn * dn;
  }
#pragma unroll
  for (int j = 0; j < EPL; ++j) sR[w][lane * EPL + j] = acc[j];
  __syncthreads();
  for (int c = tid; c < C; c += 256) {
    float v = sR[0][c] + sR[1][c] + sR[2][c] + sR[3][c];
    if (BIAS) v += bias[c];
    if (RELU) v = fmaxf(v, 0.f);
    O[(size_t)n * C + c] = v;
  }
}

// ---------------- segment sums (LDS pre-reduction) ----------------
__global__ void segsum_x3_pe_kernel(const float* __restrict__ X3, const int* __restrict__ batch,
                                    float* __restrict__ sum_x3, float* __restrict__ sum_pe,
                                    float* __restrict__ cnt, int N) {
  __shared__ float lx[512], lp[512], lc[8];
  const int tid = threadIdx.x;
  for (int i = tid; i < 512; i += 256) { lx[i] = 0.f; lp[i] = 0.f; }
  if (tid < 8) lc[tid] = 0.f;
  __syncthreads();
  int i = blockIdx.x * 256 + tid;
  if (i < N * 64) {
    int n = i >> 6, c = i & 63;
    int b = batch[n];
    atomicAdd(&lx[(b << 6) + c], X3[i]);
    const float F = -0.14391156831f;  // -ln(10000)/64
    float arg = (float)n * expf(F * (float)(c & ~1));
    atomicAdd(&lp[(b << 6) + c], (c & 1) ? cosf(arg) : sinf(arg));
    if (c == 0) atomicAdd(&lc[b], 1.f);
  }
  __syncthreads();
  for (int j = tid; j < 512; j += 256) {
    if (lx[j] != 0.f) atomicAdd(&sum_x3[j], lx[j]);
    if (lp[j] != 0.f) atomicAdd(&sum_pe[j], lp[j]);
  }
  if (tid < 8 && lc[tid] != 0.f) atomicAdd(&cnt[tid], lc[tid]);
}

__global__ void segsum_vfd_kernel(const float* __restrict__ VFD, const int* __restrict__ batch,
                                  float* __restrict__ sum_vfd, float* __restrict__ cnt, int N) {
  __shared__ float lv[1024], lc[8];
  const int tid = threadIdx.x;
  for (int i = tid; i < 1024; i += 256) lv[i] = 0.f;
  if (tid < 8) lc[tid] = 0.f;
  __syncthreads();
  int i = blockIdx.x * 256 + tid;
  if (i < N * 128) {
    int n = i >> 7, c = i & 127;
    int b = batch[n];
    atomicAdd(&lv[(b << 7) + c], VFD[i]);
    if (c == 0) atomicAdd(&lc[b], 1.f);
  }
  __syncthreads();
  for (int j = tid; j < 1024; j += 256) {
    if (lv[j] != 0.f) atomicAdd(&sum_vfd[j], lv[j]);
  }
  if (tid < 8 && lc[tid] != 0.f) atomicAdd(&cnt[tid], lc[tid]);
}

// ---------------- head ----------------
__global__ void head_kernel(const float* __restrict__ sum_x3, const float* __restrict__ sum_pe,
                            const float* __restrict__ cnt_wt, const float* __restrict__ sum_vfd,
                            const float* __restrict__ cnt_df, const float* __restrict__ sft_w,
                            const float* __restrict__ sft_b, const float* __restrict__ gru_wih,
                            const float* __restrict__ gru_bih, const float* __restrict__ gru_bhh,
                            const float* __restrict__ mlp_w1, const float* __restrict__ mlp_b1,
                            const float* __restrict__ mlp_w2, const float* __restrict__ mlp_b2,
                            const float* __restrict__ mlp_w3, const float* __restrict__ mlp_b3,
                            const float* __restrict__ pred_w, const float* __restrict__ pred_b,
                            float* __restrict__ out) {
  __shared__ float sA[512];
  __shared__ float sB[1536];
  __shared__ float sC[2048];
  __shared__ float sD[1024];
  __shared__ float sE[1024];
  const int tid = threadIdx.x;
  for (int i = tid; i < 512; i += 256) {
    int b = i >> 6;
    sA[i] = sum_x3[i] / fmaxf(cnt_wt[b], 1.f);
  }
  __syncthreads();
  for (int i = tid; i < 512; i += 256) {
    int b = i >> 6, c = i & 63;
    float acc = sft_b[c];
    for (int k = 0; k < 64; ++k) acc += sA[(b << 6) + k] * sft_w[k * 64 + c];
    sB[i] = fmaxf(acc, 0.f);
  }
  __syncthreads();
  for (int i = tid; i < 1536; i += 256) {
    int b = i / 192, r = i % 192;
    float acc = gru_bih[r];
    for (int k = 0; k < 64; ++k) acc += sB[(b << 6) + k] * gru_wih[r * 64 + k];
    sC[i] = acc;
  }
  __syncthreads();
  for (int i = tid; i < 512; i += 256) {
    int b = i >> 6, c = i & 63;
    const float* gi = sC + b * 192;
    float r = 1.f / (1.f + expf(-(gi[c] + gru_bhh[c])));
    float z = 1.f / (1.f + expf(-(gi[64 + c] + gru_bhh[64 + c])));
    float ng = tanhf(gi[128 + c] + r * gru_bhh[128 + c]);
    sA[i] = (1.f - z) * ng;
  }
  __syncthreads();
  for (int i = tid; i < 2048; i += 256) {
    int b = i >> 8, c = i & 255;
    float v;
    if (c < 64)
      v = (sum_x3[(b << 6) + c] + sum_pe[(b << 6) + c]) / fmaxf(cnt_wt[b], 1.f);
    else if (c < 128)
      v = sA[(b << 6) + (c - 64)];
    else
      v = sum_vfd[(b << 7) + (c - 128)] / fmaxf(cnt_df[b], 1.f);
    sC[i] = v;
  }
  __syncthreads();
  for (int i = tid; i < 1024; i += 256) {
    int b = i >> 7, c = i & 127;
    float acc = mlp_b1[c];
    for (int k = 0; k < 256; ++k) acc += sC[(b << 8) + k] * mlp_w1[k * 128 + c];
    sD[i] = fmaxf(acc, 0.f);
  }
  __syncthreads();
  for (int i = tid; i < 1024; i += 256) {
    int b = i >> 7, c = i & 127;
    float acc = mlp_b2[c];
    for (int k = 0; k < 128; ++k) acc += sD[(b << 7) + k] * mlp_w2[k * 128 + c];
    sE[i] = fmaxf(acc, 0.f);
  }
  __syncthreads();
  for (int i = tid; i < 1024; i += 256) {
    int b = i >> 7, c = i & 127;
    float acc = mlp_b3[c];
    for (int k = 0; k < 128; ++k) acc += sE[(b << 7) + k] * mlp_w3[k * 128 + c];
    sD[i] = acc;
  }
  __syncthreads();
  for (int b = tid; b < 8; b += 256) {
    float acc = pred_b[0];
    for (int k = 0; k < 128; ++k) acc += sD[(b << 7) + k] * pred_w[k];
    out[b] = acc;
  }
}

// ---------------------------------------------------------------------------
extern "C" void kernel_launch(void* const* d_in, const int* in_sizes, int n_in,
                              void* d_out, int out_size, void* d_ws, size_t ws_size,
                              hipStream_t stream) {
  const float* x_wt = (const float*)d_in[0];
  const float* x_diff = (const float*)d_in[1];
  const int* ei_wt = (const int*)d_in[2];
  const int* ei_df = (const int*)d_in[3];
  const int* b_wt = (const int*)d_in[4];
  const int* b_df = (const int*)d_in[5];
  const float* emb_w = (const float*)d_in[6];
  const float* emb_b = (const float*)d_in[7];
  const float* cw_lin_w = (const float*)d_in[8];
  const float* cw_lin_b = (const float*)d_in[9];
  const float* cw_q_w = (const float*)d_in[10];
  const float* cw_q_b = (const float*)d_in[11];
  const float* cw_k_w = (const float*)d_in[12];
  const float* cw_k_b = (const float*)d_in[13];
  const float* cw_v_w = (const float*)d_in[14];
  const float* cw_v_b = (const float*)d_in[15];
  const float* cw_bias = (const float*)d_in[16];
  const float* c3_lin_w = (const float*)d_in[17];
  const float* c3_lin_b = (const float*)d_in[18];
  const float* c3_q_w = (const float*)d_in[19];
  const float* c3_q_b = (const float*)d_in[20];
  const float* c3_k_w = (const float*)d_in[21];
  const float* c3_k_b = (const float*)d_in[22];
  const float* c3_v_w = (const float*)d_in[23];
  const float* c3_v_b = (const float*)d_in[24];
  const float* c3_bias = (const float*)d_in[25];
  const float* sft_w = (const float*)d_in[26];
  const float* sft_b = (const float*)d_in[27];
  const float* gru_wih = (const float*)d_in[28];
  const float* gru_bih = (const float*)d_in[30];
  const float* gru_bhh = (const float*)d_in[31];
  const float* gcn_w1 = (const float*)d_in[32];
  const float* gcn_b1 = (const float*)d_in[33];
  const float* gcn_w2 = (const float*)d_in[34];
  const float* gcn_b2 = (const float*)d_in[35];
  const float* gcn_w3 = (const float*)d_in[36];
  const float* gcn_b3 = (const float*)d_in[37];
  const float* mlp_w1 = (const float*)d_in[38];
  const float* mlp_b1 = (const float*)d_in[39];
  const float* mlp_w2 = (const float*)d_in[40];
  const float* mlp_b2 = (const float*)d_in[41];
  const float* mlp_w3 = (const float*)d_in[42];
  const float* mlp_b3 = (const float*)d_in[43];
  const float* pred_w = (const float*)d_in[44];
  const float* pred_b = (const float*)d_in[45];

  const int N = in_sizes[0] / 64;  // 6000
  const int E = in_sizes[2] / 2;   // 200000
  const int* src_wt = ei_wt;
  const int* dst_wt = ei_wt + E;
  const int* src_df = ei_df;
  const int* dst_df = ei_df + E;

  // ---- workspace layout ----
  float* ws = (float*)d_ws;
  const size_t fN256 = (size_t)N * 256;
  float* X = ws;
  float* L = ws + 1 * fN256;
  float* Qb = ws + 2 * fN256;
  float* Kb = ws + 3 * fN256;
  float* Vb = ws + 4 * fN256;
  float* X3 = ws + 5 * fN256;          // (N,64)
  float* DIS = X3 + (size_t)N * 64;    // (N)
  float* SEG = DIS + (((size_t)N + 63) / 64) * 64;
  float* sum_x3 = SEG;                 // 512
  float* sum_pe = SEG + 512;           // 512
  float* cnt_wt = SEG + 1024;          // 8
  float* sum_vfd = SEG + 1032;         // 1024
  float* cnt_df = SEG + 2056;          // 8
  int* ip = (int*)(SEG + 2064 + 16);
  int* rp_wt = ip;                     // N+1
  int* cur_wt = rp_wt + (N + 1);       // N
  int* adj_wt = cur_wt + N;            // E
  int* rp_df = adj_wt + E;             // N+1
  int* cur_df = rp_df + (N + 1);       // N
  int* adj_df = cur_df + N;            // E
  float* Wf = (float*)((((uintptr_t)(adj_df + E)) + 63) & ~(uintptr_t)63);  // 3*256*256
  float* bf = Wf + 3 * 256 * 256;      // 3*256

  const int TB = 256;
  auto gemm = [&](const float* A, const float* W, const float* bias, float* C,
                  int M, int K, int Nn, bool relu) {
    dim3 g(cdiv_h(M, 64), Nn / 64);
    if (relu)
      gemm_kernel<true, true><<<g, TB, 0, stream>>>(A, W, bias, C, M, K, Nn);
    else if (bias)
      gemm_kernel<false, true><<<g, TB, 0, stream>>>(A, W, bias, C, M, K, Nn);
    else
      gemm_kernel<false, false><<<g, TB, 0, stream>>>(A, W, nullptr, C, M, K, Nn);
  };

  // ---- CSR build (both graphs); reuse cur_* as temporary deg ----
  fill_i_kernel<<<32, TB, 0, stream>>>(cur_wt, 0, N);
  fill_i_kernel<<<32, TB, 0, stream>>>(cur_df, 0, N);
  hist_kernel<<<cdiv_h(E, TB), TB, 0, stream>>>(dst_wt, cur_wt, E);
  hist_kernel<<<cdiv_h(E, TB), TB, 0, stream>>>(dst_df, cur_df, E);
  scan_kernel<<<1, 1024, 0, stream>>>(cur_wt, rp_wt, cur_wt, N);
  scan_kernel<<<1, 1024, 0, stream>>>(cur_df, rp_df, cur_df, N);
  fill_adj_kernel<<<cdiv_h(E, TB), TB, 0, stream>>>(src_wt, dst_wt, cur_wt, adj_wt, E);
  fill_adj_kernel<<<cdiv_h(E, TB), TB, 0, stream>>>(src_df, dst_df, cur_df, adj_df, E);
  dis_kernel<<<cdiv_h(N, TB), TB, 0, stream>>>(rp_df, DIS, N);

  // ---- WT branch ----
  gemm(x_wt, emb_w, emb_b, X, N, 64, 256, true);
  const float isd32 = 0.17677669529663687f;  // 1/sqrt(32)
  const float isd8 = 0.35355339059327373f;   // 1/sqrt(8)
  for (int l = 0; l < 2; ++l) {
    const float* lw = cw_lin_w + (size_t)l * 256 * 256;
    const float* lb = cw_lin_b + l * 256;
    const float* qw = cw_q_w + (size_t)l * 256 * 256;
    const float* qb = cw_q_b + l * 256;
    const float* kw = cw_k_w + (size_t)l * 256 * 256;
    const float* kb = cw_k_b + l * 256;
    const float* vw = cw_v_w + (size_t)l * 256 * 256;
    const float* vb = cw_v_b + l * 256;
    const float* ab = cw_bias + l * 8;
    // fold: Wf[z] = lw @ {q,k,v}w ; bf[z] = {q,k,v}b + lb @ {q,k,v}w
    gemm3_kernel<false><<<dim3(4, 4, 3), TB, 0, stream>>>(
        lw, qw, kw, vw, nullptr, nullptr, nullptr, Wf, Wf + 65536, Wf + 131072, 256, 256, 256);
    bias_fold_kernel<<<3, TB, 0, stream>>>(lb, qw, kw, vw, qb, kb, vb, bf);
    // Q/K/V = X @ Wf[z] + bf[z]
    gemm3_kernel<true><<<dim3(cdiv_h(N, 64), 4, 3), TB, 0, stream>>>(
        X, Wf, Wf + 65536, Wf + 131072, bf, bf + 256, bf + 512, Qb, Kb, Vb, N, 256, 256);
    conv_gather4_kernel<32><<<N, TB, 0, stream>>>(Qb, Kb, Vb, rp_wt, adj_wt, ab, X, isd32);
  }
  // conv3 (256 -> 64): L = X@c3_lin + b, then small q/k/v batched
  gemm(X, c3_lin_w, c3_lin_b, L, N, 256, 64, false);
  gemm3_kernel<true><<<dim3(cdiv_h(N, 64), 1, 3), TB, 0, stream>>>(
      L, c3_q_w, c3_k_w, c3_v_w, c3_q_b, c3_k_b, c3_v_b, Qb, Kb, Vb, N, 64, 64);
  conv_gather4_kernel<8><<<N, TB, 0, stream>>>(Qb, Kb, Vb, rp_wt, adj_wt, c3_bias, X3, isd8);

  fill_f_kernel<<<8, TB, 0, stream>>>(SEG, 0.f, 2064);
  segsum_x3_pe_kernel<<<cdiv_h(N * 64, TB), TB, 0, stream>>>(X3, b_wt, sum_x3, sum_pe,
                                                             cnt_wt, N);

  // ---- diff branch (GCN), propagate/transform reordering ----
  gcn_gather4_kernel<64, false, false><<<N, TB, 0, stream>>>(x_diff, rp_df, adj_df, DIS,
                                                             nullptr, L, N);
  gemm(L, gcn_w1, gcn_b1, Qb, N, 64, 256, true);
  gemm(Qb, gcn_w2, nullptr, Kb, N, 256, 256, false);
  gcn_gather4_kernel<256, true, true><<<N, TB, 0, stream>>>(Kb, rp_df, adj_df, DIS,
                                                            gcn_b2, L, N);
  gemm(L, gcn_w3, nullptr, Qb, N, 256, 128, false);
  gcn_gather4_kernel<128, true, false><<<N, TB, 0, stream>>>(Qb, rp_df, adj_df, DIS,
                                                             gcn_b3, Kb, N);
  segsum_vfd_kernel<<<cdiv_h(N * 128, TB), TB, 0, stream>>>(Kb, b_df, sum_vfd, cnt_df, N);

  // ---- head ----
  head_kernel<<<1, TB, 0, stream>>>(sum_x3, sum_pe, cnt_wt, sum_vfd, cnt_df, sft_w, sft_b,
                                    gru_wih, gru_bih, gru_bhh, mlp_w1, mlp_b1, mlp_w2,
                                    mlp_b2, mlp_w3, mlp_b3, pred_w, pred_b, (float*)d_out);
}

// Round 4
// 667.663 us; speedup vs baseline: 4.4010x; 1.0552x over previous
//
#include <hip/hip_runtime.h>
#include <hip/hip_bf16.h>

// ---------------------------------------------------------------------------
// ProteinGraphConv (3x CustomConv edge-attention) + GCN diff branch + GRU/MLP
// head. Round 4: conv gather with q-in-registers, vectorized PV, register
// prefetch pipeline; GCN with dis folded into rows (GEMM epilogue scale).
// N=6000, E=200000, HID=256, GH=64, H=8, B=8.
// ---------------------------------------------------------------------------

static inline int cdiv_h(int a, int b) { return (a + b - 1) / b; }

__global__ void fill_f_kernel(float* __restrict__ p, float v, int n) {
  int stride = gridDim.x * blockDim.x;
  for (int i = blockIdx.x * blockDim.x + threadIdx.x; i < n; i += stride) p[i] = v;
}
__global__ void fill_i_kernel(int* __restrict__ p, int v, int n) {
  int stride = gridDim.x * blockDim.x;
  for (int i = blockIdx.x * blockDim.x + threadIdx.x; i < n; i += stride) p[i] = v;
}

// ---------------- CSR build ----------------
__global__ void hist_kernel(const int* __restrict__ dst, int* __restrict__ deg, int E) {
  int i = blockIdx.x * blockDim.x + threadIdx.x;
  if (i < E) atomicAdd(&deg[dst[i]], 1);
}

__global__ void scan_kernel(const int* __restrict__ deg, int* __restrict__ rowptr,
                            int* __restrict__ cursor, int N) {
  __shared__ int part[1024];
  const int t = threadIdx.x;
  const int chunk = (N + 1023) / 1024;
  const int base0 = t * chunk;
  int s = 0;
  for (int i = 0; i < chunk; ++i) {
    int idx = base0 + i;
    if (idx < N) s += deg[idx];
  }
  part[t] = s;
  __syncthreads();
  for (int off = 1; off < 1024; off <<= 1) {
    int v = (t >= off) ? part[t - off] : 0;
    __syncthreads();
    part[t] += v;
    __syncthreads();
  }
  int run = (t == 0) ? 0 : part[t - 1];
  for (int i = 0; i < chunk; ++i) {
    int idx = base0 + i;
    if (idx < N) {
      rowptr[idx] = run;
      cursor[idx] = run;
      run += deg[idx];
    }
  }
  if (t == 1023) rowptr[N] = part[1023];
}

__global__ void fill_adj_kernel(const int* __restrict__ src, const int* __restrict__ dst,
                                int* __restrict__ cursor, int* __restrict__ adj, int E) {
  int i = blockIdx.x * blockDim.x + threadIdx.x;
  if (i < E) {
    int p = atomicAdd(&cursor[dst[i]], 1);
    adj[p] = src[i];
  }
}

__global__ void dis_kernel(const int* __restrict__ rowptr, float* __restrict__ dis, int N) {
  int i = blockIdx.x * blockDim.x + threadIdx.x;
  if (i < N) dis[i] = rsqrtf((float)(rowptr[i + 1] - rowptr[i] + 1));
}

// Xd = x * dis[row]   (C = 64)
__global__ void xd_scale_kernel(const float* __restrict__ x, const float* __restrict__ dis,
                                float* __restrict__ out, int n) {
  int i = blockIdx.x * blockDim.x + threadIdx.x;
  if (i < n) out[i] = x[i] * dis[i >> 6];
}

// ---------------- GEMM: C = [relu](A(MxK) @ W(KxN) [+ bias]) [* dis[m]] -----
template <bool RELU, bool BIAS, bool SCALE>
__global__ void gemm_kernel(const float* __restrict__ A, const float* __restrict__ W,
                            const float* __restrict__ bias, const float* __restrict__ rsc,
                            float* __restrict__ C, int M, int K, int N) {
  __shared__ float As[16][64];
  __shared__ float Bs[16][64];
  const int tx = threadIdx.x;
  const int m0 = blockIdx.x * 64, n0 = blockIdx.y * 64;
  const int tm = (tx & 15) * 4, tn = (tx >> 4) * 4;
  float acc[4][4] = {};
  for (int k0 = 0; k0 < K; k0 += 16) {
    {
      int m = tx >> 2, kq = (tx & 3) * 4;
      float4 av = make_float4(0.f, 0.f, 0.f, 0.f);
      if (m0 + m < M) av = *(const float4*)(A + (size_t)(m0 + m) * K + (k0 + kq));
      As[kq + 0][m] = av.x; As[kq + 1][m] = av.y;
      As[kq + 2][m] = av.z; As[kq + 3][m] = av.w;
      int kk = tx >> 4, nq = (tx & 15) * 4;
      *(float4*)&Bs[kk][nq] = *(const float4*)(W + (size_t)(k0 + kk) * N + (n0 + nq));
    }
    __syncthreads();
#pragma unroll
    for (int k = 0; k < 16; ++k) {
      float4 a4 = *(const float4*)&As[k][tm];
      float4 b4 = *(const float4*)&Bs[k][tn];
      float av[4] = {a4.x, a4.y, a4.z, a4.w};
      float bv[4] = {b4.x, b4.y, b4.z, b4.w};
#pragma unroll
      for (int i = 0; i < 4; ++i)
#pragma unroll
        for (int j = 0; j < 4; ++j) acc[i][j] += av[i] * bv[j];
    }
    __syncthreads();
  }
#pragma unroll
  for (int i = 0; i < 4; ++i) {
    int m = m0 + tm + i;
    if (m >= M) continue;
    float sc = SCALE ? rsc[m] : 1.f;
#pragma unroll
    for (int j = 0; j < 4; ++j) {
      float v = acc[i][j];
      int n = n0 + tn + j;
      if (BIAS) v += bias[n];
      if (SCALE) v *= sc;
      if (RELU) v = fmaxf(v, 0.f);
      C[(size_t)m * N + n] = v;
    }
  }
}

// ---------------- batched 3-way GEMM (blockIdx.z selects W/bias/C) ----------
template <bool BIAS>
__global__ void gemm3_kernel(const float* __restrict__ A, const float* __restrict__ W0,
                             const float* __restrict__ W1, const float* __restrict__ W2,
                             const float* __restrict__ b0, const float* __restrict__ b1,
                             const float* __restrict__ b2, float* __restrict__ C0,
                             float* __restrict__ C1, float* __restrict__ C2,
                             int M, int K, int N) {
  const int z = blockIdx.z;
  const float* W = (z == 0) ? W0 : (z == 1) ? W1 : W2;
  const float* bias = (z == 0) ? b0 : (z == 1) ? b1 : b2;
  float* C = (z == 0) ? C0 : (z == 1) ? C1 : C2;
  __shared__ float As[16][64];
  __shared__ float Bs[16][64];
  const int tx = threadIdx.x;
  const int m0 = blockIdx.x * 64, n0 = blockIdx.y * 64;
  const int tm = (tx & 15) * 4, tn = (tx >> 4) * 4;
  float acc[4][4] = {};
  for (int k0 = 0; k0 < K; k0 += 16) {
    {
      int m = tx >> 2, kq = (tx & 3) * 4;
      float4 av = make_float4(0.f, 0.f, 0.f, 0.f);
      if (m0 + m < M) av = *(const float4*)(A + (size_t)(m0 + m) * K + (k0 + kq));
      As[kq + 0][m] = av.x; As[kq + 1][m] = av.y;
      As[kq + 2][m] = av.z; As[kq + 3][m] = av.w;
      int kk = tx >> 4, nq = (tx & 15) * 4;
      *(float4*)&Bs[kk][nq] = *(const float4*)(W + (size_t)(k0 + kk) * N + (n0 + nq));
    }
    __syncthreads();
#pragma unroll
    for (int k = 0; k < 16; ++k) {
      float4 a4 = *(const float4*)&As[k][tm];
      float4 b4 = *(const float4*)&Bs[k][tn];
      float av[4] = {a4.x, a4.y, a4.z, a4.w};
      float bv[4] = {b4.x, b4.y, b4.z, b4.w};
#pragma unroll
      for (int i = 0; i < 4; ++i)
#pragma unroll
        for (int j = 0; j < 4; ++j) acc[i][j] += av[i] * bv[j];
    }
    __syncthreads();
  }
#pragma unroll
  for (int i = 0; i < 4; ++i) {
    int m = m0 + tm + i;
    if (m >= M) continue;
#pragma unroll
    for (int j = 0; j < 4; ++j) {
      float v = acc[i][j];
      int n = n0 + tn + j;
      if (BIAS) v += bias[n];
      C[(size_t)m * N + n] = v;
    }
  }
}

// bias' = b + lb @ W  (one block per z)
__global__ void bias_fold_kernel(const float* __restrict__ lb, const float* __restrict__ W0,
                                 const float* __restrict__ W1, const float* __restrict__ W2,
                                 const float* __restrict__ b0, const float* __restrict__ b1,
                                 const float* __restrict__ b2, float* __restrict__ bf) {
  const int z = blockIdx.x, c = threadIdx.x;
  const float* W = (z == 0) ? W0 : (z == 1) ? W1 : W2;
  const float* b = (z == 0) ? b0 : (z == 1) ? b1 : b2;
  float acc = b[c];
  for (int k = 0; k < 256; ++k) acc += lb[k] * W[k * 256 + c];
  bf[z * 256 + c] = acc;
}

// ---------------- CustomConv via dst-CSR gather, 4 waves/node ---------------
// Block = 256 threads = 4 waves, one block per dst node; waves split the edge
// list (i = s+w, +4). Per-lane (h,g) = (lane>>3, lane&7). Q row in registers;
// K staged in padded LDS, V in LDS; register prefetch of next edge's K/V
// chunks overlaps the gather latency with current-edge compute.
template <int D>  // 32 (C=256) or 8 (C=64)
__global__ __launch_bounds__(256) void conv_gather5_kernel(
    const float* __restrict__ Qn, const float* __restrict__ Kn,
    const float* __restrict__ Vn, const int* __restrict__ rowptr,
    const int* __restrict__ adj, const float* __restrict__ abias,
    float* __restrict__ Xout, float inv_sqrt_d) {
  constexpr int C = 8 * D;
  constexpr int KS = D + 4;  // padded row stride (floats) for sK
  __shared__ float sK[4][8 * KS];
  __shared__ float sV[4][C];
  __shared__ float sR[4][C];
  const int tid = threadIdx.x, w = tid >> 6, lane = tid & 63;
  const int n = blockIdx.x;
  const int h = lane >> 3, g = lane & 7;

  // q[h] row into registers (8 lanes per h load the same row; L1-served)
  float4 q[D / 4];
#pragma unroll
  for (int j = 0; j < D / 4; ++j)
    q[j] = *(const float4*)(Qn + (size_t)n * C + h * D + j * 4);

  // staging roles / offsets
  int kgl, koff, vgl, voff;
  bool krole, vrole;
  if (D == 32) {
    krole = true; vrole = true;
    kgl = lane * 4;                                 // = (lane>>3)*32 + (lane&7)*4
    koff = (lane >> 3) * KS + (lane & 7) * 4;
    vgl = lane * 4; voff = lane * 4;
  } else {  // D=8, C=64
    krole = (lane < 16); vrole = (lane >= 16 && lane < 32);
    kgl = (lane >> 1) * 8 + (lane & 1) * 4;
    koff = (lane >> 1) * KS + (lane & 1) * 4;
    vgl = (lane - 16) * 4; voff = (lane - 16) * 4;
  }

  const float bh = abias[h];
  float acc[D / 8] = {};
  const int s = rowptr[n], t = rowptr[n + 1];
  int i = s + w;
  float4 kst = make_float4(0.f, 0.f, 0.f, 0.f), vst = kst;
  if (i < t) {
    const int vs = adj[i];
    if (krole) kst = *(const float4*)(Kn + (size_t)vs * C + kgl);
    if (vrole) vst = *(const float4*)(Vn + (size_t)vs * C + vgl);
  }
  for (; i < t; i += 4) {
    if (krole) *(float4*)&sK[w][koff] = kst;
    if (vrole) *(float4*)&sV[w][voff] = vst;
    const int i2 = i + 4;
    if (i2 < t) {  // prefetch next edge into registers (overlaps compute)
      const int vs2 = adj[i2];
      if (krole) kst = *(const float4*)(Kn + (size_t)vs2 * C + kgl);
      if (vrole) vst = *(const float4*)(Vn + (size_t)vs2 * C + vgl);
    }
    __builtin_amdgcn_wave_barrier();  // keep LDS writes before reads
    float sc = 0.f;
#pragma unroll
    for (int d4 = 0; d4 < D / 4; ++d4) {
      float4 k4 = *(const float4*)&sK[w][g * KS + d4 * 4];
      sc += q[d4].x * k4.x + q[d4].y * k4.y + q[d4].z * k4.z + q[d4].w * k4.w;
    }
    sc = sc * inv_sqrt_d + bh;
    float m = fmaxf(sc, __shfl_xor(sc, 1));
    m = fmaxf(m, __shfl_xor(m, 2));
    m = fmaxf(m, __shfl_xor(m, 4));
    float ex = __expf(sc - m);
    float sum = ex;
    sum += __shfl_xor(sum, 1);
    sum += __shfl_xor(sum, 2);
    sum += __shfl_xor(sum, 4);
    float a = ex / sum;
    if (D == 32) {  // lane (h,g) owns out[h][4g..4g+3]
#pragma unroll
      for (int g2 = 0; g2 < 8; ++g2) {
        float ag = __shfl(a, (h << 3) + g2);
        float4 v4 = *(const float4*)&sV[w][g2 * 32 + g * 4];
        acc[0] += ag * v4.x; acc[1] += ag * v4.y;
        acc[2] += ag * v4.z; acc[3] += ag * v4.w;
      }
    } else {  // lane (h,g) owns out[h][g]
#pragma unroll
      for (int g2 = 0; g2 < 8; ++g2) {
        float ag = __shfl(a, (h << 3) + g2);
        acc[0] += ag * sV[w][g2 * 8 + g];
      }
    }
    __builtin_amdgcn_wave_barrier();  // reads before next iteration's writes
  }
  if (D == 32) {
    *(float4*)&sR[w][h * 32 + g * 4] = *(float4*)acc;
  } else {
    sR[w][h * 8 + g] = acc[0];
  }
  __syncthreads();
  for (int c = tid; c < C; c += 256) {
    float v = sR[0][c] + sR[1][c] + sR[2][c] + sR[3][c];
    Xout[(size_t)n * C + c] = fmaxf(v, 0.f);
  }
}

// ---------------- GCN propagate via dst-CSR gather, 4 waves/node ------------
// Input rows are pre-scaled by dis[src] (Hd = H * dis). out =
// [relu]( dis[n] * (sum_src Hd[src] + Hd[n]) [+ bias] )
template <int C, bool BIAS, bool RELU>
__global__ __launch_bounds__(256) void gcn_gather4_kernel(
    const float* __restrict__ Hd, const int* __restrict__ rowptr,
    const int* __restrict__ adj, const float* __restrict__ dis,
    const float* __restrict__ bias, float* __restrict__ O, int Nn) {
  constexpr int EPL = C / 64;  // 4, 2, 1
  __shared__ float sR[4][C];
  const int tid = threadIdx.x, w = tid >> 6, lane = tid & 63;
  const int n = blockIdx.x;
  float acc[EPL] = {};
  const int s = rowptr[n], t = rowptr[n + 1];
  int i = s + w;
  int vs = (i < t) ? adj[i] : 0;
  while (i < t) {
    const int i2 = i + 4;
    const int vs2 = (i2 < t) ? adj[i2] : 0;  // prefetch adj
    const float* hs = Hd + (size_t)vs * C;
    if constexpr (EPL == 4) {
      float4 hv = *(const float4*)(hs + lane * 4);
      acc[0] += hv.x; acc[1] += hv.y; acc[2] += hv.z; acc[3] += hv.w;
    } else if constexpr (EPL == 2) {
      float2 hv = *(const float2*)(hs + lane * 2);
      acc[0] += hv.x; acc[1] += hv.y;
    } else {
      acc[0] += hs[lane];
    }
    vs = vs2; i = i2;
  }
  if (w == 0) {  // self-loop
    const float* hn = Hd + (size_t)n * C;
#pragma unroll
    for (int j = 0; j < EPL; ++j) acc[j] += hn[lane * EPL + j];
  }
#pragma unroll
  for (int j = 0; j < EPL; ++j) sR[w][lane * EPL + j] = acc[j];
  __syncthreads();
  const float dn = dis[n];
  for (int c = tid; c < C; c += 256) {
    float v = (sR[0][c] + sR[1][c] + sR[2][c] + sR[3][c]) * dn;
    if (BIAS) v += bias[c];
    if (RELU) v = fmaxf(v, 0.f);
    O[(size_t)n * C + c] = v;
  }
}

// ---------------- segment sums (LDS pre-reduction) ----------------
__global__ void segsum_x3_pe_kernel(const float* __restrict__ X3, const int* __restrict__ batch,
                                    float* __restrict__ sum_x3, float* __restrict__ sum_pe,
                                    float* __restrict__ cnt, int N) {
  __shared__ float lx[512], lp[512], lc[8];
  const int tid = threadIdx.x;
  for (int i = tid; i < 512; i += 256) { lx[i] = 0.f; lp[i] = 0.f; }
  if (tid < 8) lc[tid] = 0.f;
  __syncthreads();
  int i = blockIdx.x * 256 + tid;
  if (i < N * 64) {
    int n = i >> 6, c = i & 63;
    int b = batch[n];
    atomicAdd(&lx[(b << 6) + c], X3[i]);
    const float F = -0.14391156831f;  // -ln(10000)/64
    float arg = (float)n * expf(F * (float)(c & ~1));
    atomicAdd(&lp[(b << 6) + c], (c & 1) ? cosf(arg) : sinf(arg));
    if (c == 0) atomicAdd(&lc[b], 1.f);
  }
  __syncthreads();
  for (int j = tid; j < 512; j += 256) {
    if (lx[j] != 0.f) atomicAdd(&sum_x3[j], lx[j]);
    if (lp[j] != 0.f) atomicAdd(&sum_pe[j], lp[j]);
  }
  if (tid < 8 && lc[tid] != 0.f) atomicAdd(&cnt[tid], lc[tid]);
}

__global__ void segsum_vfd_kernel(const float* __restrict__ VFD, const int* __restrict__ batch,
                                  float* __restrict__ sum_vfd, float* __restrict__ cnt, int N) {
  __shared__ float lv[1024], lc[8];
  const int tid = threadIdx.x;
  for (int i = tid; i < 1024; i += 256) lv[i] = 0.f;
  if (tid < 8) lc[tid] = 0.f;
  __syncthreads();
  int i = blockIdx.x * 256 + tid;
  if (i < N * 128) {
    int n = i >> 7, c = i & 127;
    int b = batch[n];
    atomicAdd(&lv[(b << 7) + c], VFD[i]);
    if (c == 0) atomicAdd(&lc[b], 1.f);
  }
  __syncthreads();
  for (int j = tid; j < 1024; j += 256) {
    if (lv[j] != 0.f) atomicAdd(&sum_vfd[j], lv[j]);
  }
  if (tid < 8 && lc[tid] != 0.f) atomicAdd(&cnt[tid], lc[tid]);
}

// ---------------- head ----------------
__global__ void head_kernel(const float* __restrict__ sum_x3, const float* __restrict__ sum_pe,
                            const float* __restrict__ cnt_wt, const float* __restrict__ sum_vfd,
                            const float* __restrict__ cnt_df, const float* __restrict__ sft_w,
                            const float* __restrict__ sft_b, const float* __restrict__ gru_wih,
                            const float* __restrict__ gru_bih, const float* __restrict__ gru_bhh,
                            const float* __restrict__ mlp_w1, const float* __restrict__ mlp_b1,
                            const float* __restrict__ mlp_w2, const float* __restrict__ mlp_b2,
                            const float* __restrict__ mlp_w3, const float* __restrict__ mlp_b3,
                            const float* __restrict__ pred_w, const float* __restrict__ pred_b,
                            float* __restrict__ out) {
  __shared__ float sA[512];
  __shared__ float sB[1536];
  __shared__ float sC[2048];
  __shared__ float sD[1024];
  __shared__ float sE[1024];
  const int tid = threadIdx.x;
  for (int i = tid; i < 512; i += 256) {
    int b = i >> 6;
    sA[i] = sum_x3[i] / fmaxf(cnt_wt[b], 1.f);
  }
  __syncthreads();
  for (int i = tid; i < 512; i += 256) {
    int b = i >> 6, c = i & 63;
    float acc = sft_b[c];
    for (int k = 0; k < 64; ++k) acc += sA[(b << 6) + k] * sft_w[k * 64 + c];
    sB[i] = fmaxf(acc, 0.f);
  }
  __syncthreads();
  for (int i = tid; i < 1536; i += 256) {
    int b = i / 192, r = i % 192;
    float acc = gru_bih[r];
    for (int k = 0; k < 64; ++k) acc += sB[(b << 6) + k] * gru_wih[r * 64 + k];
    sC[i] = acc;
  }
  __syncthreads();
  for (int i = tid; i < 512; i += 256) {
    int b = i >> 6, c = i & 63;
    const float* gi = sC + b * 192;
    float r = 1.f / (1.f + expf(-(gi[c] + gru_bhh[c])));
    float z = 1.f / (1.f + expf(-(gi[64 + c] + gru_bhh[64 + c])));
    float ng = tanhf(gi[128 + c] + r * gru_bhh[128 + c]);
    sA[i] = (1.f - z) * ng;
  }
  __syncthreads();
  for (int i = tid; i < 2048; i += 256) {
    int b = i >> 8, c = i & 255;
    float v;
    if (c < 64)
      v = (sum_x3[(b << 6) + c] + sum_pe[(b << 6) + c]) / fmaxf(cnt_wt[b], 1.f);
    else if (c < 128)
      v = sA[(b << 6) + (c - 64)];
    else
      v = sum_vfd[(b << 7) + (c - 128)] / fmaxf(cnt_df[b], 1.f);
    sC[i] = v;
  }
  __syncthreads();
  for (int i = tid; i < 1024; i += 256) {
    int b = i >> 7, c = i & 127;
    float acc = mlp_b1[c];
    for (int k = 0; k < 256; ++k) acc += sC[(b << 8) + k] * mlp_w1[k * 128 + c];
    sD[i] = fmaxf(acc, 0.f);
  }
  __syncthreads();
  for (int i = tid; i < 1024; i += 256) {
    int b = i >> 7, c = i & 127;
    float acc = mlp_b2[c];
    for (int k = 0; k < 128; ++k) acc += sD[(b << 7) + k] * mlp_w2[k * 128 + c];
    sE[i] = fmaxf(acc, 0.f);
  }
  __syncthreads();
  for (int i = tid; i < 1024; i += 256) {
    int b = i >> 7, c = i & 127;
    float acc = mlp_b3[c];
    for (int k = 0; k < 128; ++k) acc += sE[(b << 7) + k] * mlp_w3[k * 128 + c];
    sD[i] = acc;
  }
  __syncthreads();
  for (int b = tid; b < 8; b += 256) {
    float acc = pred_b[0];
    for (int k = 0; k < 128; ++k) acc += sD[(b << 7) + k] * pred_w[k];
    out[b] = acc;
  }
}

// ---------------------------------------------------------------------------
extern "C" void kernel_launch(void* const* d_in, const int* in_sizes, int n_in,
                              void* d_out, int out_size, void* d_ws, size_t ws_size,
                              hipStream_t stream) {
  const float* x_wt = (const float*)d_in[0];
  const float* x_diff = (const float*)d_in[1];
  const int* ei_wt = (const int*)d_in[2];
  const int* ei_df = (const int*)d_in[3];
  const int* b_wt = (const int*)d_in[4];
  const int* b_df = (const int*)d_in[5];
  const float* emb_w = (const float*)d_in[6];
  const float* emb_b = (const float*)d_in[7];
  const float* cw_lin_w = (const float*)d_in[8];
  const float* cw_lin_b = (const float*)d_in[9];
  const float* cw_q_w = (const float*)d_in[10];
  const float* cw_q_b = (const float*)d_in[11];
  const float* cw_k_w = (const float*)d_in[12];
  const float* cw_k_b = (const float*)d_in[13];
  const float* cw_v_w = (const float*)d_in[14];
  const float* cw_v_b = (const float*)d_in[15];
  const float* cw_bias = (const float*)d_in[16];
  const float* c3_lin_w = (const float*)d_in[17];
  const float* c3_lin_b = (const float*)d_in[18];
  const float* c3_q_w = (const float*)d_in[19];
  const float* c3_q_b = (const float*)d_in[20];
  const float* c3_k_w = (const float*)d_in[21];
  const float* c3_k_b = (const float*)d_in[22];
  const float* c3_v_w = (const float*)d_in[23];
  const float* c3_v_b = (const float*)d_in[24];
  const float* c3_bias = (const float*)d_in[25];
  const float* sft_w = (const float*)d_in[26];
  const float* sft_b = (const float*)d_in[27];
  const float* gru_wih = (const float*)d_in[28];
  const float* gru_bih = (const float*)d_in[30];
  const float* gru_bhh = (const float*)d_in[31];
  const float* gcn_w1 = (const float*)d_in[32];
  const float* gcn_b1 = (const float*)d_in[33];
  const float* gcn_w2 = (const float*)d_in[34];
  const float* gcn_b2 = (const float*)d_in[35];
  const float* gcn_w3 = (const float*)d_in[36];
  const float* gcn_b3 = (const float*)d_in[37];
  const float* mlp_w1 = (const float*)d_in[38];
  const float* mlp_b1 = (const float*)d_in[39];
  const float* mlp_w2 = (const float*)d_in[40];
  const float* mlp_b2 = (const float*)d_in[41];
  const float* mlp_w3 = (const float*)d_in[42];
  const float* mlp_b3 = (const float*)d_in[43];
  const float* pred_w = (const float*)d_in[44];
  const float* pred_b = (const float*)d_in[45];

  const int N = in_sizes[0] / 64;  // 6000
  const int E = in_sizes[2] / 2;   // 200000
  const int* src_wt = ei_wt;
  const int* dst_wt = ei_wt + E;
  const int* src_df = ei_df;
  const int* dst_df = ei_df + E;

  // ---- workspace layout ----
  float* ws = (float*)d_ws;
  const size_t fN256 = (size_t)N * 256;
  float* X = ws;
  float* L = ws + 1 * fN256;
  float* Qb = ws + 2 * fN256;
  float* Kb = ws + 3 * fN256;
  float* Vb = ws + 4 * fN256;
  float* X3 = ws + 5 * fN256;          // (N,64)
  float* DIS = X3 + (size_t)N * 64;    // (N)
  float* SEG = DIS + (((size_t)N + 63) / 64) * 64;
  float* sum_x3 = SEG;                 // 512
  float* sum_pe = SEG + 512;           // 512
  float* cnt_wt = SEG + 1024;          // 8
  float* sum_vfd = SEG + 1032;         // 1024
  float* cnt_df = SEG + 2056;          // 8
  int* ip = (int*)(SEG + 2064 + 16);
  int* rp_wt = ip;                     // N+1
  int* cur_wt = rp_wt + (N + 1);       // N
  int* adj_wt = cur_wt + N;            // E
  int* rp_df = adj_wt + E;             // N+1
  int* cur_df = rp_df + (N + 1);       // N
  int* adj_df = cur_df + N;            // E
  float* Wf = (float*)((((uintptr_t)(adj_df + E)) + 63) & ~(uintptr_t)63);  // 3*256*256
  float* bf = Wf + 3 * 256 * 256;      // 3*256

  const int TB = 256;
  auto gemm = [&](const float* A, const float* W, const float* bias, float* C,
                  int M, int K, int Nn, bool relu) {
    dim3 g(cdiv_h(M, 64), Nn / 64);
    if (relu)
      gemm_kernel<true, true, false><<<g, TB, 0, stream>>>(A, W, bias, nullptr, C, M, K, Nn);
    else if (bias)
      gemm_kernel<false, true, false><<<g, TB, 0, stream>>>(A, W, bias, nullptr, C, M, K, Nn);
    else
      gemm_kernel<false, false, false><<<g, TB, 0, stream>>>(A, W, nullptr, nullptr, C, M, K, Nn);
  };
  auto gemm_scale = [&](const float* A, const float* W, const float* rsc, float* C,
                        int M, int K, int Nn) {
    dim3 g(cdiv_h(M, 64), Nn / 64);
    gemm_kernel<false, false, true><<<g, TB, 0, stream>>>(A, W, nullptr, rsc, C, M, K, Nn);
  };

  // ---- CSR build (both graphs); reuse cur_* as temporary deg ----
  fill_i_kernel<<<32, TB, 0, stream>>>(cur_wt, 0, N);
  fill_i_kernel<<<32, TB, 0, stream>>>(cur_df, 0, N);
  hist_kernel<<<cdiv_h(E, TB), TB, 0, stream>>>(dst_wt, cur_wt, E);
  hist_kernel<<<cdiv_h(E, TB), TB, 0, stream>>>(dst_df, cur_df, E);
  scan_kernel<<<1, 1024, 0, stream>>>(cur_wt, rp_wt, cur_wt, N);
  scan_kernel<<<1, 1024, 0, stream>>>(cur_df, rp_df, cur_df, N);
  fill_adj_kernel<<<cdiv_h(E, TB), TB, 0, stream>>>(src_wt, dst_wt, cur_wt, adj_wt, E);
  fill_adj_kernel<<<cdiv_h(E, TB), TB, 0, stream>>>(src_df, dst_df, cur_df, adj_df, E);
  dis_kernel<<<cdiv_h(N, TB), TB, 0, stream>>>(rp_df, DIS, N);

  // ---- WT branch ----
  gemm(x_wt, emb_w, emb_b, X, N, 64, 256, true);
  const float isd32 = 0.17677669529663687f;  // 1/sqrt(32)
  const float isd8 = 0.35355339059327373f;   // 1/sqrt(8)
  for (int l = 0; l < 2; ++l) {
    const float* lw = cw_lin_w + (size_t)l * 256 * 256;
    const float* lb = cw_lin_b + l * 256;
    const float* qw = cw_q_w + (size_t)l * 256 * 256;
    const float* qb = cw_q_b + l * 256;
    const float* kw = cw_k_w + (size_t)l * 256 * 256;
    const float* kb = cw_k_b + l * 256;
    const float* vw = cw_v_w + (size_t)l * 256 * 256;
    const float* vb = cw_v_b + l * 256;
    const float* ab = cw_bias + l * 8;
    // fold: Wf[z] = lw @ {q,k,v}w ; bf[z] = {q,k,v}b + lb @ {q,k,v}w
    gemm3_kernel<false><<<dim3(4, 4, 3), TB, 0, stream>>>(
        lw, qw, kw, vw, nullptr, nullptr, nullptr, Wf, Wf + 65536, Wf + 131072, 256, 256, 256);
    bias_fold_kernel<<<3, TB, 0, stream>>>(lb, qw, kw, vw, qb, kb, vb, bf);
    // Q/K/V = X @ Wf[z] + bf[z]
    gemm3_kernel<true><<<dim3(cdiv_h(N, 64), 4, 3), TB, 0, stream>>>(
        X, Wf, Wf + 65536, Wf + 131072, bf, bf + 256, bf + 512, Qb, Kb, Vb, N, 256, 256);
    conv_gather5_kernel<32><<<N, TB, 0, stream>>>(Qb, Kb, Vb, rp_wt, adj_wt, ab, X, isd32);
  }
  // conv3 (256 -> 64)
  gemm(X, c3_lin_w, c3_lin_b, L, N, 256, 64, false);
  gemm3_kernel<true><<<dim3(cdiv_h(N, 64), 1, 3), TB, 0, stream>>>(
      L, c3_q_w, c3_k_w, c3_v_w, c3_q_b, c3_k_b, c3_v_b, Qb, Kb, Vb, N, 64, 64);
  conv_gather5_kernel<8><<<N, TB, 0, stream>>>(Qb, Kb, Vb, rp_wt, adj_wt, c3_bias, X3, isd8);

  fill_f_kernel<<<8, TB, 0, stream>>>(SEG, 0.f, 2064);
  segsum_x3_pe_kernel<<<cdiv_h(N * 64, TB), TB, 0, stream>>>(X3, b_wt, sum_x3, sum_pe,
                                                             cnt_wt, N);

  // ---- diff branch (GCN); dis[src] folded into rows ----
  // layer 1: Xd = x_diff * dis ; P = dn*(gather Xd) ; Y1 = relu(P@W1 + b1)
  xd_scale_kernel<<<cdiv_h(N * 64, TB), TB, 0, stream>>>(x_diff, DIS, X, N * 64);
  gcn_gather4_kernel<64, false, false><<<N, TB, 0, stream>>>(X, rp_df, adj_df, DIS,
                                                             nullptr, L, N);
  gemm(L, gcn_w1, gcn_b1, Qb, N, 64, 256, true);
  // layer 2: H2d = (Y1@W2)*dis ; Y2 = relu(dn*gather(H2d) + b2)
  gemm_scale(Qb, gcn_w2, DIS, Kb, N, 256, 256);
  gcn_gather4_kernel<256, true, true><<<N, TB, 0, stream>>>(Kb, rp_df, adj_df, DIS,
                                                            gcn_b2, L, N);
  // layer 3: H3d = (Y2@W3)*dis ; VFD = dn*gather(H3d) + b3
  gemm_scale(L, gcn_w3, DIS, Qb, N, 256, 128);
  gcn_gather4_kernel<128, true, false><<<N, TB, 0, stream>>>(Qb, rp_df, adj_df, DIS,
                                                             gcn_b3, Kb, N);
  segsum_vfd_kernel<<<cdiv_h(N * 128, TB), TB, 0, stream>>>(Kb, b_df, sum_vfd, cnt_df, N);

  // ---- head ----
  head_kernel<<<1, TB, 0, stream>>>(sum_x3, sum_pe, cnt_wt, sum_vfd, cnt_df, sft_w, sft_b,
                                    gru_wih, gru_bih, gru_bhh, mlp_w1, mlp_b1, mlp_w2,
                                    mlp_b2, mlp_w3, mlp_b3, pred_w, pred_b, (float*)d_out);
}

// Round 5
// 639.810 us; speedup vs baseline: 4.5926x; 1.0435x over previous
//
#include <hip/hip_runtime.h>
#include <hip/hip_bf16.h>

// ---------------------------------------------------------------------------
// ProteinGraphConv (3x CustomConv edge-attention) + GCN diff branch + GRU/MLP
// head. Round 5: bf16 gather operands (K/V interleaved per node row), bf16
// GCN rows, c3_lin folded into QKV, single batched weight-fold launch.
// N=6000, E=200000, HID=256, GH=64, H=8, B=8.
// ---------------------------------------------------------------------------

static inline int cdiv_h(int a, int b) { return (a + b - 1) / b; }

__device__ __forceinline__ float bf16lo(uint32_t w) { return __uint_as_float(w << 16); }
__device__ __forceinline__ float bf16hi(uint32_t w) { return __uint_as_float(w & 0xffff0000u); }
__device__ __forceinline__ void bf16x8_to_f32(const uint4& u, float* f) {
  f[0] = bf16lo(u.x); f[1] = bf16hi(u.x);
  f[2] = bf16lo(u.y); f[3] = bf16hi(u.y);
  f[4] = bf16lo(u.z); f[5] = bf16hi(u.z);
  f[6] = bf16lo(u.w); f[7] = bf16hi(u.w);
}

__global__ void fill_f_kernel(float* __restrict__ p, float v, int n) {
  int stride = gridDim.x * blockDim.x;
  for (int i = blockIdx.x * blockDim.x + threadIdx.x; i < n; i += stride) p[i] = v;
}
__global__ void fill_i_kernel(int* __restrict__ p, int v, int n) {
  int stride = gridDim.x * blockDim.x;
  for (int i = blockIdx.x * blockDim.x + threadIdx.x; i < n; i += stride) p[i] = v;
}

// ---------------- CSR build ----------------
__global__ void hist_kernel(const int* __restrict__ dst, int* __restrict__ deg, int E) {
  int i = blockIdx.x * blockDim.x + threadIdx.x;
  if (i < E) atomicAdd(&deg[dst[i]], 1);
}

__global__ void scan_kernel(const int* __restrict__ deg, int* __restrict__ rowptr,
                            int* __restrict__ cursor, int N) {
  __shared__ int part[1024];
  const int t = threadIdx.x;
  const int chunk = (N + 1023) / 1024;
  const int base0 = t * chunk;
  int s = 0;
  for (int i = 0; i < chunk; ++i) {
    int idx = base0 + i;
    if (idx < N) s += deg[idx];
  }
  part[t] = s;
  __syncthreads();
  for (int off = 1; off < 1024; off <<= 1) {
    int v = (t >= off) ? part[t - off] : 0;
    __syncthreads();
    part[t] += v;
    __syncthreads();
  }
  int run = (t == 0) ? 0 : part[t - 1];
  for (int i = 0; i < chunk; ++i) {
    int idx = base0 + i;
    if (idx < N) {
      rowptr[idx] = run;
      cursor[idx] = run;
      run += deg[idx];
    }
  }
  if (t == 1023) rowptr[N] = part[1023];
}

__global__ void fill_adj_kernel(const int* __restrict__ src, const int* __restrict__ dst,
                                int* __restrict__ cursor, int* __restrict__ adj, int E) {
  int i = blockIdx.x * blockDim.x + threadIdx.x;
  if (i < E) {
    int p = atomicAdd(&cursor[dst[i]], 1);
    adj[p] = src[i];
  }
}

__global__ void dis_kernel(const int* __restrict__ rowptr, float* __restrict__ dis, int N) {
  int i = blockIdx.x * blockDim.x + threadIdx.x;
  if (i < N) dis[i] = rsqrtf((float)(rowptr[i + 1] - rowptr[i] + 1));
}

// Xd = bf16(x * dis[row])   (C = 64)
__global__ void xd_scale_bf16_kernel(const float* __restrict__ x, const float* __restrict__ dis,
                                     __hip_bfloat16* __restrict__ out, int n) {
  int i = blockIdx.x * blockDim.x + threadIdx.x;
  if (i < n) out[i] = __float2bfloat16(x[i] * dis[i >> 6]);
}

// ---------------- GEMM: C = [relu](A(MxK) @ W(KxN) [+ bias]) ----------------
template <bool RELU, bool BIAS>
__global__ void gemm_kernel(const float* __restrict__ A, const float* __restrict__ W,
                            const float* __restrict__ bias, float* __restrict__ C,
                            int M, int K, int N) {
  __shared__ float As[16][64];
  __shared__ float Bs[16][64];
  const int tx = threadIdx.x;
  const int m0 = blockIdx.x * 64, n0 = blockIdx.y * 64;
  const int tm = (tx & 15) * 4, tn = (tx >> 4) * 4;
  float acc[4][4] = {};
  for (int k0 = 0; k0 < K; k0 += 16) {
    {
      int m = tx >> 2, kq = (tx & 3) * 4;
      float4 av = make_float4(0.f, 0.f, 0.f, 0.f);
      if (m0 + m < M) av = *(const float4*)(A + (size_t)(m0 + m) * K + (k0 + kq));
      As[kq + 0][m] = av.x; As[kq + 1][m] = av.y;
      As[kq + 2][m] = av.z; As[kq + 3][m] = av.w;
      int kk = tx >> 4, nq = (tx & 15) * 4;
      *(float4*)&Bs[kk][nq] = *(const float4*)(W + (size_t)(k0 + kk) * N + (n0 + nq));
    }
    __syncthreads();
#pragma unroll
    for (int k = 0; k < 16; ++k) {
      float4 a4 = *(const float4*)&As[k][tm];
      float4 b4 = *(const float4*)&Bs[k][tn];
      float av[4] = {a4.x, a4.y, a4.z, a4.w};
      float bv[4] = {b4.x, b4.y, b4.z, b4.w};
#pragma unroll
      for (int i = 0; i < 4; ++i)
#pragma unroll
        for (int j = 0; j < 4; ++j) acc[i][j] += av[i] * bv[j];
    }
    __syncthreads();
  }
#pragma unroll
  for (int i = 0; i < 4; ++i) {
    int m = m0 + tm + i;
    if (m >= M) continue;
#pragma unroll
    for (int j = 0; j < 4; ++j) {
      float v = acc[i][j];
      int n = n0 + tn + j;
      if (BIAS) v += bias[n];
      if (RELU) v = fmaxf(v, 0.f);
      C[(size_t)m * N + n] = v;
    }
  }
}

// GEMM with row-scale epilogue, bf16 output: Cb = bf16((A@W) * rsc[m])
__global__ void gemm_scale_bf16_kernel(const float* __restrict__ A, const float* __restrict__ W,
                                       const float* __restrict__ rsc,
                                       __hip_bfloat16* __restrict__ Cb, int M, int K, int N) {
  __shared__ float As[16][64];
  __shared__ float Bs[16][64];
  const int tx = threadIdx.x;
  const int m0 = blockIdx.x * 64, n0 = blockIdx.y * 64;
  const int tm = (tx & 15) * 4, tn = (tx >> 4) * 4;
  float acc[4][4] = {};
  for (int k0 = 0; k0 < K; k0 += 16) {
    {
      int m = tx >> 2, kq = (tx & 3) * 4;
      float4 av = make_float4(0.f, 0.f, 0.f, 0.f);
      if (m0 + m < M) av = *(const float4*)(A + (size_t)(m0 + m) * K + (k0 + kq));
      As[kq + 0][m] = av.x; As[kq + 1][m] = av.y;
      As[kq + 2][m] = av.z; As[kq + 3][m] = av.w;
      int kk = tx >> 4, nq = (tx & 15) * 4;
      *(float4*)&Bs[kk][nq] = *(const float4*)(W + (size_t)(k0 + kk) * N + (n0 + nq));
    }
    __syncthreads();
#pragma unroll
    for (int k = 0; k < 16; ++k) {
      float4 a4 = *(const float4*)&As[k][tm];
      float4 b4 = *(const float4*)&Bs[k][tn];
      float av[4] = {a4.x, a4.y, a4.z, a4.w};
      float bv[4] = {b4.x, b4.y, b4.z, b4.w};
#pragma unroll
      for (int i = 0; i < 4; ++i)
#pragma unroll
        for (int j = 0; j < 4; ++j) acc[i][j] += av[i] * bv[j];
    }
    __syncthreads();
  }
#pragma unroll
  for (int i = 0; i < 4; ++i) {
    int m = m0 + tm + i;
    if (m >= M) continue;
    float sc = rsc[m];
#pragma unroll
    for (int j = 0; j < 4; ++j)
      Cb[(size_t)m * N + (n0 + tn + j)] = __float2bfloat16(acc[i][j] * sc);
  }
}

// ---------------- batched 3-way GEMM (blockIdx.z selects W/C) ----------
template <bool BIAS>
__global__ void gemm3_kernel(const float* __restrict__ A, const float* __restrict__ W0,
                             const float* __restrict__ W1, const float* __restrict__ W2,
                             const float* __restrict__ b0, const float* __restrict__ b1,
                             const float* __restrict__ b2, float* __restrict__ C0,
                             float* __restrict__ C1, float* __restrict__ C2,
                             int M, int K, int N) {
  const int z = blockIdx.z;
  const float* W = (z == 0) ? W0 : (z == 1) ? W1 : W2;
  const float* bias = (z == 0) ? b0 : (z == 1) ? b1 : b2;
  float* C = (z == 0) ? C0 : (z == 1) ? C1 : C2;
  __shared__ float As[16][64];
  __shared__ float Bs[16][64];
  const int tx = threadIdx.x;
  const int m0 = blockIdx.x * 64, n0 = blockIdx.y * 64;
  const int tm = (tx & 15) * 4, tn = (tx >> 4) * 4;
  float acc[4][4] = {};
  for (int k0 = 0; k0 < K; k0 += 16) {
    {
      int m = tx >> 2, kq = (tx & 3) * 4;
      float4 av = make_float4(0.f, 0.f, 0.f, 0.f);
      if (m0 + m < M) av = *(const float4*)(A + (size_t)(m0 + m) * K + (k0 + kq));
      As[kq + 0][m] = av.x; As[kq + 1][m] = av.y;
      As[kq + 2][m] = av.z; As[kq + 3][m] = av.w;
      int kk = tx >> 4, nq = (tx & 15) * 4;
      *(float4*)&Bs[kk][nq] = *(const float4*)(W + (size_t)(k0 + kk) * N + (n0 + nq));
    }
    __syncthreads();
#pragma unroll
    for (int k = 0; k < 16; ++k) {
      float4 a4 = *(const float4*)&As[k][tm];
      float4 b4 = *(const float4*)&Bs[k][tn];
      float av[4] = {a4.x, a4.y, a4.z, a4.w};
      float bv[4] = {b4.x, b4.y, b4.z, b4.w};
#pragma unroll
      for (int i = 0; i < 4; ++i)
#pragma unroll
        for (int j = 0; j < 4; ++j) acc[i][j] += av[i] * bv[j];
    }
    __syncthreads();
  }
#pragma unroll
  for (int i = 0; i < 4; ++i) {
    int m = m0 + tm + i;
    if (m >= M) continue;
#pragma unroll
    for (int j = 0; j < 4; ++j) {
      float v = acc[i][j];
      int n = n0 + tn + j;
      if (BIAS) v += bias[n];
      C[(size_t)m * N + n] = v;
    }
  }
}

// ---------------- QKV GEMM: z=0 -> Q (f32), z=1/2 -> KV interleaved bf16 ----
// Wf layout: z-stride K*N. bf layout: z-stride N. KV row stride = 2N (bf16).
__global__ void gemm3_qkv_kernel(const float* __restrict__ A, const float* __restrict__ Wf,
                                 const float* __restrict__ bf, float* __restrict__ Q,
                                 __hip_bfloat16* __restrict__ KV, int M, int K, int N) {
  const int z = blockIdx.z;
  const float* W = Wf + (size_t)z * K * N;
  const float* bias = bf + (size_t)z * N;
  __shared__ float As[16][64];
  __shared__ float Bs[16][64];
  const int tx = threadIdx.x;
  const int m0 = blockIdx.x * 64, n0 = blockIdx.y * 64;
  const int tm = (tx & 15) * 4, tn = (tx >> 4) * 4;
  float acc[4][4] = {};
  for (int k0 = 0; k0 < K; k0 += 16) {
    {
      int m = tx >> 2, kq = (tx & 3) * 4;
      float4 av = make_float4(0.f, 0.f, 0.f, 0.f);
      if (m0 + m < M) av = *(const float4*)(A + (size_t)(m0 + m) * K + (k0 + kq));
      As[kq + 0][m] = av.x; As[kq + 1][m] = av.y;
      As[kq + 2][m] = av.z; As[kq + 3][m] = av.w;
      int kk = tx >> 4, nq = (tx & 15) * 4;
      *(float4*)&Bs[kk][nq] = *(const float4*)(W + (size_t)(k0 + kk) * N + (n0 + nq));
    }
    __syncthreads();
#pragma unroll
    for (int k = 0; k < 16; ++k) {
      float4 a4 = *(const float4*)&As[k][tm];
      float4 b4 = *(const float4*)&Bs[k][tn];
      float av[4] = {a4.x, a4.y, a4.z, a4.w};
      float bv[4] = {b4.x, b4.y, b4.z, b4.w};
#pragma unroll
      for (int i = 0; i < 4; ++i)
#pragma unroll
        for (int j = 0; j < 4; ++j) acc[i][j] += av[i] * bv[j];
    }
    __syncthreads();
  }
#pragma unroll
  for (int i = 0; i < 4; ++i) {
    int m = m0 + tm + i;
    if (m >= M) continue;
#pragma unroll
    for (int j = 0; j < 4; ++j) {
      float v = acc[i][j] + bias[n0 + tn + j];
      int n = n0 + tn + j;
      if (z == 0)
        Q[(size_t)m * N + n] = v;
      else
        KV[(size_t)m * 2 * N + (size_t)(z - 1) * N + n] = __float2bfloat16(v);
    }
  }
}

// Wf6[z=3l+j] = cw_lin_w[l] @ {q,k,v}w[l]   (grid 4x4x6)
__global__ void gemm_fold6_kernel(const float* __restrict__ lin_w, const float* __restrict__ qw,
                                  const float* __restrict__ kw, const float* __restrict__ vw,
                                  float* __restrict__ Wf) {
  const int z = blockIdx.z, l = z / 3, j = z % 3;
  const float* A = lin_w + (size_t)l * 65536;
  const float* W = ((j == 0) ? qw : (j == 1) ? kw : vw) + (size_t)l * 65536;
  float* C = Wf + (size_t)z * 65536;
  __shared__ float As[16][64];
  __shared__ float Bs[16][64];
  const int tx = threadIdx.x;
  const int m0 = blockIdx.x * 64, n0 = blockIdx.y * 64;
  const int tm = (tx & 15) * 4, tn = (tx >> 4) * 4;
  float acc[4][4] = {};
  for (int k0 = 0; k0 < 256; k0 += 16) {
    {
      int m = tx >> 2, kq = (tx & 3) * 4;
      float4 av = *(const float4*)(A + (size_t)(m0 + m) * 256 + (k0 + kq));
      As[kq + 0][m] = av.x; As[kq + 1][m] = av.y;
      As[kq + 2][m] = av.z; As[kq + 3][m] = av.w;
      int kk = tx >> 4, nq = (tx & 15) * 4;
      *(float4*)&Bs[kk][nq] = *(const float4*)(W + (size_t)(k0 + kk) * 256 + (n0 + nq));
    }
    __syncthreads();
#pragma unroll
    for (int k = 0; k < 16; ++k) {
      float4 a4 = *(const float4*)&As[k][tm];
      float4 b4 = *(const float4*)&Bs[k][tn];
      float av[4] = {a4.x, a4.y, a4.z, a4.w};
      float bv[4] = {b4.x, b4.y, b4.z, b4.w};
#pragma unroll
      for (int i = 0; i < 4; ++i)
#pragma unroll
        for (int j2 = 0; j2 < 4; ++j2) acc[i][j2] += av[i] * bv[j2];
    }
    __syncthreads();
  }
#pragma unroll
  for (int i = 0; i < 4; ++i)
#pragma unroll
    for (int j2 = 0; j2 < 4; ++j2)
      C[(size_t)(m0 + tm + i) * 256 + (n0 + tn + j2)] = acc[i][j2];
}

// bf6[z=3l+j] = {q,k,v}b[l] + cw_lin_b[l] @ {q,k,v}w[l]   (grid 6 x 256)
__global__ void bias_fold6_kernel(const float* __restrict__ lin_b, const float* __restrict__ qw,
                                  const float* __restrict__ kw, const float* __restrict__ vw,
                                  const float* __restrict__ qb, const float* __restrict__ kb,
                                  const float* __restrict__ vb, float* __restrict__ bf) {
  const int z = blockIdx.x, l = z / 3, j = z % 3, c = threadIdx.x;
  const float* W = ((j == 0) ? qw : (j == 1) ? kw : vw) + (size_t)l * 65536;
  const float* b = ((j == 0) ? qb : (j == 1) ? kb : vb) + l * 256;
  const float* lb = lin_b + l * 256;
  float acc = b[c];
  for (int k = 0; k < 256; ++k) acc += lb[k] * W[k * 256 + c];
  bf[z * 256 + c] = acc;
}

// bf3[j] = c3_{q,k,v}_b + c3_lin_b @ c3_{q,k,v}_w  (grid 3 x 64)
__global__ void bias_fold3_kernel(const float* __restrict__ lin_b, const float* __restrict__ qw,
                                  const float* __restrict__ kw, const float* __restrict__ vw,
                                  const float* __restrict__ qb, const float* __restrict__ kb,
                                  const float* __restrict__ vb, float* __restrict__ bf) {
  const int j = blockIdx.x, c = threadIdx.x;
  const float* W = (j == 0) ? qw : (j == 1) ? kw : vw;
  const float* b = (j == 0) ? qb : (j == 1) ? kb : vb;
  float acc = b[c];
  for (int k = 0; k < 64; ++k) acc += lin_b[k] * W[k * 64 + c];
  bf[j * 64 + c] = acc;
}

// ---------------- CustomConv via dst-CSR gather, bf16 KV, 4 waves/node ------
// KV row: 2C bf16 (K then V). Each staging lane fetches one uint4 (8 bf16),
// unpacks to f32 LDS. Q row in f32 registers. Register prefetch pipeline.
template <int D>  // 32 (C=256) or 8 (C=64)
__global__ __launch_bounds__(256) void conv_gather6_kernel(
    const float* __restrict__ Qn, const __hip_bfloat16* __restrict__ KV,
    const int* __restrict__ rowptr, const int* __restrict__ adj,
    const float* __restrict__ abias, float* __restrict__ Xout, float inv_sqrt_d) {
  constexpr int C = 8 * D;
  constexpr int KS = D + 4;     // padded row stride (floats) for sK
  constexpr int NLD = (2 * C) / 8;  // staging lanes: 64 (D=32) or 16 (D=8)
  __shared__ float sK[4][8 * KS];
  __shared__ float sV[4][C];
  __shared__ float sR[4][C];
  const int tid = threadIdx.x, w = tid >> 6, lane = tid & 63;
  const int n = blockIdx.x;
  const int h = lane >> 3, g = lane & 7;

  float4 q[D / 4];
#pragma unroll
  for (int j = 0; j < D / 4; ++j)
    q[j] = *(const float4*)(Qn + (size_t)n * C + h * D + j * 4);

  const bool stg = lane < NLD;
  float* ldst = nullptr;
  if (stg) {
    int e = lane * 8;
    if (e < C) {
      int hh = e / D, dd = e % D;
      ldst = &sK[w][hh * KS + dd];
    } else {
      ldst = &sV[w][e - C];
    }
  }

  const float bh = abias[h];
  float acc[D / 8] = {};
  const int s = rowptr[n], t = rowptr[n + 1];
  int i = s + w;
  uint4 kvst = make_uint4(0u, 0u, 0u, 0u);
  if (i < t && stg)
    kvst = ((const uint4*)(KV + (size_t)adj[i] * 2 * C))[lane];
  for (; i < t; i += 4) {
    if (stg) {
      float f[8];
      bf16x8_to_f32(kvst, f);
      *(float4*)(ldst) = *(float4*)(f);
      *(float4*)(ldst + 4) = *(float4*)(f + 4);
    }
    const int i2 = i + 4;
    if (i2 < t && stg)
      kvst = ((const uint4*)(KV + (size_t)adj[i2] * 2 * C))[lane];
    __builtin_amdgcn_wave_barrier();
    float sc = 0.f;
#pragma unroll
    for (int d4 = 0; d4 < D / 4; ++d4) {
      float4 k4 = *(const float4*)&sK[w][g * KS + d4 * 4];
      sc += q[d4].x * k4.x + q[d4].y * k4.y + q[d4].z * k4.z + q[d4].w * k4.w;
    }
    sc = sc * inv_sqrt_d + bh;
    float m = fmaxf(sc, __shfl_xor(sc, 1));
    m = fmaxf(m, __shfl_xor(m, 2));
    m = fmaxf(m, __shfl_xor(m, 4));
    float ex = __expf(sc - m);
    float sum = ex;
    sum += __shfl_xor(sum, 1);
    sum += __shfl_xor(sum, 2);
    sum += __shfl_xor(sum, 4);
    float a = ex / sum;
    if (D == 32) {
#pragma unroll
      for (int g2 = 0; g2 < 8; ++g2) {
        float ag = __shfl(a, (h << 3) + g2);
        float4 v4 = *(const float4*)&sV[w][g2 * 32 + g * 4];
        acc[0] += ag * v4.x; acc[1] += ag * v4.y;
        acc[2] += ag * v4.z; acc[3] += ag * v4.w;
      }
    } else {
#pragma unroll
      for (int g2 = 0; g2 < 8; ++g2) {
        float ag = __shfl(a, (h << 3) + g2);
        acc[0] += ag * sV[w][g2 * 8 + g];
      }
    }
    __builtin_amdgcn_wave_barrier();
  }
  if (D == 32) {
    *(float4*)&sR[w][h * 32 + g * 4] = *(float4*)acc;
  } else {
    sR[w][h * 8 + g] = acc[0];
  }
  __syncthreads();
  for (int c = tid; c < C; c += 256) {
    float v = sR[0][c] + sR[1][c] + sR[2][c] + sR[3][c];
    Xout[(size_t)n * C + c] = fmaxf(v, 0.f);
  }
}

// ---------------- GCN propagate via dst-CSR gather, bf16 rows ---------------
// Hd rows pre-scaled by dis[src], bf16. out = [relu](dn*(sum+self) [+bias])
template <int C, bool BIAS, bool RELU>
__global__ __launch_bounds__(256) void gcn_gather5_kernel(
    const __hip_bfloat16* __restrict__ Hd, const int* __restrict__ rowptr,
    const int* __restrict__ adj, const float* __restrict__ dis,
    const float* __restrict__ bias, float* __restrict__ O, int Nn) {
  constexpr int EPL = C / 64;  // 4, 2, 1
  __shared__ float sR[4][C];
  const int tid = threadIdx.x, w = tid >> 6, lane = tid & 63;
  const int n = blockIdx.x;
  float acc[EPL] = {};
  const int s = rowptr[n], t = rowptr[n + 1];
  int i = s + w;
  int vs = (i < t) ? adj[i] : 0;
  while (i < t) {
    const int i2 = i + 4;
    const int vs2 = (i2 < t) ? adj[i2] : 0;
    const __hip_bfloat16* hs = Hd + (size_t)vs * C;
    if constexpr (EPL == 4) {
      uint2 u = *(const uint2*)(hs + lane * 4);
      acc[0] += bf16lo(u.x); acc[1] += bf16hi(u.x);
      acc[2] += bf16lo(u.y); acc[3] += bf16hi(u.y);
    } else if constexpr (EPL == 2) {
      uint32_t u = *(const uint32_t*)(hs + lane * 2);
      acc[0] += bf16lo(u); acc[1] += bf16hi(u);
    } else {
      acc[0] += bf16lo((uint32_t)*(const unsigned short*)(hs + lane));
    }
    vs = vs2; i = i2;
  }
  if (w == 0) {  // self-loop
    const __hip_bfloat16* hn = Hd + (size_t)n * C;
#pragma unroll
    for (int j = 0; j < EPL; ++j)
      acc[j] += bf16lo((uint32_t)*(const unsigned short*)(hn + lane * EPL + j));
  }
#pragma unroll
  for (int j = 0; j < EPL; ++j) sR[w][lane * EPL + j] = acc[j];
  __syncthreads();
  const float dn = dis[n];
  for (int c = tid; c < C; c += 256) {
    float v = (sR[0][c] + sR[1][c] + sR[2][c] + sR[3][c]) * dn;
    if (BIAS) v += bias[c];
    if (RELU) v = fmaxf(v, 0.f);
    O[(size_t)n * C + c] = v;
  }
}

// ---------------- segment sums (LDS pre-reduction) ----------------
__global__ void segsum_x3_pe_kernel(const float* __restrict__ X3, const int* __restrict__ batch,
                                    float* __restrict__ sum_x3, float* __restrict__ sum_pe,
                                    float* __restrict__ cnt, int N) {
  __shared__ float lx[512], lp[512], lc[8];
  const int tid = threadIdx.x;
  for (int i = tid; i < 512; i += 256) { lx[i] = 0.f; lp[i] = 0.f; }
  if (tid < 8) lc[tid] = 0.f;
  __syncthreads();
  int i = blockIdx.x * 256 + tid;
  if (i < N * 64) {
    int n = i >> 6, c = i & 63;
    int b = batch[n];
    atomicAdd(&lx[(b << 6) + c], X3[i]);
    const float F = -0.14391156831f;  // -ln(10000)/64
    float arg = (float)n * expf(F * (float)(c & ~1));
    atomicAdd(&lp[(b << 6) + c], (c & 1) ? cosf(arg) : sinf(arg));
    if (c == 0) atomicAdd(&lc[b], 1.f);
  }
  __syncthreads();
  for (int j = tid; j < 512; j += 256) {
    if (lx[j] != 0.f) atomicAdd(&sum_x3[j], lx[j]);
    if (lp[j] != 0.f) atomicAdd(&sum_pe[j], lp[j]);
  }
  if (tid < 8 && lc[tid] != 0.f) atomicAdd(&cnt[tid], lc[tid]);
}

__global__ void segsum_vfd_kernel(const float* __restrict__ VFD, const int* __restrict__ batch,
                                  float* __restrict__ sum_vfd, float* __restrict__ cnt, int N) {
  __shared__ float lv[1024], lc[8];
  const int tid = threadIdx.x;
  for (int i = tid; i < 1024; i += 256) lv[i] = 0.f;
  if (tid < 8) lc[tid] = 0.f;
  __syncthreads();
  int i = blockIdx.x * 256 + tid;
  if (i < N * 128) {
    int n = i >> 7, c = i & 127;
    int b = batch[n];
    atomicAdd(&lv[(b << 7) + c], VFD[i]);
    if (c == 0) atomicAdd(&lc[b], 1.f);
  }
  __syncthreads();
  for (int j = tid; j < 1024; j += 256) {
    if (lv[j] != 0.f) atomicAdd(&sum_vfd[j], lv[j]);
  }
  if (tid < 8 && lc[tid] != 0.f) atomicAdd(&cnt[tid], lc[tid]);
}

// ---------------- head ----------------
__global__ void head_kernel(const float* __restrict__ sum_x3, const float* __restrict__ sum_pe,
                            const float* __restrict__ cnt_wt, const float* __restrict__ sum_vfd,
                            const float* __restrict__ cnt_df, const float* __restrict__ sft_w,
                            const float* __restrict__ sft_b, const float* __restrict__ gru_wih,
                            const float* __restrict__ gru_bih, const float* __restrict__ gru_bhh,
                            const float* __restrict__ mlp_w1, const float* __restrict__ mlp_b1,
                            const float* __restrict__ mlp_w2, const float* __restrict__ mlp_b2,
                            const float* __restrict__ mlp_w3, const float* __restrict__ mlp_b3,
                            const float* __restrict__ pred_w, const float* __restrict__ pred_b,
                            float* __restrict__ out) {
  __shared__ float sA[512];
  __shared__ float sB[1536];
  __shared__ float sC[2048];
  __shared__ float sD[1024];
  __shared__ float sE[1024];
  const int tid = threadIdx.x;
  for (int i = tid; i < 512; i += 256) {
    int b = i >> 6;
    sA[i] = sum_x3[i] / fmaxf(cnt_wt[b], 1.f);
  }
  __syncthreads();
  for (int i = tid; i < 512; i += 256) {
    int b = i >> 6, c = i & 63;
    float acc = sft_b[c];
    for (int k = 0; k < 64; ++k) acc += sA[(b << 6) + k] * sft_w[k * 64 + c];
    sB[i] = fmaxf(acc, 0.f);
  }
  __syncthreads();
  for (int i = tid; i < 1536; i += 256) {
    int b = i / 192, r = i % 192;
    float acc = gru_bih[r];
    for (int k = 0; k < 64; ++k) acc += sB[(b << 6) + k] * gru_wih[r * 64 + k];
    sC[i] = acc;
  }
  __syncthreads();
  for (int i = tid; i < 512; i += 256) {
    int b = i >> 6, c = i & 63;
    const float* gi = sC + b * 192;
    float r = 1.f / (1.f + expf(-(gi[c] + gru_bhh[c])));
    float z = 1.f / (1.f + expf(-(gi[64 + c] + gru_bhh[64 + c])));
    float ng = tanhf(gi[128 + c] + r * gru_bhh[128 + c]);
    sA[i] = (1.f - z) * ng;
  }
  __syncthreads();
  for (int i = tid; i < 2048; i += 256) {
    int b = i >> 8, c = i & 255;
    float v;
    if (c < 64)
      v = (sum_x3[(b << 6) + c] + sum_pe[(b << 6) + c]) / fmaxf(cnt_wt[b], 1.f);
    else if (c < 128)
      v = sA[(b << 6) + (c - 64)];
    else
      v = sum_vfd[(b << 7) + (c - 128)] / fmaxf(cnt_df[b], 1.f);
    sC[i] = v;
  }
  __syncthreads();
  for (int i = tid; i < 1024; i += 256) {
    int b = i >> 7, c = i & 127;
    float acc = mlp_b1[c];
    for (int k = 0; k < 256; ++k) acc += sC[(b << 8) + k] * mlp_w1[k * 128 + c];
    sD[i] = fmaxf(acc, 0.f);
  }
  __syncthreads();
  for (int i = tid; i < 1024; i += 256) {
    int b = i >> 7, c = i & 127;
    float acc = mlp_b2[c];
    for (int k = 0; k < 128; ++k) acc += sD[(b << 7) + k] * mlp_w2[k * 128 + c];
    sE[i] = fmaxf(acc, 0.f);
  }
  __syncthreads();
  for (int i = tid; i < 1024; i += 256) {
    int b = i >> 7, c = i & 127;
    float acc = mlp_b3[c];
    for (int k = 0; k < 128; ++k) acc += sE[(b << 7) + k] * mlp_w3[k * 128 + c];
    sD[i] = acc;
  }
  __syncthreads();
  for (int b = tid; b < 8; b += 256) {
    float acc = pred_b[0];
    for (int k = 0; k < 128; ++k) acc += sD[(b << 7) + k] * pred_w[k];
    out[b] = acc;
  }
}

// ---------------------------------------------------------------------------
extern "C" void kernel_launch(void* const* d_in, const int* in_sizes, int n_in,
                              void* d_out, int out_size, void* d_ws, size_t ws_size,
                              hipStream_t stream) {
  const float* x_wt = (const float*)d_in[0];
  const float* x_diff = (const float*)d_in[1];
  const int* ei_wt = (const int*)d_in[2];
  const int* ei_df = (const int*)d_in[3];
  const int* b_wt = (const int*)d_in[4];
  const int* b_df = (const int*)d_in[5];
  const float* emb_w = (const float*)d_in[6];
  const float* emb_b = (const float*)d_in[7];
  const float* cw_lin_w = (const float*)d_in[8];
  const float* cw_lin_b = (const float*)d_in[9];
  const float* cw_q_w = (const float*)d_in[10];
  const float* cw_q_b = (const float*)d_in[11];
  const float* cw_k_w = (const float*)d_in[12];
  const float* cw_k_b = (const float*)d_in[13];
  const float* cw_v_w = (const float*)d_in[14];
  const float* cw_v_b = (const float*)d_in[15];
  const float* cw_bias = (const float*)d_in[16];
  const float* c3_lin_w = (const float*)d_in[17];
  const float* c3_lin_b = (const float*)d_in[18];
  const float* c3_q_w = (const float*)d_in[19];
  const float* c3_q_b = (const float*)d_in[20];
  const float* c3_k_w = (const float*)d_in[21];
  const float* c3_k_b = (const float*)d_in[22];
  const float* c3_v_w = (const float*)d_in[23];
  const float* c3_v_b = (const float*)d_in[24];
  const float* c3_bias = (const float*)d_in[25];
  const float* sft_w = (const float*)d_in[26];
  const float* sft_b = (const float*)d_in[27];
  const float* gru_wih = (const float*)d_in[28];
  const float* gru_bih = (const float*)d_in[30];
  const float* gru_bhh = (const float*)d_in[31];
  const float* gcn_w1 = (const float*)d_in[32];
  const float* gcn_b1 = (const float*)d_in[33];
  const float* gcn_w2 = (const float*)d_in[34];
  const float* gcn_b2 = (const float*)d_in[35];
  const float* gcn_w3 = (const float*)d_in[36];
  const float* gcn_b3 = (const float*)d_in[37];
  const float* mlp_w1 = (const float*)d_in[38];
  const float* mlp_b1 = (const float*)d_in[39];
  const float* mlp_w2 = (const float*)d_in[40];
  const float* mlp_b2 = (const float*)d_in[41];
  const float* mlp_w3 = (const float*)d_in[42];
  const float* mlp_b3 = (const float*)d_in[43];
  const float* pred_w = (const float*)d_in[44];
  const float* pred_b = (const float*)d_in[45];

  const int N = in_sizes[0] / 64;  // 6000
  const int E = in_sizes[2] / 2;   // 200000
  const int* src_wt = ei_wt;
  const int* dst_wt = ei_wt + E;
  const int* src_df = ei_df;
  const int* dst_df = ei_df + E;

  // ---- workspace layout ----
  float* ws = (float*)d_ws;
  const size_t fN256 = (size_t)N * 256;
  float* X = ws;
  float* L = ws + 1 * fN256;
  float* Qb = ws + 2 * fN256;
  float* Kb = ws + 3 * fN256;          // also bf16 KV (N x 512 bf16 = same bytes)
  float* Vb = ws + 4 * fN256;          // also bf16 Hd buffers
  float* X3 = ws + 5 * fN256;          // (N,64)
  float* DIS = X3 + (size_t)N * 64;    // (N)
  float* SEG = DIS + (((size_t)N + 63) / 64) * 64;
  float* sum_x3 = SEG;                 // 512
  float* sum_pe = SEG + 512;           // 512
  float* cnt_wt = SEG + 1024;          // 8
  float* sum_vfd = SEG + 1032;         // 1024
  float* cnt_df = SEG + 2056;          // 8
  int* ip = (int*)(SEG + 2064 + 16);
  int* rp_wt = ip;                     // N+1
  int* cur_wt = rp_wt + (N + 1);       // N
  int* adj_wt = cur_wt + N;            // E
  int* rp_df = adj_wt + E;             // N+1
  int* cur_df = rp_df + (N + 1);       // N
  int* adj_df = cur_df + N;            // E
  float* Wf6 = (float*)((((uintptr_t)(adj_df + E)) + 63) & ~(uintptr_t)63);  // 6*65536
  float* bf6 = Wf6 + 6 * 65536;        // 6*256
  float* Wf3 = bf6 + 6 * 256;          // 3*16384
  float* bf3 = Wf3 + 3 * 16384;        // 3*64

  __hip_bfloat16* KVb = (__hip_bfloat16*)Kb;
  __hip_bfloat16* Hd1 = (__hip_bfloat16*)Vb;   // N x 64
  __hip_bfloat16* Hd2 = (__hip_bfloat16*)Kb;   // N x 256
  __hip_bfloat16* Hd3 = (__hip_bfloat16*)Vb;   // N x 128

  const int TB = 256;
  auto gemm = [&](const float* A, const float* W, const float* bias, float* C,
                  int M, int K, int Nn, bool relu) {
    dim3 g(cdiv_h(M, 64), Nn / 64);
    if (relu)
      gemm_kernel<true, true><<<g, TB, 0, stream>>>(A, W, bias, C, M, K, Nn);
    else if (bias)
      gemm_kernel<false, true><<<g, TB, 0, stream>>>(A, W, bias, C, M, K, Nn);
    else
      gemm_kernel<false, false><<<g, TB, 0, stream>>>(A, W, nullptr, C, M, K, Nn);
  };

  // ---- weight/bias folds (independent of data) ----
  gemm_fold6_kernel<<<dim3(4, 4, 6), TB, 0, stream>>>(cw_lin_w, cw_q_w, cw_k_w, cw_v_w, Wf6);
  bias_fold6_kernel<<<6, TB, 0, stream>>>(cw_lin_b, cw_q_w, cw_k_w, cw_v_w, cw_q_b, cw_k_b,
                                          cw_v_b, bf6);
  gemm3_kernel<false><<<dim3(4, 1, 3), TB, 0, stream>>>(
      c3_lin_w, c3_q_w, c3_k_w, c3_v_w, nullptr, nullptr, nullptr,
      Wf3, Wf3 + 16384, Wf3 + 32768, 256, 64, 64);
  bias_fold3_kernel<<<3, 64, 0, stream>>>(c3_lin_b, c3_q_w, c3_k_w, c3_v_w, c3_q_b, c3_k_b,
                                          c3_v_b, bf3);

  // ---- CSR build (both graphs); reuse cur_* as temporary deg ----
  fill_i_kernel<<<32, TB, 0, stream>>>(cur_wt, 0, N);
  fill_i_kernel<<<32, TB, 0, stream>>>(cur_df, 0, N);
  hist_kernel<<<cdiv_h(E, TB), TB, 0, stream>>>(dst_wt, cur_wt, E);
  hist_kernel<<<cdiv_h(E, TB), TB, 0, stream>>>(dst_df, cur_df, E);
  scan_kernel<<<1, 1024, 0, stream>>>(cur_wt, rp_wt, cur_wt, N);
  scan_kernel<<<1, 1024, 0, stream>>>(cur_df, rp_df, cur_df, N);
  fill_adj_kernel<<<cdiv_h(E, TB), TB, 0, stream>>>(src_wt, dst_wt, cur_wt, adj_wt, E);
  fill_adj_kernel<<<cdiv_h(E, TB), TB, 0, stream>>>(src_df, dst_df, cur_df, adj_df, E);
  dis_kernel<<<cdiv_h(N, TB), TB, 0, stream>>>(rp_df, DIS, N);

  // ---- WT branch ----
  gemm(x_wt, emb_w, emb_b, X, N, 64, 256, true);
  const float isd32 = 0.17677669529663687f;  // 1/sqrt(32)
  const float isd8 = 0.35355339059327373f;   // 1/sqrt(8)
  for (int l = 0; l < 2; ++l) {
    gemm3_qkv_kernel<<<dim3(cdiv_h(N, 64), 4, 3), TB, 0, stream>>>(
        X, Wf6 + (size_t)l * 3 * 65536, bf6 + l * 768, Qb, KVb, N, 256, 256);
    conv_gather6_kernel<32><<<N, TB, 0, stream>>>(Qb, KVb, rp_wt, adj_wt, cw_bias + l * 8,
                                                  X, isd32);
  }
  // conv3 (256 -> 64), lin folded into QKV
  gemm3_qkv_kernel<<<dim3(cdiv_h(N, 64), 1, 3), TB, 0, stream>>>(X, Wf3, bf3, Qb, KVb,
                                                                 N, 256, 64);
  conv_gather6_kernel<8><<<N, TB, 0, stream>>>(Qb, KVb, rp_wt, adj_wt, c3_bias, X3, isd8);

  fill_f_kernel<<<8, TB, 0, stream>>>(SEG, 0.f, 2064);
  segsum_x3_pe_kernel<<<cdiv_h(N * 64, TB), TB, 0, stream>>>(X3, b_wt, sum_x3, sum_pe,
                                                             cnt_wt, N);

  // ---- diff branch (GCN); dis[src] folded into bf16 rows ----
  xd_scale_bf16_kernel<<<cdiv_h(N * 64, TB), TB, 0, stream>>>(x_diff, DIS, Hd1, N * 64);
  gcn_gather5_kernel<64, false, false><<<N, TB, 0, stream>>>(Hd1, rp_df, adj_df, DIS,
                                                             nullptr, L, N);
  gemm(L, gcn_w1, gcn_b1, Qb, N, 64, 256, true);
  gemm_scale_bf16_kernel<<<dim3(cdiv_h(N, 64), 4), TB, 0, stream>>>(Qb, gcn_w2, DIS, Hd2,
                                                                    N, 256, 256);
  gcn_gather5_kernel<256, true, true><<<N, TB, 0, stream>>>(Hd2, rp_df, adj_df, DIS,
                                                            gcn_b2, L, N);
  gemm_scale_bf16_kernel<<<dim3(cdiv_h(N, 64), 2), TB, 0, stream>>>(L, gcn_w3, DIS, Hd3,
                                                                    N, 256, 128);
  gcn_gather5_kernel<128, true, false><<<N, TB, 0, stream>>>(Hd3, rp_df, adj_df, DIS,
                                                             gcn_b3, Qb, N);
  segsum_vfd_kernel<<<cdiv_h(N * 128, TB), TB, 0, stream>>>(Qb, b_df, sum_vfd, cnt_df, N);

  // ---- head ----
  head_kernel<<<1, TB, 0, stream>>>(sum_x3, sum_pe, cnt_wt, sum_vfd, cnt_df, sft_w, sft_b,
                                    gru_wih, gru_bih, gru_bhh, mlp_w1, mlp_b1, mlp_w2,
                                    mlp_b2, mlp_w3, mlp_b3, pred_w, pred_b, (float*)d_out);
}

// Round 6
// 634.894 us; speedup vs baseline: 4.6282x; 1.0077x over previous
//
#include <hip/hip_runtime.h>
#include <hip/hip_bf16.h>

// ---------------------------------------------------------------------------
// ProteinGraphConv (3x CustomConv edge-attention) + GCN diff branch + GRU/MLP
// head. Round 6: conv<32> gather rewritten to minimize LDS-pipe ops:
// packed-bf16 K/V in LDS (unpack at use), a-broadcast via LDS instead of
// shuffles. DS ops/edge ~35 -> ~22. Rest unchanged from Round 5.
// N=6000, E=200000, HID=256, GH=64, H=8, B=8.
// ---------------------------------------------------------------------------

static inline int cdiv_h(int a, int b) { return (a + b - 1) / b; }

__device__ __forceinline__ float bf16lo(uint32_t w) { return __uint_as_float(w << 16); }
__device__ __forceinline__ float bf16hi(uint32_t w) { return __uint_as_float(w & 0xffff0000u); }
__device__ __forceinline__ void bf16x8_to_f32(const uint4& u, float* f) {
  f[0] = bf16lo(u.x); f[1] = bf16hi(u.x);
  f[2] = bf16lo(u.y); f[3] = bf16hi(u.y);
  f[4] = bf16lo(u.z); f[5] = bf16hi(u.z);
  f[6] = bf16lo(u.w); f[7] = bf16hi(u.w);
}

__global__ void fill_f_kernel(float* __restrict__ p, float v, int n) {
  int stride = gridDim.x * blockDim.x;
  for (int i = blockIdx.x * blockDim.x + threadIdx.x; i < n; i += stride) p[i] = v;
}
__global__ void fill_i_kernel(int* __restrict__ p, int v, int n) {
  int stride = gridDim.x * blockDim.x;
  for (int i = blockIdx.x * blockDim.x + threadIdx.x; i < n; i += stride) p[i] = v;
}

// ---------------- CSR build ----------------
__global__ void hist_kernel(const int* __restrict__ dst, int* __restrict__ deg, int E) {
  int i = blockIdx.x * blockDim.x + threadIdx.x;
  if (i < E) atomicAdd(&deg[dst[i]], 1);
}

__global__ void scan_kernel(const int* __restrict__ deg, int* __restrict__ rowptr,
                            int* __restrict__ cursor, int N) {
  __shared__ int part[1024];
  const int t = threadIdx.x;
  const int chunk = (N + 1023) / 1024;
  const int base0 = t * chunk;
  int s = 0;
  for (int i = 0; i < chunk; ++i) {
    int idx = base0 + i;
    if (idx < N) s += deg[idx];
  }
  part[t] = s;
  __syncthreads();
  for (int off = 1; off < 1024; off <<= 1) {
    int v = (t >= off) ? part[t - off] : 0;
    __syncthreads();
    part[t] += v;
    __syncthreads();
  }
  int run = (t == 0) ? 0 : part[t - 1];
  for (int i = 0; i < chunk; ++i) {
    int idx = base0 + i;
    if (idx < N) {
      rowptr[idx] = run;
      cursor[idx] = run;
      run += deg[idx];
    }
  }
  if (t == 1023) rowptr[N] = part[1023];
}

__global__ void fill_adj_kernel(const int* __restrict__ src, const int* __restrict__ dst,
                                int* __restrict__ cursor, int* __restrict__ adj, int E) {
  int i = blockIdx.x * blockDim.x + threadIdx.x;
  if (i < E) {
    int p = atomicAdd(&cursor[dst[i]], 1);
    adj[p] = src[i];
  }
}

__global__ void dis_kernel(const int* __restrict__ rowptr, float* __restrict__ dis, int N) {
  int i = blockIdx.x * blockDim.x + threadIdx.x;
  if (i < N) dis[i] = rsqrtf((float)(rowptr[i + 1] - rowptr[i] + 1));
}

// Xd = bf16(x * dis[row])   (C = 64)
__global__ void xd_scale_bf16_kernel(const float* __restrict__ x, const float* __restrict__ dis,
                                     __hip_bfloat16* __restrict__ out, int n) {
  int i = blockIdx.x * blockDim.x + threadIdx.x;
  if (i < n) out[i] = __float2bfloat16(x[i] * dis[i >> 6]);
}

// ---------------- GEMM: C = [relu](A(MxK) @ W(KxN) [+ bias]) ----------------
template <bool RELU, bool BIAS>
__global__ void gemm_kernel(const float* __restrict__ A, const float* __restrict__ W,
                            const float* __restrict__ bias, float* __restrict__ C,
                            int M, int K, int N) {
  __shared__ float As[16][64];
  __shared__ float Bs[16][64];
  const int tx = threadIdx.x;
  const int m0 = blockIdx.x * 64, n0 = blockIdx.y * 64;
  const int tm = (tx & 15) * 4, tn = (tx >> 4) * 4;
  float acc[4][4] = {};
  for (int k0 = 0; k0 < K; k0 += 16) {
    {
      int m = tx >> 2, kq = (tx & 3) * 4;
      float4 av = make_float4(0.f, 0.f, 0.f, 0.f);
      if (m0 + m < M) av = *(const float4*)(A + (size_t)(m0 + m) * K + (k0 + kq));
      As[kq + 0][m] = av.x; As[kq + 1][m] = av.y;
      As[kq + 2][m] = av.z; As[kq + 3][m] = av.w;
      int kk = tx >> 4, nq = (tx & 15) * 4;
      *(float4*)&Bs[kk][nq] = *(const float4*)(W + (size_t)(k0 + kk) * N + (n0 + nq));
    }
    __syncthreads();
#pragma unroll
    for (int k = 0; k < 16; ++k) {
      float4 a4 = *(const float4*)&As[k][tm];
      float4 b4 = *(const float4*)&Bs[k][tn];
      float av[4] = {a4.x, a4.y, a4.z, a4.w};
      float bv[4] = {b4.x, b4.y, b4.z, b4.w};
#pragma unroll
      for (int i = 0; i < 4; ++i)
#pragma unroll
        for (int j = 0; j < 4; ++j) acc[i][j] += av[i] * bv[j];
    }
    __syncthreads();
  }
#pragma unroll
  for (int i = 0; i < 4; ++i) {
    int m = m0 + tm + i;
    if (m >= M) continue;
#pragma unroll
    for (int j = 0; j < 4; ++j) {
      float v = acc[i][j];
      int n = n0 + tn + j;
      if (BIAS) v += bias[n];
      if (RELU) v = fmaxf(v, 0.f);
      C[(size_t)m * N + n] = v;
    }
  }
}

// GEMM with row-scale epilogue, bf16 output: Cb = bf16((A@W) * rsc[m])
__global__ void gemm_scale_bf16_kernel(const float* __restrict__ A, const float* __restrict__ W,
                                       const float* __restrict__ rsc,
                                       __hip_bfloat16* __restrict__ Cb, int M, int K, int N) {
  __shared__ float As[16][64];
  __shared__ float Bs[16][64];
  const int tx = threadIdx.x;
  const int m0 = blockIdx.x * 64, n0 = blockIdx.y * 64;
  const int tm = (tx & 15) * 4, tn = (tx >> 4) * 4;
  float acc[4][4] = {};
  for (int k0 = 0; k0 < K; k0 += 16) {
    {
      int m = tx >> 2, kq = (tx & 3) * 4;
      float4 av = make_float4(0.f, 0.f, 0.f, 0.f);
      if (m0 + m < M) av = *(const float4*)(A + (size_t)(m0 + m) * K + (k0 + kq));
      As[kq + 0][m] = av.x; As[kq + 1][m] = av.y;
      As[kq + 2][m] = av.z; As[kq + 3][m] = av.w;
      int kk = tx >> 4, nq = (tx & 15) * 4;
      *(float4*)&Bs[kk][nq] = *(const float4*)(W + (size_t)(k0 + kk) * N + (n0 + nq));
    }
    __syncthreads();
#pragma unroll
    for (int k = 0; k < 16; ++k) {
      float4 a4 = *(const float4*)&As[k][tm];
      float4 b4 = *(const float4*)&Bs[k][tn];
      float av[4] = {a4.x, a4.y, a4.z, a4.w};
      float bv[4] = {b4.x, b4.y, b4.z, b4.w};
#pragma unroll
      for (int i = 0; i < 4; ++i)
#pragma unroll
        for (int j = 0; j < 4; ++j) acc[i][j] += av[i] * bv[j];
    }
    __syncthreads();
  }
#pragma unroll
  for (int i = 0; i < 4; ++i) {
    int m = m0 + tm + i;
    if (m >= M) continue;
    float sc = rsc[m];
#pragma unroll
    for (int j = 0; j < 4; ++j)
      Cb[(size_t)m * N + (n0 + tn + j)] = __float2bfloat16(acc[i][j] * sc);
  }
}

// ---------------- batched 3-way GEMM (blockIdx.z selects W/C) ----------
template <bool BIAS>
__global__ void gemm3_kernel(const float* __restrict__ A, const float* __restrict__ W0,
                             const float* __restrict__ W1, const float* __restrict__ W2,
                             const float* __restrict__ b0, const float* __restrict__ b1,
                             const float* __restrict__ b2, float* __restrict__ C0,
                             float* __restrict__ C1, float* __restrict__ C2,
                             int M, int K, int N) {
  const int z = blockIdx.z;
  const float* W = (z == 0) ? W0 : (z == 1) ? W1 : W2;
  const float* bias = (z == 0) ? b0 : (z == 1) ? b1 : b2;
  float* C = (z == 0) ? C0 : (z == 1) ? C1 : C2;
  __shared__ float As[16][64];
  __shared__ float Bs[16][64];
  const int tx = threadIdx.x;
  const int m0 = blockIdx.x * 64, n0 = blockIdx.y * 64;
  const int tm = (tx & 15) * 4, tn = (tx >> 4) * 4;
  float acc[4][4] = {};
  for (int k0 = 0; k0 < K; k0 += 16) {
    {
      int m = tx >> 2, kq = (tx & 3) * 4;
      float4 av = make_float4(0.f, 0.f, 0.f, 0.f);
      if (m0 + m < M) av = *(const float4*)(A + (size_t)(m0 + m) * K + (k0 + kq));
      As[kq + 0][m] = av.x; As[kq + 1][m] = av.y;
      As[kq + 2][m] = av.z; As[kq + 3][m] = av.w;
      int kk = tx >> 4, nq = (tx & 15) * 4;
      *(float4*)&Bs[kk][nq] = *(const float4*)(W + (size_t)(k0 + kk) * N + (n0 + nq));
    }
    __syncthreads();
#pragma unroll
    for (int k = 0; k < 16; ++k) {
      float4 a4 = *(const float4*)&As[k][tm];
      float4 b4 = *(const float4*)&Bs[k][tn];
      float av[4] = {a4.x, a4.y, a4.z, a4.w};
      float bv[4] = {b4.x, b4.y, b4.z, b4.w};
#pragma unroll
      for (int i = 0; i < 4; ++i)
#pragma unroll
        for (int j = 0; j < 4; ++j) acc[i][j] += av[i] * bv[j];
    }
    __syncthreads();
  }
#pragma unroll
  for (int i = 0; i < 4; ++i) {
    int m = m0 + tm + i;
    if (m >= M) continue;
#pragma unroll
    for (int j = 0; j < 4; ++j) {
      float v = acc[i][j];
      int n = n0 + tn + j;
      if (BIAS) v += bias[n];
      C[(size_t)m * N + n] = v;
    }
  }
}

// ---------------- QKV GEMM: z=0 -> Q (f32), z=1/2 -> KV interleaved bf16 ----
__global__ void gemm3_qkv_kernel(const float* __restrict__ A, const float* __restrict__ Wf,
                                 const float* __restrict__ bf, float* __restrict__ Q,
                                 __hip_bfloat16* __restrict__ KV, int M, int K, int N) {
  const int z = blockIdx.z;
  const float* W = Wf + (size_t)z * K * N;
  const float* bias = bf + (size_t)z * N;
  __shared__ float As[16][64];
  __shared__ float Bs[16][64];
  const int tx = threadIdx.x;
  const int m0 = blockIdx.x * 64, n0 = blockIdx.y * 64;
  const int tm = (tx & 15) * 4, tn = (tx >> 4) * 4;
  float acc[4][4] = {};
  for (int k0 = 0; k0 < K; k0 += 16) {
    {
      int m = tx >> 2, kq = (tx & 3) * 4;
      float4 av = make_float4(0.f, 0.f, 0.f, 0.f);
      if (m0 + m < M) av = *(const float4*)(A + (size_t)(m0 + m) * K + (k0 + kq));
      As[kq + 0][m] = av.x; As[kq + 1][m] = av.y;
      As[kq + 2][m] = av.z; As[kq + 3][m] = av.w;
      int kk = tx >> 4, nq = (tx & 15) * 4;
      *(float4*)&Bs[kk][nq] = *(const float4*)(W + (size_t)(k0 + kk) * N + (n0 + nq));
    }
    __syncthreads();
#pragma unroll
    for (int k = 0; k < 16; ++k) {
      float4 a4 = *(const float4*)&As[k][tm];
      float4 b4 = *(const float4*)&Bs[k][tn];
      float av[4] = {a4.x, a4.y, a4.z, a4.w};
      float bv[4] = {b4.x, b4.y, b4.z, b4.w};
#pragma unroll
      for (int i = 0; i < 4; ++i)
#pragma unroll
        for (int j = 0; j < 4; ++j) acc[i][j] += av[i] * bv[j];
    }
    __syncthreads();
  }
#pragma unroll
  for (int i = 0; i < 4; ++i) {
    int m = m0 + tm + i;
    if (m >= M) continue;
#pragma unroll
    for (int j = 0; j < 4; ++j) {
      float v = acc[i][j] + bias[n0 + tn + j];
      int n = n0 + tn + j;
      if (z == 0)
        Q[(size_t)m * N + n] = v;
      else
        KV[(size_t)m * 2 * N + (size_t)(z - 1) * N + n] = __float2bfloat16(v);
    }
  }
}

// Wf6[z=3l+j] = cw_lin_w[l] @ {q,k,v}w[l]   (grid 4x4x6)
__global__ void gemm_fold6_kernel(const float* __restrict__ lin_w, const float* __restrict__ qw,
                                  const float* __restrict__ kw, const float* __restrict__ vw,
                                  float* __restrict__ Wf) {
  const int z = blockIdx.z, l = z / 3, j = z % 3;
  const float* A = lin_w + (size_t)l * 65536;
  const float* W = ((j == 0) ? qw : (j == 1) ? kw : vw) + (size_t)l * 65536;
  float* C = Wf + (size_t)z * 65536;
  __shared__ float As[16][64];
  __shared__ float Bs[16][64];
  const int tx = threadIdx.x;
  const int m0 = blockIdx.x * 64, n0 = blockIdx.y * 64;
  const int tm = (tx & 15) * 4, tn = (tx >> 4) * 4;
  float acc[4][4] = {};
  for (int k0 = 0; k0 < 256; k0 += 16) {
    {
      int m = tx >> 2, kq = (tx & 3) * 4;
      float4 av = *(const float4*)(A + (size_t)(m0 + m) * 256 + (k0 + kq));
      As[kq + 0][m] = av.x; As[kq + 1][m] = av.y;
      As[kq + 2][m] = av.z; As[kq + 3][m] = av.w;
      int kk = tx >> 4, nq = (tx & 15) * 4;
      *(float4*)&Bs[kk][nq] = *(const float4*)(W + (size_t)(k0 + kk) * 256 + (n0 + nq));
    }
    __syncthreads();
#pragma unroll
    for (int k = 0; k < 16; ++k) {
      float4 a4 = *(const float4*)&As[k][tm];
      float4 b4 = *(const float4*)&Bs[k][tn];
      float av[4] = {a4.x, a4.y, a4.z, a4.w};
      float bv[4] = {b4.x, b4.y, b4.z, b4.w};
#pragma unroll
      for (int i = 0; i < 4; ++i)
#pragma unroll
        for (int j2 = 0; j2 < 4; ++j2) acc[i][j2] += av[i] * bv[j2];
    }
    __syncthreads();
  }
#pragma unroll
  for (int i = 0; i < 4; ++i)
#pragma unroll
    for (int j2 = 0; j2 < 4; ++j2)
      C[(size_t)(m0 + tm + i) * 256 + (n0 + tn + j2)] = acc[i][j2];
}

// bf6[z=3l+j] = {q,k,v}b[l] + cw_lin_b[l] @ {q,k,v}w[l]   (grid 6 x 256)
__global__ void bias_fold6_kernel(const float* __restrict__ lin_b, const float* __restrict__ qw,
                                  const float* __restrict__ kw, const float* __restrict__ vw,
                                  const float* __restrict__ qb, const float* __restrict__ kb,
                                  const float* __restrict__ vb, float* __restrict__ bf) {
  const int z = blockIdx.x, l = z / 3, j = z % 3, c = threadIdx.x;
  const float* W = ((j == 0) ? qw : (j == 1) ? kw : vw) + (size_t)l * 65536;
  const float* b = ((j == 0) ? qb : (j == 1) ? kb : vb) + l * 256;
  const float* lb = lin_b + l * 256;
  float acc = b[c];
  for (int k = 0; k < 256; ++k) acc += lb[k] * W[k * 256 + c];
  bf[z * 256 + c] = acc;
}

// bf3[j] = c3_{q,k,v}_b + c3_lin_b @ c3_{q,k,v}_w  (grid 3 x 64)
__global__ void bias_fold3_kernel(const float* __restrict__ lin_b, const float* __restrict__ qw,
                                  const float* __restrict__ kw, const float* __restrict__ vw,
                                  const float* __restrict__ qb, const float* __restrict__ kb,
                                  const float* __restrict__ vb, float* __restrict__ bf) {
  const int j = blockIdx.x, c = threadIdx.x;
  const float* W = (j == 0) ? qw : (j == 1) ? kw : vw;
  const float* b = (j == 0) ? qb : (j == 1) ? kb : vb;
  float acc = b[c];
  for (int k = 0; k < 64; ++k) acc += lin_b[k] * W[k * 64 + c];
  bf[j * 64 + c] = acc;
}

// ------- CustomConv D=32 via dst-CSR gather: packed-bf16 LDS, a-in-LDS ------
// KV row: 512 bf16 (K then V). Staging lane stores its raw uint4 into packed
// LDS (K rows stride 48 halfs, V rows stride 40 halfs — <=2-way bank alias).
// Per edge DS ops/lane: 1 write b128 + 4 read b128 (K) + 6 swizzle (softmax)
// + 1 write b32 + 2 read b128 (a) + 8 read b64 (V)  (~22 vs ~35 before).
__global__ __launch_bounds__(256) void conv_gather7_kernel(
    const float* __restrict__ Qn, const __hip_bfloat16* __restrict__ KV,
    const int* __restrict__ rowptr, const int* __restrict__ adj,
    const float* __restrict__ abias, float* __restrict__ Xout, float inv_sqrt_d) {
  __shared__ __align__(16) unsigned short sKV[4][704];  // K: 8x48, V(base 384): 8x40
  __shared__ float sA[4][64];
  __shared__ float sR[4][256];
  const int tid = threadIdx.x, w = tid >> 6, lane = tid & 63;
  const int n = blockIdx.x;
  const int h = lane >> 3, g = lane & 7;

  // q row h in f32 registers (broadcast among the 8 lanes of head h)
  float q[32];
#pragma unroll
  for (int j = 0; j < 8; ++j)
    *(float4*)&q[4 * j] = *(const float4*)(Qn + (size_t)n * 256 + h * 32 + 4 * j);

  // staging destination (half index within sKV[w]) for this lane's uint4
  const int e = lane * 8;
  int dsth;
  if (e < 256) dsth = (e >> 5) * 48 + (e & 31);
  else { int jj = e - 256; dsth = 384 + (jj >> 5) * 40 + (jj & 31); }
  unsigned short* ldst = &sKV[w][dsth];

  const float bh = abias[h];
  float acc0 = 0.f, acc1 = 0.f, acc2 = 0.f, acc3 = 0.f;
  const int s = rowptr[n], t = rowptr[n + 1];
  int i = s + w;
  uint4 kvst = make_uint4(0u, 0u, 0u, 0u);
  if (i < t) kvst = ((const uint4*)(KV + (size_t)adj[i] * 512))[lane];
  for (; i < t; i += 4) {
    *(uint4*)ldst = kvst;
    const int i2 = i + 4;
    if (i2 < t) kvst = ((const uint4*)(KV + (size_t)adj[i2] * 512))[lane];
    __builtin_amdgcn_wave_barrier();
    // score s(h,g) = q[h] . k[g]
    float sc = 0.f;
    const unsigned short* kr = &sKV[w][g * 48];
#pragma unroll
    for (int j = 0; j < 4; ++j) {
      uint4 kw4 = *(const uint4*)(kr + j * 8);
      sc += q[8 * j + 0] * bf16lo(kw4.x) + q[8 * j + 1] * bf16hi(kw4.x);
      sc += q[8 * j + 2] * bf16lo(kw4.y) + q[8 * j + 3] * bf16hi(kw4.y);
      sc += q[8 * j + 4] * bf16lo(kw4.z) + q[8 * j + 5] * bf16hi(kw4.z);
      sc += q[8 * j + 6] * bf16lo(kw4.w) + q[8 * j + 7] * bf16hi(kw4.w);
    }
    sc = sc * inv_sqrt_d + bh;
    float m = fmaxf(sc, __shfl_xor(sc, 1));
    m = fmaxf(m, __shfl_xor(m, 2));
    m = fmaxf(m, __shfl_xor(m, 4));
    float ex = __expf(sc - m);
    float sum = ex;
    sum += __shfl_xor(sum, 1);
    sum += __shfl_xor(sum, 2);
    sum += __shfl_xor(sum, 4);
    sA[w][lane] = ex / sum;  // lane == h*8+g
    __builtin_amdgcn_wave_barrier();
    float4 a0 = *(const float4*)&sA[w][h * 8];
    float4 a1 = *(const float4*)&sA[w][h * 8 + 4];
    float av[8] = {a0.x, a0.y, a0.z, a0.w, a1.x, a1.y, a1.z, a1.w};
    // out[h][4g..4g+3] += sum_g2 a[h][g2] * v[g2][4g..4g+3]
#pragma unroll
    for (int g2 = 0; g2 < 8; ++g2) {
      uint2 vw2 = *(const uint2*)&sKV[w][384 + 40 * g2 + 4 * g];
      acc0 += av[g2] * bf16lo(vw2.x); acc1 += av[g2] * bf16hi(vw2.x);
      acc2 += av[g2] * bf16lo(vw2.y); acc3 += av[g2] * bf16hi(vw2.y);
    }
    __builtin_amdgcn_wave_barrier();
  }
  float accv[4] = {acc0, acc1, acc2, acc3};
  *(float4*)&sR[w][h * 32 + g * 4] = *(float4*)accv;
  __syncthreads();
  for (int c = tid; c < 256; c += 256) {
    float v = sR[0][c] + sR[1][c] + sR[2][c] + sR[3][c];
    Xout[(size_t)n * 256 + c] = fmaxf(v, 0.f);
  }
}

// ---------------- CustomConv D=8 (conv3) — unchanged from Round 5 -----------
template <int D>
__global__ __launch_bounds__(256) void conv_gather6_kernel(
    const float* __restrict__ Qn, const __hip_bfloat16* __restrict__ KV,
    const int* __restrict__ rowptr, const int* __restrict__ adj,
    const float* __restrict__ abias, float* __restrict__ Xout, float inv_sqrt_d) {
  constexpr int C = 8 * D;
  constexpr int KS = D + 4;
  constexpr int NLD = (2 * C) / 8;
  __shared__ float sK[4][8 * KS];
  __shared__ float sV[4][C];
  __shared__ float sR[4][C];
  const int tid = threadIdx.x, w = tid >> 6, lane = tid & 63;
  const int n = blockIdx.x;
  const int h = lane >> 3, g = lane & 7;

  float4 q[D / 4];
#pragma unroll
  for (int j = 0; j < D / 4; ++j)
    q[j] = *(const float4*)(Qn + (size_t)n * C + h * D + j * 4);

  const bool stg = lane < NLD;
  float* ldst = nullptr;
  if (stg) {
    int e = lane * 8;
    if (e < C) {
      int hh = e / D, dd = e % D;
      ldst = &sK[w][hh * KS + dd];
    } else {
      ldst = &sV[w][e - C];
    }
  }

  const float bh = abias[h];
  float acc[D / 8] = {};
  const int s = rowptr[n], t = rowptr[n + 1];
  int i = s + w;
  uint4 kvst = make_uint4(0u, 0u, 0u, 0u);
  if (i < t && stg)
    kvst = ((const uint4*)(KV + (size_t)adj[i] * 2 * C))[lane];
  for (; i < t; i += 4) {
    if (stg) {
      float f[8];
      bf16x8_to_f32(kvst, f);
      *(float4*)(ldst) = *(float4*)(f);
      *(float4*)(ldst + 4) = *(float4*)(f + 4);
    }
    const int i2 = i + 4;
    if (i2 < t && stg)
      kvst = ((const uint4*)(KV + (size_t)adj[i2] * 2 * C))[lane];
    __builtin_amdgcn_wave_barrier();
    float sc = 0.f;
#pragma unroll
    for (int d4 = 0; d4 < D / 4; ++d4) {
      float4 k4 = *(const float4*)&sK[w][g * KS + d4 * 4];
      sc += q[d4].x * k4.x + q[d4].y * k4.y + q[d4].z * k4.z + q[d4].w * k4.w;
    }
    sc = sc * inv_sqrt_d + bh;
    float m = fmaxf(sc, __shfl_xor(sc, 1));
    m = fmaxf(m, __shfl_xor(m, 2));
    m = fmaxf(m, __shfl_xor(m, 4));
    float ex = __expf(sc - m);
    float sum = ex;
    sum += __shfl_xor(sum, 1);
    sum += __shfl_xor(sum, 2);
    sum += __shfl_xor(sum, 4);
    float a = ex / sum;
#pragma unroll
    for (int g2 = 0; g2 < 8; ++g2) {
      float ag = __shfl(a, (h << 3) + g2);
      acc[0] += ag * sV[w][g2 * 8 + g];
    }
    __builtin_amdgcn_wave_barrier();
  }
  sR[w][h * 8 + g] = acc[0];
  __syncthreads();
  for (int c = tid; c < C; c += 256) {
    float v = sR[0][c] + sR[1][c] + sR[2][c] + sR[3][c];
    Xout[(size_t)n * C + c] = fmaxf(v, 0.f);
  }
}

// ---------------- GCN propagate via dst-CSR gather, bf16 rows ---------------
template <int C, bool BIAS, bool RELU>
__global__ __launch_bounds__(256) void gcn_gather5_kernel(
    const __hip_bfloat16* __restrict__ Hd, const int* __restrict__ rowptr,
    const int* __restrict__ adj, const float* __restrict__ dis,
    const float* __restrict__ bias, float* __restrict__ O, int Nn) {
  constexpr int EPL = C / 64;  // 4, 2, 1
  __shared__ float sR[4][C];
  const int tid = threadIdx.x, w = tid >> 6, lane = tid & 63;
  const int n = blockIdx.x;
  float acc[EPL] = {};
  const int s = rowptr[n], t = rowptr[n + 1];
  int i = s + w;
  int vs = (i < t) ? adj[i] : 0;
  while (i < t) {
    const int i2 = i + 4;
    const int vs2 = (i2 < t) ? adj[i2] : 0;
    const __hip_bfloat16* hs = Hd + (size_t)vs * C;
    if constexpr (EPL == 4) {
      uint2 u = *(const uint2*)(hs + lane * 4);
      acc[0] += bf16lo(u.x); acc[1] += bf16hi(u.x);
      acc[2] += bf16lo(u.y); acc[3] += bf16hi(u.y);
    } else if constexpr (EPL == 2) {
      uint32_t u = *(const uint32_t*)(hs + lane * 2);
      acc[0] += bf16lo(u); acc[1] += bf16hi(u);
    } else {
      acc[0] += bf16lo((uint32_t)*(const unsigned short*)(hs + lane));
    }
    vs = vs2; i = i2;
  }
  if (w == 0) {  // self-loop
    const __hip_bfloat16* hn = Hd + (size_t)n * C;
#pragma unroll
    for (int j = 0; j < EPL; ++j)
      acc[j] += bf16lo((uint32_t)*(const unsigned short*)(hn + lane * EPL + j));
  }
#pragma unroll
  for (int j = 0; j < EPL; ++j) sR[w][lane * EPL + j] = acc[j];
  __syncthreads();
  const float dn = dis[n];
  for (int c = tid; c < C; c += 256) {
    float v = (sR[0][c] + sR[1][c] + sR[2][c] + sR[3][c]) * dn;
    if (BIAS) v += bias[c];
    if (RELU) v = fmaxf(v, 0.f);
    O[(size_t)n * C + c] = v;
  }
}

// ---------------- segment sums (LDS pre-reduction) ----------------
__global__ void segsum_x3_pe_kernel(const float* __restrict__ X3, const int* __restrict__ batch,
                                    float* __restrict__ sum_x3, float* __restrict__ sum_pe,
                                    float* __restrict__ cnt, int N) {
  __shared__ float lx[512], lp[512], lc[8];
  const int tid = threadIdx.x;
  for (int i = tid; i < 512; i += 256) { lx[i] = 0.f; lp[i] = 0.f; }
  if (tid < 8) lc[tid] = 0.f;
  __syncthreads();
  int i = blockIdx.x * 256 + tid;
  if (i < N * 64) {
    int n = i >> 6, c = i & 63;
    int b = batch[n];
    atomicAdd(&lx[(b << 6) + c], X3[i]);
    const float F = -0.14391156831f;  // -ln(10000)/64
    float arg = (float)n * expf(F * (float)(c & ~1));
    atomicAdd(&lp[(b << 6) + c], (c & 1) ? cosf(arg) : sinf(arg));
    if (c == 0) atomicAdd(&lc[b], 1.f);
  }
  __syncthreads();
  for (int j = tid; j < 512; j += 256) {
    if (lx[j] != 0.f) atomicAdd(&sum_x3[j], lx[j]);
    if (lp[j] != 0.f) atomicAdd(&sum_pe[j], lp[j]);
  }
  if (tid < 8 && lc[tid] != 0.f) atomicAdd(&cnt[tid], lc[tid]);
}

__global__ void segsum_vfd_kernel(const float* __restrict__ VFD, const int* __restrict__ batch,
                                  float* __restrict__ sum_vfd, float* __restrict__ cnt, int N) {
  __shared__ float lv[1024], lc[8];
  const int tid = threadIdx.x;
  for (int i = tid; i < 1024; i += 256) lv[i] = 0.f;
  if (tid < 8) lc[tid] = 0.f;
  __syncthreads();
  int i = blockIdx.x * 256 + tid;
  if (i < N * 128) {
    int n = i >> 7, c = i & 127;
    int b = batch[n];
    atomicAdd(&lv[(b << 7) + c], VFD[i]);
    if (c == 0) atomicAdd(&lc[b], 1.f);
  }
  __syncthreads();
  for (int j = tid; j < 1024; j += 256) {
    if (lv[j] != 0.f) atomicAdd(&sum_vfd[j], lv[j]);
  }
  if (tid < 8 && lc[tid] != 0.f) atomicAdd(&cnt[tid], lc[tid]);
}

// ---------------- head ----------------
__global__ void head_kernel(const float* __restrict__ sum_x3, const float* __restrict__ sum_pe,
                            const float* __restrict__ cnt_wt, const float* __restrict__ sum_vfd,
                            const float* __restrict__ cnt_df, const float* __restrict__ sft_w,
                            const float* __restrict__ sft_b, const float* __restrict__ gru_wih,
                            const float* __restrict__ gru_bih, const float* __restrict__ gru_bhh,
                            const float* __restrict__ mlp_w1, const float* __restrict__ mlp_b1,
                            const float* __restrict__ mlp_w2, const float* __restrict__ mlp_b2,
                            const float* __restrict__ mlp_w3, const float* __restrict__ mlp_b3,
                            const float* __restrict__ pred_w, const float* __restrict__ pred_b,
                            float* __restrict__ out) {
  __shared__ float sA[512];
  __shared__ float sB[1536];
  __shared__ float sC[2048];
  __shared__ float sD[1024];
  __shared__ float sE[1024];
  const int tid = threadIdx.x;
  for (int i = tid; i < 512; i += 256) {
    int b = i >> 6;
    sA[i] = sum_x3[i] / fmaxf(cnt_wt[b], 1.f);
  }
  __syncthreads();
  for (int i = tid; i < 512; i += 256) {
    int b = i >> 6, c = i & 63;
    float acc = sft_b[c];
    for (int k = 0; k < 64; ++k) acc += sA[(b << 6) + k] * sft_w[k * 64 + c];
    sB[i] = fmaxf(acc, 0.f);
  }
  __syncthreads();
  for (int i = tid; i < 1536; i += 256) {
    int b = i / 192, r = i % 192;
    float acc = gru_bih[r];
    for (int k = 0; k < 64; ++k) acc += sB[(b << 6) + k] * gru_wih[r * 64 + k];
    sC[i] = acc;
  }
  __syncthreads();
  for (int i = tid; i < 512; i += 256) {
    int b = i >> 6, c = i & 63;
    const float* gi = sC + b * 192;
    float r = 1.f / (1.f + expf(-(gi[c] + gru_bhh[c])));
    float z = 1.f / (1.f + expf(-(gi[64 + c] + gru_bhh[64 + c])));
    float ng = tanhf(gi[128 + c] + r * gru_bhh[128 + c]);
    sA[i] = (1.f - z) * ng;
  }
  __syncthreads();
  for (int i = tid; i < 2048; i += 256) {
    int b = i >> 8, c = i & 255;
    float v;
    if (c < 64)
      v = (sum_x3[(b << 6) + c] + sum_pe[(b << 6) + c]) / fmaxf(cnt_wt[b], 1.f);
    else if (c < 128)
      v = sA[(b << 6) + (c - 64)];
    else
      v = sum_vfd[(b << 7) + (c - 128)] / fmaxf(cnt_df[b], 1.f);
    sC[i] = v;
  }
  __syncthreads();
  for (int i = tid; i < 1024; i += 256) {
    int b = i >> 7, c = i & 127;
    float acc = mlp_b1[c];
    for (int k = 0; k < 256; ++k) acc += sC[(b << 8) + k] * mlp_w1[k * 128 + c];
    sD[i] = fmaxf(acc, 0.f);
  }
  __syncthreads();
  for (int i = tid; i < 1024; i += 256) {
    int b = i >> 7, c = i & 127;
    float acc = mlp_b2[c];
    for (int k = 0; k < 128; ++k) acc += sD[(b << 7) + k] * mlp_w2[k * 128 + c];
    sE[i] = fmaxf(acc, 0.f);
  }
  __syncthreads();
  for (int i = tid; i < 1024; i += 256) {
    int b = i >> 7, c = i & 127;
    float acc = mlp_b3[c];
    for (int k = 0; k < 128; ++k) acc += sE[(b << 7) + k] * mlp_w3[k * 128 + c];
    sD[i] = acc;
  }
  __syncthreads();
  for (int b = tid; b < 8; b += 256) {
    float acc = pred_b[0];
    for (int k = 0; k < 128; ++k) acc += sD[(b << 7) + k] * pred_w[k];
    out[b] = acc;
  }
}

// ---------------------------------------------------------------------------
extern "C" void kernel_launch(void* const* d_in, const int* in_sizes, int n_in,
                              void* d_out, int out_size, void* d_ws, size_t ws_size,
                              hipStream_t stream) {
  const float* x_wt = (const float*)d_in[0];
  const float* x_diff = (const float*)d_in[1];
  const int* ei_wt = (const int*)d_in[2];
  const int* ei_df = (const int*)d_in[3];
  const int* b_wt = (const int*)d_in[4];
  const int* b_df = (const int*)d_in[5];
  const float* emb_w = (const float*)d_in[6];
  const float* emb_b = (const float*)d_in[7];
  const float* cw_lin_w = (const float*)d_in[8];
  const float* cw_lin_b = (const float*)d_in[9];
  const float* cw_q_w = (const float*)d_in[10];
  const float* cw_q_b = (const float*)d_in[11];
  const float* cw_k_w = (const float*)d_in[12];
  const float* cw_k_b = (const float*)d_in[13];
  const float* cw_v_w = (const float*)d_in[14];
  const float* cw_v_b = (const float*)d_in[15];
  const float* cw_bias = (const float*)d_in[16];
  const float* c3_lin_w = (const float*)d_in[17];
  const float* c3_lin_b = (const float*)d_in[18];
  const float* c3_q_w = (const float*)d_in[19];
  const float* c3_q_b = (const float*)d_in[20];
  const float* c3_k_w = (const float*)d_in[21];
  const float* c3_k_b = (const float*)d_in[22];
  const float* c3_v_w = (const float*)d_in[23];
  const float* c3_v_b = (const float*)d_in[24];
  const float* c3_bias = (const float*)d_in[25];
  const float* sft_w = (const float*)d_in[26];
  const float* sft_b = (const float*)d_in[27];
  const float* gru_wih = (const float*)d_in[28];
  const float* gru_bih = (const float*)d_in[30];
  const float* gru_bhh = (const float*)d_in[31];
  const float* gcn_w1 = (const float*)d_in[32];
  const float* gcn_b1 = (const float*)d_in[33];
  const float* gcn_w2 = (const float*)d_in[34];
  const float* gcn_b2 = (const float*)d_in[35];
  const float* gcn_w3 = (const float*)d_in[36];
  const float* gcn_b3 = (const float*)d_in[37];
  const float* mlp_w1 = (const float*)d_in[38];
  const float* mlp_b1 = (const float*)d_in[39];
  const float* mlp_w2 = (const float*)d_in[40];
  const float* mlp_b2 = (const float*)d_in[41];
  const float* mlp_w3 = (const float*)d_in[42];
  const float* mlp_b3 = (const float*)d_in[43];
  const float* pred_w = (const float*)d_in[44];
  const float* pred_b = (const float*)d_in[45];

  const int N = in_sizes[0] / 64;  // 6000
  const int E = in_sizes[2] / 2;   // 200000
  const int* src_wt = ei_wt;
  const int* dst_wt = ei_wt + E;
  const int* src_df = ei_df;
  const int* dst_df = ei_df + E;

  // ---- workspace layout ----
  float* ws = (float*)d_ws;
  const size_t fN256 = (size_t)N * 256;
  float* X = ws;
  float* L = ws + 1 * fN256;
  float* Qb = ws + 2 * fN256;
  float* Kb = ws + 3 * fN256;          // also bf16 KV (N x 512 bf16)
  float* Vb = ws + 4 * fN256;          // also bf16 Hd buffers
  float* X3 = ws + 5 * fN256;          // (N,64)
  float* DIS = X3 + (size_t)N * 64;    // (N)
  float* SEG = DIS + (((size_t)N + 63) / 64) * 64;
  float* sum_x3 = SEG;                 // 512
  float* sum_pe = SEG + 512;           // 512
  float* cnt_wt = SEG + 1024;          // 8
  float* sum_vfd = SEG + 1032;         // 1024
  float* cnt_df = SEG + 2056;          // 8
  int* ip = (int*)(SEG + 2064 + 16);
  int* rp_wt = ip;                     // N+1
  int* cur_wt = rp_wt + (N + 1);       // N
  int* adj_wt = cur_wt + N;            // E
  int* rp_df = adj_wt + E;             // N+1
  int* cur_df = rp_df + (N + 1);       // N
  int* adj_df = cur_df + N;            // E
  float* Wf6 = (float*)((((uintptr_t)(adj_df + E)) + 63) & ~(uintptr_t)63);  // 6*65536
  float* bf6 = Wf6 + 6 * 65536;        // 6*256
  float* Wf3 = bf6 + 6 * 256;          // 3*16384
  float* bf3 = Wf3 + 3 * 16384;        // 3*64

  __hip_bfloat16* KVb = (__hip_bfloat16*)Kb;
  __hip_bfloat16* Hd1 = (__hip_bfloat16*)Vb;   // N x 64
  __hip_bfloat16* Hd2 = (__hip_bfloat16*)Kb;   // N x 256
  __hip_bfloat16* Hd3 = (__hip_bfloat16*)Vb;   // N x 128

  const int TB = 256;
  auto gemm = [&](const float* A, const float* W, const float* bias, float* C,
                  int M, int K, int Nn, bool relu) {
    dim3 g(cdiv_h(M, 64), Nn / 64);
    if (relu)
      gemm_kernel<true, true><<<g, TB, 0, stream>>>(A, W, bias, C, M, K, Nn);
    else if (bias)
      gemm_kernel<false, true><<<g, TB, 0, stream>>>(A, W, bias, C, M, K, Nn);
    else
      gemm_kernel<false, false><<<g, TB, 0, stream>>>(A, W, nullptr, C, M, K, Nn);
  };

  // ---- weight/bias folds (independent of data) ----
  gemm_fold6_kernel<<<dim3(4, 4, 6), TB, 0, stream>>>(cw_lin_w, cw_q_w, cw_k_w, cw_v_w, Wf6);
  bias_fold6_kernel<<<6, TB, 0, stream>>>(cw_lin_b, cw_q_w, cw_k_w, cw_v_w, cw_q_b, cw_k_b,
                                          cw_v_b, bf6);
  gemm3_kernel<false><<<dim3(4, 1, 3), TB, 0, stream>>>(
      c3_lin_w, c3_q_w, c3_k_w, c3_v_w, nullptr, nullptr, nullptr,
      Wf3, Wf3 + 16384, Wf3 + 32768, 256, 64, 64);
  bias_fold3_kernel<<<3, 64, 0, stream>>>(c3_lin_b, c3_q_w, c3_k_w, c3_v_w, c3_q_b, c3_k_b,
                                          c3_v_b, bf3);

  // ---- CSR build (both graphs); reuse cur_* as temporary deg ----
  fill_i_kernel<<<32, TB, 0, stream>>>(cur_wt, 0, N);
  fill_i_kernel<<<32, TB, 0, stream>>>(cur_df, 0, N);
  hist_kernel<<<cdiv_h(E, TB), TB, 0, stream>>>(dst_wt, cur_wt, E);
  hist_kernel<<<cdiv_h(E, TB), TB, 0, stream>>>(dst_df, cur_df, E);
  scan_kernel<<<1, 1024, 0, stream>>>(cur_wt, rp_wt, cur_wt, N);
  scan_kernel<<<1, 1024, 0, stream>>>(cur_df, rp_df, cur_df, N);
  fill_adj_kernel<<<cdiv_h(E, TB), TB, 0, stream>>>(src_wt, dst_wt, cur_wt, adj_wt, E);
  fill_adj_kernel<<<cdiv_h(E, TB), TB, 0, stream>>>(src_df, dst_df, cur_df, adj_df, E);
  dis_kernel<<<cdiv_h(N, TB), TB, 0, stream>>>(rp_df, DIS, N);

  // ---- WT branch ----
  gemm(x_wt, emb_w, emb_b, X, N, 64, 256, true);
  const float isd32 = 0.17677669529663687f;  // 1/sqrt(32)
  const float isd8 = 0.35355339059327373f;   // 1/sqrt(8)
  for (int l = 0; l < 2; ++l) {
    gemm3_qkv_kernel<<<dim3(cdiv_h(N, 64), 4, 3), TB, 0, stream>>>(
        X, Wf6 + (size_t)l * 3 * 65536, bf6 + l * 768, Qb, KVb, N, 256, 256);
    conv_gather7_kernel<<<N, TB, 0, stream>>>(Qb, KVb, rp_wt, adj_wt, cw_bias + l * 8,
                                              X, isd32);
  }
  // conv3 (256 -> 64), lin folded into QKV
  gemm3_qkv_kernel<<<dim3(cdiv_h(N, 64), 1, 3), TB, 0, stream>>>(X, Wf3, bf3, Qb, KVb,
                                                                 N, 256, 64);
  conv_gather6_kernel<8><<<N, TB, 0, stream>>>(Qb, KVb, rp_wt, adj_wt, c3_bias, X3, isd8);

  fill_f_kernel<<<8, TB, 0, stream>>>(SEG, 0.f, 2064);
  segsum_x3_pe_kernel<<<cdiv_h(N * 64, TB), TB, 0, stream>>>(X3, b_wt, sum_x3, sum_pe,
                                                             cnt_wt, N);

  // ---- diff branch (GCN); dis[src] folded into bf16 rows ----
  xd_scale_bf16_kernel<<<cdiv_h(N * 64, TB), TB, 0, stream>>>(x_diff, DIS, Hd1, N * 64);
  gcn_gather5_kernel<64, false, false><<<N, TB, 0, stream>>>(Hd1, rp_df, adj_df, DIS,
                                                             nullptr, L, N);
  gemm(L, gcn_w1, gcn_b1, Qb, N, 64, 256, true);
  gemm_scale_bf16_kernel<<<dim3(cdiv_h(N, 64), 4), TB, 0, stream>>>(Qb, gcn_w2, DIS, Hd2,
                                                                    N, 256, 256);
  gcn_gather5_kernel<256, true, true><<<N, TB, 0, stream>>>(Hd2, rp_df, adj_df, DIS,
                                                            gcn_b2, L, N);
  gemm_scale_bf16_kernel<<<dim3(cdiv_h(N, 64), 2), TB, 0, stream>>>(L, gcn_w3, DIS, Hd3,
                                                                    N, 256, 128);
  gcn_gather5_kernel<128, true, false><<<N, TB, 0, stream>>>(Hd3, rp_df, adj_df, DIS,
                                                             gcn_b3, Qb, N);
  segsum_vfd_kernel<<<cdiv_h(N * 128, TB), TB, 0, stream>>>(Qb, b_df, sum_vfd, cnt_df, N);

  // ---- head ----
  head_kernel<<<1, TB, 0, stream>>>(sum_x3, sum_pe, cnt_wt, sum_vfd, cnt_df, sft_w, sft_b,
                                    gru_wih, gru_bih, gru_bhh, mlp_w1, mlp_b1, mlp_w2,
                                    mlp_b2, mlp_w3, mlp_b3, pred_w, pred_b, (float*)d_out);
}

// Round 7
// 599.004 us; speedup vs baseline: 4.9055x; 1.0599x over previous
//
#include <hip/hip_runtime.h>
#include <hip/hip_bf16.h>

// ---------------------------------------------------------------------------
// ProteinGraphConv (3x CustomConv edge-attention) + GCN diff branch + GRU/MLP
// head. Round 7: all activation GEMMs moved to MFMA bf16 (16x16x32), weights
// pre-transposed to WT[n][k] bf16; fused epilogues (QKV split / bias+relu /
// row-scale). Gather kernels unchanged from R6 except bf16 outputs where they
// feed GEMMs. N=6000, E=200000, HID=256, GH=64, H=8, B=8.
// ---------------------------------------------------------------------------

static inline int cdiv_h(int a, int b) { return (a + b - 1) / b; }

typedef __attribute__((ext_vector_type(8))) short bf16x8_t;
typedef __attribute__((ext_vector_type(4))) float f32x4_t;

__device__ __forceinline__ float bf16lo(uint32_t w) { return __uint_as_float(w << 16); }
__device__ __forceinline__ float bf16hi(uint32_t w) { return __uint_as_float(w & 0xffff0000u); }
__device__ __forceinline__ void bf16x8_to_f32(const uint4& u, float* f) {
  f[0] = bf16lo(u.x); f[1] = bf16hi(u.x);
  f[2] = bf16lo(u.y); f[3] = bf16hi(u.y);
  f[4] = bf16lo(u.z); f[5] = bf16hi(u.z);
  f[6] = bf16lo(u.w); f[7] = bf16hi(u.w);
}

__global__ void fill_f_kernel(float* __restrict__ p, float v, int n) {
  int stride = gridDim.x * blockDim.x;
  for (int i = blockIdx.x * blockDim.x + threadIdx.x; i < n; i += stride) p[i] = v;
}
__global__ void fill_i_kernel(int* __restrict__ p, int v, int n) {
  int stride = gridDim.x * blockDim.x;
  for (int i = blockIdx.x * blockDim.x + threadIdx.x; i < n; i += stride) p[i] = v;
}
__global__ void f2b_kernel(const float* __restrict__ in, __hip_bfloat16* __restrict__ out, int n) {
  int i = blockIdx.x * blockDim.x + threadIdx.x;
  if (i < n) out[i] = __float2bfloat16(in[i]);
}

// ---------------- CSR build ----------------
__global__ void hist_kernel(const int* __restrict__ dst, int* __restrict__ deg, int E) {
  int i = blockIdx.x * blockDim.x + threadIdx.x;
  if (i < E) atomicAdd(&deg[dst[i]], 1);
}

__global__ void scan_kernel(const int* __restrict__ deg, int* __restrict__ rowptr,
                            int* __restrict__ cursor, int N) {
  __shared__ int part[1024];
  const int t = threadIdx.x;
  const int chunk = (N + 1023) / 1024;
  const int base0 = t * chunk;
  int s = 0;
  for (int i = 0; i < chunk; ++i) {
    int idx = base0 + i;
    if (idx < N) s += deg[idx];
  }
  part[t] = s;
  __syncthreads();
  for (int off = 1; off < 1024; off <<= 1) {
    int v = (t >= off) ? part[t - off] : 0;
    __syncthreads();
    part[t] += v;
    __syncthreads();
  }
  int run = (t == 0) ? 0 : part[t - 1];
  for (int i = 0; i < chunk; ++i) {
    int idx = base0 + i;
    if (idx < N) {
      rowptr[idx] = run;
      cursor[idx] = run;
      run += deg[idx];
    }
  }
  if (t == 1023) rowptr[N] = part[1023];
}

__global__ void fill_adj_kernel(const int* __restrict__ src, const int* __restrict__ dst,
                                int* __restrict__ cursor, int* __restrict__ adj, int E) {
  int i = blockIdx.x * blockDim.x + threadIdx.x;
  if (i < E) {
    int p = atomicAdd(&cursor[dst[i]], 1);
    adj[p] = src[i];
  }
}

__global__ void dis_kernel(const int* __restrict__ rowptr, float* __restrict__ dis, int N) {
  int i = blockIdx.x * blockDim.x + threadIdx.x;
  if (i < N) dis[i] = rsqrtf((float)(rowptr[i + 1] - rowptr[i] + 1));
}

// Xd = bf16(x * dis[row])   (C = 64)
__global__ void xd_scale_bf16_kernel(const float* __restrict__ x, const float* __restrict__ dis,
                                     __hip_bfloat16* __restrict__ out, int n) {
  int i = blockIdx.x * blockDim.x + threadIdx.x;
  if (i < n) out[i] = __float2bfloat16(x[i] * dis[i >> 6]);
}

// WT[z][n][k] = bf16(W[z][k][n])
__global__ void transpose_bf16_kernel(const float* __restrict__ W,
                                      __hip_bfloat16* __restrict__ WT, int K, int N) {
  const size_t zoff = (size_t)blockIdx.z * K * N;
  int idx = blockIdx.x * blockDim.x + threadIdx.x;
  if (idx < K * N) {
    int k = idx / N, n = idx % N;
    WT[zoff + (size_t)n * K + k] = __float2bfloat16(W[zoff + idx]);
  }
}

// ---------------- MFMA GEMM: C = A(bf16 MxK) @ WT(bf16 [N][K])^T ------------
// Block 256 = 4 waves; wave w -> 16x16 tile at (blockIdx.x*16, blockIdx.y*64+w*16).
// A-frag: lane row=l&15, k=(l>>4)*8+j (16B load). B-frag: lane col=l&15, same k
// (16B from WT row). C: col=l&15, row=(l>>4)*4+j.  [verified m89/m92 layouts]
// EPI: 0 = +bias, relu -> bf16 ; 1 = *rsc[m] -> bf16 ; 2 = QKV by z
//   (z=0: +bias -> f32 Q ; z=1/2: +bias -> bf16 KV interleaved, row stride 2N)
template <int EPI>
__global__ __launch_bounds__(256) void mfma_gemm_kernel(
    const __hip_bfloat16* __restrict__ A, const __hip_bfloat16* __restrict__ WT,
    const float* __restrict__ bias, const float* __restrict__ rsc,
    float* __restrict__ outF, __hip_bfloat16* __restrict__ outB,
    int M, int K, int N) {
  const int tid = threadIdx.x, w = tid >> 6, lane = tid & 63;
  int z = 0;
  const __hip_bfloat16* Wz = WT;
  const float* bz = bias;
  if (EPI == 2) {
    z = blockIdx.z;
    Wz = WT + (size_t)z * K * N;
    bz = bias + (size_t)z * N;
  }
  const int row0 = blockIdx.x * 16;
  const int col0 = blockIdx.y * 64 + w * 16;
  if (col0 >= N) return;
  const int r = lane & 15, kb = lane >> 4;
  f32x4_t acc = {0.f, 0.f, 0.f, 0.f};
  const __hip_bfloat16* ap = A + (size_t)(row0 + r) * K + kb * 8;
  const __hip_bfloat16* bp = Wz + (size_t)(col0 + r) * K + kb * 8;
  for (int k0 = 0; k0 < K; k0 += 32) {
    bf16x8_t av = *(const bf16x8_t*)(ap + k0);
    bf16x8_t bv = *(const bf16x8_t*)(bp + k0);
    acc = __builtin_amdgcn_mfma_f32_16x16x32_bf16(av, bv, acc, 0, 0, 0);
  }
  const int n = col0 + r;
#pragma unroll
  for (int j = 0; j < 4; ++j) {
    const int m = row0 + kb * 4 + j;
    float v = acc[j];
    if (EPI == 0) {
      v += bias[n];
      outB[(size_t)m * N + n] = __float2bfloat16(fmaxf(v, 0.f));
    } else if (EPI == 1) {
      v *= rsc[m];
      outB[(size_t)m * N + n] = __float2bfloat16(v);
    } else {
      v += bz[n];
      if (z == 0)
        outF[(size_t)m * N + n] = v;
      else
        outB[(size_t)m * 2 * N + (size_t)(z - 1) * N + n] = __float2bfloat16(v);
    }
  }
}

// ---------------- f32 fold GEMMs (one-time weight prep) ----------------
template <bool BIAS>
__global__ void gemm3_kernel(const float* __restrict__ A, const float* __restrict__ W0,
                             const float* __restrict__ W1, const float* __restrict__ W2,
                             const float* __restrict__ b0, const float* __restrict__ b1,
                             const float* __restrict__ b2, float* __restrict__ C0,
                             float* __restrict__ C1, float* __restrict__ C2,
                             int M, int K, int N) {
  const int z = blockIdx.z;
  const float* W = (z == 0) ? W0 : (z == 1) ? W1 : W2;
  const float* bias = (z == 0) ? b0 : (z == 1) ? b1 : b2;
  float* C = (z == 0) ? C0 : (z == 1) ? C1 : C2;
  __shared__ float As[16][64];
  __shared__ float Bs[16][64];
  const int tx = threadIdx.x;
  const int m0 = blockIdx.x * 64, n0 = blockIdx.y * 64;
  const int tm = (tx & 15) * 4, tn = (tx >> 4) * 4;
  float acc[4][4] = {};
  for (int k0 = 0; k0 < K; k0 += 16) {
    {
      int m = tx >> 2, kq = (tx & 3) * 4;
      float4 av = make_float4(0.f, 0.f, 0.f, 0.f);
      if (m0 + m < M) av = *(const float4*)(A + (size_t)(m0 + m) * K + (k0 + kq));
      As[kq + 0][m] = av.x; As[kq + 1][m] = av.y;
      As[kq + 2][m] = av.z; As[kq + 3][m] = av.w;
      int kk = tx >> 4, nq = (tx & 15) * 4;
      *(float4*)&Bs[kk][nq] = *(const float4*)(W + (size_t)(k0 + kk) * N + (n0 + nq));
    }
    __syncthreads();
#pragma unroll
    for (int k = 0; k < 16; ++k) {
      float4 a4 = *(const float4*)&As[k][tm];
      float4 b4 = *(const float4*)&Bs[k][tn];
      float av[4] = {a4.x, a4.y, a4.z, a4.w};
      float bv[4] = {b4.x, b4.y, b4.z, b4.w};
#pragma unroll
      for (int i = 0; i < 4; ++i)
#pragma unroll
        for (int j = 0; j < 4; ++j) acc[i][j] += av[i] * bv[j];
    }
    __syncthreads();
  }
#pragma unroll
  for (int i = 0; i < 4; ++i) {
    int m = m0 + tm + i;
    if (m >= M) continue;
#pragma unroll
    for (int j = 0; j < 4; ++j) {
      float v = acc[i][j];
      int n = n0 + tn + j;
      if (BIAS) v += bias[n];
      C[(size_t)m * N + n] = v;
    }
  }
}

// Wf6[z=3l+j] = cw_lin_w[l] @ {q,k,v}w[l]   (grid 4x4x6)
__global__ void gemm_fold6_kernel(const float* __restrict__ lin_w, const float* __restrict__ qw,
                                  const float* __restrict__ kw, const float* __restrict__ vw,
                                  float* __restrict__ Wf) {
  const int z = blockIdx.z, l = z / 3, j = z % 3;
  const float* A = lin_w + (size_t)l * 65536;
  const float* W = ((j == 0) ? qw : (j == 1) ? kw : vw) + (size_t)l * 65536;
  float* C = Wf + (size_t)z * 65536;
  __shared__ float As[16][64];
  __shared__ float Bs[16][64];
  const int tx = threadIdx.x;
  const int m0 = blockIdx.x * 64, n0 = blockIdx.y * 64;
  const int tm = (tx & 15) * 4, tn = (tx >> 4) * 4;
  float acc[4][4] = {};
  for (int k0 = 0; k0 < 256; k0 += 16) {
    {
      int m = tx >> 2, kq = (tx & 3) * 4;
      float4 av = *(const float4*)(A + (size_t)(m0 + m) * 256 + (k0 + kq));
      As[kq + 0][m] = av.x; As[kq + 1][m] = av.y;
      As[kq + 2][m] = av.z; As[kq + 3][m] = av.w;
      int kk = tx >> 4, nq = (tx & 15) * 4;
      *(float4*)&Bs[kk][nq] = *(const float4*)(W + (size_t)(k0 + kk) * 256 + (n0 + nq));
    }
    __syncthreads();
#pragma unroll
    for (int k = 0; k < 16; ++k) {
      float4 a4 = *(const float4*)&As[k][tm];
      float4 b4 = *(const float4*)&Bs[k][tn];
      float av[4] = {a4.x, a4.y, a4.z, a4.w};
      float bv[4] = {b4.x, b4.y, b4.z, b4.w};
#pragma unroll
      for (int i = 0; i < 4; ++i)
#pragma unroll
        for (int j2 = 0; j2 < 4; ++j2) acc[i][j2] += av[i] * bv[j2];
    }
    __syncthreads();
  }
#pragma unroll
  for (int i = 0; i < 4; ++i)
#pragma unroll
    for (int j2 = 0; j2 < 4; ++j2)
      C[(size_t)(m0 + tm + i) * 256 + (n0 + tn + j2)] = acc[i][j2];
}

__global__ void bias_fold6_kernel(const float* __restrict__ lin_b, const float* __restrict__ qw,
                                  const float* __restrict__ kw, const float* __restrict__ vw,
                                  const float* __restrict__ qb, const float* __restrict__ kb,
                                  const float* __restrict__ vb, float* __restrict__ bf) {
  const int z = blockIdx.x, l = z / 3, j = z % 3, c = threadIdx.x;
  const float* W = ((j == 0) ? qw : (j == 1) ? kw : vw) + (size_t)l * 65536;
  const float* b = ((j == 0) ? qb : (j == 1) ? kb : vb) + l * 256;
  const float* lb = lin_b + l * 256;
  float acc = b[c];
  for (int k = 0; k < 256; ++k) acc += lb[k] * W[k * 256 + c];
  bf[z * 256 + c] = acc;
}

__global__ void bias_fold3_kernel(const float* __restrict__ lin_b, const float* __restrict__ qw,
                                  const float* __restrict__ kw, const float* __restrict__ vw,
                                  const float* __restrict__ qb, const float* __restrict__ kb,
                                  const float* __restrict__ vb, float* __restrict__ bf) {
  const int j = blockIdx.x, c = threadIdx.x;
  const float* W = (j == 0) ? qw : (j == 1) ? kw : vw;
  const float* b = (j == 0) ? qb : (j == 1) ? kb : vb;
  float acc = b[c];
  for (int k = 0; k < 64; ++k) acc += lin_b[k] * W[k * 64 + c];
  bf[j * 64 + c] = acc;
}

// ------- CustomConv D=32 via dst-CSR gather: packed-bf16 LDS, a-in-LDS ------
__global__ __launch_bounds__(256) void conv_gather7_kernel(
    const float* __restrict__ Qn, const __hip_bfloat16* __restrict__ KV,
    const int* __restrict__ rowptr, const int* __restrict__ adj,
    const float* __restrict__ abias, __hip_bfloat16* __restrict__ Xout,
    float inv_sqrt_d) {
  __shared__ __align__(16) unsigned short sKV[4][704];  // K: 8x48, V(base 384): 8x40
  __shared__ float sA[4][64];
  __shared__ float sR[4][256];
  const int tid = threadIdx.x, w = tid >> 6, lane = tid & 63;
  const int n = blockIdx.x;
  const int h = lane >> 3, g = lane & 7;

  float q[32];
#pragma unroll
  for (int j = 0; j < 8; ++j)
    *(float4*)&q[4 * j] = *(const float4*)(Qn + (size_t)n * 256 + h * 32 + 4 * j);

  const int e = lane * 8;
  int dsth;
  if (e < 256) dsth = (e >> 5) * 48 + (e & 31);
  else { int jj = e - 256; dsth = 384 + (jj >> 5) * 40 + (jj & 31); }
  unsigned short* ldst = &sKV[w][dsth];

  const float bh = abias[h];
  float acc0 = 0.f, acc1 = 0.f, acc2 = 0.f, acc3 = 0.f;
  const int s = rowptr[n], t = rowptr[n + 1];
  int i = s + w;
  uint4 kvst = make_uint4(0u, 0u, 0u, 0u);
  if (i < t) kvst = ((const uint4*)(KV + (size_t)adj[i] * 512))[lane];
  for (; i < t; i += 4) {
    *(uint4*)ldst = kvst;
    const int i2 = i + 4;
    if (i2 < t) kvst = ((const uint4*)(KV + (size_t)adj[i2] * 512))[lane];
    __builtin_amdgcn_wave_barrier();
    float sc = 0.f;
    const unsigned short* kr = &sKV[w][g * 48];
#pragma unroll
    for (int j = 0; j < 4; ++j) {
      uint4 kw4 = *(const uint4*)(kr + j * 8);
      sc += q[8 * j + 0] * bf16lo(kw4.x) + q[8 * j + 1] * bf16hi(kw4.x);
      sc += q[8 * j + 2] * bf16lo(kw4.y) + q[8 * j + 3] * bf16hi(kw4.y);
      sc += q[8 * j + 4] * bf16lo(kw4.z) + q[8 * j + 5] * bf16hi(kw4.z);
      sc += q[8 * j + 6] * bf16lo(kw4.w) + q[8 * j + 7] * bf16hi(kw4.w);
    }
    sc = sc * inv_sqrt_d + bh;
    float m = fmaxf(sc, __shfl_xor(sc, 1));
    m = fmaxf(m, __shfl_xor(m, 2));
    m = fmaxf(m, __shfl_xor(m, 4));
    float ex = __expf(sc - m);
    float sum = ex;
    sum += __shfl_xor(sum, 1);
    sum += __shfl_xor(sum, 2);
    sum += __shfl_xor(sum, 4);
    sA[w][lane] = ex / sum;
    __builtin_amdgcn_wave_barrier();
    float4 a0 = *(const float4*)&sA[w][h * 8];
    float4 a1 = *(const float4*)&sA[w][h * 8 + 4];
    float av[8] = {a0.x, a0.y, a0.z, a0.w, a1.x, a1.y, a1.z, a1.w};
#pragma unroll
    for (int g2 = 0; g2 < 8; ++g2) {
      uint2 vw2 = *(const uint2*)&sKV[w][384 + 40 * g2 + 4 * g];
      acc0 += av[g2] * bf16lo(vw2.x); acc1 += av[g2] * bf16hi(vw2.x);
      acc2 += av[g2] * bf16lo(vw2.y); acc3 += av[g2] * bf16hi(vw2.y);
    }
    __builtin_amdgcn_wave_barrier();
  }
  float accv[4] = {acc0, acc1, acc2, acc3};
  *(float4*)&sR[w][h * 32 + g * 4] = *(float4*)accv;
  __syncthreads();
  for (int c = tid; c < 256; c += 256) {
    float v = sR[0][c] + sR[1][c] + sR[2][c] + sR[3][c];
    Xout[(size_t)n * 256 + c] = __float2bfloat16(fmaxf(v, 0.f));
  }
}

// ---------------- CustomConv D=8 (conv3), f32 X3 out ----------------
template <int D>
__global__ __launch_bounds__(256) void conv_gather6_kernel(
    const float* __restrict__ Qn, const __hip_bfloat16* __restrict__ KV,
    const int* __restrict__ rowptr, const int* __restrict__ adj,
    const float* __restrict__ abias, float* __restrict__ Xout, float inv_sqrt_d) {
  constexpr int C = 8 * D;
  constexpr int KS = D + 4;
  constexpr int NLD = (2 * C) / 8;
  __shared__ float sK[4][8 * KS];
  __shared__ float sV[4][C];
  __shared__ float sR[4][C];
  const int tid = threadIdx.x, w = tid >> 6, lane = tid & 63;
  const int n = blockIdx.x;
  const int h = lane >> 3, g = lane & 7;

  float4 q[D / 4];
#pragma unroll
  for (int j = 0; j < D / 4; ++j)
    q[j] = *(const float4*)(Qn + (size_t)n * C + h * D + j * 4);

  const bool stg = lane < NLD;
  float* ldst = nullptr;
  if (stg) {
    int e = lane * 8;
    if (e < C) {
      int hh = e / D, dd = e % D;
      ldst = &sK[w][hh * KS + dd];
    } else {
      ldst = &sV[w][e - C];
    }
  }

  const float bh = abias[h];
  float acc[D / 8] = {};
  const int s = rowptr[n], t = rowptr[n + 1];
  int i = s + w;
  uint4 kvst = make_uint4(0u, 0u, 0u, 0u);
  if (i < t && stg)
    kvst = ((const uint4*)(KV + (size_t)adj[i] * 2 * C))[lane];
  for (; i < t; i += 4) {
    if (stg) {
      float f[8];
      bf16x8_to_f32(kvst, f);
      *(float4*)(ldst) = *(float4*)(f);
      *(float4*)(ldst + 4) = *(float4*)(f + 4);
    }
    const int i2 = i + 4;
    if (i2 < t && stg)
      kvst = ((const uint4*)(KV + (size_t)adj[i2] * 2 * C))[lane];
    __builtin_amdgcn_wave_barrier();
    float sc = 0.f;
#pragma unroll
    for (int d4 = 0; d4 < D / 4; ++d4) {
      float4 k4 = *(const float4*)&sK[w][g * KS + d4 * 4];
      sc += q[d4].x * k4.x + q[d4].y * k4.y + q[d4].z * k4.z + q[d4].w * k4.w;
    }
    sc = sc * inv_sqrt_d + bh;
    float m = fmaxf(sc, __shfl_xor(sc, 1));
    m = fmaxf(m, __shfl_xor(m, 2));
    m = fmaxf(m, __shfl_xor(m, 4));
    float ex = __expf(sc - m);
    float sum = ex;
    sum += __shfl_xor(sum, 1);
    sum += __shfl_xor(sum, 2);
    sum += __shfl_xor(sum, 4);
    float a = ex / sum;
#pragma unroll
    for (int g2 = 0; g2 < 8; ++g2) {
      float ag = __shfl(a, (h << 3) + g2);
      acc[0] += ag * sV[w][g2 * 8 + g];
    }
    __builtin_amdgcn_wave_barrier();
  }
  sR[w][h * 8 + g] = acc[0];
  __syncthreads();
  for (int c = tid; c < C; c += 256) {
    float v = sR[0][c] + sR[1][c] + sR[2][c] + sR[3][c];
    Xout[(size_t)n * C + c] = fmaxf(v, 0.f);
  }
}

// ---------------- GCN propagate via dst-CSR gather, bf16 rows ---------------
// OBF: write bf16 output (feeds an MFMA GEMM) else f32.
template <int C, bool BIAS, bool RELU, bool OBF>
__global__ __launch_bounds__(256) void gcn_gather5_kernel(
    const __hip_bfloat16* __restrict__ Hd, const int* __restrict__ rowptr,
    const int* __restrict__ adj, const float* __restrict__ dis,
    const float* __restrict__ bias, void* __restrict__ O, int Nn) {
  constexpr int EPL = C / 64;  // 4, 2, 1
  __shared__ float sR[4][C];
  const int tid = threadIdx.x, w = tid >> 6, lane = tid & 63;
  const int n = blockIdx.x;
  float acc[EPL] = {};
  const int s = rowptr[n], t = rowptr[n + 1];
  int i = s + w;
  int vs = (i < t) ? adj[i] : 0;
  while (i < t) {
    const int i2 = i + 4;
    const int vs2 = (i2 < t) ? adj[i2] : 0;
    const __hip_bfloat16* hs = Hd + (size_t)vs * C;
    if constexpr (EPL == 4) {
      uint2 u = *(const uint2*)(hs + lane * 4);
      acc[0] += bf16lo(u.x); acc[1] += bf16hi(u.x);
      acc[2] += bf16lo(u.y); acc[3] += bf16hi(u.y);
    } else if constexpr (EPL == 2) {
      uint32_t u = *(const uint32_t*)(hs + lane * 2);
      acc[0] += bf16lo(u); acc[1] += bf16hi(u);
    } else {
      acc[0] += bf16lo((uint32_t)*(const unsigned short*)(hs + lane));
    }
    vs = vs2; i = i2;
  }
  if (w == 0) {
    const __hip_bfloat16* hn = Hd + (size_t)n * C;
#pragma unroll
    for (int j = 0; j < EPL; ++j)
      acc[j] += bf16lo((uint32_t)*(const unsigned short*)(hn + lane * EPL + j));
  }
#pragma unroll
  for (int j = 0; j < EPL; ++j) sR[w][lane * EPL + j] = acc[j];
  __syncthreads();
  const float dn = dis[n];
  for (int c = tid; c < C; c += 256) {
    float v = (sR[0][c] + sR[1][c] + sR[2][c] + sR[3][c]) * dn;
    if (BIAS) v += bias[c];
    if (RELU) v = fmaxf(v, 0.f);
    if (OBF)
      ((__hip_bfloat16*)O)[(size_t)n * C + c] = __float2bfloat16(v);
    else
      ((float*)O)[(size_t)n * C + c] = v;
  }
}

// ---------------- segment sums (LDS pre-reduction) ----------------
__global__ void segsum_x3_pe_kernel(const float* __restrict__ X3, const int* __restrict__ batch,
                                    float* __restrict__ sum_x3, float* __restrict__ sum_pe,
                                    float* __restrict__ cnt, int N) {
  __shared__ float lx[512], lp[512], lc[8];
  const int tid = threadIdx.x;
  for (int i = tid; i < 512; i += 256) { lx[i] = 0.f; lp[i] = 0.f; }
  if (tid < 8) lc[tid] = 0.f;
  __syncthreads();
  int i = blockIdx.x * 256 + tid;
  if (i < N * 64) {
    int n = i >> 6, c = i & 63;
    int b = batch[n];
    atomicAdd(&lx[(b << 6) + c], X3[i]);
    const float F = -0.14391156831f;  // -ln(10000)/64
    float arg = (float)n * expf(F * (float)(c & ~1));
    atomicAdd(&lp[(b << 6) + c], (c & 1) ? cosf(arg) : sinf(arg));
    if (c == 0) atomicAdd(&lc[b], 1.f);
  }
  __syncthreads();
  for (int j = tid; j < 512; j += 256) {
    if (lx[j] != 0.f) atomicAdd(&sum_x3[j], lx[j]);
    if (lp[j] != 0.f) atomicAdd(&sum_pe[j], lp[j]);
  }
  if (tid < 8 && lc[tid] != 0.f) atomicAdd(&cnt[tid], lc[tid]);
}

__global__ void segsum_vfd_kernel(const float* __restrict__ VFD, const int* __restrict__ batch,
                                  float* __restrict__ sum_vfd, float* __restrict__ cnt, int N) {
  __shared__ float lv[1024], lc[8];
  const int tid = threadIdx.x;
  for (int i = tid; i < 1024; i += 256) lv[i] = 0.f;
  if (tid < 8) lc[tid] = 0.f;
  __syncthreads();
  int i = blockIdx.x * 256 + tid;
  if (i < N * 128) {
    int n = i >> 7, c = i & 127;
    int b = batch[n];
    atomicAdd(&lv[(b << 7) + c], VFD[i]);
    if (c == 0) atomicAdd(&lc[b], 1.f);
  }
  __syncthreads();
  for (int j = tid; j < 1024; j += 256) {
    if (lv[j] != 0.f) atomicAdd(&sum_vfd[j], lv[j]);
  }
  if (tid < 8 && lc[tid] != 0.f) atomicAdd(&cnt[tid], lc[tid]);
}

// ---------------- head ----------------
__global__ void head_kernel(const float* __restrict__ sum_x3, const float* __restrict__ sum_pe,
                            const float* __restrict__ cnt_wt, const float* __restrict__ sum_vfd,
                            const float* __restrict__ cnt_df, const float* __restrict__ sft_w,
                            const float* __restrict__ sft_b, const float* __restrict__ gru_wih,
                            const float* __restrict__ gru_bih, const float* __restrict__ gru_bhh,
                            const float* __restrict__ mlp_w1, const float* __restrict__ mlp_b1,
                            const float* __restrict__ mlp_w2, const float* __restrict__ mlp_b2,
                            const float* __restrict__ mlp_w3, const float* __restrict__ mlp_b3,
                            const float* __restrict__ pred_w, const float* __restrict__ pred_b,
                            float* __restrict__ out) {
  __shared__ float sA[512];
  __shared__ float sB[1536];
  __shared__ float sC[2048];
  __shared__ float sD[1024];
  __shared__ float sE[1024];
  const int tid = threadIdx.x;
  for (int i = tid; i < 512; i += 256) {
    int b = i >> 6;
    sA[i] = sum_x3[i] / fmaxf(cnt_wt[b], 1.f);
  }
  __syncthreads();
  for (int i = tid; i < 512; i += 256) {
    int b = i >> 6, c = i & 63;
    float acc = sft_b[c];
    for (int k = 0; k < 64; ++k) acc += sA[(b << 6) + k] * sft_w[k * 64 + c];
    sB[i] = fmaxf(acc, 0.f);
  }
  __syncthreads();
  for (int i = tid; i < 1536; i += 256) {
    int b = i / 192, r = i % 192;
    float acc = gru_bih[r];
    for (int k = 0; k < 64; ++k) acc += sB[(b << 6) + k] * gru_wih[r * 64 + k];
    sC[i] = acc;
  }
  __syncthreads();
  for (int i = tid; i < 512; i += 256) {
    int b = i >> 6, c = i & 63;
    const float* gi = sC + b * 192;
    float r = 1.f / (1.f + expf(-(gi[c] + gru_bhh[c])));
    float z = 1.f / (1.f + expf(-(gi[64 + c] + gru_bhh[64 + c])));
    float ng = tanhf(gi[128 + c] + r * gru_bhh[128 + c]);
    sA[i] = (1.f - z) * ng;
  }
  __syncthreads();
  for (int i = tid; i < 2048; i += 256) {
    int b = i >> 8, c = i & 255;
    float v;
    if (c < 64)
      v = (sum_x3[(b << 6) + c] + sum_pe[(b << 6) + c]) / fmaxf(cnt_wt[b], 1.f);
    else if (c < 128)
      v = sA[(b << 6) + (c - 64)];
    else
      v = sum_vfd[(b << 7) + (c - 128)] / fmaxf(cnt_df[b], 1.f);
    sC[i] = v;
  }
  __syncthreads();
  for (int i = tid; i < 1024; i += 256) {
    int b = i >> 7, c = i & 127;
    float acc = mlp_b1[c];
    for (int k = 0; k < 256; ++k) acc += sC[(b << 8) + k] * mlp_w1[k * 128 + c];
    sD[i] = fmaxf(acc, 0.f);
  }
  __syncthreads();
  for (int i = tid; i < 1024; i += 256) {
    int b = i >> 7, c = i & 127;
    float acc = mlp_b2[c];
    for (int k = 0; k < 128; ++k) acc += sD[(b << 7) + k] * mlp_w2[k * 128 + c];
    sE[i] = fmaxf(acc, 0.f);
  }
  __syncthreads();
  for (int i = tid; i < 1024; i += 256) {
    int b = i >> 7, c = i & 127;
    float acc = mlp_b3[c];
    for (int k = 0; k < 128; ++k) acc += sE[(b << 7) + k] * mlp_w3[k * 128 + c];
    sD[i] = acc;
  }
  __syncthreads();
  for (int b = tid; b < 8; b += 256) {
    float acc = pred_b[0];
    for (int k = 0; k < 128; ++k) acc += sD[(b << 7) + k] * pred_w[k];
    out[b] = acc;
  }
}

// ---------------------------------------------------------------------------
extern "C" void kernel_launch(void* const* d_in, const int* in_sizes, int n_in,
                              void* d_out, int out_size, void* d_ws, size_t ws_size,
                              hipStream_t stream) {
  const float* x_wt = (const float*)d_in[0];
  const float* x_diff = (const float*)d_in[1];
  const int* ei_wt = (const int*)d_in[2];
  const int* ei_df = (const int*)d_in[3];
  const int* b_wt = (const int*)d_in[4];
  const int* b_df = (const int*)d_in[5];
  const float* emb_w = (const float*)d_in[6];
  const float* emb_b = (const float*)d_in[7];
  const float* cw_lin_w = (const float*)d_in[8];
  const float* cw_lin_b = (const float*)d_in[9];
  const float* cw_q_w = (const float*)d_in[10];
  const float* cw_q_b = (const float*)d_in[11];
  const float* cw_k_w = (const float*)d_in[12];
  const float* cw_k_b = (const float*)d_in[13];
  const float* cw_v_w = (const float*)d_in[14];
  const float* cw_v_b = (const float*)d_in[15];
  const float* cw_bias = (const float*)d_in[16];
  const float* c3_lin_w = (const float*)d_in[17];
  const float* c3_lin_b = (const float*)d_in[18];
  const float* c3_q_w = (const float*)d_in[19];
  const float* c3_q_b = (const float*)d_in[20];
  const float* c3_k_w = (const float*)d_in[21];
  const float* c3_k_b = (const float*)d_in[22];
  const float* c3_v_w = (const float*)d_in[23];
  const float* c3_v_b = (const float*)d_in[24];
  const float* c3_bias = (const float*)d_in[25];
  const float* sft_w = (const float*)d_in[26];
  const float* sft_b = (const float*)d_in[27];
  const float* gru_wih = (const float*)d_in[28];
  const float* gru_bih = (const float*)d_in[30];
  const float* gru_bhh = (const float*)d_in[31];
  const float* gcn_w1 = (const float*)d_in[32];
  const float* gcn_b1 = (const float*)d_in[33];
  const float* gcn_w2 = (const float*)d_in[34];
  const float* gcn_b2 = (const float*)d_in[35];
  const float* gcn_w3 = (const float*)d_in[36];
  const float* gcn_b3 = (const float*)d_in[37];
  const float* mlp_w1 = (const float*)d_in[38];
  const float* mlp_b1 = (const float*)d_in[39];
  const float* mlp_w2 = (const float*)d_in[40];
  const float* mlp_b2 = (const float*)d_in[41];
  const float* mlp_w3 = (const float*)d_in[42];
  const float* mlp_b3 = (const float*)d_in[43];
  const float* pred_w = (const float*)d_in[44];
  const float* pred_b = (const float*)d_in[45];

  const int N = in_sizes[0] / 64;  // 6000
  const int E = in_sizes[2] / 2;   // 200000
  const int* src_wt = ei_wt;
  const int* dst_wt = ei_wt + E;
  const int* src_df = ei_df;
  const int* dst_df = ei_df + E;

  // ---- workspace layout ----
  float* ws = (float*)d_ws;
  const size_t fN256 = (size_t)N * 256;
  float* X = ws;                       // X bf16 region (also scratch)
  float* L = ws + 1 * fN256;           // VFD f32 / xwt bf16
  float* Qb = ws + 2 * fN256;          // Q f32
  float* Kb = ws + 3 * fN256;          // bf16 KV / GCN ping
  float* Vb = ws + 4 * fN256;          // GCN pong
  float* X3 = ws + 5 * fN256;          // (N,64) f32
  float* DIS = X3 + (size_t)N * 64;    // (N)
  float* SEG = DIS + (((size_t)N + 63) / 64) * 64;
  float* sum_x3 = SEG;                 // 512
  float* sum_pe = SEG + 512;           // 512
  float* cnt_wt = SEG + 1024;          // 8
  float* sum_vfd = SEG + 1032;         // 1024
  float* cnt_df = SEG + 2056;          // 8
  int* ip = (int*)(SEG + 2064 + 16);
  int* rp_wt = ip;                     // N+1
  int* cur_wt = rp_wt + (N + 1);       // N
  int* adj_wt = cur_wt + N;            // E
  int* rp_df = adj_wt + E;             // N+1
  int* cur_df = rp_df + (N + 1);       // N
  int* adj_df = cur_df + N;            // E
  float* Wf6 = (float*)((((uintptr_t)(adj_df + E)) + 63) & ~(uintptr_t)63);  // 6*65536 f32
  float* bf6 = Wf6 + 6 * 65536;        // 6*256
  float* Wf3 = bf6 + 6 * 256;          // 3*16384 f32
  float* bf3 = Wf3 + 3 * 16384;        // 3*64
  // bf16 transposed-weight region (64B aligned)
  __hip_bfloat16* wb = (__hip_bfloat16*)((((uintptr_t)(bf3 + 3 * 64)) + 63) & ~(uintptr_t)63);
  __hip_bfloat16* WfT6 = wb;                    // 6*65536
  __hip_bfloat16* Wf3T = WfT6 + 6 * 65536;      // 3*16384
  __hip_bfloat16* embT = Wf3T + 3 * 16384;      // 256*64
  __hip_bfloat16* w1T = embT + 16384;           // 256*64
  __hip_bfloat16* w2T = w1T + 16384;            // 256*256
  __hip_bfloat16* w3T = w2T + 65536;            // 128*256

  __hip_bfloat16* Xb = (__hip_bfloat16*)X;      // N x 256
  __hip_bfloat16* xwtb = (__hip_bfloat16*)L;    // N x 64 (emb input)
  __hip_bfloat16* KVb = (__hip_bfloat16*)Kb;    // N x 512
  __hip_bfloat16* Hd1 = (__hip_bfloat16*)Kb;    // GCN ping/pong
  __hip_bfloat16* G1 = (__hip_bfloat16*)Vb;
  __hip_bfloat16* Y1 = (__hip_bfloat16*)Kb;
  __hip_bfloat16* Hd2 = (__hip_bfloat16*)Vb;
  __hip_bfloat16* Y2b = (__hip_bfloat16*)Kb;
  __hip_bfloat16* Hd3 = (__hip_bfloat16*)Vb;
  float* VFD = L;

  const int TB = 256;

  // ---- weight folds (f32) + transposes to bf16 WT[n][k] ----
  gemm_fold6_kernel<<<dim3(4, 4, 6), TB, 0, stream>>>(cw_lin_w, cw_q_w, cw_k_w, cw_v_w, Wf6);
  bias_fold6_kernel<<<6, TB, 0, stream>>>(cw_lin_b, cw_q_w, cw_k_w, cw_v_w, cw_q_b, cw_k_b,
                                          cw_v_b, bf6);
  gemm3_kernel<false><<<dim3(4, 1, 3), TB, 0, stream>>>(
      c3_lin_w, c3_q_w, c3_k_w, c3_v_w, nullptr, nullptr, nullptr,
      Wf3, Wf3 + 16384, Wf3 + 32768, 256, 64, 64);
  bias_fold3_kernel<<<3, 64, 0, stream>>>(c3_lin_b, c3_q_w, c3_k_w, c3_v_w, c3_q_b, c3_k_b,
                                          c3_v_b, bf3);
  transpose_bf16_kernel<<<dim3(cdiv_h(65536, TB), 1, 6), TB, 0, stream>>>(Wf6, WfT6, 256, 256);
  transpose_bf16_kernel<<<dim3(cdiv_h(16384, TB), 1, 3), TB, 0, stream>>>(Wf3, Wf3T, 256, 64);
  transpose_bf16_kernel<<<dim3(cdiv_h(16384, TB), 1, 1), TB, 0, stream>>>(emb_w, embT, 64, 256);
  transpose_bf16_kernel<<<dim3(cdiv_h(16384, TB), 1, 1), TB, 0, stream>>>(gcn_w1, w1T, 64, 256);
  transpose_bf16_kernel<<<dim3(cdiv_h(65536, TB), 1, 1), TB, 0, stream>>>(gcn_w2, w2T, 256, 256);
  transpose_bf16_kernel<<<dim3(cdiv_h(32768, TB), 1, 1), TB, 0, stream>>>(gcn_w3, w3T, 256, 128);

  // ---- CSR build (both graphs); reuse cur_* as temporary deg ----
  fill_i_kernel<<<32, TB, 0, stream>>>(cur_wt, 0, N);
  fill_i_kernel<<<32, TB, 0, stream>>>(cur_df, 0, N);
  hist_kernel<<<cdiv_h(E, TB), TB, 0, stream>>>(dst_wt, cur_wt, E);
  hist_kernel<<<cdiv_h(E, TB), TB, 0, stream>>>(dst_df, cur_df, E);
  scan_kernel<<<1, 1024, 0, stream>>>(cur_wt, rp_wt, cur_wt, N);
  scan_kernel<<<1, 1024, 0, stream>>>(cur_df, rp_df, cur_df, N);
  fill_adj_kernel<<<cdiv_h(E, TB), TB, 0, stream>>>(src_wt, dst_wt, cur_wt, adj_wt, E);
  fill_adj_kernel<<<cdiv_h(E, TB), TB, 0, stream>>>(src_df, dst_df, cur_df, adj_df, E);
  dis_kernel<<<cdiv_h(N, TB), TB, 0, stream>>>(rp_df, DIS, N);

  const int MT = N / 16;  // 375 row-tiles
  // ---- WT branch ----
  f2b_kernel<<<cdiv_h(N * 64, TB), TB, 0, stream>>>(x_wt, xwtb, N * 64);
  // X = relu(x_wt @ emb_w + emb_b)  (bf16 out)
  mfma_gemm_kernel<0><<<dim3(MT, 4), TB, 0, stream>>>(xwtb, embT, emb_b, nullptr, nullptr,
                                                      Xb, N, 64, 256);
  const float isd32 = 0.17677669529663687f;  // 1/sqrt(32)
  const float isd8 = 0.35355339059327373f;   // 1/sqrt(8)
  for (int l = 0; l < 2; ++l) {
    mfma_gemm_kernel<2><<<dim3(MT, 4, 3), TB, 0, stream>>>(
        Xb, WfT6 + (size_t)l * 3 * 65536, bf6 + l * 768, nullptr, Qb, KVb, N, 256, 256);
    conv_gather7_kernel<<<N, TB, 0, stream>>>(Qb, KVb, rp_wt, adj_wt, cw_bias + l * 8,
                                              Xb, isd32);
  }
  // conv3 (256 -> 64), lin folded into QKV
  mfma_gemm_kernel<2><<<dim3(MT, 1, 3), TB, 0, stream>>>(Xb, Wf3T, bf3, nullptr, Qb, KVb,
                                                         N, 256, 64);
  conv_gather6_kernel<8><<<N, TB, 0, stream>>>(Qb, KVb, rp_wt, adj_wt, c3_bias, X3, isd8);

  fill_f_kernel<<<8, TB, 0, stream>>>(SEG, 0.f, 2064);
  segsum_x3_pe_kernel<<<cdiv_h(N * 64, TB), TB, 0, stream>>>(X3, b_wt, sum_x3, sum_pe,
                                                             cnt_wt, N);

  // ---- diff branch (GCN); dis[src] folded into bf16 rows ----
  xd_scale_bf16_kernel<<<cdiv_h(N * 64, TB), TB, 0, stream>>>(x_diff, DIS, Hd1, N * 64);
  gcn_gather5_kernel<64, false, false, true><<<N, TB, 0, stream>>>(Hd1, rp_df, adj_df, DIS,
                                                                   nullptr, G1, N);
  // Y1 = relu(G1 @ W1 + b1)  (bf16)
  mfma_gemm_kernel<0><<<dim3(MT, 4), TB, 0, stream>>>(G1, w1T, gcn_b1, nullptr, nullptr,
                                                      Y1, N, 64, 256);
  // Hd2 = (Y1 @ W2) * dis  (bf16)
  mfma_gemm_kernel<1><<<dim3(MT, 4), TB, 0, stream>>>(Y1, w2T, nullptr, DIS, nullptr,
                                                      Hd2, N, 256, 256);
  gcn_gather5_kernel<256, true, true, true><<<N, TB, 0, stream>>>(Hd2, rp_df, adj_df, DIS,
                                                                  gcn_b2, Y2b, N);
  // Hd3 = (Y2 @ W3) * dis  (bf16)
  mfma_gemm_kernel<1><<<dim3(MT, 2), TB, 0, stream>>>(Y2b, w3T, nullptr, DIS, nullptr,
                                                      Hd3, N, 256, 128);
  gcn_gather5_kernel<128, true, false, false><<<N, TB, 0, stream>>>(Hd3, rp_df, adj_df, DIS,
                                                                    gcn_b3, VFD, N);
  segsum_vfd_kernel<<<cdiv_h(N * 128, TB), TB, 0, stream>>>(VFD, b_df, sum_vfd, cnt_df, N);

  // ---- head ----
  head_kernel<<<1, TB, 0, stream>>>(sum_x3, sum_pe, cnt_wt, sum_vfd, cnt_df, sft_w, sft_b,
                                    gru_wih, gru_bih, gru_bhh, mlp_w1, mlp_b1, mlp_w2,
                                    mlp_b2, mlp_w3, mlp_b3, pred_w, pred_b, (float*)d_out);
}

// Round 8
// 529.395 us; speedup vs baseline: 5.5505x; 1.1315x over previous
//
#include <hip/hip_runtime.h>
#include <hip/hip_bf16.h>

// ---------------------------------------------------------------------------
// ProteinGraphConv (3x CustomConv edge-attention) + GCN diff branch + GRU/MLP
// head. Round 8: conv (D=32) fully on MFMA — per wave, 4 edges/iter:
// QK^T = 2x mfma_16x16x32 (K-stack x Q^T), lane-local softmax, P re-frag via
// LDS, PV = 2x mfma_16x16x32 against per-node pre-transposed V (written by
// the QKV GEMM epilogue). N=6000, E=200000, HID=256, GH=64, H=8, B=8.
// ---------------------------------------------------------------------------

static inline int cdiv_h(int a, int b) { return (a + b - 1) / b; }

typedef __attribute__((ext_vector_type(8))) short bf16x8_t;
typedef __attribute__((ext_vector_type(4))) float f32x4_t;

__device__ __forceinline__ float bf16lo(uint32_t w) { return __uint_as_float(w << 16); }
__device__ __forceinline__ float bf16hi(uint32_t w) { return __uint_as_float(w & 0xffff0000u); }
__device__ __forceinline__ void bf16x8_to_f32(const uint4& u, float* f) {
  f[0] = bf16lo(u.x); f[1] = bf16hi(u.x);
  f[2] = bf16lo(u.y); f[3] = bf16hi(u.y);
  f[4] = bf16lo(u.z); f[5] = bf16hi(u.z);
  f[6] = bf16lo(u.w); f[7] = bf16hi(u.w);
}
__device__ __forceinline__ unsigned short f2bu(float f) {
  __hip_bfloat16 h = __float2bfloat16(f);
  return *reinterpret_cast<unsigned short*>(&h);
}
__device__ __forceinline__ uint32_t pk_bf16(float a, float b) {
  return (uint32_t)f2bu(a) | ((uint32_t)f2bu(b) << 16);
}

__global__ void fill_f_kernel(float* __restrict__ p, float v, int n) {
  int stride = gridDim.x * blockDim.x;
  for (int i = blockIdx.x * blockDim.x + threadIdx.x; i < n; i += stride) p[i] = v;
}
__global__ void fill_i_kernel(int* __restrict__ p, int v, int n) {
  int stride = gridDim.x * blockDim.x;
  for (int i = blockIdx.x * blockDim.x + threadIdx.x; i < n; i += stride) p[i] = v;
}
__global__ void f2b_kernel(const float* __restrict__ in, __hip_bfloat16* __restrict__ out, int n) {
  int i = blockIdx.x * blockDim.x + threadIdx.x;
  if (i < n) out[i] = __float2bfloat16(in[i]);
}

// ---------------- CSR build ----------------
__global__ void hist_kernel(const int* __restrict__ dst, int* __restrict__ deg, int E) {
  int i = blockIdx.x * blockDim.x + threadIdx.x;
  if (i < E) atomicAdd(&deg[dst[i]], 1);
}

__global__ void scan_kernel(const int* __restrict__ deg, int* __restrict__ rowptr,
                            int* __restrict__ cursor, int N) {
  __shared__ int part[1024];
  const int t = threadIdx.x;
  const int chunk = (N + 1023) / 1024;
  const int base0 = t * chunk;
  int s = 0;
  for (int i = 0; i < chunk; ++i) {
    int idx = base0 + i;
    if (idx < N) s += deg[idx];
  }
  part[t] = s;
  __syncthreads();
  for (int off = 1; off < 1024; off <<= 1) {
    int v = (t >= off) ? part[t - off] : 0;
    __syncthreads();
    part[t] += v;
    __syncthreads();
  }
  int run = (t == 0) ? 0 : part[t - 1];
  for (int i = 0; i < chunk; ++i) {
    int idx = base0 + i;
    if (idx < N) {
      rowptr[idx] = run;
      cursor[idx] = run;
      run += deg[idx];
    }
  }
  if (t == 1023) rowptr[N] = part[1023];
}

__global__ void fill_adj_kernel(const int* __restrict__ src, const int* __restrict__ dst,
                                int* __restrict__ cursor, int* __restrict__ adj, int E) {
  int i = blockIdx.x * blockDim.x + threadIdx.x;
  if (i < E) {
    int p = atomicAdd(&cursor[dst[i]], 1);
    adj[p] = src[i];
  }
}

__global__ void dis_kernel(const int* __restrict__ rowptr, float* __restrict__ dis, int N) {
  int i = blockIdx.x * blockDim.x + threadIdx.x;
  if (i < N) dis[i] = rsqrtf((float)(rowptr[i + 1] - rowptr[i] + 1));
}

// Xd = bf16(x * dis[row])   (C = 64)
__global__ void xd_scale_bf16_kernel(const float* __restrict__ x, const float* __restrict__ dis,
                                     __hip_bfloat16* __restrict__ out, int n) {
  int i = blockIdx.x * blockDim.x + threadIdx.x;
  if (i < n) out[i] = __float2bfloat16(x[i] * dis[i >> 6]);
}

// WT[z][n][k] = bf16(W[z][k][n])
__global__ void transpose_bf16_kernel(const float* __restrict__ W,
                                      __hip_bfloat16* __restrict__ WT, int K, int N) {
  const size_t zoff = (size_t)blockIdx.z * K * N;
  int idx = blockIdx.x * blockDim.x + threadIdx.x;
  if (idx < K * N) {
    int k = idx / N, n = idx % N;
    WT[zoff + (size_t)n * K + k] = __float2bfloat16(W[zoff + idx]);
  }
}

// ---------------- MFMA GEMM: C = A(bf16 MxK) @ WT(bf16 [N][K])^T ------------
// EPI: 0 = +bias, relu -> bf16 ; 1 = *rsc[m] -> bf16 ; 2 = QKV (z0 f32 Q,
// z1/2 KV interleaved bf16, stride 2N) ; 3 = QKV big (z0 bf16 Q via outF cast,
// z1 K into KV[m*2N+n], z2 V TRANSPOSED into KV[m*2N+N+(n&31)*8+(n>>5)])
template <int EPI>
__global__ __launch_bounds__(256) void mfma_gemm_kernel(
    const __hip_bfloat16* __restrict__ A, const __hip_bfloat16* __restrict__ WT,
    const float* __restrict__ bias, const float* __restrict__ rsc,
    float* __restrict__ outF, __hip_bfloat16* __restrict__ outB,
    int M, int K, int N) {
  const int tid = threadIdx.x, w = tid >> 6, lane = tid & 63;
  int z = 0;
  const __hip_bfloat16* Wz = WT;
  const float* bz = bias;
  if (EPI == 2 || EPI == 3) {
    z = blockIdx.z;
    Wz = WT + (size_t)z * K * N;
    bz = bias + (size_t)z * N;
  }
  const int row0 = blockIdx.x * 16;
  const int col0 = blockIdx.y * 64 + w * 16;
  if (col0 >= N) return;
  const int r = lane & 15, kb = lane >> 4;
  f32x4_t acc = {0.f, 0.f, 0.f, 0.f};
  const __hip_bfloat16* ap = A + (size_t)(row0 + r) * K + kb * 8;
  const __hip_bfloat16* bp = Wz + (size_t)(col0 + r) * K + kb * 8;
  for (int k0 = 0; k0 < K; k0 += 32) {
    bf16x8_t av = *(const bf16x8_t*)(ap + k0);
    bf16x8_t bv = *(const bf16x8_t*)(bp + k0);
    acc = __builtin_amdgcn_mfma_f32_16x16x32_bf16(av, bv, acc, 0, 0, 0);
  }
  const int n = col0 + r;
#pragma unroll
  for (int j = 0; j < 4; ++j) {
    const int m = row0 + kb * 4 + j;
    float v = acc[j];
    if (EPI == 0) {
      v += bias[n];
      outB[(size_t)m * N + n] = __float2bfloat16(fmaxf(v, 0.f));
    } else if (EPI == 1) {
      v *= rsc[m];
      outB[(size_t)m * N + n] = __float2bfloat16(v);
    } else if (EPI == 2) {
      v += bz[n];
      if (z == 0)
        outF[(size_t)m * N + n] = v;
      else
        outB[(size_t)m * 2 * N + (size_t)(z - 1) * N + n] = __float2bfloat16(v);
    } else {
      v += bz[n];
      if (z == 0)
        ((__hip_bfloat16*)outF)[(size_t)m * N + n] = __float2bfloat16(v);
      else if (z == 1)
        outB[(size_t)m * 2 * N + n] = __float2bfloat16(v);
      else
        outB[(size_t)m * 2 * N + N + (size_t)(n & 31) * 8 + (n >> 5)] = __float2bfloat16(v);
    }
  }
}

// ---------------- f32 fold GEMMs (one-time weight prep) ----------------
template <bool BIAS>
__global__ void gemm3_kernel(const float* __restrict__ A, const float* __restrict__ W0,
                             const float* __restrict__ W1, const float* __restrict__ W2,
                             const float* __restrict__ b0, const float* __restrict__ b1,
                             const float* __restrict__ b2, float* __restrict__ C0,
                             float* __restrict__ C1, float* __restrict__ C2,
                             int M, int K, int N) {
  const int z = blockIdx.z;
  const float* W = (z == 0) ? W0 : (z == 1) ? W1 : W2;
  const float* bias = (z == 0) ? b0 : (z == 1) ? b1 : b2;
  float* C = (z == 0) ? C0 : (z == 1) ? C1 : C2;
  __shared__ float As[16][64];
  __shared__ float Bs[16][64];
  const int tx = threadIdx.x;
  const int m0 = blockIdx.x * 64, n0 = blockIdx.y * 64;
  const int tm = (tx & 15) * 4, tn = (tx >> 4) * 4;
  float acc[4][4] = {};
  for (int k0 = 0; k0 < K; k0 += 16) {
    {
      int m = tx >> 2, kq = (tx & 3) * 4;
      float4 av = make_float4(0.f, 0.f, 0.f, 0.f);
      if (m0 + m < M) av = *(const float4*)(A + (size_t)(m0 + m) * K + (k0 + kq));
      As[kq + 0][m] = av.x; As[kq + 1][m] = av.y;
      As[kq + 2][m] = av.z; As[kq + 3][m] = av.w;
      int kk = tx >> 4, nq = (tx & 15) * 4;
      *(float4*)&Bs[kk][nq] = *(const float4*)(W + (size_t)(k0 + kk) * N + (n0 + nq));
    }
    __syncthreads();
#pragma unroll
    for (int k = 0; k < 16; ++k) {
      float4 a4 = *(const float4*)&As[k][tm];
      float4 b4 = *(const float4*)&Bs[k][tn];
      float av[4] = {a4.x, a4.y, a4.z, a4.w};
      float bv[4] = {b4.x, b4.y, b4.z, b4.w};
#pragma unroll
      for (int i = 0; i < 4; ++i)
#pragma unroll
        for (int j = 0; j < 4; ++j) acc[i][j] += av[i] * bv[j];
    }
    __syncthreads();
  }
#pragma unroll
  for (int i = 0; i < 4; ++i) {
    int m = m0 + tm + i;
    if (m >= M) continue;
#pragma unroll
    for (int j = 0; j < 4; ++j) {
      float v = acc[i][j];
      int n = n0 + tn + j;
      if (BIAS) v += bias[n];
      C[(size_t)m * N + n] = v;
    }
  }
}

// Wf6[z=3l+j] = cw_lin_w[l] @ {q,k,v}w[l]   (grid 4x4x6)
__global__ void gemm_fold6_kernel(const float* __restrict__ lin_w, const float* __restrict__ qw,
                                  const float* __restrict__ kw, const float* __restrict__ vw,
                                  float* __restrict__ Wf) {
  const int z = blockIdx.z, l = z / 3, j = z % 3;
  const float* A = lin_w + (size_t)l * 65536;
  const float* W = ((j == 0) ? qw : (j == 1) ? kw : vw) + (size_t)l * 65536;
  float* C = Wf + (size_t)z * 65536;
  __shared__ float As[16][64];
  __shared__ float Bs[16][64];
  const int tx = threadIdx.x;
  const int m0 = blockIdx.x * 64, n0 = blockIdx.y * 64;
  const int tm = (tx & 15) * 4, tn = (tx >> 4) * 4;
  float acc[4][4] = {};
  for (int k0 = 0; k0 < 256; k0 += 16) {
    {
      int m = tx >> 2, kq = (tx & 3) * 4;
      float4 av = *(const float4*)(A + (size_t)(m0 + m) * 256 + (k0 + kq));
      As[kq + 0][m] = av.x; As[kq + 1][m] = av.y;
      As[kq + 2][m] = av.z; As[kq + 3][m] = av.w;
      int kk = tx >> 4, nq = (tx & 15) * 4;
      *(float4*)&Bs[kk][nq] = *(const float4*)(W + (size_t)(k0 + kk) * 256 + (n0 + nq));
    }
    __syncthreads();
#pragma unroll
    for (int k = 0; k < 16; ++k) {
      float4 a4 = *(const float4*)&As[k][tm];
      float4 b4 = *(const float4*)&Bs[k][tn];
      float av[4] = {a4.x, a4.y, a4.z, a4.w};
      float bv[4] = {b4.x, b4.y, b4.z, b4.w};
#pragma unroll
      for (int i = 0; i < 4; ++i)
#pragma unroll
        for (int j2 = 0; j2 < 4; ++j2) acc[i][j2] += av[i] * bv[j2];
    }
    __syncthreads();
  }
#pragma unroll
  for (int i = 0; i < 4; ++i)
#pragma unroll
    for (int j2 = 0; j2 < 4; ++j2)
      C[(size_t)(m0 + tm + i) * 256 + (n0 + tn + j2)] = acc[i][j2];
}

__global__ void bias_fold6_kernel(const float* __restrict__ lin_b, const float* __restrict__ qw,
                                  const float* __restrict__ kw, const float* __restrict__ vw,
                                  const float* __restrict__ qb, const float* __restrict__ kb,
                                  const float* __restrict__ vb, float* __restrict__ bf) {
  const int z = blockIdx.x, l = z / 3, j = z % 3, c = threadIdx.x;
  const float* W = ((j == 0) ? qw : (j == 1) ? kw : vw) + (size_t)l * 65536;
  const float* b = ((j == 0) ? qb : (j == 1) ? kb : vb) + l * 256;
  const float* lb = lin_b + l * 256;
  float acc = b[c];
  for (int k = 0; k < 256; ++k) acc += lb[k] * W[k * 256 + c];
  bf[z * 256 + c] = acc;
}

__global__ void bias_fold3_kernel(const float* __restrict__ lin_b, const float* __restrict__ qw,
                                  const float* __restrict__ kw, const float* __restrict__ vw,
                                  const float* __restrict__ qb, const float* __restrict__ kb,
                                  const float* __restrict__ vb, float* __restrict__ bf) {
  const int j = blockIdx.x, c = threadIdx.x;
  const float* W = (j == 0) ? qw : (j == 1) ? kw : vw;
  const float* b = (j == 0) ? qb : (j == 1) ? kb : vb;
  float acc = b[c];
  for (int k = 0; k < 64; ++k) acc += lin_b[k] * W[k * 64 + c];
  bf[j * 64 + c] = acc;
}

// ---------------- CustomConv D=32 — full MFMA path --------------------------
// One block (4 waves) per dst node; wave w handles edges s+w*4+16k .. +3.
// KV row per node: [K 256 halfs (g*32+d)][Vt 256 halfs (d*8+g)].
// Per iter: stage 4 edges' KV (4x uint4/lane), S^T = mfma(K16, Q^T) x2 tiles,
// lane-local softmax over g (regs + shfl_xor 16), P -> LDS (bf16, padded
// 16x40), A-frag b128 read, PV = mfma(P^T, Vt) x2 d-tiles into running acc.
__global__ __launch_bounds__(256) void conv_mfma_kernel(
    const __hip_bfloat16* __restrict__ Qn, const __hip_bfloat16* __restrict__ KV,
    const int* __restrict__ rowptr, const int* __restrict__ adj,
    const float* __restrict__ abias, __hip_bfloat16* __restrict__ Xout,
    float inv_sqrt_d) {
  __shared__ __align__(16) unsigned short sKV[4][2048];  // 4 edges x 512 halfs
  __shared__ __align__(16) unsigned short sP[4][640];    // 16 rows x 40 halfs
  __shared__ float sR[4][256];
  const int tid = threadIdx.x, w = tid >> 6, lane = tid & 63;
  const int n = blockIdx.x;
  const int c = lane & 15, kb = lane >> 4;

  // Q^T B-frag: lane holds Q[c&7][kb*8 .. +8] (cols 8-15 duplicate heads)
  const bf16x8_t qf = *(const bf16x8_t*)(Qn + (size_t)n * 256 + (size_t)(c & 7) * 32 + kb * 8);
  const float bh = abias[c & 7];

  unsigned short* myKV = sKV[w];
  unsigned short* myP = sP[w];
  f32x4_t acc0 = {0.f, 0.f, 0.f, 0.f};
  f32x4_t acc1 = {0.f, 0.f, 0.f, 0.f};
  const f32x4_t z4 = {0.f, 0.f, 0.f, 0.f};

  const int s0 = rowptr[n], t0 = rowptr[n + 1];
  auto ld = [&](int idx) -> uint4 {
    if (idx < t0) return *(const uint4*)(KV + (size_t)adj[idx] * 512 + (lane << 3));
    return make_uint4(0u, 0u, 0u, 0u);
  };
  int i = s0 + w * 4;
  uint4 kv0, kv1, kv2, kv3;
  if (i < t0) {
    kv0 = ld(i); kv1 = ld(i + 1); kv2 = ld(i + 2); kv3 = ld(i + 3);
  }
  for (; i < t0; i += 16) {
    *(uint4*)(myKV + 0 + (lane << 3)) = kv0;
    *(uint4*)(myKV + 512 + (lane << 3)) = kv1;
    *(uint4*)(myKV + 1024 + (lane << 3)) = kv2;
    *(uint4*)(myKV + 1536 + (lane << 3)) = kv3;
    const int i2 = i + 16;
    if (i2 < t0) {
      kv0 = ld(i2); kv1 = ld(i2 + 1); kv2 = ld(i2 + 2); kv3 = ld(i2 + 3);
    }
    __builtin_amdgcn_wave_barrier();
    // QK^T: A rows r=c: edge=c>>3, g=c&7 (tile0 edges 0/1, tile1 edges 2/3)
    const int aoff = (c >> 3) * 512 + (c & 7) * 32 + kb * 8;
    bf16x8_t a0 = *(const bf16x8_t*)(myKV + aoff);
    bf16x8_t a1 = *(const bf16x8_t*)(myKV + 1024 + aoff);
    f32x4_t S0 = __builtin_amdgcn_mfma_f32_16x16x32_bf16(a0, qf, z4, 0, 0, 0);
    f32x4_t S1 = __builtin_amdgcn_mfma_f32_16x16x32_bf16(a1, qf, z4, 0, 0, 0);
    // softmax over g within each edge: lane holds rows (kb*4+j); partner = xor 16
    float p0[4], p1[4];
    {
      float sv[4];
#pragma unroll
      for (int j = 0; j < 4; ++j) sv[j] = S0[j] * inv_sqrt_d + bh;
      float m = fmaxf(fmaxf(sv[0], sv[1]), fmaxf(sv[2], sv[3]));
      m = fmaxf(m, __shfl_xor(m, 16));
      float sum = 0.f;
#pragma unroll
      for (int j = 0; j < 4; ++j) { p0[j] = __expf(sv[j] - m); sum += p0[j]; }
      sum += __shfl_xor(sum, 16);
      float rs = 1.f / sum;
#pragma unroll
      for (int j = 0; j < 4; ++j) p0[j] *= rs;
    }
    {
      float sv[4];
#pragma unroll
      for (int j = 0; j < 4; ++j) sv[j] = S1[j] * inv_sqrt_d + bh;
      float m = fmaxf(fmaxf(sv[0], sv[1]), fmaxf(sv[2], sv[3]));
      m = fmaxf(m, __shfl_xor(m, 16));
      float sum = 0.f;
#pragma unroll
      for (int j = 0; j < 4; ++j) { p1[j] = __expf(sv[j] - m); sum += p1[j]; }
      sum += __shfl_xor(sum, 16);
      float rs = 1.f / sum;
#pragma unroll
      for (int j = 0; j < 4; ++j) p1[j] *= rs;
    }
    // P^T[h=c][eg]: tile0 -> cols kb*4..+3, tile1 -> cols 16+kb*4..+3
    *(uint32_t*)(myP + c * 40 + kb * 4) = pk_bf16(p0[0], p0[1]);
    *(uint32_t*)(myP + c * 40 + kb * 4 + 2) = pk_bf16(p0[2], p0[3]);
    *(uint32_t*)(myP + c * 40 + 16 + kb * 4) = pk_bf16(p1[0], p1[1]);
    *(uint32_t*)(myP + c * 40 + 16 + kb * 4 + 2) = pk_bf16(p1[2], p1[3]);
    __builtin_amdgcn_wave_barrier();
    // PV: A-frag P^T[r=c][k=kb*8..+8]; B-frag Vt[edge=kb][d=c | c+16][g=0..7]
    bf16x8_t pa = *(const bf16x8_t*)(myP + c * 40 + kb * 8);
    bf16x8_t vb0 = *(const bf16x8_t*)(myKV + kb * 512 + 256 + c * 8);
    bf16x8_t vb1 = *(const bf16x8_t*)(myKV + kb * 512 + 256 + (c + 16) * 8);
    acc0 = __builtin_amdgcn_mfma_f32_16x16x32_bf16(pa, vb0, acc0, 0, 0, 0);
    acc1 = __builtin_amdgcn_mfma_f32_16x16x32_bf16(pa, vb1, acc1, 0, 0, 0);
    __builtin_amdgcn_wave_barrier();
  }
  // D rows h = kb*4+j valid for kb<2 (rows 8-15 duplicate); cols d = c / c+16
  if (kb < 2) {
#pragma unroll
    for (int j = 0; j < 4; ++j) {
      int h = kb * 4 + j;
      sR[w][h * 32 + c] = acc0[j];
      sR[w][h * 32 + 16 + c] = acc1[j];
    }
  }
  __syncthreads();
  for (int cc = tid; cc < 256; cc += 256) {
    float v = sR[0][cc] + sR[1][cc] + sR[2][cc] + sR[3][cc];
    Xout[(size_t)n * 256 + cc] = __float2bfloat16(fmaxf(v, 0.f));
  }
}

// ---------------- CustomConv D=8 (conv3), f32 X3 out ----------------
template <int D>
__global__ __launch_bounds__(256) void conv_gather6_kernel(
    const float* __restrict__ Qn, const __hip_bfloat16* __restrict__ KV,
    const int* __restrict__ rowptr, const int* __restrict__ adj,
    const float* __restrict__ abias, float* __restrict__ Xout, float inv_sqrt_d) {
  constexpr int C = 8 * D;
  constexpr int KS = D + 4;
  constexpr int NLD = (2 * C) / 8;
  __shared__ float sK[4][8 * KS];
  __shared__ float sV[4][C];
  __shared__ float sR[4][C];
  const int tid = threadIdx.x, w = tid >> 6, lane = tid & 63;
  const int n = blockIdx.x;
  const int h = lane >> 3, g = lane & 7;

  float4 q[D / 4];
#pragma unroll
  for (int j = 0; j < D / 4; ++j)
    q[j] = *(const float4*)(Qn + (size_t)n * C + h * D + j * 4);

  const bool stg = lane < NLD;
  float* ldst = nullptr;
  if (stg) {
    int e = lane * 8;
    if (e < C) {
      int hh = e / D, dd = e % D;
      ldst = &sK[w][hh * KS + dd];
    } else {
      ldst = &sV[w][e - C];
    }
  }

  const float bh = abias[h];
  float acc[D / 8] = {};
  const int s = rowptr[n], t = rowptr[n + 1];
  int i = s + w;
  uint4 kvst = make_uint4(0u, 0u, 0u, 0u);
  if (i < t && stg)
    kvst = ((const uint4*)(KV + (size_t)adj[i] * 2 * C))[lane];
  for (; i < t; i += 4) {
    if (stg) {
      float f[8];
      bf16x8_to_f32(kvst, f);
      *(float4*)(ldst) = *(float4*)(f);
      *(float4*)(ldst + 4) = *(float4*)(f + 4);
    }
    const int i2 = i + 4;
    if (i2 < t && stg)
      kvst = ((const uint4*)(KV + (size_t)adj[i2] * 2 * C))[lane];
    __builtin_amdgcn_wave_barrier();
    float sc = 0.f;
#pragma unroll
    for (int d4 = 0; d4 < D / 4; ++d4) {
      float4 k4 = *(const float4*)&sK[w][g * KS + d4 * 4];
      sc += q[d4].x * k4.x + q[d4].y * k4.y + q[d4].z * k4.z + q[d4].w * k4.w;
    }
    sc = sc * inv_sqrt_d + bh;
    float m = fmaxf(sc, __shfl_xor(sc, 1));
    m = fmaxf(m, __shfl_xor(m, 2));
    m = fmaxf(m, __shfl_xor(m, 4));
    float ex = __expf(sc - m);
    float sum = ex;
    sum += __shfl_xor(sum, 1);
    sum += __shfl_xor(sum, 2);
    sum += __shfl_xor(sum, 4);
    float a = ex / sum;
#pragma unroll
    for (int g2 = 0; g2 < 8; ++g2) {
      float ag = __shfl(a, (h << 3) + g2);
      acc[0] += ag * sV[w][g2 * 8 + g];
    }
    __builtin_amdgcn_wave_barrier();
  }
  sR[w][h * 8 + g] = acc[0];
  __syncthreads();
  for (int c = tid; c < C; c += 256) {
    float v = sR[0][c] + sR[1][c] + sR[2][c] + sR[3][c];
    Xout[(size_t)n * C + c] = fmaxf(v, 0.f);
  }
}

// ---------------- GCN propagate via dst-CSR gather, bf16 rows ---------------
template <int C, bool BIAS, bool RELU, bool OBF>
__global__ __launch_bounds__(256) void gcn_gather5_kernel(
    const __hip_bfloat16* __restrict__ Hd, const int* __restrict__ rowptr,
    const int* __restrict__ adj, const float* __restrict__ dis,
    const float* __restrict__ bias, void* __restrict__ O, int Nn) {
  constexpr int EPL = C / 64;  // 4, 2, 1
  __shared__ float sR[4][C];
  const int tid = threadIdx.x, w = tid >> 6, lane = tid & 63;
  const int n = blockIdx.x;
  float acc[EPL] = {};
  const int s = rowptr[n], t = rowptr[n + 1];
  int i = s + w;
  int vs = (i < t) ? adj[i] : 0;
  while (i < t) {
    const int i2 = i + 4;
    const int vs2 = (i2 < t) ? adj[i2] : 0;
    const __hip_bfloat16* hs = Hd + (size_t)vs * C;
    if constexpr (EPL == 4) {
      uint2 u = *(const uint2*)(hs + lane * 4);
      acc[0] += bf16lo(u.x); acc[1] += bf16hi(u.x);
      acc[2] += bf16lo(u.y); acc[3] += bf16hi(u.y);
    } else if constexpr (EPL == 2) {
      uint32_t u = *(const uint32_t*)(hs + lane * 2);
      acc[0] += bf16lo(u); acc[1] += bf16hi(u);
    } else {
      acc[0] += bf16lo((uint32_t)*(const unsigned short*)(hs + lane));
    }
    vs = vs2; i = i2;
  }
  if (w == 0) {
    const __hip_bfloat16* hn = Hd + (size_t)n * C;
#pragma unroll
    for (int j = 0; j < EPL; ++j)
      acc[j] += bf16lo((uint32_t)*(const unsigned short*)(hn + lane * EPL + j));
  }
#pragma unroll
  for (int j = 0; j < EPL; ++j) sR[w][lane * EPL + j] = acc[j];
  __syncthreads();
  const float dn = dis[n];
  for (int c = tid; c < C; c += 256) {
    float v = (sR[0][c] + sR[1][c] + sR[2][c] + sR[3][c]) * dn;
    if (BIAS) v += bias[c];
    if (RELU) v = fmaxf(v, 0.f);
    if (OBF)
      ((__hip_bfloat16*)O)[(size_t)n * C + c] = __float2bfloat16(v);
    else
      ((float*)O)[(size_t)n * C + c] = v;
  }
}

// ---------------- segment sums (LDS pre-reduction) ----------------
__global__ void segsum_x3_pe_kernel(const float* __restrict__ X3, const int* __restrict__ batch,
                                    float* __restrict__ sum_x3, float* __restrict__ sum_pe,
                                    float* __restrict__ cnt, int N) {
  __shared__ float lx[512], lp[512], lc[8];
  const int tid = threadIdx.x;
  for (int i = tid; i < 512; i += 256) { lx[i] = 0.f; lp[i] = 0.f; }
  if (tid < 8) lc[tid] = 0.f;
  __syncthreads();
  int i = blockIdx.x * 256 + tid;
  if (i < N * 64) {
    int n = i >> 6, c = i & 63;
    int b = batch[n];
    atomicAdd(&lx[(b << 6) + c], X3[i]);
    const float F = -0.14391156831f;  // -ln(10000)/64
    float arg = (float)n * expf(F * (float)(c & ~1));
    atomicAdd(&lp[(b << 6) + c], (c & 1) ? cosf(arg) : sinf(arg));
    if (c == 0) atomicAdd(&lc[b], 1.f);
  }
  __syncthreads();
  for (int j = tid; j < 512; j += 256) {
    if (lx[j] != 0.f) atomicAdd(&sum_x3[j], lx[j]);
    if (lp[j] != 0.f) atomicAdd(&sum_pe[j], lp[j]);
  }
  if (tid < 8 && lc[tid] != 0.f) atomicAdd(&cnt[tid], lc[tid]);
}

__global__ void segsum_vfd_kernel(const float* __restrict__ VFD, const int* __restrict__ batch,
                                  float* __restrict__ sum_vfd, float* __restrict__ cnt, int N) {
  __shared__ float lv[1024], lc[8];
  const int tid = threadIdx.x;
  for (int i = tid; i < 1024; i += 256) lv[i] = 0.f;
  if (tid < 8) lc[tid] = 0.f;
  __syncthreads();
  int i = blockIdx.x * 256 + tid;
  if (i < N * 128) {
    int n = i >> 7, c = i & 127;
    int b = batch[n];
    atomicAdd(&lv[(b << 7) + c], VFD[i]);
    if (c == 0) atomicAdd(&lc[b], 1.f);
  }
  __syncthreads();
  for (int j = tid; j < 1024; j += 256) {
    if (lv[j] != 0.f) atomicAdd(&sum_vfd[j], lv[j]);
  }
  if (tid < 8 && lc[tid] != 0.f) atomicAdd(&cnt[tid], lc[tid]);
}

// ---------------- head ----------------
__global__ void head_kernel(const float* __restrict__ sum_x3, const float* __restrict__ sum_pe,
                            const float* __restrict__ cnt_wt, const float* __restrict__ sum_vfd,
                            const float* __restrict__ cnt_df, const float* __restrict__ sft_w,
                            const float* __restrict__ sft_b, const float* __restrict__ gru_wih,
                            const float* __restrict__ gru_bih, const float* __restrict__ gru_bhh,
                            const float* __restrict__ mlp_w1, const float* __restrict__ mlp_b1,
                            const float* __restrict__ mlp_w2, const float* __restrict__ mlp_b2,
                            const float* __restrict__ mlp_w3, const float* __restrict__ mlp_b3,
                            const float* __restrict__ pred_w, const float* __restrict__ pred_b,
                            float* __restrict__ out) {
  __shared__ float sA[512];
  __shared__ float sB[1536];
  __shared__ float sC[2048];
  __shared__ float sD[1024];
  __shared__ float sE[1024];
  const int tid = threadIdx.x;
  for (int i = tid; i < 512; i += 256) {
    int b = i >> 6;
    sA[i] = sum_x3[i] / fmaxf(cnt_wt[b], 1.f);
  }
  __syncthreads();
  for (int i = tid; i < 512; i += 256) {
    int b = i >> 6, c = i & 63;
    float acc = sft_b[c];
    for (int k = 0; k < 64; ++k) acc += sA[(b << 6) + k] * sft_w[k * 64 + c];
    sB[i] = fmaxf(acc, 0.f);
  }
  __syncthreads();
  for (int i = tid; i < 1536; i += 256) {
    int b = i / 192, r = i % 192;
    float acc = gru_bih[r];
    for (int k = 0; k < 64; ++k) acc += sB[(b << 6) + k] * gru_wih[r * 64 + k];
    sC[i] = acc;
  }
  __syncthreads();
  for (int i = tid; i < 512; i += 256) {
    int b = i >> 6, c = i & 63;
    const float* gi = sC + b * 192;
    float r = 1.f / (1.f + expf(-(gi[c] + gru_bhh[c])));
    float z = 1.f / (1.f + expf(-(gi[64 + c] + gru_bhh[64 + c])));
    float ng = tanhf(gi[128 + c] + r * gru_bhh[128 + c]);
    sA[i] = (1.f - z) * ng;
  }
  __syncthreads();
  for (int i = tid; i < 2048; i += 256) {
    int b = i >> 8, c = i & 255;
    float v;
    if (c < 64)
      v = (sum_x3[(b << 6) + c] + sum_pe[(b << 6) + c]) / fmaxf(cnt_wt[b], 1.f);
    else if (c < 128)
      v = sA[(b << 6) + (c - 64)];
    else
      v = sum_vfd[(b << 7) + (c - 128)] / fmaxf(cnt_df[b], 1.f);
    sC[i] = v;
  }
  __syncthreads();
  for (int i = tid; i < 1024; i += 256) {
    int b = i >> 7, c = i & 127;
    float acc = mlp_b1[c];
    for (int k = 0; k < 256; ++k) acc += sC[(b << 8) + k] * mlp_w1[k * 128 + c];
    sD[i] = fmaxf(acc, 0.f);
  }
  __syncthreads();
  for (int i = tid; i < 1024; i += 256) {
    int b = i >> 7, c = i & 127;
    float acc = mlp_b2[c];
    for (int k = 0; k < 128; ++k) acc += sD[(b << 7) + k] * mlp_w2[k * 128 + c];
    sE[i] = fmaxf(acc, 0.f);
  }
  __syncthreads();
  for (int i = tid; i < 1024; i += 256) {
    int b = i >> 7, c = i & 127;
    float acc = mlp_b3[c];
    for (int k = 0; k < 128; ++k) acc += sE[(b << 7) + k] * mlp_w3[k * 128 + c];
    sD[i] = acc;
  }
  __syncthreads();
  for (int b = tid; b < 8; b += 256) {
    float acc = pred_b[0];
    for (int k = 0; k < 128; ++k) acc += sD[(b << 7) + k] * pred_w[k];
    out[b] = acc;
  }
}

// ---------------------------------------------------------------------------
extern "C" void kernel_launch(void* const* d_in, const int* in_sizes, int n_in,
                              void* d_out, int out_size, void* d_ws, size_t ws_size,
                              hipStream_t stream) {
  const float* x_wt = (const float*)d_in[0];
  const float* x_diff = (const float*)d_in[1];
  const int* ei_wt = (const int*)d_in[2];
  const int* ei_df = (const int*)d_in[3];
  const int* b_wt = (const int*)d_in[4];
  const int* b_df = (const int*)d_in[5];
  const float* emb_w = (const float*)d_in[6];
  const float* emb_b = (const float*)d_in[7];
  const float* cw_lin_w = (const float*)d_in[8];
  const float* cw_lin_b = (const float*)d_in[9];
  const float* cw_q_w = (const float*)d_in[10];
  const float* cw_q_b = (const float*)d_in[11];
  const float* cw_k_w = (const float*)d_in[12];
  const float* cw_k_b = (const float*)d_in[13];
  const float* cw_v_w = (const float*)d_in[14];
  const float* cw_v_b = (const float*)d_in[15];
  const float* cw_bias = (const float*)d_in[16];
  const float* c3_lin_w = (const float*)d_in[17];
  const float* c3_lin_b = (const float*)d_in[18];
  const float* c3_q_w = (const float*)d_in[19];
  const float* c3_q_b = (const float*)d_in[20];
  const float* c3_k_w = (const float*)d_in[21];
  const float* c3_k_b = (const float*)d_in[22];
  const float* c3_v_w = (const float*)d_in[23];
  const float* c3_v_b = (const float*)d_in[24];
  const float* c3_bias = (const float*)d_in[25];
  const float* sft_w = (const float*)d_in[26];
  const float* sft_b = (const float*)d_in[27];
  const float* gru_wih = (const float*)d_in[28];
  const float* gru_bih = (const float*)d_in[30];
  const float* gru_bhh = (const float*)d_in[31];
  const float* gcn_w1 = (const float*)d_in[32];
  const float* gcn_b1 = (const float*)d_in[33];
  const float* gcn_w2 = (const float*)d_in[34];
  const float* gcn_b2 = (const float*)d_in[35];
  const float* gcn_w3 = (const float*)d_in[36];
  const float* gcn_b3 = (const float*)d_in[37];
  const float* mlp_w1 = (const float*)d_in[38];
  const float* mlp_b1 = (const float*)d_in[39];
  const float* mlp_w2 = (const float*)d_in[40];
  const float* mlp_b2 = (const float*)d_in[41];
  const float* mlp_w3 = (const float*)d_in[42];
  const float* mlp_b3 = (const float*)d_in[43];
  const float* pred_w = (const float*)d_in[44];
  const float* pred_b = (const float*)d_in[45];

  const int N = in_sizes[0] / 64;  // 6000
  const int E = in_sizes[2] / 2;   // 200000
  const int* src_wt = ei_wt;
  const int* dst_wt = ei_wt + E;
  const int* src_df = ei_df;
  const int* dst_df = ei_df + E;

  // ---- workspace layout ----
  float* ws = (float*)d_ws;
  const size_t fN256 = (size_t)N * 256;
  float* X = ws;
  float* L = ws + 1 * fN256;
  float* Qb = ws + 2 * fN256;
  float* Kb = ws + 3 * fN256;
  float* Vb = ws + 4 * fN256;
  float* X3 = ws + 5 * fN256;          // (N,64) f32
  float* DIS = X3 + (size_t)N * 64;    // (N)
  float* SEG = DIS + (((size_t)N + 63) / 64) * 64;
  float* sum_x3 = SEG;                 // 512
  float* sum_pe = SEG + 512;           // 512
  float* cnt_wt = SEG + 1024;          // 8
  float* sum_vfd = SEG + 1032;         // 1024
  float* cnt_df = SEG + 2056;          // 8
  int* ip = (int*)(SEG + 2064 + 16);
  int* rp_wt = ip;                     // N+1
  int* cur_wt = rp_wt + (N + 1);       // N
  int* adj_wt = cur_wt + N;            // E
  int* rp_df = adj_wt + E;             // N+1
  int* cur_df = rp_df + (N + 1);       // N
  int* adj_df = cur_df + N;            // E
  float* Wf6 = (float*)((((uintptr_t)(adj_df + E)) + 63) & ~(uintptr_t)63);  // 6*65536 f32
  float* bf6 = Wf6 + 6 * 65536;        // 6*256
  float* Wf3 = bf6 + 6 * 256;          // 3*16384 f32
  float* bf3 = Wf3 + 3 * 16384;        // 3*64
  __hip_bfloat16* wb = (__hip_bfloat16*)((((uintptr_t)(bf3 + 3 * 64)) + 63) & ~(uintptr_t)63);
  __hip_bfloat16* WfT6 = wb;                    // 6*65536
  __hip_bfloat16* Wf3T = WfT6 + 6 * 65536;      // 3*16384
  __hip_bfloat16* embT = Wf3T + 3 * 16384;      // 256*64
  __hip_bfloat16* w1T = embT + 16384;           // 256*64
  __hip_bfloat16* w2T = w1T + 16384;            // 256*256
  __hip_bfloat16* w3T = w2T + 65536;            // 128*256

  __hip_bfloat16* Xb = (__hip_bfloat16*)X;      // N x 256
  __hip_bfloat16* xwtb = (__hip_bfloat16*)L;    // N x 64 (emb input)
  __hip_bfloat16* Qb16 = (__hip_bfloat16*)Qb;   // N x 256 bf16 Q (conv7 layers)
  __hip_bfloat16* KVb = (__hip_bfloat16*)Kb;    // N x 512
  __hip_bfloat16* Hd1 = (__hip_bfloat16*)Kb;    // GCN ping/pong
  __hip_bfloat16* G1 = (__hip_bfloat16*)Vb;
  __hip_bfloat16* Y1 = (__hip_bfloat16*)Kb;
  __hip_bfloat16* Hd2 = (__hip_bfloat16*)Vb;
  __hip_bfloat16* Y2b = (__hip_bfloat16*)Kb;
  __hip_bfloat16* Hd3 = (__hip_bfloat16*)Vb;
  float* VFD = L;

  const int TB = 256;

  // ---- weight folds (f32) + transposes to bf16 WT[n][k] ----
  gemm_fold6_kernel<<<dim3(4, 4, 6), TB, 0, stream>>>(cw_lin_w, cw_q_w, cw_k_w, cw_v_w, Wf6);
  bias_fold6_kernel<<<6, TB, 0, stream>>>(cw_lin_b, cw_q_w, cw_k_w, cw_v_w, cw_q_b, cw_k_b,
                                          cw_v_b, bf6);
  gemm3_kernel<false><<<dim3(4, 1, 3), TB, 0, stream>>>(
      c3_lin_w, c3_q_w, c3_k_w, c3_v_w, nullptr, nullptr, nullptr,
      Wf3, Wf3 + 16384, Wf3 + 32768, 256, 64, 64);
  bias_fold3_kernel<<<3, 64, 0, stream>>>(c3_lin_b, c3_q_w, c3_k_w, c3_v_w, c3_q_b, c3_k_b,
                                          c3_v_b, bf3);
  transpose_bf16_kernel<<<dim3(cdiv_h(65536, TB), 1, 6), TB, 0, stream>>>(Wf6, WfT6, 256, 256);
  transpose_bf16_kernel<<<dim3(cdiv_h(16384, TB), 1, 3), TB, 0, stream>>>(Wf3, Wf3T, 256, 64);
  transpose_bf16_kernel<<<dim3(cdiv_h(16384, TB), 1, 1), TB, 0, stream>>>(emb_w, embT, 64, 256);
  transpose_bf16_kernel<<<dim3(cdiv_h(16384, TB), 1, 1), TB, 0, stream>>>(gcn_w1, w1T, 64, 256);
  transpose_bf16_kernel<<<dim3(cdiv_h(65536, TB), 1, 1), TB, 0, stream>>>(gcn_w2, w2T, 256, 256);
  transpose_bf16_kernel<<<dim3(cdiv_h(32768, TB), 1, 1), TB, 0, stream>>>(gcn_w3, w3T, 256, 128);

  // ---- CSR build (both graphs); reuse cur_* as temporary deg ----
  fill_i_kernel<<<32, TB, 0, stream>>>(cur_wt, 0, N);
  fill_i_kernel<<<32, TB, 0, stream>>>(cur_df, 0, N);
  hist_kernel<<<cdiv_h(E, TB), TB, 0, stream>>>(dst_wt, cur_wt, E);
  hist_kernel<<<cdiv_h(E, TB), TB, 0, stream>>>(dst_df, cur_df, E);
  scan_kernel<<<1, 1024, 0, stream>>>(cur_wt, rp_wt, cur_wt, N);
  scan_kernel<<<1, 1024, 0, stream>>>(cur_df, rp_df, cur_df, N);
  fill_adj_kernel<<<cdiv_h(E, TB), TB, 0, stream>>>(src_wt, dst_wt, cur_wt, adj_wt, E);
  fill_adj_kernel<<<cdiv_h(E, TB), TB, 0, stream>>>(src_df, dst_df, cur_df, adj_df, E);
  dis_kernel<<<cdiv_h(N, TB), TB, 0, stream>>>(rp_df, DIS, N);

  const int MT = N / 16;  // 375 row-tiles
  // ---- WT branch ----
  f2b_kernel<<<cdiv_h(N * 64, TB), TB, 0, stream>>>(x_wt, xwtb, N * 64);
  mfma_gemm_kernel<0><<<dim3(MT, 4), TB, 0, stream>>>(xwtb, embT, emb_b, nullptr, nullptr,
                                                      Xb, N, 64, 256);
  const float isd32 = 0.17677669529663687f;  // 1/sqrt(32)
  const float isd8 = 0.35355339059327373f;   // 1/sqrt(8)
  for (int l = 0; l < 2; ++l) {
    mfma_gemm_kernel<3><<<dim3(MT, 4, 3), TB, 0, stream>>>(
        Xb, WfT6 + (size_t)l * 3 * 65536, bf6 + l * 768, nullptr, (float*)Qb16, KVb,
        N, 256, 256);
    conv_mfma_kernel<<<N, TB, 0, stream>>>(Qb16, KVb, rp_wt, adj_wt, cw_bias + l * 8,
                                           Xb, isd32);
  }
  // conv3 (256 -> 64), lin folded into QKV (f32 Q + interleaved KV)
  mfma_gemm_kernel<2><<<dim3(MT, 1, 3), TB, 0, stream>>>(Xb, Wf3T, bf3, nullptr, Qb, KVb,
                                                         N, 256, 64);
  conv_gather6_kernel<8><<<N, TB, 0, stream>>>(Qb, KVb, rp_wt, adj_wt, c3_bias, X3, isd8);

  fill_f_kernel<<<8, TB, 0, stream>>>(SEG, 0.f, 2064);
  segsum_x3_pe_kernel<<<cdiv_h(N * 64, TB), TB, 0, stream>>>(X3, b_wt, sum_x3, sum_pe,
                                                             cnt_wt, N);

  // ---- diff branch (GCN); dis[src] folded into bf16 rows ----
  xd_scale_bf16_kernel<<<cdiv_h(N * 64, TB), TB, 0, stream>>>(x_diff, DIS, Hd1, N * 64);
  gcn_gather5_kernel<64, false, false, true><<<N, TB, 0, stream>>>(Hd1, rp_df, adj_df, DIS,
                                                                   nullptr, G1, N);
  mfma_gemm_kernel<0><<<dim3(MT, 4), TB, 0, stream>>>(G1, w1T, gcn_b1, nullptr, nullptr,
                                                      Y1, N, 64, 256);
  mfma_gemm_kernel<1><<<dim3(MT, 4), TB, 0, stream>>>(Y1, w2T, nullptr, DIS, nullptr,
                                                      Hd2, N, 256, 256);
  gcn_gather5_kernel<256, true, true, true><<<N, TB, 0, stream>>>(Hd2, rp_df, adj_df, DIS,
                                                                  gcn_b2, Y2b, N);
  mfma_gemm_kernel<1><<<dim3(MT, 2), TB, 0, stream>>>(Y2b, w3T, nullptr, DIS, nullptr,
                                                      Hd3, N, 256, 128);
  gcn_gather5_kernel<128, true, false, false><<<N, TB, 0, stream>>>(Hd3, rp_df, adj_df, DIS,
                                                                    gcn_b3, VFD, N);
  segsum_vfd_kernel<<<cdiv_h(N * 128, TB), TB, 0, stream>>>(VFD, b_df, sum_vfd, cnt_df, N);

  // ---- head ----
  head_kernel<<<1, TB, 0, stream>>>(sum_x3, sum_pe, cnt_wt, sum_vfd, cnt_df, sft_w, sft_b,
                                    gru_wih, gru_bih, gru_bhh, mlp_w1, mlp_b1, mlp_w2,
                                    mlp_b2, mlp_w3, mlp_b3, pred_w, pred_b, (float*)d_out);
}

// Round 9
// 493.739 us; speedup vs baseline: 5.9513x; 1.0722x over previous
//
#include <hip/hip_runtime.h>
#include <hip/hip_bf16.h>

// ---------------------------------------------------------------------------
// ProteinGraphConv (3x CustomConv edge-attention) + GCN diff branch + GRU/MLP
// head. Round 9: conv3 (D=8) moved to the MFMA path too — 4 edges per wave
// iter: QK^T = 2x mfma (k=d zero-padded), softmax, PV = 1x mfma with k=32
// fully used (4 edges x 8 g). GCN gather gets 1-deep data prefetch.
// N=6000, E=200000, HID=256, GH=64, H=8, B=8.
// ---------------------------------------------------------------------------

static inline int cdiv_h(int a, int b) { return (a + b - 1) / b; }

typedef __attribute__((ext_vector_type(8))) short bf16x8_t;
typedef __attribute__((ext_vector_type(4))) float f32x4_t;

__device__ __forceinline__ float bf16lo(uint32_t w) { return __uint_as_float(w << 16); }
__device__ __forceinline__ float bf16hi(uint32_t w) { return __uint_as_float(w & 0xffff0000u); }
__device__ __forceinline__ unsigned short f2bu(float f) {
  __hip_bfloat16 h = __float2bfloat16(f);
  return *reinterpret_cast<unsigned short*>(&h);
}
__device__ __forceinline__ uint32_t pk_bf16(float a, float b) {
  return (uint32_t)f2bu(a) | ((uint32_t)f2bu(b) << 16);
}

__global__ void fill_f_kernel(float* __restrict__ p, float v, int n) {
  int stride = gridDim.x * blockDim.x;
  for (int i = blockIdx.x * blockDim.x + threadIdx.x; i < n; i += stride) p[i] = v;
}
__global__ void fill_i_kernel(int* __restrict__ p, int v, int n) {
  int stride = gridDim.x * blockDim.x;
  for (int i = blockIdx.x * blockDim.x + threadIdx.x; i < n; i += stride) p[i] = v;
}
__global__ void f2b_kernel(const float* __restrict__ in, __hip_bfloat16* __restrict__ out, int n) {
  int i = blockIdx.x * blockDim.x + threadIdx.x;
  if (i < n) out[i] = __float2bfloat16(in[i]);
}

// ---------------- CSR build ----------------
__global__ void hist_kernel(const int* __restrict__ dst, int* __restrict__ deg, int E) {
  int i = blockIdx.x * blockDim.x + threadIdx.x;
  if (i < E) atomicAdd(&deg[dst[i]], 1);
}

__global__ void scan_kernel(const int* __restrict__ deg, int* __restrict__ rowptr,
                            int* __restrict__ cursor, int N) {
  __shared__ int part[1024];
  const int t = threadIdx.x;
  const int chunk = (N + 1023) / 1024;
  const int base0 = t * chunk;
  int s = 0;
  for (int i = 0; i < chunk; ++i) {
    int idx = base0 + i;
    if (idx < N) s += deg[idx];
  }
  part[t] = s;
  __syncthreads();
  for (int off = 1; off < 1024; off <<= 1) {
    int v = (t >= off) ? part[t - off] : 0;
    __syncthreads();
    part[t] += v;
    __syncthreads();
  }
  int run = (t == 0) ? 0 : part[t - 1];
  for (int i = 0; i < chunk; ++i) {
    int idx = base0 + i;
    if (idx < N) {
      rowptr[idx] = run;
      cursor[idx] = run;
      run += deg[idx];
    }
  }
  if (t == 1023) rowptr[N] = part[1023];
}

__global__ void fill_adj_kernel(const int* __restrict__ src, const int* __restrict__ dst,
                                int* __restrict__ cursor, int* __restrict__ adj, int E) {
  int i = blockIdx.x * blockDim.x + threadIdx.x;
  if (i < E) {
    int p = atomicAdd(&cursor[dst[i]], 1);
    adj[p] = src[i];
  }
}

__global__ void dis_kernel(const int* __restrict__ rowptr, float* __restrict__ dis, int N) {
  int i = blockIdx.x * blockDim.x + threadIdx.x;
  if (i < N) dis[i] = rsqrtf((float)(rowptr[i + 1] - rowptr[i] + 1));
}

// Xd = bf16(x * dis[row])   (C = 64)
__global__ void xd_scale_bf16_kernel(const float* __restrict__ x, const float* __restrict__ dis,
                                     __hip_bfloat16* __restrict__ out, int n) {
  int i = blockIdx.x * blockDim.x + threadIdx.x;
  if (i < n) out[i] = __float2bfloat16(x[i] * dis[i >> 6]);
}

// WT[z][n][k] = bf16(W[z][k][n])
__global__ void transpose_bf16_kernel(const float* __restrict__ W,
                                      __hip_bfloat16* __restrict__ WT, int K, int N) {
  const size_t zoff = (size_t)blockIdx.z * K * N;
  int idx = blockIdx.x * blockDim.x + threadIdx.x;
  if (idx < K * N) {
    int k = idx / N, n = idx % N;
    WT[zoff + (size_t)n * K + k] = __float2bfloat16(W[zoff + idx]);
  }
}

// ---------------- MFMA GEMM: C = A(bf16 MxK) @ WT(bf16 [N][K])^T ------------
// EPI: 0 = +bias, relu -> bf16 ; 1 = *rsc[m] -> bf16 ; 2 = QKV (z0 f32 Q,
// z1/2 KV interleaved bf16, stride 2N) ; 3 = QKV D=32 (z0 bf16 Q, z1 K,
// z2 V transposed (n&31)*8+(n>>5)) ; 4 = QKV D=8 (z0 bf16 Q, z1 K,
// z2 V transposed (n&7)*8+(n>>3))
template <int EPI>
__global__ __launch_bounds__(256) void mfma_gemm_kernel(
    const __hip_bfloat16* __restrict__ A, const __hip_bfloat16* __restrict__ WT,
    const float* __restrict__ bias, const float* __restrict__ rsc,
    float* __restrict__ outF, __hip_bfloat16* __restrict__ outB,
    int M, int K, int N) {
  const int tid = threadIdx.x, w = tid >> 6, lane = tid & 63;
  int z = 0;
  const __hip_bfloat16* Wz = WT;
  const float* bz = bias;
  if (EPI >= 2) {
    z = blockIdx.z;
    Wz = WT + (size_t)z * K * N;
    bz = bias + (size_t)z * N;
  }
  const int row0 = blockIdx.x * 16;
  const int col0 = blockIdx.y * 64 + w * 16;
  if (col0 >= N) return;
  const int r = lane & 15, kb = lane >> 4;
  f32x4_t acc = {0.f, 0.f, 0.f, 0.f};
  const __hip_bfloat16* ap = A + (size_t)(row0 + r) * K + kb * 8;
  const __hip_bfloat16* bp = Wz + (size_t)(col0 + r) * K + kb * 8;
  for (int k0 = 0; k0 < K; k0 += 32) {
    bf16x8_t av = *(const bf16x8_t*)(ap + k0);
    bf16x8_t bv = *(const bf16x8_t*)(bp + k0);
    acc = __builtin_amdgcn_mfma_f32_16x16x32_bf16(av, bv, acc, 0, 0, 0);
  }
  const int n = col0 + r;
#pragma unroll
  for (int j = 0; j < 4; ++j) {
    const int m = row0 + kb * 4 + j;
    float v = acc[j];
    if (EPI == 0) {
      v += bias[n];
      outB[(size_t)m * N + n] = __float2bfloat16(fmaxf(v, 0.f));
    } else if (EPI == 1) {
      v *= rsc[m];
      outB[(size_t)m * N + n] = __float2bfloat16(v);
    } else if (EPI == 2) {
      v += bz[n];
      if (z == 0)
        outF[(size_t)m * N + n] = v;
      else
        outB[(size_t)m * 2 * N + (size_t)(z - 1) * N + n] = __float2bfloat16(v);
    } else if (EPI == 3) {
      v += bz[n];
      if (z == 0)
        ((__hip_bfloat16*)outF)[(size_t)m * N + n] = __float2bfloat16(v);
      else if (z == 1)
        outB[(size_t)m * 2 * N + n] = __float2bfloat16(v);
      else
        outB[(size_t)m * 2 * N + N + (size_t)(n & 31) * 8 + (n >> 5)] = __float2bfloat16(v);
    } else {
      v += bz[n];
      if (z == 0)
        ((__hip_bfloat16*)outF)[(size_t)m * N + n] = __float2bfloat16(v);
      else if (z == 1)
        outB[(size_t)m * 2 * N + n] = __float2bfloat16(v);
      else
        outB[(size_t)m * 2 * N + N + (size_t)(n & 7) * 8 + (n >> 3)] = __float2bfloat16(v);
    }
  }
}

// ---------------- f32 fold GEMMs (one-time weight prep) ----------------
template <bool BIAS>
__global__ void gemm3_kernel(const float* __restrict__ A, const float* __restrict__ W0,
                             const float* __restrict__ W1, const float* __restrict__ W2,
                             const float* __restrict__ b0, const float* __restrict__ b1,
                             const float* __restrict__ b2, float* __restrict__ C0,
                             float* __restrict__ C1, float* __restrict__ C2,
                             int M, int K, int N) {
  const int z = blockIdx.z;
  const float* W = (z == 0) ? W0 : (z == 1) ? W1 : W2;
  const float* bias = (z == 0) ? b0 : (z == 1) ? b1 : b2;
  float* C = (z == 0) ? C0 : (z == 1) ? C1 : C2;
  __shared__ float As[16][64];
  __shared__ float Bs[16][64];
  const int tx = threadIdx.x;
  const int m0 = blockIdx.x * 64, n0 = blockIdx.y * 64;
  const int tm = (tx & 15) * 4, tn = (tx >> 4) * 4;
  float acc[4][4] = {};
  for (int k0 = 0; k0 < K; k0 += 16) {
    {
      int m = tx >> 2, kq = (tx & 3) * 4;
      float4 av = make_float4(0.f, 0.f, 0.f, 0.f);
      if (m0 + m < M) av = *(const float4*)(A + (size_t)(m0 + m) * K + (k0 + kq));
      As[kq + 0][m] = av.x; As[kq + 1][m] = av.y;
      As[kq + 2][m] = av.z; As[kq + 3][m] = av.w;
      int kk = tx >> 4, nq = (tx & 15) * 4;
      *(float4*)&Bs[kk][nq] = *(const float4*)(W + (size_t)(k0 + kk) * N + (n0 + nq));
    }
    __syncthreads();
#pragma unroll
    for (int k = 0; k < 16; ++k) {
      float4 a4 = *(const float4*)&As[k][tm];
      float4 b4 = *(const float4*)&Bs[k][tn];
      float av[4] = {a4.x, a4.y, a4.z, a4.w};
      float bv[4] = {b4.x, b4.y, b4.z, b4.w};
#pragma unroll
      for (int i = 0; i < 4; ++i)
#pragma unroll
        for (int j = 0; j < 4; ++j) acc[i][j] += av[i] * bv[j];
    }
    __syncthreads();
  }
#pragma unroll
  for (int i = 0; i < 4; ++i) {
    int m = m0 + tm + i;
    if (m >= M) continue;
#pragma unroll
    for (int j = 0; j < 4; ++j) {
      float v = acc[i][j];
      int n = n0 + tn + j;
      if (BIAS) v += bias[n];
      C[(size_t)m * N + n] = v;
    }
  }
}

// Wf6[z=3l+j] = cw_lin_w[l] @ {q,k,v}w[l]   (grid 4x4x6)
__global__ void gemm_fold6_kernel(const float* __restrict__ lin_w, const float* __restrict__ qw,
                                  const float* __restrict__ kw, const float* __restrict__ vw,
                                  float* __restrict__ Wf) {
  const int z = blockIdx.z, l = z / 3, j = z % 3;
  const float* A = lin_w + (size_t)l * 65536;
  const float* W = ((j == 0) ? qw : (j == 1) ? kw : vw) + (size_t)l * 65536;
  float* C = Wf + (size_t)z * 65536;
  __shared__ float As[16][64];
  __shared__ float Bs[16][64];
  const int tx = threadIdx.x;
  const int m0 = blockIdx.x * 64, n0 = blockIdx.y * 64;
  const int tm = (tx & 15) * 4, tn = (tx >> 4) * 4;
  float acc[4][4] = {};
  for (int k0 = 0; k0 < 256; k0 += 16) {
    {
      int m = tx >> 2, kq = (tx & 3) * 4;
      float4 av = *(const float4*)(A + (size_t)(m0 + m) * 256 + (k0 + kq));
      As[kq + 0][m] = av.x; As[kq + 1][m] = av.y;
      As[kq + 2][m] = av.z; As[kq + 3][m] = av.w;
      int kk = tx >> 4, nq = (tx & 15) * 4;
      *(float4*)&Bs[kk][nq] = *(const float4*)(W + (size_t)(k0 + kk) * 256 + (n0 + nq));
    }
    __syncthreads();
#pragma unroll
    for (int k = 0; k < 16; ++k) {
      float4 a4 = *(const float4*)&As[k][tm];
      float4 b4 = *(const float4*)&Bs[k][tn];
      float av[4] = {a4.x, a4.y, a4.z, a4.w};
      float bv[4] = {b4.x, b4.y, b4.z, b4.w};
#pragma unroll
      for (int i = 0; i < 4; ++i)
#pragma unroll
        for (int j2 = 0; j2 < 4; ++j2) acc[i][j2] += av[i] * bv[j2];
    }
    __syncthreads();
  }
#pragma unroll
  for (int i = 0; i < 4; ++i)
#pragma unroll
    for (int j2 = 0; j2 < 4; ++j2)
      C[(size_t)(m0 + tm + i) * 256 + (n0 + tn + j2)] = acc[i][j2];
}

__global__ void bias_fold6_kernel(const float* __restrict__ lin_b, const float* __restrict__ qw,
                                  const float* __restrict__ kw, const float* __restrict__ vw,
                                  const float* __restrict__ qb, const float* __restrict__ kb,
                                  const float* __restrict__ vb, float* __restrict__ bf) {
  const int z = blockIdx.x, l = z / 3, j = z % 3, c = threadIdx.x;
  const float* W = ((j == 0) ? qw : (j == 1) ? kw : vw) + (size_t)l * 65536;
  const float* b = ((j == 0) ? qb : (j == 1) ? kb : vb) + l * 256;
  const float* lb = lin_b + l * 256;
  float acc = b[c];
  for (int k = 0; k < 256; ++k) acc += lb[k] * W[k * 256 + c];
  bf[z * 256 + c] = acc;
}

__global__ void bias_fold3_kernel(const float* __restrict__ lin_b, const float* __restrict__ qw,
                                  const float* __restrict__ kw, const float* __restrict__ vw,
                                  const float* __restrict__ qb, const float* __restrict__ kb,
                                  const float* __restrict__ vb, float* __restrict__ bf) {
  const int j = blockIdx.x, c = threadIdx.x;
  const float* W = (j == 0) ? qw : (j == 1) ? kw : vw;
  const float* b = (j == 0) ? qb : (j == 1) ? kb : vb;
  float acc = b[c];
  for (int k = 0; k < 64; ++k) acc += lin_b[k] * W[k * 64 + c];
  bf[j * 64 + c] = acc;
}

// ---------------- CustomConv D=32 — full MFMA path --------------------------
__global__ __launch_bounds__(256) void conv_mfma_kernel(
    const __hip_bfloat16* __restrict__ Qn, const __hip_bfloat16* __restrict__ KV,
    const int* __restrict__ rowptr, const int* __restrict__ adj,
    const float* __restrict__ abias, __hip_bfloat16* __restrict__ Xout,
    float inv_sqrt_d) {
  __shared__ __align__(16) unsigned short sKV[4][2048];  // 4 edges x 512 halfs
  __shared__ __align__(16) unsigned short sP[4][640];    // 16 rows x 40 halfs
  __shared__ float sR[4][256];
  const int tid = threadIdx.x, w = tid >> 6, lane = tid & 63;
  const int n = blockIdx.x;
  const int c = lane & 15, kb = lane >> 4;

  const bf16x8_t qf = *(const bf16x8_t*)(Qn + (size_t)n * 256 + (size_t)(c & 7) * 32 + kb * 8);
  const float bh = abias[c & 7];

  unsigned short* myKV = sKV[w];
  unsigned short* myP = sP[w];
  f32x4_t acc0 = {0.f, 0.f, 0.f, 0.f};
  f32x4_t acc1 = {0.f, 0.f, 0.f, 0.f};
  const f32x4_t z4 = {0.f, 0.f, 0.f, 0.f};

  const int s0 = rowptr[n], t0 = rowptr[n + 1];
  auto ld = [&](int idx) -> uint4 {
    if (idx < t0) return *(const uint4*)(KV + (size_t)adj[idx] * 512 + (lane << 3));
    return make_uint4(0u, 0u, 0u, 0u);
  };
  int i = s0 + w * 4;
  uint4 kv0, kv1, kv2, kv3;
  if (i < t0) {
    kv0 = ld(i); kv1 = ld(i + 1); kv2 = ld(i + 2); kv3 = ld(i + 3);
  }
  for (; i < t0; i += 16) {
    *(uint4*)(myKV + 0 + (lane << 3)) = kv0;
    *(uint4*)(myKV + 512 + (lane << 3)) = kv1;
    *(uint4*)(myKV + 1024 + (lane << 3)) = kv2;
    *(uint4*)(myKV + 1536 + (lane << 3)) = kv3;
    const int i2 = i + 16;
    if (i2 < t0) {
      kv0 = ld(i2); kv1 = ld(i2 + 1); kv2 = ld(i2 + 2); kv3 = ld(i2 + 3);
    }
    __builtin_amdgcn_wave_barrier();
    const int aoff = (c >> 3) * 512 + (c & 7) * 32 + kb * 8;
    bf16x8_t a0 = *(const bf16x8_t*)(myKV + aoff);
    bf16x8_t a1 = *(const bf16x8_t*)(myKV + 1024 + aoff);
    f32x4_t S0 = __builtin_amdgcn_mfma_f32_16x16x32_bf16(a0, qf, z4, 0, 0, 0);
    f32x4_t S1 = __builtin_amdgcn_mfma_f32_16x16x32_bf16(a1, qf, z4, 0, 0, 0);
    float p0[4], p1[4];
    {
      float sv[4];
#pragma unroll
      for (int j = 0; j < 4; ++j) sv[j] = S0[j] * inv_sqrt_d + bh;
      float m = fmaxf(fmaxf(sv[0], sv[1]), fmaxf(sv[2], sv[3]));
      m = fmaxf(m, __shfl_xor(m, 16));
      float sum = 0.f;
#pragma unroll
      for (int j = 0; j < 4; ++j) { p0[j] = __expf(sv[j] - m); sum += p0[j]; }
      sum += __shfl_xor(sum, 16);
      float rs = 1.f / sum;
#pragma unroll
      for (int j = 0; j < 4; ++j) p0[j] *= rs;
    }
    {
      float sv[4];
#pragma unroll
      for (int j = 0; j < 4; ++j) sv[j] = S1[j] * inv_sqrt_d + bh;
      float m = fmaxf(fmaxf(sv[0], sv[1]), fmaxf(sv[2], sv[3]));
      m = fmaxf(m, __shfl_xor(m, 16));
      float sum = 0.f;
#pragma unroll
      for (int j = 0; j < 4; ++j) { p1[j] = __expf(sv[j] - m); sum += p1[j]; }
      sum += __shfl_xor(sum, 16);
      float rs = 1.f / sum;
#pragma unroll
      for (int j = 0; j < 4; ++j) p1[j] *= rs;
    }
    *(uint32_t*)(myP + c * 40 + kb * 4) = pk_bf16(p0[0], p0[1]);
    *(uint32_t*)(myP + c * 40 + kb * 4 + 2) = pk_bf16(p0[2], p0[3]);
    *(uint32_t*)(myP + c * 40 + 16 + kb * 4) = pk_bf16(p1[0], p1[1]);
    *(uint32_t*)(myP + c * 40 + 16 + kb * 4 + 2) = pk_bf16(p1[2], p1[3]);
    __builtin_amdgcn_wave_barrier();
    bf16x8_t pa = *(const bf16x8_t*)(myP + c * 40 + kb * 8);
    bf16x8_t vb0 = *(const bf16x8_t*)(myKV + kb * 512 + 256 + c * 8);
    bf16x8_t vb1 = *(const bf16x8_t*)(myKV + kb * 512 + 256 + (c + 16) * 8);
    acc0 = __builtin_amdgcn_mfma_f32_16x16x32_bf16(pa, vb0, acc0, 0, 0, 0);
    acc1 = __builtin_amdgcn_mfma_f32_16x16x32_bf16(pa, vb1, acc1, 0, 0, 0);
    __builtin_amdgcn_wave_barrier();
  }
  if (kb < 2) {
#pragma unroll
    for (int j = 0; j < 4; ++j) {
      int h = kb * 4 + j;
      sR[w][h * 32 + c] = acc0[j];
      sR[w][h * 32 + 16 + c] = acc1[j];
    }
  }
  __syncthreads();
  for (int cc = tid; cc < 256; cc += 256) {
    float v = sR[0][cc] + sR[1][cc] + sR[2][cc] + sR[3][cc];
    Xout[(size_t)n * 256 + cc] = __float2bfloat16(fmaxf(v, 0.f));
  }
}

// ---------------- CustomConv D=8 (conv3) — MFMA path ------------------------
// 4 edges per wave iter. KV row per node: [K 64 halfs (g*8+d)][Vt 64 (d*8+g)].
// LDS edge stride 136 halfs (pad 8). QK^T: A rows = 2 edges x 8 g, k = d
// (kb==0 lanes only, zero-padded to 32); B = Q^T (kb==0). Softmax = 4 local +
// shfl_xor(16). PV: one mfma, k = 32 = (4 edges x 8 g) fully used; B = Vt.
__global__ __launch_bounds__(256) void conv3_mfma_kernel(
    const __hip_bfloat16* __restrict__ Qn, const __hip_bfloat16* __restrict__ KV,
    const int* __restrict__ rowptr, const int* __restrict__ adj,
    const float* __restrict__ abias, float* __restrict__ Xout, float inv_sqrt_d) {
  __shared__ __align__(16) unsigned short sKV[4][544];  // 4 edges x 136 halfs
  __shared__ __align__(16) unsigned short sP[4][320];   // 8 rows x 40 halfs
  __shared__ float sR[4][64];
  const int tid = threadIdx.x, w = tid >> 6, lane = tid & 63;
  const int n = blockIdx.x;
  const int c = lane & 15, kb = lane >> 4;

  bf16x8_t qf = {};
  if (kb == 0) qf = *(const bf16x8_t*)(Qn + (size_t)n * 64 + (size_t)(c & 7) * 8);
  const float bh = abias[c & 7];

  unsigned short* myKV = sKV[w];
  unsigned short* myP = sP[w];
  f32x4_t acc = {0.f, 0.f, 0.f, 0.f};
  const f32x4_t z4 = {0.f, 0.f, 0.f, 0.f};

  const int s0 = rowptr[n], t0 = rowptr[n + 1];
  auto ld = [&](int idx) -> uint4 {
    if (idx < t0) return *(const uint4*)(KV + (size_t)adj[idx] * 128 + (c << 3));
    return make_uint4(0u, 0u, 0u, 0u);
  };
  int i = s0 + w * 4;
  uint4 kvst = make_uint4(0u, 0u, 0u, 0u);
  if (i < t0) kvst = ld(i + kb);  // lane's edge = i + kb
  for (; i < t0; i += 16) {
    *(uint4*)(myKV + kb * 136 + (c << 3)) = kvst;
    kvst = ld(i + 16 + kb);
    __builtin_amdgcn_wave_barrier();
    // QK^T: tile0 edges 0,1 ; tile1 edges 2,3 ; k valid only for kb==0
    bf16x8_t a0 = {}, a1 = {};
    if (kb == 0) {
      a0 = *(const bf16x8_t*)(myKV + (c >> 3) * 136 + (c & 7) * 8);
      a1 = *(const bf16x8_t*)(myKV + (2 + (c >> 3)) * 136 + (c & 7) * 8);
    }
    f32x4_t S0 = __builtin_amdgcn_mfma_f32_16x16x32_bf16(a0, qf, z4, 0, 0, 0);
    f32x4_t S1 = __builtin_amdgcn_mfma_f32_16x16x32_bf16(a1, qf, z4, 0, 0, 0);
    // softmax over g: rows kb*4+j = (e=kb>>1, g=(kb&1)*4+j); partner xor 16
    float p0[4], p1[4];
    {
      float sv[4];
#pragma unroll
      for (int j = 0; j < 4; ++j) sv[j] = S0[j] * inv_sqrt_d + bh;
      float m = fmaxf(fmaxf(sv[0], sv[1]), fmaxf(sv[2], sv[3]));
      m = fmaxf(m, __shfl_xor(m, 16));
      float sum = 0.f;
#pragma unroll
      for (int j = 0; j < 4; ++j) { p0[j] = __expf(sv[j] - m); sum += p0[j]; }
      sum += __shfl_xor(sum, 16);
      float rs = 1.f / sum;
#pragma unroll
      for (int j = 0; j < 4; ++j) p0[j] *= rs;
    }
    {
      float sv[4];
#pragma unroll
      for (int j = 0; j < 4; ++j) sv[j] = S1[j] * inv_sqrt_d + bh;
      float m = fmaxf(fmaxf(sv[0], sv[1]), fmaxf(sv[2], sv[3]));
      m = fmaxf(m, __shfl_xor(m, 16));
      float sum = 0.f;
#pragma unroll
      for (int j = 0; j < 4; ++j) { p1[j] = __expf(sv[j] - m); sum += p1[j]; }
      sum += __shfl_xor(sum, 16);
      float rs = 1.f / sum;
#pragma unroll
      for (int j = 0; j < 4; ++j) p1[j] *= rs;
    }
    // P[h=c][k=e*8+g] (c<8; cols 8-15 were head duplicates)
    if (c < 8) {
      const int k0 = (kb >> 1) * 8 + (kb & 1) * 4;
      *(uint32_t*)(myP + c * 40 + k0) = pk_bf16(p0[0], p0[1]);
      *(uint32_t*)(myP + c * 40 + k0 + 2) = pk_bf16(p0[2], p0[3]);
      *(uint32_t*)(myP + c * 40 + 16 + k0) = pk_bf16(p1[0], p1[1]);
      *(uint32_t*)(myP + c * 40 + 16 + k0 + 2) = pk_bf16(p1[2], p1[3]);
    }
    __builtin_amdgcn_wave_barrier();
    // PV: A = P[row=h][k=(e,g)] ; B[k=kb*8+j][col=d=c] = Vt_{e=kb}[d=c][g=j]
    bf16x8_t pa = *(const bf16x8_t*)(myP + (c & 7) * 40 + kb * 8);
    bf16x8_t vb = {};
    if (c < 8) vb = *(const bf16x8_t*)(myKV + kb * 136 + 64 + c * 8);
    acc = __builtin_amdgcn_mfma_f32_16x16x32_bf16(pa, vb, acc, 0, 0, 0);
    __builtin_amdgcn_wave_barrier();
  }
  if (kb < 2 && c < 8) {
#pragma unroll
    for (int j = 0; j < 4; ++j) sR[w][(kb * 4 + j) * 8 + c] = acc[j];
  }
  __syncthreads();
  if (tid < 64) {
    float v = sR[0][tid] + sR[1][tid] + sR[2][tid] + sR[3][tid];
    Xout[(size_t)n * 64 + tid] = fmaxf(v, 0.f);
  }
}

// ---------------- GCN propagate via dst-CSR gather, bf16 rows ---------------
template <int C, bool BIAS, bool RELU, bool OBF>
__global__ __launch_bounds__(256) void gcn_gather5_kernel(
    const __hip_bfloat16* __restrict__ Hd, const int* __restrict__ rowptr,
    const int* __restrict__ adj, const float* __restrict__ dis,
    const float* __restrict__ bias, void* __restrict__ O, int Nn) {
  constexpr int EPL = C / 64;  // 4, 2, 1
  __shared__ float sR[4][C];
  const int tid = threadIdx.x, w = tid >> 6, lane = tid & 63;
  const int n = blockIdx.x;
  float acc[EPL] = {};
  const int s = rowptr[n], t = rowptr[n + 1];
  int i = s + w;
  int vs = (i < t) ? adj[i] : 0;
  if constexpr (EPL == 4) {
    uint2 u = (i < t) ? *(const uint2*)(Hd + (size_t)vs * C + lane * 4) : make_uint2(0u, 0u);
    while (i < t) {
      const int i2 = i + 4;
      const int vs2 = (i2 < t) ? adj[i2] : 0;
      uint2 un = (i2 < t) ? *(const uint2*)(Hd + (size_t)vs2 * C + lane * 4) : make_uint2(0u, 0u);
      acc[0] += bf16lo(u.x); acc[1] += bf16hi(u.x);
      acc[2] += bf16lo(u.y); acc[3] += bf16hi(u.y);
      u = un; i = i2; vs = vs2;
    }
  } else if constexpr (EPL == 2) {
    uint32_t u = (i < t) ? *(const uint32_t*)(Hd + (size_t)vs * C + lane * 2) : 0u;
    while (i < t) {
      const int i2 = i + 4;
      const int vs2 = (i2 < t) ? adj[i2] : 0;
      uint32_t un = (i2 < t) ? *(const uint32_t*)(Hd + (size_t)vs2 * C + lane * 2) : 0u;
      acc[0] += bf16lo(u); acc[1] += bf16hi(u);
      u = un; i = i2; vs = vs2;
    }
  } else {
    unsigned short u = (i < t) ? *(const unsigned short*)(Hd + (size_t)vs * C + lane) : 0;
    while (i < t) {
      const int i2 = i + 4;
      const int vs2 = (i2 < t) ? adj[i2] : 0;
      unsigned short un = (i2 < t) ? *(const unsigned short*)(Hd + (size_t)vs2 * C + lane) : 0;
      acc[0] += bf16lo((uint32_t)u);
      u = un; i = i2; vs = vs2;
    }
  }
  if (w == 0) {
    const __hip_bfloat16* hn = Hd + (size_t)n * C;
#pragma unroll
    for (int j = 0; j < EPL; ++j)
      acc[j] += bf16lo((uint32_t)*(const unsigned short*)(hn + lane * EPL + j));
  }
#pragma unroll
  for (int j = 0; j < EPL; ++j) sR[w][lane * EPL + j] = acc[j];
  __syncthreads();
  const float dn = dis[n];
  for (int c = tid; c < C; c += 256) {
    float v = (sR[0][c] + sR[1][c] + sR[2][c] + sR[3][c]) * dn;
    if (BIAS) v += bias[c];
    if (RELU) v = fmaxf(v, 0.f);
    if (OBF)
      ((__hip_bfloat16*)O)[(size_t)n * C + c] = __float2bfloat16(v);
    else
      ((float*)O)[(size_t)n * C + c] = v;
  }
}

// ---------------- segment sums (LDS pre-reduction) ----------------
__global__ void segsum_x3_pe_kernel(const float* __restrict__ X3, const int* __restrict__ batch,
                                    float* __restrict__ sum_x3, float* __restrict__ sum_pe,
                                    float* __restrict__ cnt, int N) {
  __shared__ float lx[512], lp[512], lc[8];
  const int tid = threadIdx.x;
  for (int i = tid; i < 512; i += 256) { lx[i] = 0.f; lp[i] = 0.f; }
  if (tid < 8) lc[tid] = 0.f;
  __syncthreads();
  int i = blockIdx.x * 256 + tid;
  if (i < N * 64) {
    int n = i >> 6, c = i & 63;
    int b = batch[n];
    atomicAdd(&lx[(b << 6) + c], X3[i]);
    const float F = -0.14391156831f;  // -ln(10000)/64
    float arg = (float)n * expf(F * (float)(c & ~1));
    atomicAdd(&lp[(b << 6) + c], (c & 1) ? cosf(arg) : sinf(arg));
    if (c == 0) atomicAdd(&lc[b], 1.f);
  }
  __syncthreads();
  for (int j = tid; j < 512; j += 256) {
    if (lx[j] != 0.f) atomicAdd(&sum_x3[j], lx[j]);
    if (lp[j] != 0.f) atomicAdd(&sum_pe[j], lp[j]);
  }
  if (tid < 8 && lc[tid] != 0.f) atomicAdd(&cnt[tid], lc[tid]);
}

__global__ void segsum_vfd_kernel(const float* __restrict__ VFD, const int* __restrict__ batch,
                                  float* __restrict__ sum_vfd, float* __restrict__ cnt, int N) {
  __shared__ float lv[1024], lc[8];
  const int tid = threadIdx.x;
  for (int i = tid; i < 1024; i += 256) lv[i] = 0.f;
  if (tid < 8) lc[tid] = 0.f;
  __syncthreads();
  int i = blockIdx.x * 256 + tid;
  if (i < N * 128) {
    int n = i >> 7, c = i & 127;
    int b = batch[n];
    atomicAdd(&lv[(b << 7) + c], VFD[i]);
    if (c == 0) atomicAdd(&lc[b], 1.f);
  }
  __syncthreads();
  for (int j = tid; j < 1024; j += 256) {
    if (lv[j] != 0.f) atomicAdd(&sum_vfd[j], lv[j]);
  }
  if (tid < 8 && lc[tid] != 0.f) atomicAdd(&cnt[tid], lc[tid]);
}

// ---------------- head ----------------
__global__ void head_kernel(const float* __restrict__ sum_x3, const float* __restrict__ sum_pe,
                            const float* __restrict__ cnt_wt, const float* __restrict__ sum_vfd,
                            const float* __restrict__ cnt_df, const float* __restrict__ sft_w,
                            const float* __restrict__ sft_b, const float* __restrict__ gru_wih,
                            const float* __restrict__ gru_bih, const float* __restrict__ gru_bhh,
                            const float* __restrict__ mlp_w1, const float* __restrict__ mlp_b1,
                            const float* __restrict__ mlp_w2, const float* __restrict__ mlp_b2,
                            const float* __restrict__ mlp_w3, const float* __restrict__ mlp_b3,
                            const float* __restrict__ pred_w, const float* __restrict__ pred_b,
                            float* __restrict__ out) {
  __shared__ float sA[512];
  __shared__ float sB[1536];
  __shared__ float sC[2048];
  __shared__ float sD[1024];
  __shared__ float sE[1024];
  const int tid = threadIdx.x;
  for (int i = tid; i < 512; i += 256) {
    int b = i >> 6;
    sA[i] = sum_x3[i] / fmaxf(cnt_wt[b], 1.f);
  }
  __syncthreads();
  for (int i = tid; i < 512; i += 256) {
    int b = i >> 6, c = i & 63;
    float acc = sft_b[c];
    for (int k = 0; k < 64; ++k) acc += sA[(b << 6) + k] * sft_w[k * 64 + c];
    sB[i] = fmaxf(acc, 0.f);
  }
  __syncthreads();
  for (int i = tid; i < 1536; i += 256) {
    int b = i / 192, r = i % 192;
    float acc = gru_bih[r];
    for (int k = 0; k < 64; ++k) acc += sB[(b << 6) + k] * gru_wih[r * 64 + k];
    sC[i] = acc;
  }
  __syncthreads();
  for (int i = tid; i < 512; i += 256) {
    int b = i >> 6, c = i & 63;
    const float* gi = sC + b * 192;
    float r = 1.f / (1.f + expf(-(gi[c] + gru_bhh[c])));
    float z = 1.f / (1.f + expf(-(gi[64 + c] + gru_bhh[64 + c])));
    float ng = tanhf(gi[128 + c] + r * gru_bhh[128 + c]);
    sA[i] = (1.f - z) * ng;
  }
  __syncthreads();
  for (int i = tid; i < 2048; i += 256) {
    int b = i >> 8, c = i & 255;
    float v;
    if (c < 64)
      v = (sum_x3[(b << 6) + c] + sum_pe[(b << 6) + c]) / fmaxf(cnt_wt[b], 1.f);
    else if (c < 128)
      v = sA[(b << 6) + (c - 64)];
    else
      v = sum_vfd[(b << 7) + (c - 128)] / fmaxf(cnt_df[b], 1.f);
    sC[i] = v;
  }
  __syncthreads();
  for (int i = tid; i < 1024; i += 256) {
    int b = i >> 7, c = i & 127;
    float acc = mlp_b1[c];
    for (int k = 0; k < 256; ++k) acc += sC[(b << 8) + k] * mlp_w1[k * 128 + c];
    sD[i] = fmaxf(acc, 0.f);
  }
  __syncthreads();
  for (int i = tid; i < 1024; i += 256) {
    int b = i >> 7, c = i & 127;
    float acc = mlp_b2[c];
    for (int k = 0; k < 128; ++k) acc += sD[(b << 7) + k] * mlp_w2[k * 128 + c];
    sE[i] = fmaxf(acc, 0.f);
  }
  __syncthreads();
  for (int i = tid; i < 1024; i += 256) {
    int b = i >> 7, c = i & 127;
    float acc = mlp_b3[c];
    for (int k = 0; k < 128; ++k) acc += sE[(b << 7) + k] * mlp_w3[k * 128 + c];
    sD[i] = acc;
  }
  __syncthreads();
  for (int b = tid; b < 8; b += 256) {
    float acc = pred_b[0];
    for (int k = 0; k < 128; ++k) acc += sD[(b << 7) + k] * pred_w[k];
    out[b] = acc;
  }
}

// ---------------------------------------------------------------------------
extern "C" void kernel_launch(void* const* d_in, const int* in_sizes, int n_in,
                              void* d_out, int out_size, void* d_ws, size_t ws_size,
                              hipStream_t stream) {
  const float* x_wt = (const float*)d_in[0];
  const float* x_diff = (const float*)d_in[1];
  const int* ei_wt = (const int*)d_in[2];
  const int* ei_df = (const int*)d_in[3];
  const int* b_wt = (const int*)d_in[4];
  const int* b_df = (const int*)d_in[5];
  const float* emb_w = (const float*)d_in[6];
  const float* emb_b = (const float*)d_in[7];
  const float* cw_lin_w = (const float*)d_in[8];
  const float* cw_lin_b = (const float*)d_in[9];
  const float* cw_q_w = (const float*)d_in[10];
  const float* cw_q_b = (const float*)d_in[11];
  const float* cw_k_w = (const float*)d_in[12];
  const float* cw_k_b = (const float*)d_in[13];
  const float* cw_v_w = (const float*)d_in[14];
  const float* cw_v_b = (const float*)d_in[15];
  const float* cw_bias = (const float*)d_in[16];
  const float* c3_lin_w = (const float*)d_in[17];
  const float* c3_lin_b = (const float*)d_in[18];
  const float* c3_q_w = (const float*)d_in[19];
  const float* c3_q_b = (const float*)d_in[20];
  const float* c3_k_w = (const float*)d_in[21];
  const float* c3_k_b = (const float*)d_in[22];
  const float* c3_v_w = (const float*)d_in[23];
  const float* c3_v_b = (const float*)d_in[24];
  const float* c3_bias = (const float*)d_in[25];
  const float* sft_w = (const float*)d_in[26];
  const float* sft_b = (const float*)d_in[27];
  const float* gru_wih = (const float*)d_in[28];
  const float* gru_bih = (const float*)d_in[30];
  const float* gru_bhh = (const float*)d_in[31];
  const float* gcn_w1 = (const float*)d_in[32];
  const float* gcn_b1 = (const float*)d_in[33];
  const float* gcn_w2 = (const float*)d_in[34];
  const float* gcn_b2 = (const float*)d_in[35];
  const float* gcn_w3 = (const float*)d_in[36];
  const float* gcn_b3 = (const float*)d_in[37];
  const float* mlp_w1 = (const float*)d_in[38];
  const float* mlp_b1 = (const float*)d_in[39];
  const float* mlp_w2 = (const float*)d_in[40];
  const float* mlp_b2 = (const float*)d_in[41];
  const float* mlp_w3 = (const float*)d_in[42];
  const float* mlp_b3 = (const float*)d_in[43];
  const float* pred_w = (const float*)d_in[44];
  const float* pred_b = (const float*)d_in[45];

  const int N = in_sizes[0] / 64;  // 6000
  const int E = in_sizes[2] / 2;   // 200000
  const int* src_wt = ei_wt;
  const int* dst_wt = ei_wt + E;
  const int* src_df = ei_df;
  const int* dst_df = ei_df + E;

  // ---- workspace layout ----
  float* ws = (float*)d_ws;
  const size_t fN256 = (size_t)N * 256;
  float* X = ws;
  float* L = ws + 1 * fN256;
  float* Qb = ws + 2 * fN256;
  float* Kb = ws + 3 * fN256;
  float* Vb = ws + 4 * fN256;
  float* X3 = ws + 5 * fN256;          // (N,64) f32
  float* DIS = X3 + (size_t)N * 64;    // (N)
  float* SEG = DIS + (((size_t)N + 63) / 64) * 64;
  float* sum_x3 = SEG;                 // 512
  float* sum_pe = SEG + 512;           // 512
  float* cnt_wt = SEG + 1024;          // 8
  float* sum_vfd = SEG + 1032;         // 1024
  float* cnt_df = SEG + 2056;          // 8
  int* ip = (int*)(SEG + 2064 + 16);
  int* rp_wt = ip;                     // N+1
  int* cur_wt = rp_wt + (N + 1);       // N
  int* adj_wt = cur_wt + N;            // E
  int* rp_df = adj_wt + E;             // N+1
  int* cur_df = rp_df + (N + 1);       // N
  int* adj_df = cur_df + N;            // E
  float* Wf6 = (float*)((((uintptr_t)(adj_df + E)) + 63) & ~(uintptr_t)63);  // 6*65536 f32
  float* bf6 = Wf6 + 6 * 65536;        // 6*256
  float* Wf3 = bf6 + 6 * 256;          // 3*16384 f32
  float* bf3 = Wf3 + 3 * 16384;        // 3*64
  __hip_bfloat16* wb = (__hip_bfloat16*)((((uintptr_t)(bf3 + 3 * 64)) + 63) & ~(uintptr_t)63);
  __hip_bfloat16* WfT6 = wb;                    // 6*65536
  __hip_bfloat16* Wf3T = WfT6 + 6 * 65536;      // 3*16384
  __hip_bfloat16* embT = Wf3T + 3 * 16384;      // 256*64
  __hip_bfloat16* w1T = embT + 16384;           // 256*64
  __hip_bfloat16* w2T = w1T + 16384;            // 256*256
  __hip_bfloat16* w3T = w2T + 65536;            // 128*256

  __hip_bfloat16* Xb = (__hip_bfloat16*)X;      // N x 256
  __hip_bfloat16* xwtb = (__hip_bfloat16*)L;    // N x 64 (emb input)
  __hip_bfloat16* Qb16 = (__hip_bfloat16*)Qb;   // N x 256 / N x 64 bf16 Q
  __hip_bfloat16* KVb = (__hip_bfloat16*)Kb;    // N x 512 / N x 128
  __hip_bfloat16* Hd1 = (__hip_bfloat16*)Kb;    // GCN ping/pong
  __hip_bfloat16* G1 = (__hip_bfloat16*)Vb;
  __hip_bfloat16* Y1 = (__hip_bfloat16*)Kb;
  __hip_bfloat16* Hd2 = (__hip_bfloat16*)Vb;
  __hip_bfloat16* Y2b = (__hip_bfloat16*)Kb;
  __hip_bfloat16* Hd3 = (__hip_bfloat16*)Vb;
  float* VFD = L;

  const int TB = 256;

  // ---- weight folds (f32) + transposes to bf16 WT[n][k] ----
  gemm_fold6_kernel<<<dim3(4, 4, 6), TB, 0, stream>>>(cw_lin_w, cw_q_w, cw_k_w, cw_v_w, Wf6);
  bias_fold6_kernel<<<6, TB, 0, stream>>>(cw_lin_b, cw_q_w, cw_k_w, cw_v_w, cw_q_b, cw_k_b,
                                          cw_v_b, bf6);
  gemm3_kernel<false><<<dim3(4, 1, 3), TB, 0, stream>>>(
      c3_lin_w, c3_q_w, c3_k_w, c3_v_w, nullptr, nullptr, nullptr,
      Wf3, Wf3 + 16384, Wf3 + 32768, 256, 64, 64);
  bias_fold3_kernel<<<3, 64, 0, stream>>>(c3_lin_b, c3_q_w, c3_k_w, c3_v_w, c3_q_b, c3_k_b,
                                          c3_v_b, bf3);
  transpose_bf16_kernel<<<dim3(cdiv_h(65536, TB), 1, 6), TB, 0, stream>>>(Wf6, WfT6, 256, 256);
  transpose_bf16_kernel<<<dim3(cdiv_h(16384, TB), 1, 3), TB, 0, stream>>>(Wf3, Wf3T, 256, 64);
  transpose_bf16_kernel<<<dim3(cdiv_h(16384, TB), 1, 1), TB, 0, stream>>>(emb_w, embT, 64, 256);
  transpose_bf16_kernel<<<dim3(cdiv_h(16384, TB), 1, 1), TB, 0, stream>>>(gcn_w1, w1T, 64, 256);
  transpose_bf16_kernel<<<dim3(cdiv_h(65536, TB), 1, 1), TB, 0, stream>>>(gcn_w2, w2T, 256, 256);
  transpose_bf16_kernel<<<dim3(cdiv_h(32768, TB), 1, 1), TB, 0, stream>>>(gcn_w3, w3T, 256, 128);

  // ---- CSR build (both graphs); reuse cur_* as temporary deg ----
  fill_i_kernel<<<32, TB, 0, stream>>>(cur_wt, 0, N);
  fill_i_kernel<<<32, TB, 0, stream>>>(cur_df, 0, N);
  hist_kernel<<<cdiv_h(E, TB), TB, 0, stream>>>(dst_wt, cur_wt, E);
  hist_kernel<<<cdiv_h(E, TB), TB, 0, stream>>>(dst_df, cur_df, E);
  scan_kernel<<<1, 1024, 0, stream>>>(cur_wt, rp_wt, cur_wt, N);
  scan_kernel<<<1, 1024, 0, stream>>>(cur_df, rp_df, cur_df, N);
  fill_adj_kernel<<<cdiv_h(E, TB), TB, 0, stream>>>(src_wt, dst_wt, cur_wt, adj_wt, E);
  fill_adj_kernel<<<cdiv_h(E, TB), TB, 0, stream>>>(src_df, dst_df, cur_df, adj_df, E);
  dis_kernel<<<cdiv_h(N, TB), TB, 0, stream>>>(rp_df, DIS, N);

  const int MT = N / 16;  // 375 row-tiles
  // ---- WT branch ----
  f2b_kernel<<<cdiv_h(N * 64, TB), TB, 0, stream>>>(x_wt, xwtb, N * 64);
  mfma_gemm_kernel<0><<<dim3(MT, 4), TB, 0, stream>>>(xwtb, embT, emb_b, nullptr, nullptr,
                                                      Xb, N, 64, 256);
  const float isd32 = 0.17677669529663687f;  // 1/sqrt(32)
  const float isd8 = 0.35355339059327373f;   // 1/sqrt(8)
  for (int l = 0; l < 2; ++l) {
    mfma_gemm_kernel<3><<<dim3(MT, 4, 3), TB, 0, stream>>>(
        Xb, WfT6 + (size_t)l * 3 * 65536, bf6 + l * 768, nullptr, (float*)Qb16, KVb,
        N, 256, 256);
    conv_mfma_kernel<<<N, TB, 0, stream>>>(Qb16, KVb, rp_wt, adj_wt, cw_bias + l * 8,
                                           Xb, isd32);
  }
  // conv3 (256 -> 64), lin folded into QKV (bf16 Q + K|Vt interleaved)
  mfma_gemm_kernel<4><<<dim3(MT, 1, 3), TB, 0, stream>>>(Xb, Wf3T, bf3, nullptr,
                                                         (float*)Qb16, KVb, N, 256, 64);
  conv3_mfma_kernel<<<N, TB, 0, stream>>>(Qb16, KVb, rp_wt, adj_wt, c3_bias, X3, isd8);

  fill_f_kernel<<<8, TB, 0, stream>>>(SEG, 0.f, 2064);
  segsum_x3_pe_kernel<<<cdiv_h(N * 64, TB), TB, 0, stream>>>(X3, b_wt, sum_x3, sum_pe,
                                                             cnt_wt, N);

  // ---- diff branch (GCN); dis[src] folded into bf16 rows ----
  xd_scale_bf16_kernel<<<cdiv_h(N * 64, TB), TB, 0, stream>>>(x_diff, DIS, Hd1, N * 64);
  gcn_gather5_kernel<64, false, false, true><<<N, TB, 0, stream>>>(Hd1, rp_df, adj_df, DIS,
                                                                   nullptr, G1, N);
  mfma_gemm_kernel<0><<<dim3(MT, 4), TB, 0, stream>>>(G1, w1T, gcn_b1, nullptr, nullptr,
                                                      Y1, N, 64, 256);
  mfma_gemm_kernel<1><<<dim3(MT, 4), TB, 0, stream>>>(Y1, w2T, nullptr, DIS, nullptr,
                                                      Hd2, N, 256, 256);
  gcn_gather5_kernel<256, true, true, true><<<N, TB, 0, stream>>>(Hd2, rp_df, adj_df, DIS,
                                                                  gcn_b2, Y2b, N);
  mfma_gemm_kernel<1><<<dim3(MT, 2), TB, 0, stream>>>(Y2b, w3T, nullptr, DIS, nullptr,
                                                      Hd3, N, 256, 128);
  gcn_gather5_kernel<128, true, false, false><<<N, TB, 0, stream>>>(Hd3, rp_df, adj_df, DIS,
                                                                    gcn_b3, VFD, N);
  segsum_vfd_kernel<<<cdiv_h(N * 128, TB), TB, 0, stream>>>(VFD, b_df, sum_vfd, cnt_df, N);

  // ---- head ----
  head_kernel<<<1, TB, 0, stream>>>(sum_x3, sum_pe, cnt_wt, sum_vfd, cnt_df, sft_w, sft_b,
                                    gru_wih, gru_bih, gru_bhh, mlp_w1, mlp_b1, mlp_w2,
                                    mlp_b2, mlp_w3, mlp_b3, pred_w, pred_b, (float*)d_out);
}

// Round 10
// 464.112 us; speedup vs baseline: 6.3313x; 1.0638x over previous
//
#include <hip/hip_runtime.h>
#include <hip/hip_bf16.h>

// ---------------------------------------------------------------------------
// ProteinGraphConv (3x CustomConv edge-attention) + GCN diff branch + GRU/MLP
// head. Round 10: head_kernel re-tiled — 8 blocks (one per batch), dot
// products K-split across threads with LDS combine (serial depth ~2.5k -> ~350
// MACs/thread). Everything else unchanged from Round 9.
// N=6000, E=200000, HID=256, GH=64, H=8, B=8.
// ---------------------------------------------------------------------------

static inline int cdiv_h(int a, int b) { return (a + b - 1) / b; }

typedef __attribute__((ext_vector_type(8))) short bf16x8_t;
typedef __attribute__((ext_vector_type(4))) float f32x4_t;

__device__ __forceinline__ float bf16lo(uint32_t w) { return __uint_as_float(w << 16); }
__device__ __forceinline__ float bf16hi(uint32_t w) { return __uint_as_float(w & 0xffff0000u); }
__device__ __forceinline__ unsigned short f2bu(float f) {
  __hip_bfloat16 h = __float2bfloat16(f);
  return *reinterpret_cast<unsigned short*>(&h);
}
__device__ __forceinline__ uint32_t pk_bf16(float a, float b) {
  return (uint32_t)f2bu(a) | ((uint32_t)f2bu(b) << 16);
}

__global__ void fill_f_kernel(float* __restrict__ p, float v, int n) {
  int stride = gridDim.x * blockDim.x;
  for (int i = blockIdx.x * blockDim.x + threadIdx.x; i < n; i += stride) p[i] = v;
}
__global__ void fill_i_kernel(int* __restrict__ p, int v, int n) {
  int stride = gridDim.x * blockDim.x;
  for (int i = blockIdx.x * blockDim.x + threadIdx.x; i < n; i += stride) p[i] = v;
}
__global__ void f2b_kernel(const float* __restrict__ in, __hip_bfloat16* __restrict__ out, int n) {
  int i = blockIdx.x * blockDim.x + threadIdx.x;
  if (i < n) out[i] = __float2bfloat16(in[i]);
}

// ---------------- CSR build ----------------
__global__ void hist_kernel(const int* __restrict__ dst, int* __restrict__ deg, int E) {
  int i = blockIdx.x * blockDim.x + threadIdx.x;
  if (i < E) atomicAdd(&deg[dst[i]], 1);
}

__global__ void scan_kernel(const int* __restrict__ deg, int* __restrict__ rowptr,
                            int* __restrict__ cursor, int N) {
  __shared__ int part[1024];
  const int t = threadIdx.x;
  const int chunk = (N + 1023) / 1024;
  const int base0 = t * chunk;
  int s = 0;
  for (int i = 0; i < chunk; ++i) {
    int idx = base0 + i;
    if (idx < N) s += deg[idx];
  }
  part[t] = s;
  __syncthreads();
  for (int off = 1; off < 1024; off <<= 1) {
    int v = (t >= off) ? part[t - off] : 0;
    __syncthreads();
    part[t] += v;
    __syncthreads();
  }
  int run = (t == 0) ? 0 : part[t - 1];
  for (int i = 0; i < chunk; ++i) {
    int idx = base0 + i;
    if (idx < N) {
      rowptr[idx] = run;
      cursor[idx] = run;
      run += deg[idx];
    }
  }
  if (t == 1023) rowptr[N] = part[1023];
}

__global__ void fill_adj_kernel(const int* __restrict__ src, const int* __restrict__ dst,
                                int* __restrict__ cursor, int* __restrict__ adj, int E) {
  int i = blockIdx.x * blockDim.x + threadIdx.x;
  if (i < E) {
    int p = atomicAdd(&cursor[dst[i]], 1);
    adj[p] = src[i];
  }
}

__global__ void dis_kernel(const int* __restrict__ rowptr, float* __restrict__ dis, int N) {
  int i = blockIdx.x * blockDim.x + threadIdx.x;
  if (i < N) dis[i] = rsqrtf((float)(rowptr[i + 1] - rowptr[i] + 1));
}

// Xd = bf16(x * dis[row])   (C = 64)
__global__ void xd_scale_bf16_kernel(const float* __restrict__ x, const float* __restrict__ dis,
                                     __hip_bfloat16* __restrict__ out, int n) {
  int i = blockIdx.x * blockDim.x + threadIdx.x;
  if (i < n) out[i] = __float2bfloat16(x[i] * dis[i >> 6]);
}

// WT[z][n][k] = bf16(W[z][k][n])
__global__ void transpose_bf16_kernel(const float* __restrict__ W,
                                      __hip_bfloat16* __restrict__ WT, int K, int N) {
  const size_t zoff = (size_t)blockIdx.z * K * N;
  int idx = blockIdx.x * blockDim.x + threadIdx.x;
  if (idx < K * N) {
    int k = idx / N, n = idx % N;
    WT[zoff + (size_t)n * K + k] = __float2bfloat16(W[zoff + idx]);
  }
}

// ---------------- MFMA GEMM: C = A(bf16 MxK) @ WT(bf16 [N][K])^T ------------
// EPI: 0 = +bias, relu -> bf16 ; 1 = *rsc[m] -> bf16 ; 2 = QKV (z0 f32 Q,
// z1/2 KV interleaved bf16, stride 2N) ; 3 = QKV D=32 (z0 bf16 Q, z1 K,
// z2 V transposed (n&31)*8+(n>>5)) ; 4 = QKV D=8 (z0 bf16 Q, z1 K,
// z2 V transposed (n&7)*8+(n>>3))
template <int EPI>
__global__ __launch_bounds__(256) void mfma_gemm_kernel(
    const __hip_bfloat16* __restrict__ A, const __hip_bfloat16* __restrict__ WT,
    const float* __restrict__ bias, const float* __restrict__ rsc,
    float* __restrict__ outF, __hip_bfloat16* __restrict__ outB,
    int M, int K, int N) {
  const int tid = threadIdx.x, w = tid >> 6, lane = tid & 63;
  int z = 0;
  const __hip_bfloat16* Wz = WT;
  const float* bz = bias;
  if (EPI >= 2) {
    z = blockIdx.z;
    Wz = WT + (size_t)z * K * N;
    bz = bias + (size_t)z * N;
  }
  const int row0 = blockIdx.x * 16;
  const int col0 = blockIdx.y * 64 + w * 16;
  if (col0 >= N) return;
  const int r = lane & 15, kb = lane >> 4;
  f32x4_t acc = {0.f, 0.f, 0.f, 0.f};
  const __hip_bfloat16* ap = A + (size_t)(row0 + r) * K + kb * 8;
  const __hip_bfloat16* bp = Wz + (size_t)(col0 + r) * K + kb * 8;
  for (int k0 = 0; k0 < K; k0 += 32) {
    bf16x8_t av = *(const bf16x8_t*)(ap + k0);
    bf16x8_t bv = *(const bf16x8_t*)(bp + k0);
    acc = __builtin_amdgcn_mfma_f32_16x16x32_bf16(av, bv, acc, 0, 0, 0);
  }
  const int n = col0 + r;
#pragma unroll
  for (int j = 0; j < 4; ++j) {
    const int m = row0 + kb * 4 + j;
    float v = acc[j];
    if (EPI == 0) {
      v += bias[n];
      outB[(size_t)m * N + n] = __float2bfloat16(fmaxf(v, 0.f));
    } else if (EPI == 1) {
      v *= rsc[m];
      outB[(size_t)m * N + n] = __float2bfloat16(v);
    } else if (EPI == 2) {
      v += bz[n];
      if (z == 0)
        outF[(size_t)m * N + n] = v;
      else
        outB[(size_t)m * 2 * N + (size_t)(z - 1) * N + n] = __float2bfloat16(v);
    } else if (EPI == 3) {
      v += bz[n];
      if (z == 0)
        ((__hip_bfloat16*)outF)[(size_t)m * N + n] = __float2bfloat16(v);
      else if (z == 1)
        outB[(size_t)m * 2 * N + n] = __float2bfloat16(v);
      else
        outB[(size_t)m * 2 * N + N + (size_t)(n & 31) * 8 + (n >> 5)] = __float2bfloat16(v);
    } else {
      v += bz[n];
      if (z == 0)
        ((__hip_bfloat16*)outF)[(size_t)m * N + n] = __float2bfloat16(v);
      else if (z == 1)
        outB[(size_t)m * 2 * N + n] = __float2bfloat16(v);
      else
        outB[(size_t)m * 2 * N + N + (size_t)(n & 7) * 8 + (n >> 3)] = __float2bfloat16(v);
    }
  }
}

// ---------------- f32 fold GEMMs (one-time weight prep) ----------------
template <bool BIAS>
__global__ void gemm3_kernel(const float* __restrict__ A, const float* __restrict__ W0,
                             const float* __restrict__ W1, const float* __restrict__ W2,
                             const float* __restrict__ b0, const float* __restrict__ b1,
                             const float* __restrict__ b2, float* __restrict__ C0,
                             float* __restrict__ C1, float* __restrict__ C2,
                             int M, int K, int N) {
  const int z = blockIdx.z;
  const float* W = (z == 0) ? W0 : (z == 1) ? W1 : W2;
  const float* bias = (z == 0) ? b0 : (z == 1) ? b1 : b2;
  float* C = (z == 0) ? C0 : (z == 1) ? C1 : C2;
  __shared__ float As[16][64];
  __shared__ float Bs[16][64];
  const int tx = threadIdx.x;
  const int m0 = blockIdx.x * 64, n0 = blockIdx.y * 64;
  const int tm = (tx & 15) * 4, tn = (tx >> 4) * 4;
  float acc[4][4] = {};
  for (int k0 = 0; k0 < K; k0 += 16) {
    {
      int m = tx >> 2, kq = (tx & 3) * 4;
      float4 av = make_float4(0.f, 0.f, 0.f, 0.f);
      if (m0 + m < M) av = *(const float4*)(A + (size_t)(m0 + m) * K + (k0 + kq));
      As[kq + 0][m] = av.x; As[kq + 1][m] = av.y;
      As[kq + 2][m] = av.z; As[kq + 3][m] = av.w;
      int kk = tx >> 4, nq = (tx & 15) * 4;
      *(float4*)&Bs[kk][nq] = *(const float4*)(W + (size_t)(k0 + kk) * N + (n0 + nq));
    }
    __syncthreads();
#pragma unroll
    for (int k = 0; k < 16; ++k) {
      float4 a4 = *(const float4*)&As[k][tm];
      float4 b4 = *(const float4*)&Bs[k][tn];
      float av[4] = {a4.x, a4.y, a4.z, a4.w};
      float bv[4] = {b4.x, b4.y, b4.z, b4.w};
#pragma unroll
      for (int i = 0; i < 4; ++i)
#pragma unroll
        for (int j = 0; j < 4; ++j) acc[i][j] += av[i] * bv[j];
    }
    __syncthreads();
  }
#pragma unroll
  for (int i = 0; i < 4; ++i) {
    int m = m0 + tm + i;
    if (m >= M) continue;
#pragma unroll
    for (int j = 0; j < 4; ++j) {
      float v = acc[i][j];
      int n = n0 + tn + j;
      if (BIAS) v += bias[n];
      C[(size_t)m * N + n] = v;
    }
  }
}

// Wf6[z=3l+j] = cw_lin_w[l] @ {q,k,v}w[l]   (grid 4x4x6)
__global__ void gemm_fold6_kernel(const float* __restrict__ lin_w, const float* __restrict__ qw,
                                  const float* __restrict__ kw, const float* __restrict__ vw,
                                  float* __restrict__ Wf) {
  const int z = blockIdx.z, l = z / 3, j = z % 3;
  const float* A = lin_w + (size_t)l * 65536;
  const float* W = ((j == 0) ? qw : (j == 1) ? kw : vw) + (size_t)l * 65536;
  float* C = Wf + (size_t)z * 65536;
  __shared__ float As[16][64];
  __shared__ float Bs[16][64];
  const int tx = threadIdx.x;
  const int m0 = blockIdx.x * 64, n0 = blockIdx.y * 64;
  const int tm = (tx & 15) * 4, tn = (tx >> 4) * 4;
  float acc[4][4] = {};
  for (int k0 = 0; k0 < 256; k0 += 16) {
    {
      int m = tx >> 2, kq = (tx & 3) * 4;
      float4 av = *(const float4*)(A + (size_t)(m0 + m) * 256 + (k0 + kq));
      As[kq + 0][m] = av.x; As[kq + 1][m] = av.y;
      As[kq + 2][m] = av.z; As[kq + 3][m] = av.w;
      int kk = tx >> 4, nq = (tx & 15) * 4;
      *(float4*)&Bs[kk][nq] = *(const float4*)(W + (size_t)(k0 + kk) * 256 + (n0 + nq));
    }
    __syncthreads();
#pragma unroll
    for (int k = 0; k < 16; ++k) {
      float4 a4 = *(const float4*)&As[k][tm];
      float4 b4 = *(const float4*)&Bs[k][tn];
      float av[4] = {a4.x, a4.y, a4.z, a4.w};
      float bv[4] = {b4.x, b4.y, b4.z, b4.w};
#pragma unroll
      for (int i = 0; i < 4; ++i)
#pragma unroll
        for (int j2 = 0; j2 < 4; ++j2) acc[i][j2] += av[i] * bv[j2];
    }
    __syncthreads();
  }
#pragma unroll
  for (int i = 0; i < 4; ++i)
#pragma unroll
    for (int j2 = 0; j2 < 4; ++j2)
      C[(size_t)(m0 + tm + i) * 256 + (n0 + tn + j2)] = acc[i][j2];
}

__global__ void bias_fold6_kernel(const float* __restrict__ lin_b, const float* __restrict__ qw,
                                  const float* __restrict__ kw, const float* __restrict__ vw,
                                  const float* __restrict__ qb, const float* __restrict__ kb,
                                  const float* __restrict__ vb, float* __restrict__ bf) {
  const int z = blockIdx.x, l = z / 3, j = z % 3, c = threadIdx.x;
  const float* W = ((j == 0) ? qw : (j == 1) ? kw : vw) + (size_t)l * 65536;
  const float* b = ((j == 0) ? qb : (j == 1) ? kb : vb) + l * 256;
  const float* lb = lin_b + l * 256;
  float acc = b[c];
  for (int k = 0; k < 256; ++k) acc += lb[k] * W[k * 256 + c];
  bf[z * 256 + c] = acc;
}

__global__ void bias_fold3_kernel(const float* __restrict__ lin_b, const float* __restrict__ qw,
                                  const float* __restrict__ kw, const float* __restrict__ vw,
                                  const float* __restrict__ qb, const float* __restrict__ kb,
                                  const float* __restrict__ vb, float* __restrict__ bf) {
  const int j = blockIdx.x, c = threadIdx.x;
  const float* W = (j == 0) ? qw : (j == 1) ? kw : vw;
  const float* b = (j == 0) ? qb : (j == 1) ? kb : vb;
  float acc = b[c];
  for (int k = 0; k < 64; ++k) acc += lin_b[k] * W[k * 64 + c];
  bf[j * 64 + c] = acc;
}

// ---------------- CustomConv D=32 — full MFMA path --------------------------
__global__ __launch_bounds__(256) void conv_mfma_kernel(
    const __hip_bfloat16* __restrict__ Qn, const __hip_bfloat16* __restrict__ KV,
    const int* __restrict__ rowptr, const int* __restrict__ adj,
    const float* __restrict__ abias, __hip_bfloat16* __restrict__ Xout,
    float inv_sqrt_d) {
  __shared__ __align__(16) unsigned short sKV[4][2048];  // 4 edges x 512 halfs
  __shared__ __align__(16) unsigned short sP[4][640];    // 16 rows x 40 halfs
  __shared__ float sR[4][256];
  const int tid = threadIdx.x, w = tid >> 6, lane = tid & 63;
  const int n = blockIdx.x;
  const int c = lane & 15, kb = lane >> 4;

  const bf16x8_t qf = *(const bf16x8_t*)(Qn + (size_t)n * 256 + (size_t)(c & 7) * 32 + kb * 8);
  const float bh = abias[c & 7];

  unsigned short* myKV = sKV[w];
  unsigned short* myP = sP[w];
  f32x4_t acc0 = {0.f, 0.f, 0.f, 0.f};
  f32x4_t acc1 = {0.f, 0.f, 0.f, 0.f};
  const f32x4_t z4 = {0.f, 0.f, 0.f, 0.f};

  const int s0 = rowptr[n], t0 = rowptr[n + 1];
  auto ld = [&](int idx) -> uint4 {
    if (idx < t0) return *(const uint4*)(KV + (size_t)adj[idx] * 512 + (lane << 3));
    return make_uint4(0u, 0u, 0u, 0u);
  };
  int i = s0 + w * 4;
  uint4 kv0, kv1, kv2, kv3;
  if (i < t0) {
    kv0 = ld(i); kv1 = ld(i + 1); kv2 = ld(i + 2); kv3 = ld(i + 3);
  }
  for (; i < t0; i += 16) {
    *(uint4*)(myKV + 0 + (lane << 3)) = kv0;
    *(uint4*)(myKV + 512 + (lane << 3)) = kv1;
    *(uint4*)(myKV + 1024 + (lane << 3)) = kv2;
    *(uint4*)(myKV + 1536 + (lane << 3)) = kv3;
    const int i2 = i + 16;
    if (i2 < t0) {
      kv0 = ld(i2); kv1 = ld(i2 + 1); kv2 = ld(i2 + 2); kv3 = ld(i2 + 3);
    }
    __builtin_amdgcn_wave_barrier();
    const int aoff = (c >> 3) * 512 + (c & 7) * 32 + kb * 8;
    bf16x8_t a0 = *(const bf16x8_t*)(myKV + aoff);
    bf16x8_t a1 = *(const bf16x8_t*)(myKV + 1024 + aoff);
    f32x4_t S0 = __builtin_amdgcn_mfma_f32_16x16x32_bf16(a0, qf, z4, 0, 0, 0);
    f32x4_t S1 = __builtin_amdgcn_mfma_f32_16x16x32_bf16(a1, qf, z4, 0, 0, 0);
    float p0[4], p1[4];
    {
      float sv[4];
#pragma unroll
      for (int j = 0; j < 4; ++j) sv[j] = S0[j] * inv_sqrt_d + bh;
      float m = fmaxf(fmaxf(sv[0], sv[1]), fmaxf(sv[2], sv[3]));
      m = fmaxf(m, __shfl_xor(m, 16));
      float sum = 0.f;
#pragma unroll
      for (int j = 0; j < 4; ++j) { p0[j] = __expf(sv[j] - m); sum += p0[j]; }
      sum += __shfl_xor(sum, 16);
      float rs = 1.f / sum;
#pragma unroll
      for (int j = 0; j < 4; ++j) p0[j] *= rs;
    }
    {
      float sv[4];
#pragma unroll
      for (int j = 0; j < 4; ++j) sv[j] = S1[j] * inv_sqrt_d + bh;
      float m = fmaxf(fmaxf(sv[0], sv[1]), fmaxf(sv[2], sv[3]));
      m = fmaxf(m, __shfl_xor(m, 16));
      float sum = 0.f;
#pragma unroll
      for (int j = 0; j < 4; ++j) { p1[j] = __expf(sv[j] - m); sum += p1[j]; }
      sum += __shfl_xor(sum, 16);
      float rs = 1.f / sum;
#pragma unroll
      for (int j = 0; j < 4; ++j) p1[j] *= rs;
    }
    *(uint32_t*)(myP + c * 40 + kb * 4) = pk_bf16(p0[0], p0[1]);
    *(uint32_t*)(myP + c * 40 + kb * 4 + 2) = pk_bf16(p0[2], p0[3]);
    *(uint32_t*)(myP + c * 40 + 16 + kb * 4) = pk_bf16(p1[0], p1[1]);
    *(uint32_t*)(myP + c * 40 + 16 + kb * 4 + 2) = pk_bf16(p1[2], p1[3]);
    __builtin_amdgcn_wave_barrier();
    bf16x8_t pa = *(const bf16x8_t*)(myP + c * 40 + kb * 8);
    bf16x8_t vb0 = *(const bf16x8_t*)(myKV + kb * 512 + 256 + c * 8);
    bf16x8_t vb1 = *(const bf16x8_t*)(myKV + kb * 512 + 256 + (c + 16) * 8);
    acc0 = __builtin_amdgcn_mfma_f32_16x16x32_bf16(pa, vb0, acc0, 0, 0, 0);
    acc1 = __builtin_amdgcn_mfma_f32_16x16x32_bf16(pa, vb1, acc1, 0, 0, 0);
    __builtin_amdgcn_wave_barrier();
  }
  if (kb < 2) {
#pragma unroll
    for (int j = 0; j < 4; ++j) {
      int h = kb * 4 + j;
      sR[w][h * 32 + c] = acc0[j];
      sR[w][h * 32 + 16 + c] = acc1[j];
    }
  }
  __syncthreads();
  for (int cc = tid; cc < 256; cc += 256) {
    float v = sR[0][cc] + sR[1][cc] + sR[2][cc] + sR[3][cc];
    Xout[(size_t)n * 256 + cc] = __float2bfloat16(fmaxf(v, 0.f));
  }
}

// ---------------- CustomConv D=8 (conv3) — MFMA path ------------------------
__global__ __launch_bounds__(256) void conv3_mfma_kernel(
    const __hip_bfloat16* __restrict__ Qn, const __hip_bfloat16* __restrict__ KV,
    const int* __restrict__ rowptr, const int* __restrict__ adj,
    const float* __restrict__ abias, float* __restrict__ Xout, float inv_sqrt_d) {
  __shared__ __align__(16) unsigned short sKV[4][544];  // 4 edges x 136 halfs
  __shared__ __align__(16) unsigned short sP[4][320];   // 8 rows x 40 halfs
  __shared__ float sR[4][64];
  const int tid = threadIdx.x, w = tid >> 6, lane = tid & 63;
  const int n = blockIdx.x;
  const int c = lane & 15, kb = lane >> 4;

  bf16x8_t qf = {};
  if (kb == 0) qf = *(const bf16x8_t*)(Qn + (size_t)n * 64 + (size_t)(c & 7) * 8);
  const float bh = abias[c & 7];

  unsigned short* myKV = sKV[w];
  unsigned short* myP = sP[w];
  f32x4_t acc = {0.f, 0.f, 0.f, 0.f};
  const f32x4_t z4 = {0.f, 0.f, 0.f, 0.f};

  const int s0 = rowptr[n], t0 = rowptr[n + 1];
  auto ld = [&](int idx) -> uint4 {
    if (idx < t0) return *(const uint4*)(KV + (size_t)adj[idx] * 128 + (c << 3));
    return make_uint4(0u, 0u, 0u, 0u);
  };
  int i = s0 + w * 4;
  uint4 kvst = make_uint4(0u, 0u, 0u, 0u);
  if (i < t0) kvst = ld(i + kb);
  for (; i < t0; i += 16) {
    *(uint4*)(myKV + kb * 136 + (c << 3)) = kvst;
    kvst = ld(i + 16 + kb);
    __builtin_amdgcn_wave_barrier();
    bf16x8_t a0 = {}, a1 = {};
    if (kb == 0) {
      a0 = *(const bf16x8_t*)(myKV + (c >> 3) * 136 + (c & 7) * 8);
      a1 = *(const bf16x8_t*)(myKV + (2 + (c >> 3)) * 136 + (c & 7) * 8);
    }
    f32x4_t S0 = __builtin_amdgcn_mfma_f32_16x16x32_bf16(a0, qf, z4, 0, 0, 0);
    f32x4_t S1 = __builtin_amdgcn_mfma_f32_16x16x32_bf16(a1, qf, z4, 0, 0, 0);
    float p0[4], p1[4];
    {
      float sv[4];
#pragma unroll
      for (int j = 0; j < 4; ++j) sv[j] = S0[j] * inv_sqrt_d + bh;
      float m = fmaxf(fmaxf(sv[0], sv[1]), fmaxf(sv[2], sv[3]));
      m = fmaxf(m, __shfl_xor(m, 16));
      float sum = 0.f;
#pragma unroll
      for (int j = 0; j < 4; ++j) { p0[j] = __expf(sv[j] - m); sum += p0[j]; }
      sum += __shfl_xor(sum, 16);
      float rs = 1.f / sum;
#pragma unroll
      for (int j = 0; j < 4; ++j) p0[j] *= rs;
    }
    {
      float sv[4];
#pragma unroll
      for (int j = 0; j < 4; ++j) sv[j] = S1[j] * inv_sqrt_d + bh;
      float m = fmaxf(fmaxf(sv[0], sv[1]), fmaxf(sv[2], sv[3]));
      m = fmaxf(m, __shfl_xor(m, 16));
      float sum = 0.f;
#pragma unroll
      for (int j = 0; j < 4; ++j) { p1[j] = __expf(sv[j] - m); sum += p1[j]; }
      sum += __shfl_xor(sum, 16);
      float rs = 1.f / sum;
#pragma unroll
      for (int j = 0; j < 4; ++j) p1[j] *= rs;
    }
    if (c < 8) {
      const int k0 = (kb >> 1) * 8 + (kb & 1) * 4;
      *(uint32_t*)(myP + c * 40 + k0) = pk_bf16(p0[0], p0[1]);
      *(uint32_t*)(myP + c * 40 + k0 + 2) = pk_bf16(p0[2], p0[3]);
      *(uint32_t*)(myP + c * 40 + 16 + k0) = pk_bf16(p1[0], p1[1]);
      *(uint32_t*)(myP + c * 40 + 16 + k0 + 2) = pk_bf16(p1[2], p1[3]);
    }
    __builtin_amdgcn_wave_barrier();
    bf16x8_t pa = *(const bf16x8_t*)(myP + (c & 7) * 40 + kb * 8);
    bf16x8_t vb = {};
    if (c < 8) vb = *(const bf16x8_t*)(myKV + kb * 136 + 64 + c * 8);
    acc = __builtin_amdgcn_mfma_f32_16x16x32_bf16(pa, vb, acc, 0, 0, 0);
    __builtin_amdgcn_wave_barrier();
  }
  if (kb < 2 && c < 8) {
#pragma unroll
    for (int j = 0; j < 4; ++j) sR[w][(kb * 4 + j) * 8 + c] = acc[j];
  }
  __syncthreads();
  if (tid < 64) {
    float v = sR[0][tid] + sR[1][tid] + sR[2][tid] + sR[3][tid];
    Xout[(size_t)n * 64 + tid] = fmaxf(v, 0.f);
  }
}

// ---------------- GCN propagate via dst-CSR gather, bf16 rows ---------------
template <int C, bool BIAS, bool RELU, bool OBF>
__global__ __launch_bounds__(256) void gcn_gather5_kernel(
    const __hip_bfloat16* __restrict__ Hd, const int* __restrict__ rowptr,
    const int* __restrict__ adj, const float* __restrict__ dis,
    const float* __restrict__ bias, void* __restrict__ O, int Nn) {
  constexpr int EPL = C / 64;  // 4, 2, 1
  __shared__ float sR[4][C];
  const int tid = threadIdx.x, w = tid >> 6, lane = tid & 63;
  const int n = blockIdx.x;
  float acc[EPL] = {};
  const int s = rowptr[n], t = rowptr[n + 1];
  int i = s + w;
  int vs = (i < t) ? adj[i] : 0;
  if constexpr (EPL == 4) {
    uint2 u = (i < t) ? *(const uint2*)(Hd + (size_t)vs * C + lane * 4) : make_uint2(0u, 0u);
    while (i < t) {
      const int i2 = i + 4;
      const int vs2 = (i2 < t) ? adj[i2] : 0;
      uint2 un = (i2 < t) ? *(const uint2*)(Hd + (size_t)vs2 * C + lane * 4) : make_uint2(0u, 0u);
      acc[0] += bf16lo(u.x); acc[1] += bf16hi(u.x);
      acc[2] += bf16lo(u.y); acc[3] += bf16hi(u.y);
      u = un; i = i2; vs = vs2;
    }
  } else if constexpr (EPL == 2) {
    uint32_t u = (i < t) ? *(const uint32_t*)(Hd + (size_t)vs * C + lane * 2) : 0u;
    while (i < t) {
      const int i2 = i + 4;
      const int vs2 = (i2 < t) ? adj[i2] : 0;
      uint32_t un = (i2 < t) ? *(const uint32_t*)(Hd + (size_t)vs2 * C + lane * 2) : 0u;
      acc[0] += bf16lo(u); acc[1] += bf16hi(u);
      u = un; i = i2; vs = vs2;
    }
  } else {
    unsigned short u = (i < t) ? *(const unsigned short*)(Hd + (size_t)vs * C + lane) : 0;
    while (i < t) {
      const int i2 = i + 4;
      const int vs2 = (i2 < t) ? adj[i2] : 0;
      unsigned short un = (i2 < t) ? *(const unsigned short*)(Hd + (size_t)vs2 * C + lane) : 0;
      acc[0] += bf16lo((uint32_t)u);
      u = un; i = i2; vs = vs2;
    }
  }
  if (w == 0) {
    const __hip_bfloat16* hn = Hd + (size_t)n * C;
#pragma unroll
    for (int j = 0; j < EPL; ++j)
      acc[j] += bf16lo((uint32_t)*(const unsigned short*)(hn + lane * EPL + j));
  }
#pragma unroll
  for (int j = 0; j < EPL; ++j) sR[w][lane * EPL + j] = acc[j];
  __syncthreads();
  const float dn = dis[n];
  for (int c = tid; c < C; c += 256) {
    float v = (sR[0][c] + sR[1][c] + sR[2][c] + sR[3][c]) * dn;
    if (BIAS) v += bias[c];
    if (RELU) v = fmaxf(v, 0.f);
    if (OBF)
      ((__hip_bfloat16*)O)[(size_t)n * C + c] = __float2bfloat16(v);
    else
      ((float*)O)[(size_t)n * C + c] = v;
  }
}

// ---------------- segment sums (LDS pre-reduction) ----------------
__global__ void segsum_x3_pe_kernel(const float* __restrict__ X3, const int* __restrict__ batch,
                                    float* __restrict__ sum_x3, float* __restrict__ sum_pe,
                                    float* __restrict__ cnt, int N) {
  __shared__ float lx[512], lp[512], lc[8];
  const int tid = threadIdx.x;
  for (int i = tid; i < 512; i += 256) { lx[i] = 0.f; lp[i] = 0.f; }
  if (tid < 8) lc[tid] = 0.f;
  __syncthreads();
  int i = blockIdx.x * 256 + tid;
  if (i < N * 64) {
    int n = i >> 6, c = i & 63;
    int b = batch[n];
    atomicAdd(&lx[(b << 6) + c], X3[i]);
    const float F = -0.14391156831f;  // -ln(10000)/64
    float arg = (float)n * expf(F * (float)(c & ~1));
    atomicAdd(&lp[(b << 6) + c], (c & 1) ? cosf(arg) : sinf(arg));
    if (c == 0) atomicAdd(&lc[b], 1.f);
  }
  __syncthreads();
  for (int j = tid; j < 512; j += 256) {
    if (lx[j] != 0.f) atomicAdd(&sum_x3[j], lx[j]);
    if (lp[j] != 0.f) atomicAdd(&sum_pe[j], lp[j]);
  }
  if (tid < 8 && lc[tid] != 0.f) atomicAdd(&cnt[tid], lc[tid]);
}

__global__ void segsum_vfd_kernel(const float* __restrict__ VFD, const int* __restrict__ batch,
                                  float* __restrict__ sum_vfd, float* __restrict__ cnt, int N) {
  __shared__ float lv[1024], lc[8];
  const int tid = threadIdx.x;
  for (int i = tid; i < 1024; i += 256) lv[i] = 0.f;
  if (tid < 8) lc[tid] = 0.f;
  __syncthreads();
  int i = blockIdx.x * 256 + tid;
  if (i < N * 128) {
    int n = i >> 7, c = i & 127;
    int b = batch[n];
    atomicAdd(&lv[(b << 7) + c], VFD[i]);
    if (c == 0) atomicAdd(&lc[b], 1.f);
  }
  __syncthreads();
  for (int j = tid; j < 1024; j += 256) {
    if (lv[j] != 0.f) atomicAdd(&sum_vfd[j], lv[j]);
  }
  if (tid < 8 && lc[tid] != 0.f) atomicAdd(&cnt[tid], lc[tid]);
}

// ---------------- head: 8 blocks (one per batch), K-split dot products ------
__global__ __launch_bounds__(256) void head_kernel(
    const float* __restrict__ sum_x3, const float* __restrict__ sum_pe,
    const float* __restrict__ cnt_wt, const float* __restrict__ sum_vfd,
    const float* __restrict__ cnt_df, const float* __restrict__ sft_w,
    const float* __restrict__ sft_b, const float* __restrict__ gru_wih,
    const float* __restrict__ gru_bih, const float* __restrict__ gru_bhh,
    const float* __restrict__ mlp_w1, const float* __restrict__ mlp_b1,
    const float* __restrict__ mlp_w2, const float* __restrict__ mlp_b2,
    const float* __restrict__ mlp_w3, const float* __restrict__ mlp_b3,
    const float* __restrict__ pred_w, const float* __restrict__ pred_b,
    float* __restrict__ out) {
  const int b = blockIdx.x;  // batch row
  const int tid = threadIdx.x;
  __shared__ float sf0[64], sf1[64], sfr[64];
  __shared__ float hcat[256];
  __shared__ float m1[128], m2[128], m3[128];
  __shared__ float part4[4][64];   // K-split partials (sf1)
  __shared__ float part2[2][128];  // K-split partials (m1/m2/m3)
  __shared__ float gi[192];
  __shared__ float rsum[4];

  const float cw = fmaxf(cnt_wt[b], 1.f), cd = fmaxf(cnt_df[b], 1.f);
  // sf0 = segmean(X3)
  if (tid < 64) sf0[tid] = sum_x3[(b << 6) + tid] / cw;
  __syncthreads();
  // sf1 = relu(sf0 @ sft_w + b): (c = tid&63, q = tid>>6) 16 MACs each
  {
    const int c = tid & 63, q = tid >> 6;
    float acc = 0.f;
#pragma unroll
    for (int k = q * 16; k < q * 16 + 16; ++k) acc += sf0[k] * sft_w[k * 64 + c];
    part4[q][c] = acc;
  }
  __syncthreads();
  if (tid < 64)
    sf1[tid] = fmaxf(part4[0][tid] + part4[1][tid] + part4[2][tid] + part4[3][tid] +
                         sft_b[tid], 0.f);
  __syncthreads();
  // gi = sf1 @ wih^T + bih (192 rows, 64 MACs each; rows contiguous in k)
  if (tid < 192) {
    float acc = gru_bih[tid];
    const float* wr = gru_wih + tid * 64;
#pragma unroll 8
    for (int k = 0; k < 64; ++k) acc += sf1[k] * wr[k];
    gi[tid] = acc;
  }
  __syncthreads();
  // GRU (h0=0): sfr
  if (tid < 64) {
    float r = 1.f / (1.f + __expf(-(gi[tid] + gru_bhh[tid])));
    float z = 1.f / (1.f + __expf(-(gi[64 + tid] + gru_bhh[64 + tid])));
    float ng = tanhf(gi[128 + tid] + r * gru_bhh[128 + tid]);
    sfr[tid] = (1.f - z) * ng;
  }
  __syncthreads();
  // hcat
  {
    const int c = tid;
    float v;
    if (c < 64)
      v = (sum_x3[(b << 6) + c] + sum_pe[(b << 6) + c]) / cw;
    else if (c < 128)
      v = sfr[c - 64];
    else
      v = sum_vfd[(b << 7) + (c - 128)] / cd;
    hcat[c] = v;
  }
  __syncthreads();
  // m1 = relu(hcat @ w1 + b1): (c = tid&127, h = tid>>7) 128 MACs
  {
    const int c = tid & 127, h = tid >> 7;
    float acc = 0.f;
#pragma unroll 8
    for (int k = h * 128; k < h * 128 + 128; ++k) acc += hcat[k] * mlp_w1[k * 128 + c];
    part2[h][c] = acc;
  }
  __syncthreads();
  if (tid < 128) m1[tid] = fmaxf(part2[0][tid] + part2[1][tid] + mlp_b1[tid], 0.f);
  __syncthreads();
  // m2 = relu(m1 @ w2 + b2): 64 MACs each
  {
    const int c = tid & 127, h = tid >> 7;
    float acc = 0.f;
#pragma unroll 8
    for (int k = h * 64; k < h * 64 + 64; ++k) acc += m1[k] * mlp_w2[k * 128 + c];
    part2[h][c] = acc;
  }
  __syncthreads();
  if (tid < 128) m2[tid] = fmaxf(part2[0][tid] + part2[1][tid] + mlp_b2[tid], 0.f);
  __syncthreads();
  // m3 = m2 @ w3 + b3
  {
    const int c = tid & 127, h = tid >> 7;
    float acc = 0.f;
#pragma unroll 8
    for (int k = h * 64; k < h * 64 + 64; ++k) acc += m2[k] * mlp_w3[k * 128 + c];
    part2[h][c] = acc;
  }
  __syncthreads();
  if (tid < 128) m3[tid] = part2[0][tid] + part2[1][tid] + mlp_b3[tid];
  __syncthreads();
  // out[b] = m3 . pred_w + pred_b  (128-dot: 2 waves of shfl reduce)
  if (tid < 128) {
    float p = m3[tid] * pred_w[tid];
    p += __shfl_down(p, 32);
    p += __shfl_down(p, 16);
    p += __shfl_down(p, 8);
    p += __shfl_down(p, 4);
    p += __shfl_down(p, 2);
    p += __shfl_down(p, 1);
    if ((tid & 63) == 0) rsum[tid >> 6] = p;
  }
  __syncthreads();
  if (tid == 0) out[b] = rsum[0] + rsum[1] + pred_b[0];
}

// ---------------------------------------------------------------------------
extern "C" void kernel_launch(void* const* d_in, const int* in_sizes, int n_in,
                              void* d_out, int out_size, void* d_ws, size_t ws_size,
                              hipStream_t stream) {
  const float* x_wt = (const float*)d_in[0];
  const float* x_diff = (const float*)d_in[1];
  const int* ei_wt = (const int*)d_in[2];
  const int* ei_df = (const int*)d_in[3];
  const int* b_wt = (const int*)d_in[4];
  const int* b_df = (const int*)d_in[5];
  const float* emb_w = (const float*)d_in[6];
  const float* emb_b = (const float*)d_in[7];
  const float* cw_lin_w = (const float*)d_in[8];
  const float* cw_lin_b = (const float*)d_in[9];
  const float* cw_q_w = (const float*)d_in[10];
  const float* cw_q_b = (const float*)d_in[11];
  const float* cw_k_w = (const float*)d_in[12];
  const float* cw_k_b = (const float*)d_in[13];
  const float* cw_v_w = (const float*)d_in[14];
  const float* cw_v_b = (const float*)d_in[15];
  const float* cw_bias = (const float*)d_in[16];
  const float* c3_lin_w = (const float*)d_in[17];
  const float* c3_lin_b = (const float*)d_in[18];
  const float* c3_q_w = (const float*)d_in[19];
  const float* c3_q_b = (const float*)d_in[20];
  const float* c3_k_w = (const float*)d_in[21];
  const float* c3_k_b = (const float*)d_in[22];
  const float* c3_v_w = (const float*)d_in[23];
  const float* c3_v_b = (const float*)d_in[24];
  const float* c3_bias = (const float*)d_in[25];
  const float* sft_w = (const float*)d_in[26];
  const float* sft_b = (const float*)d_in[27];
  const float* gru_wih = (const float*)d_in[28];
  const float* gru_bih = (const float*)d_in[30];
  const float* gru_bhh = (const float*)d_in[31];
  const float* gcn_w1 = (const float*)d_in[32];
  const float* gcn_b1 = (const float*)d_in[33];
  const float* gcn_w2 = (const float*)d_in[34];
  const float* gcn_b2 = (const float*)d_in[35];
  const float* gcn_w3 = (const float*)d_in[36];
  const float* gcn_b3 = (const float*)d_in[37];
  const float* mlp_w1 = (const float*)d_in[38];
  const float* mlp_b1 = (const float*)d_in[39];
  const float* mlp_w2 = (const float*)d_in[40];
  const float* mlp_b2 = (const float*)d_in[41];
  const float* mlp_w3 = (const float*)d_in[42];
  const float* mlp_b3 = (const float*)d_in[43];
  const float* pred_w = (const float*)d_in[44];
  const float* pred_b = (const float*)d_in[45];

  const int N = in_sizes[0] / 64;  // 6000
  const int E = in_sizes[2] / 2;   // 200000
  const int* src_wt = ei_wt;
  const int* dst_wt = ei_wt + E;
  const int* src_df = ei_df;
  const int* dst_df = ei_df + E;

  // ---- workspace layout ----
  float* ws = (float*)d_ws;
  const size_t fN256 = (size_t)N * 256;
  float* X = ws;
  float* L = ws + 1 * fN256;
  float* Qb = ws + 2 * fN256;
  float* Kb = ws + 3 * fN256;
  float* Vb = ws + 4 * fN256;
  float* X3 = ws + 5 * fN256;          // (N,64) f32
  float* DIS = X3 + (size_t)N * 64;    // (N)
  float* SEG = DIS + (((size_t)N + 63) / 64) * 64;
  float* sum_x3 = SEG;                 // 512
  float* sum_pe = SEG + 512;           // 512
  float* cnt_wt = SEG + 1024;          // 8
  float* sum_vfd = SEG + 1032;         // 1024
  float* cnt_df = SEG + 2056;          // 8
  int* ip = (int*)(SEG + 2064 + 16);
  int* rp_wt = ip;                     // N+1
  int* cur_wt = rp_wt + (N + 1);       // N
  int* adj_wt = cur_wt + N;            // E
  int* rp_df = adj_wt + E;             // N+1
  int* cur_df = rp_df + (N + 1);       // N
  int* adj_df = cur_df + N;            // E
  float* Wf6 = (float*)((((uintptr_t)(adj_df + E)) + 63) & ~(uintptr_t)63);  // 6*65536 f32
  float* bf6 = Wf6 + 6 * 65536;        // 6*256
  float* Wf3 = bf6 + 6 * 256;          // 3*16384 f32
  float* bf3 = Wf3 + 3 * 16384;        // 3*64
  __hip_bfloat16* wb = (__hip_bfloat16*)((((uintptr_t)(bf3 + 3 * 64)) + 63) & ~(uintptr_t)63);
  __hip_bfloat16* WfT6 = wb;                    // 6*65536
  __hip_bfloat16* Wf3T = WfT6 + 6 * 65536;      // 3*16384
  __hip_bfloat16* embT = Wf3T + 3 * 16384;      // 256*64
  __hip_bfloat16* w1T = embT + 16384;           // 256*64
  __hip_bfloat16* w2T = w1T + 16384;            // 256*256
  __hip_bfloat16* w3T = w2T + 65536;            // 128*256

  __hip_bfloat16* Xb = (__hip_bfloat16*)X;      // N x 256
  __hip_bfloat16* xwtb = (__hip_bfloat16*)L;    // N x 64 (emb input)
  __hip_bfloat16* Qb16 = (__hip_bfloat16*)Qb;   // N x 256 / N x 64 bf16 Q
  __hip_bfloat16* KVb = (__hip_bfloat16*)Kb;    // N x 512 / N x 128
  __hip_bfloat16* Hd1 = (__hip_bfloat16*)Kb;    // GCN ping/pong
  __hip_bfloat16* G1 = (__hip_bfloat16*)Vb;
  __hip_bfloat16* Y1 = (__hip_bfloat16*)Kb;
  __hip_bfloat16* Hd2 = (__hip_bfloat16*)Vb;
  __hip_bfloat16* Y2b = (__hip_bfloat16*)Kb;
  __hip_bfloat16* Hd3 = (__hip_bfloat16*)Vb;
  float* VFD = L;

  const int TB = 256;

  // ---- weight folds (f32) + transposes to bf16 WT[n][k] ----
  gemm_fold6_kernel<<<dim3(4, 4, 6), TB, 0, stream>>>(cw_lin_w, cw_q_w, cw_k_w, cw_v_w, Wf6);
  bias_fold6_kernel<<<6, TB, 0, stream>>>(cw_lin_b, cw_q_w, cw_k_w, cw_v_w, cw_q_b, cw_k_b,
                                          cw_v_b, bf6);
  gemm3_kernel<false><<<dim3(4, 1, 3), TB, 0, stream>>>(
      c3_lin_w, c3_q_w, c3_k_w, c3_v_w, nullptr, nullptr, nullptr,
      Wf3, Wf3 + 16384, Wf3 + 32768, 256, 64, 64);
  bias_fold3_kernel<<<3, 64, 0, stream>>>(c3_lin_b, c3_q_w, c3_k_w, c3_v_w, c3_q_b, c3_k_b,
                                          c3_v_b, bf3);
  transpose_bf16_kernel<<<dim3(cdiv_h(65536, TB), 1, 6), TB, 0, stream>>>(Wf6, WfT6, 256, 256);
  transpose_bf16_kernel<<<dim3(cdiv_h(16384, TB), 1, 3), TB, 0, stream>>>(Wf3, Wf3T, 256, 64);
  transpose_bf16_kernel<<<dim3(cdiv_h(16384, TB), 1, 1), TB, 0, stream>>>(emb_w, embT, 64, 256);
  transpose_bf16_kernel<<<dim3(cdiv_h(16384, TB), 1, 1), TB, 0, stream>>>(gcn_w1, w1T, 64, 256);
  transpose_bf16_kernel<<<dim3(cdiv_h(65536, TB), 1, 1), TB, 0, stream>>>(gcn_w2, w2T, 256, 256);
  transpose_bf16_kernel<<<dim3(cdiv_h(32768, TB), 1, 1), TB, 0, stream>>>(gcn_w3, w3T, 256, 128);

  // ---- CSR build (both graphs); reuse cur_* as temporary deg ----
  fill_i_kernel<<<32, TB, 0, stream>>>(cur_wt, 0, N);
  fill_i_kernel<<<32, TB, 0, stream>>>(cur_df, 0, N);
  hist_kernel<<<cdiv_h(E, TB), TB, 0, stream>>>(dst_wt, cur_wt, E);
  hist_kernel<<<cdiv_h(E, TB), TB, 0, stream>>>(dst_df, cur_df, E);
  scan_kernel<<<1, 1024, 0, stream>>>(cur_wt, rp_wt, cur_wt, N);
  scan_kernel<<<1, 1024, 0, stream>>>(cur_df, rp_df, cur_df, N);
  fill_adj_kernel<<<cdiv_h(E, TB), TB, 0, stream>>>(src_wt, dst_wt, cur_wt, adj_wt, E);
  fill_adj_kernel<<<cdiv_h(E, TB), TB, 0, stream>>>(src_df, dst_df, cur_df, adj_df, E);
  dis_kernel<<<cdiv_h(N, TB), TB, 0, stream>>>(rp_df, DIS, N);

  const int MT = N / 16;  // 375 row-tiles
  // ---- WT branch ----
  f2b_kernel<<<cdiv_h(N * 64, TB), TB, 0, stream>>>(x_wt, xwtb, N * 64);
  mfma_gemm_kernel<0><<<dim3(MT, 4), TB, 0, stream>>>(xwtb, embT, emb_b, nullptr, nullptr,
                                                      Xb, N, 64, 256);
  const float isd32 = 0.17677669529663687f;  // 1/sqrt(32)
  const float isd8 = 0.35355339059327373f;   // 1/sqrt(8)
  for (int l = 0; l < 2; ++l) {
    mfma_gemm_kernel<3><<<dim3(MT, 4, 3), TB, 0, stream>>>(
        Xb, WfT6 + (size_t)l * 3 * 65536, bf6 + l * 768, nullptr, (float*)Qb16, KVb,
        N, 256, 256);
    conv_mfma_kernel<<<N, TB, 0, stream>>>(Qb16, KVb, rp_wt, adj_wt, cw_bias + l * 8,
                                           Xb, isd32);
  }
  // conv3 (256 -> 64), lin folded into QKV (bf16 Q + K|Vt interleaved)
  mfma_gemm_kernel<4><<<dim3(MT, 1, 3), TB, 0, stream>>>(Xb, Wf3T, bf3, nullptr,
                                                         (float*)Qb16, KVb, N, 256, 64);
  conv3_mfma_kernel<<<N, TB, 0, stream>>>(Qb16, KVb, rp_wt, adj_wt, c3_bias, X3, isd8);

  fill_f_kernel<<<8, TB, 0, stream>>>(SEG, 0.f, 2064);
  segsum_x3_pe_kernel<<<cdiv_h(N * 64, TB), TB, 0, stream>>>(X3, b_wt, sum_x3, sum_pe,
                                                             cnt_wt, N);

  // ---- diff branch (GCN); dis[src] folded into bf16 rows ----
  xd_scale_bf16_kernel<<<cdiv_h(N * 64, TB), TB, 0, stream>>>(x_diff, DIS, Hd1, N * 64);
  gcn_gather5_kernel<64, false, false, true><<<N, TB, 0, stream>>>(Hd1, rp_df, adj_df, DIS,
                                                                   nullptr, G1, N);
  mfma_gemm_kernel<0><<<dim3(MT, 4), TB, 0, stream>>>(G1, w1T, gcn_b1, nullptr, nullptr,
                                                      Y1, N, 64, 256);
  mfma_gemm_kernel<1><<<dim3(MT, 4), TB, 0, stream>>>(Y1, w2T, nullptr, DIS, nullptr,
                                                      Hd2, N, 256, 256);
  gcn_gather5_kernel<256, true, true, true><<<N, TB, 0, stream>>>(Hd2, rp_df, adj_df, DIS,
                                                                  gcn_b2, Y2b, N);
  mfma_gemm_kernel<1><<<dim3(MT, 2), TB, 0, stream>>>(Y2b, w3T, nullptr, DIS, nullptr,
                                                      Hd3, N, 256, 128);
  gcn_gather5_kernel<128, true, false, false><<<N, TB, 0, stream>>>(Hd3, rp_df, adj_df, DIS,
                                                                    gcn_b3, VFD, N);
  segsum_vfd_kernel<<<cdiv_h(N * 128, TB), TB, 0, stream>>>(VFD, b_df, sum_vfd, cnt_df, N);

  // ---- head ----
  head_kernel<<<8, TB, 0, stream>>>(sum_x3, sum_pe, cnt_wt, sum_vfd, cnt_df, sft_w, sft_b,
                                    gru_wih, gru_bih, gru_bhh, mlp_w1, mlp_b1, mlp_w2,
                                    mlp_b2, mlp_w3, mlp_b3, pred_w, pred_b, (float*)d_out);
}

// Round 11
// 419.648 us; speedup vs baseline: 7.0021x; 1.1060x over previous
//
#include <hip/hip_runtime.h>
#include <hip/hip_bf16.h>

// ---------------------------------------------------------------------------
// ProteinGraphConv (3x CustomConv edge-attention) + GCN diff branch + GRU/MLP
// head. Round 11: segment-sum kernels grid-strided to 120 blocks — global
// atomic traffic into the 1-2KB accumulator drops 12-25x (was 3M same-address
// RMWs across 3000 blocks / 8 XCDs). Everything else unchanged from Round 10.
// N=6000, E=200000, HID=256, GH=64, H=8, B=8.
// ---------------------------------------------------------------------------

static inline int cdiv_h(int a, int b) { return (a + b - 1) / b; }

typedef __attribute__((ext_vector_type(8))) short bf16x8_t;
typedef __attribute__((ext_vector_type(4))) float f32x4_t;

__device__ __forceinline__ float bf16lo(uint32_t w) { return __uint_as_float(w << 16); }
__device__ __forceinline__ float bf16hi(uint32_t w) { return __uint_as_float(w & 0xffff0000u); }
__device__ __forceinline__ unsigned short f2bu(float f) {
  __hip_bfloat16 h = __float2bfloat16(f);
  return *reinterpret_cast<unsigned short*>(&h);
}
__device__ __forceinline__ uint32_t pk_bf16(float a, float b) {
  return (uint32_t)f2bu(a) | ((uint32_t)f2bu(b) << 16);
}

__global__ void fill_f_kernel(float* __restrict__ p, float v, int n) {
  int stride = gridDim.x * blockDim.x;
  for (int i = blockIdx.x * blockDim.x + threadIdx.x; i < n; i += stride) p[i] = v;
}
__global__ void fill_i_kernel(int* __restrict__ p, int v, int n) {
  int stride = gridDim.x * blockDim.x;
  for (int i = blockIdx.x * blockDim.x + threadIdx.x; i < n; i += stride) p[i] = v;
}
__global__ void f2b_kernel(const float* __restrict__ in, __hip_bfloat16* __restrict__ out, int n) {
  int i = blockIdx.x * blockDim.x + threadIdx.x;
  if (i < n) out[i] = __float2bfloat16(in[i]);
}

// ---------------- CSR build ----------------
__global__ void hist_kernel(const int* __restrict__ dst, int* __restrict__ deg, int E) {
  int i = blockIdx.x * blockDim.x + threadIdx.x;
  if (i < E) atomicAdd(&deg[dst[i]], 1);
}

__global__ void scan_kernel(const int* __restrict__ deg, int* __restrict__ rowptr,
                            int* __restrict__ cursor, int N) {
  __shared__ int part[1024];
  const int t = threadIdx.x;
  const int chunk = (N + 1023) / 1024;
  const int base0 = t * chunk;
  int s = 0;
  for (int i = 0; i < chunk; ++i) {
    int idx = base0 + i;
    if (idx < N) s += deg[idx];
  }
  part[t] = s;
  __syncthreads();
  for (int off = 1; off < 1024; off <<= 1) {
    int v = (t >= off) ? part[t - off] : 0;
    __syncthreads();
    part[t] += v;
    __syncthreads();
  }
  int run = (t == 0) ? 0 : part[t - 1];
  for (int i = 0; i < chunk; ++i) {
    int idx = base0 + i;
    if (idx < N) {
      rowptr[idx] = run;
      cursor[idx] = run;
      run += deg[idx];
    }
  }
  if (t == 1023) rowptr[N] = part[1023];
}

__global__ void fill_adj_kernel(const int* __restrict__ src, const int* __restrict__ dst,
                                int* __restrict__ cursor, int* __restrict__ adj, int E) {
  int i = blockIdx.x * blockDim.x + threadIdx.x;
  if (i < E) {
    int p = atomicAdd(&cursor[dst[i]], 1);
    adj[p] = src[i];
  }
}

__global__ void dis_kernel(const int* __restrict__ rowptr, float* __restrict__ dis, int N) {
  int i = blockIdx.x * blockDim.x + threadIdx.x;
  if (i < N) dis[i] = rsqrtf((float)(rowptr[i + 1] - rowptr[i] + 1));
}

// Xd = bf16(x * dis[row])   (C = 64)
__global__ void xd_scale_bf16_kernel(const float* __restrict__ x, const float* __restrict__ dis,
                                     __hip_bfloat16* __restrict__ out, int n) {
  int i = blockIdx.x * blockDim.x + threadIdx.x;
  if (i < n) out[i] = __float2bfloat16(x[i] * dis[i >> 6]);
}

// WT[z][n][k] = bf16(W[z][k][n])
__global__ void transpose_bf16_kernel(const float* __restrict__ W,
                                      __hip_bfloat16* __restrict__ WT, int K, int N) {
  const size_t zoff = (size_t)blockIdx.z * K * N;
  int idx = blockIdx.x * blockDim.x + threadIdx.x;
  if (idx < K * N) {
    int k = idx / N, n = idx % N;
    WT[zoff + (size_t)n * K + k] = __float2bfloat16(W[zoff + idx]);
  }
}

// ---------------- MFMA GEMM: C = A(bf16 MxK) @ WT(bf16 [N][K])^T ------------
// EPI: 0 = +bias, relu -> bf16 ; 1 = *rsc[m] -> bf16 ; 2 = QKV (z0 f32 Q,
// z1/2 KV interleaved bf16, stride 2N) ; 3 = QKV D=32 (z0 bf16 Q, z1 K,
// z2 V transposed (n&31)*8+(n>>5)) ; 4 = QKV D=8 (z0 bf16 Q, z1 K,
// z2 V transposed (n&7)*8+(n>>3))
template <int EPI>
__global__ __launch_bounds__(256) void mfma_gemm_kernel(
    const __hip_bfloat16* __restrict__ A, const __hip_bfloat16* __restrict__ WT,
    const float* __restrict__ bias, const float* __restrict__ rsc,
    float* __restrict__ outF, __hip_bfloat16* __restrict__ outB,
    int M, int K, int N) {
  const int tid = threadIdx.x, w = tid >> 6, lane = tid & 63;
  int z = 0;
  const __hip_bfloat16* Wz = WT;
  const float* bz = bias;
  if (EPI >= 2) {
    z = blockIdx.z;
    Wz = WT + (size_t)z * K * N;
    bz = bias + (size_t)z * N;
  }
  const int row0 = blockIdx.x * 16;
  const int col0 = blockIdx.y * 64 + w * 16;
  if (col0 >= N) return;
  const int r = lane & 15, kb = lane >> 4;
  f32x4_t acc = {0.f, 0.f, 0.f, 0.f};
  const __hip_bfloat16* ap = A + (size_t)(row0 + r) * K + kb * 8;
  const __hip_bfloat16* bp = Wz + (size_t)(col0 + r) * K + kb * 8;
  for (int k0 = 0; k0 < K; k0 += 32) {
    bf16x8_t av = *(const bf16x8_t*)(ap + k0);
    bf16x8_t bv = *(const bf16x8_t*)(bp + k0);
    acc = __builtin_amdgcn_mfma_f32_16x16x32_bf16(av, bv, acc, 0, 0, 0);
  }
  const int n = col0 + r;
#pragma unroll
  for (int j = 0; j < 4; ++j) {
    const int m = row0 + kb * 4 + j;
    float v = acc[j];
    if (EPI == 0) {
      v += bias[n];
      outB[(size_t)m * N + n] = __float2bfloat16(fmaxf(v, 0.f));
    } else if (EPI == 1) {
      v *= rsc[m];
      outB[(size_t)m * N + n] = __float2bfloat16(v);
    } else if (EPI == 2) {
      v += bz[n];
      if (z == 0)
        outF[(size_t)m * N + n] = v;
      else
        outB[(size_t)m * 2 * N + (size_t)(z - 1) * N + n] = __float2bfloat16(v);
    } else if (EPI == 3) {
      v += bz[n];
      if (z == 0)
        ((__hip_bfloat16*)outF)[(size_t)m * N + n] = __float2bfloat16(v);
      else if (z == 1)
        outB[(size_t)m * 2 * N + n] = __float2bfloat16(v);
      else
        outB[(size_t)m * 2 * N + N + (size_t)(n & 31) * 8 + (n >> 5)] = __float2bfloat16(v);
    } else {
      v += bz[n];
      if (z == 0)
        ((__hip_bfloat16*)outF)[(size_t)m * N + n] = __float2bfloat16(v);
      else if (z == 1)
        outB[(size_t)m * 2 * N + n] = __float2bfloat16(v);
      else
        outB[(size_t)m * 2 * N + N + (size_t)(n & 7) * 8 + (n >> 3)] = __float2bfloat16(v);
    }
  }
}

// ---------------- f32 fold GEMMs (one-time weight prep) ----------------
template <bool BIAS>
__global__ void gemm3_kernel(const float* __restrict__ A, const float* __restrict__ W0,
                             const float* __restrict__ W1, const float* __restrict__ W2,
                             const float* __restrict__ b0, const float* __restrict__ b1,
                             const float* __restrict__ b2, float* __restrict__ C0,
                             float* __restrict__ C1, float* __restrict__ C2,
                             int M, int K, int N) {
  const int z = blockIdx.z;
  const float* W = (z == 0) ? W0 : (z == 1) ? W1 : W2;
  const float* bias = (z == 0) ? b0 : (z == 1) ? b1 : b2;
  float* C = (z == 0) ? C0 : (z == 1) ? C1 : C2;
  __shared__ float As[16][64];
  __shared__ float Bs[16][64];
  const int tx = threadIdx.x;
  const int m0 = blockIdx.x * 64, n0 = blockIdx.y * 64;
  const int tm = (tx & 15) * 4, tn = (tx >> 4) * 4;
  float acc[4][4] = {};
  for (int k0 = 0; k0 < K; k0 += 16) {
    {
      int m = tx >> 2, kq = (tx & 3) * 4;
      float4 av = make_float4(0.f, 0.f, 0.f, 0.f);
      if (m0 + m < M) av = *(const float4*)(A + (size_t)(m0 + m) * K + (k0 + kq));
      As[kq + 0][m] = av.x; As[kq + 1][m] = av.y;
      As[kq + 2][m] = av.z; As[kq + 3][m] = av.w;
      int kk = tx >> 4, nq = (tx & 15) * 4;
      *(float4*)&Bs[kk][nq] = *(const float4*)(W + (size_t)(k0 + kk) * N + (n0 + nq));
    }
    __syncthreads();
#pragma unroll
    for (int k = 0; k < 16; ++k) {
      float4 a4 = *(const float4*)&As[k][tm];
      float4 b4 = *(const float4*)&Bs[k][tn];
      float av[4] = {a4.x, a4.y, a4.z, a4.w};
      float bv[4] = {b4.x, b4.y, b4.z, b4.w};
#pragma unroll
      for (int i = 0; i < 4; ++i)
#pragma unroll
        for (int j = 0; j < 4; ++j) acc[i][j] += av[i] * bv[j];
    }
    __syncthreads();
  }
#pragma unroll
  for (int i = 0; i < 4; ++i) {
    int m = m0 + tm + i;
    if (m >= M) continue;
#pragma unroll
    for (int j = 0; j < 4; ++j) {
      float v = acc[i][j];
      int n = n0 + tn + j;
      if (BIAS) v += bias[n];
      C[(size_t)m * N + n] = v;
    }
  }
}

// Wf6[z=3l+j] = cw_lin_w[l] @ {q,k,v}w[l]   (grid 4x4x6)
__global__ void gemm_fold6_kernel(const float* __restrict__ lin_w, const float* __restrict__ qw,
                                  const float* __restrict__ kw, const float* __restrict__ vw,
                                  float* __restrict__ Wf) {
  const int z = blockIdx.z, l = z / 3, j = z % 3;
  const float* A = lin_w + (size_t)l * 65536;
  const float* W = ((j == 0) ? qw : (j == 1) ? kw : vw) + (size_t)l * 65536;
  float* C = Wf + (size_t)z * 65536;
  __shared__ float As[16][64];
  __shared__ float Bs[16][64];
  const int tx = threadIdx.x;
  const int m0 = blockIdx.x * 64, n0 = blockIdx.y * 64;
  const int tm = (tx & 15) * 4, tn = (tx >> 4) * 4;
  float acc[4][4] = {};
  for (int k0 = 0; k0 < 256; k0 += 16) {
    {
      int m = tx >> 2, kq = (tx & 3) * 4;
      float4 av = *(const float4*)(A + (size_t)(m0 + m) * 256 + (k0 + kq));
      As[kq + 0][m] = av.x; As[kq + 1][m] = av.y;
      As[kq + 2][m] = av.z; As[kq + 3][m] = av.w;
      int kk = tx >> 4, nq = (tx & 15) * 4;
      *(float4*)&Bs[kk][nq] = *(const float4*)(W + (size_t)(k0 + kk) * 256 + (n0 + nq));
    }
    __syncthreads();
#pragma unroll
    for (int k = 0; k < 16; ++k) {
      float4 a4 = *(const float4*)&As[k][tm];
      float4 b4 = *(const float4*)&Bs[k][tn];
      float av[4] = {a4.x, a4.y, a4.z, a4.w};
      float bv[4] = {b4.x, b4.y, b4.z, b4.w};
#pragma unroll
      for (int i = 0; i < 4; ++i)
#pragma unroll
        for (int j2 = 0; j2 < 4; ++j2) acc[i][j2] += av[i] * bv[j2];
    }
    __syncthreads();
  }
#pragma unroll
  for (int i = 0; i < 4; ++i)
#pragma unroll
    for (int j2 = 0; j2 < 4; ++j2)
      C[(size_t)(m0 + tm + i) * 256 + (n0 + tn + j2)] = acc[i][j2];
}

__global__ void bias_fold6_kernel(const float* __restrict__ lin_b, const float* __restrict__ qw,
                                  const float* __restrict__ kw, const float* __restrict__ vw,
                                  const float* __restrict__ qb, const float* __restrict__ kb,
                                  const float* __restrict__ vb, float* __restrict__ bf) {
  const int z = blockIdx.x, l = z / 3, j = z % 3, c = threadIdx.x;
  const float* W = ((j == 0) ? qw : (j == 1) ? kw : vw) + (size_t)l * 65536;
  const float* b = ((j == 0) ? qb : (j == 1) ? kb : vb) + l * 256;
  const float* lb = lin_b + l * 256;
  float acc = b[c];
  for (int k = 0; k < 256; ++k) acc += lb[k] * W[k * 256 + c];
  bf[z * 256 + c] = acc;
}

__global__ void bias_fold3_kernel(const float* __restrict__ lin_b, const float* __restrict__ qw,
                                  const float* __restrict__ kw, const float* __restrict__ vw,
                                  const float* __restrict__ qb, const float* __restrict__ kb,
                                  const float* __restrict__ vb, float* __restrict__ bf) {
  const int j = blockIdx.x, c = threadIdx.x;
  const float* W = (j == 0) ? qw : (j == 1) ? kw : vw;
  const float* b = (j == 0) ? qb : (j == 1) ? kb : vb;
  float acc = b[c];
  for (int k = 0; k < 64; ++k) acc += lin_b[k] * W[k * 64 + c];
  bf[j * 64 + c] = acc;
}

// ---------------- CustomConv D=32 — full MFMA path --------------------------
__global__ __launch_bounds__(256) void conv_mfma_kernel(
    const __hip_bfloat16* __restrict__ Qn, const __hip_bfloat16* __restrict__ KV,
    const int* __restrict__ rowptr, const int* __restrict__ adj,
    const float* __restrict__ abias, __hip_bfloat16* __restrict__ Xout,
    float inv_sqrt_d) {
  __shared__ __align__(16) unsigned short sKV[4][2048];  // 4 edges x 512 halfs
  __shared__ __align__(16) unsigned short sP[4][640];    // 16 rows x 40 halfs
  __shared__ float sR[4][256];
  const int tid = threadIdx.x, w = tid >> 6, lane = tid & 63;
  const int n = blockIdx.x;
  const int c = lane & 15, kb = lane >> 4;

  const bf16x8_t qf = *(const bf16x8_t*)(Qn + (size_t)n * 256 + (size_t)(c & 7) * 32 + kb * 8);
  const float bh = abias[c & 7];

  unsigned short* myKV = sKV[w];
  unsigned short* myP = sP[w];
  f32x4_t acc0 = {0.f, 0.f, 0.f, 0.f};
  f32x4_t acc1 = {0.f, 0.f, 0.f, 0.f};
  const f32x4_t z4 = {0.f, 0.f, 0.f, 0.f};

  const int s0 = rowptr[n], t0 = rowptr[n + 1];
  auto ld = [&](int idx) -> uint4 {
    if (idx < t0) return *(const uint4*)(KV + (size_t)adj[idx] * 512 + (lane << 3));
    return make_uint4(0u, 0u, 0u, 0u);
  };
  int i = s0 + w * 4;
  uint4 kv0, kv1, kv2, kv3;
  if (i < t0) {
    kv0 = ld(i); kv1 = ld(i + 1); kv2 = ld(i + 2); kv3 = ld(i + 3);
  }
  for (; i < t0; i += 16) {
    *(uint4*)(myKV + 0 + (lane << 3)) = kv0;
    *(uint4*)(myKV + 512 + (lane << 3)) = kv1;
    *(uint4*)(myKV + 1024 + (lane << 3)) = kv2;
    *(uint4*)(myKV + 1536 + (lane << 3)) = kv3;
    const int i2 = i + 16;
    if (i2 < t0) {
      kv0 = ld(i2); kv1 = ld(i2 + 1); kv2 = ld(i2 + 2); kv3 = ld(i2 + 3);
    }
    __builtin_amdgcn_wave_barrier();
    const int aoff = (c >> 3) * 512 + (c & 7) * 32 + kb * 8;
    bf16x8_t a0 = *(const bf16x8_t*)(myKV + aoff);
    bf16x8_t a1 = *(const bf16x8_t*)(myKV + 1024 + aoff);
    f32x4_t S0 = __builtin_amdgcn_mfma_f32_16x16x32_bf16(a0, qf, z4, 0, 0, 0);
    f32x4_t S1 = __builtin_amdgcn_mfma_f32_16x16x32_bf16(a1, qf, z4, 0, 0, 0);
    float p0[4], p1[4];
    {
      float sv[4];
#pragma unroll
      for (int j = 0; j < 4; ++j) sv[j] = S0[j] * inv_sqrt_d + bh;
      float m = fmaxf(fmaxf(sv[0], sv[1]), fmaxf(sv[2], sv[3]));
      m = fmaxf(m, __shfl_xor(m, 16));
      float sum = 0.f;
#pragma unroll
      for (int j = 0; j < 4; ++j) { p0[j] = __expf(sv[j] - m); sum += p0[j]; }
      sum += __shfl_xor(sum, 16);
      float rs = 1.f / sum;
#pragma unroll
      for (int j = 0; j < 4; ++j) p0[j] *= rs;
    }
    {
      float sv[4];
#pragma unroll
      for (int j = 0; j < 4; ++j) sv[j] = S1[j] * inv_sqrt_d + bh;
      float m = fmaxf(fmaxf(sv[0], sv[1]), fmaxf(sv[2], sv[3]));
      m = fmaxf(m, __shfl_xor(m, 16));
      float sum = 0.f;
#pragma unroll
      for (int j = 0; j < 4; ++j) { p1[j] = __expf(sv[j] - m); sum += p1[j]; }
      sum += __shfl_xor(sum, 16);
      float rs = 1.f / sum;
#pragma unroll
      for (int j = 0; j < 4; ++j) p1[j] *= rs;
    }
    *(uint32_t*)(myP + c * 40 + kb * 4) = pk_bf16(p0[0], p0[1]);
    *(uint32_t*)(myP + c * 40 + kb * 4 + 2) = pk_bf16(p0[2], p0[3]);
    *(uint32_t*)(myP + c * 40 + 16 + kb * 4) = pk_bf16(p1[0], p1[1]);
    *(uint32_t*)(myP + c * 40 + 16 + kb * 4 + 2) = pk_bf16(p1[2], p1[3]);
    __builtin_amdgcn_wave_barrier();
    bf16x8_t pa = *(const bf16x8_t*)(myP + c * 40 + kb * 8);
    bf16x8_t vb0 = *(const bf16x8_t*)(myKV + kb * 512 + 256 + c * 8);
    bf16x8_t vb1 = *(const bf16x8_t*)(myKV + kb * 512 + 256 + (c + 16) * 8);
    acc0 = __builtin_amdgcn_mfma_f32_16x16x32_bf16(pa, vb0, acc0, 0, 0, 0);
    acc1 = __builtin_amdgcn_mfma_f32_16x16x32_bf16(pa, vb1, acc1, 0, 0, 0);
    __builtin_amdgcn_wave_barrier();
  }
  if (kb < 2) {
#pragma unroll
    for (int j = 0; j < 4; ++j) {
      int h = kb * 4 + j;
      sR[w][h * 32 + c] = acc0[j];
      sR[w][h * 32 + 16 + c] = acc1[j];
    }
  }
  __syncthreads();
  for (int cc = tid; cc < 256; cc += 256) {
    float v = sR[0][cc] + sR[1][cc] + sR[2][cc] + sR[3][cc];
    Xout[(size_t)n * 256 + cc] = __float2bfloat16(fmaxf(v, 0.f));
  }
}

// ---------------- CustomConv D=8 (conv3) — MFMA path ------------------------
__global__ __launch_bounds__(256) void conv3_mfma_kernel(
    const __hip_bfloat16* __restrict__ Qn, const __hip_bfloat16* __restrict__ KV,
    const int* __restrict__ rowptr, const int* __restrict__ adj,
    const float* __restrict__ abias, float* __restrict__ Xout, float inv_sqrt_d) {
  __shared__ __align__(16) unsigned short sKV[4][544];  // 4 edges x 136 halfs
  __shared__ __align__(16) unsigned short sP[4][320];   // 8 rows x 40 halfs
  __shared__ float sR[4][64];
  const int tid = threadIdx.x, w = tid >> 6, lane = tid & 63;
  const int n = blockIdx.x;
  const int c = lane & 15, kb = lane >> 4;

  bf16x8_t qf = {};
  if (kb == 0) qf = *(const bf16x8_t*)(Qn + (size_t)n * 64 + (size_t)(c & 7) * 8);
  const float bh = abias[c & 7];

  unsigned short* myKV = sKV[w];
  unsigned short* myP = sP[w];
  f32x4_t acc = {0.f, 0.f, 0.f, 0.f};
  const f32x4_t z4 = {0.f, 0.f, 0.f, 0.f};

  const int s0 = rowptr[n], t0 = rowptr[n + 1];
  auto ld = [&](int idx) -> uint4 {
    if (idx < t0) return *(const uint4*)(KV + (size_t)adj[idx] * 128 + (c << 3));
    return make_uint4(0u, 0u, 0u, 0u);
  };
  int i = s0 + w * 4;
  uint4 kvst = make_uint4(0u, 0u, 0u, 0u);
  if (i < t0) kvst = ld(i + kb);
  for (; i < t0; i += 16) {
    *(uint4*)(myKV + kb * 136 + (c << 3)) = kvst;
    kvst = ld(i + 16 + kb);
    __builtin_amdgcn_wave_barrier();
    bf16x8_t a0 = {}, a1 = {};
    if (kb == 0) {
      a0 = *(const bf16x8_t*)(myKV + (c >> 3) * 136 + (c & 7) * 8);
      a1 = *(const bf16x8_t*)(myKV + (2 + (c >> 3)) * 136 + (c & 7) * 8);
    }
    f32x4_t S0 = __builtin_amdgcn_mfma_f32_16x16x32_bf16(a0, qf, z4, 0, 0, 0);
    f32x4_t S1 = __builtin_amdgcn_mfma_f32_16x16x32_bf16(a1, qf, z4, 0, 0, 0);
    float p0[4], p1[4];
    {
      float sv[4];
#pragma unroll
      for (int j = 0; j < 4; ++j) sv[j] = S0[j] * inv_sqrt_d + bh;
      float m = fmaxf(fmaxf(sv[0], sv[1]), fmaxf(sv[2], sv[3]));
      m = fmaxf(m, __shfl_xor(m, 16));
      float sum = 0.f;
#pragma unroll
      for (int j = 0; j < 4; ++j) { p0[j] = __expf(sv[j] - m); sum += p0[j]; }
      sum += __shfl_xor(sum, 16);
      float rs = 1.f / sum;
#pragma unroll
      for (int j = 0; j < 4; ++j) p0[j] *= rs;
    }
    {
      float sv[4];
#pragma unroll
      for (int j = 0; j < 4; ++j) sv[j] = S1[j] * inv_sqrt_d + bh;
      float m = fmaxf(fmaxf(sv[0], sv[1]), fmaxf(sv[2], sv[3]));
      m = fmaxf(m, __shfl_xor(m, 16));
      float sum = 0.f;
#pragma unroll
      for (int j = 0; j < 4; ++j) { p1[j] = __expf(sv[j] - m); sum += p1[j]; }
      sum += __shfl_xor(sum, 16);
      float rs = 1.f / sum;
#pragma unroll
      for (int j = 0; j < 4; ++j) p1[j] *= rs;
    }
    if (c < 8) {
      const int k0 = (kb >> 1) * 8 + (kb & 1) * 4;
      *(uint32_t*)(myP + c * 40 + k0) = pk_bf16(p0[0], p0[1]);
      *(uint32_t*)(myP + c * 40 + k0 + 2) = pk_bf16(p0[2], p0[3]);
      *(uint32_t*)(myP + c * 40 + 16 + k0) = pk_bf16(p1[0], p1[1]);
      *(uint32_t*)(myP + c * 40 + 16 + k0 + 2) = pk_bf16(p1[2], p1[3]);
    }
    __builtin_amdgcn_wave_barrier();
    bf16x8_t pa = *(const bf16x8_t*)(myP + (c & 7) * 40 + kb * 8);
    bf16x8_t vb = {};
    if (c < 8) vb = *(const bf16x8_t*)(myKV + kb * 136 + 64 + c * 8);
    acc = __builtin_amdgcn_mfma_f32_16x16x32_bf16(pa, vb, acc, 0, 0, 0);
    __builtin_amdgcn_wave_barrier();
  }
  if (kb < 2 && c < 8) {
#pragma unroll
    for (int j = 0; j < 4; ++j) sR[w][(kb * 4 + j) * 8 + c] = acc[j];
  }
  __syncthreads();
  if (tid < 64) {
    float v = sR[0][tid] + sR[1][tid] + sR[2][tid] + sR[3][tid];
    Xout[(size_t)n * 64 + tid] = fmaxf(v, 0.f);
  }
}

// ---------------- GCN propagate via dst-CSR gather, bf16 rows ---------------
template <int C, bool BIAS, bool RELU, bool OBF>
__global__ __launch_bounds__(256) void gcn_gather5_kernel(
    const __hip_bfloat16* __restrict__ Hd, const int* __restrict__ rowptr,
    const int* __restrict__ adj, const float* __restrict__ dis,
    const float* __restrict__ bias, void* __restrict__ O, int Nn) {
  constexpr int EPL = C / 64;  // 4, 2, 1
  __shared__ float sR[4][C];
  const int tid = threadIdx.x, w = tid >> 6, lane = tid & 63;
  const int n = blockIdx.x;
  float acc[EPL] = {};
  const int s = rowptr[n], t = rowptr[n + 1];
  int i = s + w;
  int vs = (i < t) ? adj[i] : 0;
  if constexpr (EPL == 4) {
    uint2 u = (i < t) ? *(const uint2*)(Hd + (size_t)vs * C + lane * 4) : make_uint2(0u, 0u);
    while (i < t) {
      const int i2 = i + 4;
      const int vs2 = (i2 < t) ? adj[i2] : 0;
      uint2 un = (i2 < t) ? *(const uint2*)(Hd + (size_t)vs2 * C + lane * 4) : make_uint2(0u, 0u);
      acc[0] += bf16lo(u.x); acc[1] += bf16hi(u.x);
      acc[2] += bf16lo(u.y); acc[3] += bf16hi(u.y);
      u = un; i = i2; vs = vs2;
    }
  } else if constexpr (EPL == 2) {
    uint32_t u = (i < t) ? *(const uint32_t*)(Hd + (size_t)vs * C + lane * 2) : 0u;
    while (i < t) {
      const int i2 = i + 4;
      const int vs2 = (i2 < t) ? adj[i2] : 0;
      uint32_t un = (i2 < t) ? *(const uint32_t*)(Hd + (size_t)vs2 * C + lane * 2) : 0u;
      acc[0] += bf16lo(u); acc[1] += bf16hi(u);
      u = un; i = i2; vs = vs2;
    }
  } else {
    unsigned short u = (i < t) ? *(const unsigned short*)(Hd + (size_t)vs * C + lane) : 0;
    while (i < t) {
      const int i2 = i + 4;
      const int vs2 = (i2 < t) ? adj[i2] : 0;
      unsigned short un = (i2 < t) ? *(const unsigned short*)(Hd + (size_t)vs2 * C + lane) : 0;
      acc[0] += bf16lo((uint32_t)u);
      u = un; i = i2; vs = vs2;
    }
  }
  if (w == 0) {
    const __hip_bfloat16* hn = Hd + (size_t)n * C;
#pragma unroll
    for (int j = 0; j < EPL; ++j)
      acc[j] += bf16lo((uint32_t)*(const unsigned short*)(hn + lane * EPL + j));
  }
#pragma unroll
  for (int j = 0; j < EPL; ++j) sR[w][lane * EPL + j] = acc[j];
  __syncthreads();
  const float dn = dis[n];
  for (int c = tid; c < C; c += 256) {
    float v = (sR[0][c] + sR[1][c] + sR[2][c] + sR[3][c]) * dn;
    if (BIAS) v += bias[c];
    if (RELU) v = fmaxf(v, 0.f);
    if (OBF)
      ((__hip_bfloat16*)O)[(size_t)n * C + c] = __float2bfloat16(v);
    else
      ((float*)O)[(size_t)n * C + c] = v;
  }
}

// ---------------- segment sums (grid-stride, 120 blocks) ----------------
__global__ void segsum_x3_pe_kernel(const float* __restrict__ X3, const int* __restrict__ batch,
                                    float* __restrict__ sum_x3, float* __restrict__ sum_pe,
                                    float* __restrict__ cnt, int N) {
  __shared__ float lx[512], lp[512], lc[8];
  const int tid = threadIdx.x;
  for (int i = tid; i < 512; i += 256) { lx[i] = 0.f; lp[i] = 0.f; }
  if (tid < 8) lc[tid] = 0.f;
  __syncthreads();
  const int stride = gridDim.x * 256;
  for (int i = blockIdx.x * 256 + tid; i < N * 64; i += stride) {
    int n = i >> 6, c = i & 63;
    int b = batch[n];
    atomicAdd(&lx[(b << 6) + c], X3[i]);
    const float F = -0.14391156831f;  // -ln(10000)/64
    float arg = (float)n * __expf(F * (float)(c & ~1));
    atomicAdd(&lp[(b << 6) + c], (c & 1) ? __cosf(arg) : __sinf(arg));
    if (c == 0) atomicAdd(&lc[b], 1.f);
  }
  __syncthreads();
  for (int j = tid; j < 512; j += 256) {
    if (lx[j] != 0.f) atomicAdd(&sum_x3[j], lx[j]);
    if (lp[j] != 0.f) atomicAdd(&sum_pe[j], lp[j]);
  }
  if (tid < 8 && lc[tid] != 0.f) atomicAdd(&cnt[tid], lc[tid]);
}

__global__ void segsum_vfd_kernel(const float* __restrict__ VFD, const int* __restrict__ batch,
                                  float* __restrict__ sum_vfd, float* __restrict__ cnt, int N) {
  __shared__ float lv[1024], lc[8];
  const int tid = threadIdx.x;
  for (int i = tid; i < 1024; i += 256) lv[i] = 0.f;
  if (tid < 8) lc[tid] = 0.f;
  __syncthreads();
  const int stride = gridDim.x * 256;
  for (int i = blockIdx.x * 256 + tid; i < N * 128; i += stride) {
    int n = i >> 7, c = i & 127;
    int b = batch[n];
    atomicAdd(&lv[(b << 7) + c], VFD[i]);
    if (c == 0) atomicAdd(&lc[b], 1.f);
  }
  __syncthreads();
  for (int j = tid; j < 1024; j += 256) {
    if (lv[j] != 0.f) atomicAdd(&sum_vfd[j], lv[j]);
  }
  if (tid < 8 && lc[tid] != 0.f) atomicAdd(&cnt[tid], lc[tid]);
}

// ---------------- head: 8 blocks (one per batch), K-split dot products ------
__global__ __launch_bounds__(256) void head_kernel(
    const float* __restrict__ sum_x3, const float* __restrict__ sum_pe,
    const float* __restrict__ cnt_wt, const float* __restrict__ sum_vfd,
    const float* __restrict__ cnt_df, const float* __restrict__ sft_w,
    const float* __restrict__ sft_b, const float* __restrict__ gru_wih,
    const float* __restrict__ gru_bih, const float* __restrict__ gru_bhh,
    const float* __restrict__ mlp_w1, const float* __restrict__ mlp_b1,
    const float* __restrict__ mlp_w2, const float* __restrict__ mlp_b2,
    const float* __restrict__ mlp_w3, const float* __restrict__ mlp_b3,
    const float* __restrict__ pred_w, const float* __restrict__ pred_b,
    float* __restrict__ out) {
  const int b = blockIdx.x;  // batch row
  const int tid = threadIdx.x;
  __shared__ float sf0[64], sf1[64], sfr[64];
  __shared__ float hcat[256];
  __shared__ float m1[128], m2[128], m3[128];
  __shared__ float part4[4][64];
  __shared__ float part2[2][128];
  __shared__ float gi[192];
  __shared__ float rsum[4];

  const float cw = fmaxf(cnt_wt[b], 1.f), cd = fmaxf(cnt_df[b], 1.f);
  if (tid < 64) sf0[tid] = sum_x3[(b << 6) + tid] / cw;
  __syncthreads();
  {
    const int c = tid & 63, q = tid >> 6;
    float acc = 0.f;
#pragma unroll
    for (int k = q * 16; k < q * 16 + 16; ++k) acc += sf0[k] * sft_w[k * 64 + c];
    part4[q][c] = acc;
  }
  __syncthreads();
  if (tid < 64)
    sf1[tid] = fmaxf(part4[0][tid] + part4[1][tid] + part4[2][tid] + part4[3][tid] +
                         sft_b[tid], 0.f);
  __syncthreads();
  if (tid < 192) {
    float acc = gru_bih[tid];
    const float* wr = gru_wih + tid * 64;
#pragma unroll 8
    for (int k = 0; k < 64; ++k) acc += sf1[k] * wr[k];
    gi[tid] = acc;
  }
  __syncthreads();
  if (tid < 64) {
    float r = 1.f / (1.f + __expf(-(gi[tid] + gru_bhh[tid])));
    float z = 1.f / (1.f + __expf(-(gi[64 + tid] + gru_bhh[64 + tid])));
    float ng = tanhf(gi[128 + tid] + r * gru_bhh[128 + tid]);
    sfr[tid] = (1.f - z) * ng;
  }
  __syncthreads();
  {
    const int c = tid;
    float v;
    if (c < 64)
      v = (sum_x3[(b << 6) + c] + sum_pe[(b << 6) + c]) / cw;
    else if (c < 128)
      v = sfr[c - 64];
    else
      v = sum_vfd[(b << 7) + (c - 128)] / cd;
    hcat[c] = v;
  }
  __syncthreads();
  {
    const int c = tid & 127, h = tid >> 7;
    float acc = 0.f;
#pragma unroll 8
    for (int k = h * 128; k < h * 128 + 128; ++k) acc += hcat[k] * mlp_w1[k * 128 + c];
    part2[h][c] = acc;
  }
  __syncthreads();
  if (tid < 128) m1[tid] = fmaxf(part2[0][tid] + part2[1][tid] + mlp_b1[tid], 0.f);
  __syncthreads();
  {
    const int c = tid & 127, h = tid >> 7;
    float acc = 0.f;
#pragma unroll 8
    for (int k = h * 64; k < h * 64 + 64; ++k) acc += m1[k] * mlp_w2[k * 128 + c];
    part2[h][c] = acc;
  }
  __syncthreads();
  if (tid < 128) m2[tid] = fmaxf(part2[0][tid] + part2[1][tid] + mlp_b2[tid], 0.f);
  __syncthreads();
  {
    const int c = tid & 127, h = tid >> 7;
    float acc = 0.f;
#pragma unroll 8
    for (int k = h * 64; k < h * 64 + 64; ++k) acc += m2[k] * mlp_w3[k * 128 + c];
    part2[h][c] = acc;
  }
  __syncthreads();
  if (tid < 128) m3[tid] = part2[0][tid] + part2[1][tid] + mlp_b3[tid];
  __syncthreads();
  if (tid < 128) {
    float p = m3[tid] * pred_w[tid];
    p += __shfl_down(p, 32);
    p += __shfl_down(p, 16);
    p += __shfl_down(p, 8);
    p += __shfl_down(p, 4);
    p += __shfl_down(p, 2);
    p += __shfl_down(p, 1);
    if ((tid & 63) == 0) rsum[tid >> 6] = p;
  }
  __syncthreads();
  if (tid == 0) out[b] = rsum[0] + rsum[1] + pred_b[0];
}

// ---------------------------------------------------------------------------
extern "C" void kernel_launch(void* const* d_in, const int* in_sizes, int n_in,
                              void* d_out, int out_size, void* d_ws, size_t ws_size,
                              hipStream_t stream) {
  const float* x_wt = (const float*)d_in[0];
  const float* x_diff = (const float*)d_in[1];
  const int* ei_wt = (const int*)d_in[2];
  const int* ei_df = (const int*)d_in[3];
  const int* b_wt = (const int*)d_in[4];
  const int* b_df = (const int*)d_in[5];
  const float* emb_w = (const float*)d_in[6];
  const float* emb_b = (const float*)d_in[7];
  const float* cw_lin_w = (const float*)d_in[8];
  const float* cw_lin_b = (const float*)d_in[9];
  const float* cw_q_w = (const float*)d_in[10];
  const float* cw_q_b = (const float*)d_in[11];
  const float* cw_k_w = (const float*)d_in[12];
  const float* cw_k_b = (const float*)d_in[13];
  const float* cw_v_w = (const float*)d_in[14];
  const float* cw_v_b = (const float*)d_in[15];
  const float* cw_bias = (const float*)d_in[16];
  const float* c3_lin_w = (const float*)d_in[17];
  const float* c3_lin_b = (const float*)d_in[18];
  const float* c3_q_w = (const float*)d_in[19];
  const float* c3_q_b = (const float*)d_in[20];
  const float* c3_k_w = (const float*)d_in[21];
  const float* c3_k_b = (const float*)d_in[22];
  const float* c3_v_w = (const float*)d_in[23];
  const float* c3_v_b = (const float*)d_in[24];
  const float* c3_bias = (const float*)d_in[25];
  const float* sft_w = (const float*)d_in[26];
  const float* sft_b = (const float*)d_in[27];
  const float* gru_wih = (const float*)d_in[28];
  const float* gru_bih = (const float*)d_in[30];
  const float* gru_bhh = (const float*)d_in[31];
  const float* gcn_w1 = (const float*)d_in[32];
  const float* gcn_b1 = (const float*)d_in[33];
  const float* gcn_w2 = (const float*)d_in[34];
  const float* gcn_b2 = (const float*)d_in[35];
  const float* gcn_w3 = (const float*)d_in[36];
  const float* gcn_b3 = (const float*)d_in[37];
  const float* mlp_w1 = (const float*)d_in[38];
  const float* mlp_b1 = (const float*)d_in[39];
  const float* mlp_w2 = (const float*)d_in[40];
  const float* mlp_b2 = (const float*)d_in[41];
  const float* mlp_w3 = (const float*)d_in[42];
  const float* mlp_b3 = (const float*)d_in[43];
  const float* pred_w = (const float*)d_in[44];
  const float* pred_b = (const float*)d_in[45];

  const int N = in_sizes[0] / 64;  // 6000
  const int E = in_sizes[2] / 2;   // 200000
  const int* src_wt = ei_wt;
  const int* dst_wt = ei_wt + E;
  const int* src_df = ei_df;
  const int* dst_df = ei_df + E;

  // ---- workspace layout ----
  float* ws = (float*)d_ws;
  const size_t fN256 = (size_t)N * 256;
  float* X = ws;
  float* L = ws + 1 * fN256;
  float* Qb = ws + 2 * fN256;
  float* Kb = ws + 3 * fN256;
  float* Vb = ws + 4 * fN256;
  float* X3 = ws + 5 * fN256;          // (N,64) f32
  float* DIS = X3 + (size_t)N * 64;    // (N)
  float* SEG = DIS + (((size_t)N + 63) / 64) * 64;
  float* sum_x3 = SEG;                 // 512
  float* sum_pe = SEG + 512;           // 512
  float* cnt_wt = SEG + 1024;          // 8
  float* sum_vfd = SEG + 1032;         // 1024
  float* cnt_df = SEG + 2056;          // 8
  int* ip = (int*)(SEG + 2064 + 16);
  int* rp_wt = ip;                     // N+1
  int* cur_wt = rp_wt + (N + 1);       // N
  int* adj_wt = cur_wt + N;            // E
  int* rp_df = adj_wt + E;             // N+1
  int* cur_df = rp_df + (N + 1);       // N
  int* adj_df = cur_df + N;            // E
  float* Wf6 = (float*)((((uintptr_t)(adj_df + E)) + 63) & ~(uintptr_t)63);  // 6*65536 f32
  float* bf6 = Wf6 + 6 * 65536;        // 6*256
  float* Wf3 = bf6 + 6 * 256;          // 3*16384 f32
  float* bf3 = Wf3 + 3 * 16384;        // 3*64
  __hip_bfloat16* wb = (__hip_bfloat16*)((((uintptr_t)(bf3 + 3 * 64)) + 63) & ~(uintptr_t)63);
  __hip_bfloat16* WfT6 = wb;                    // 6*65536
  __hip_bfloat16* Wf3T = WfT6 + 6 * 65536;      // 3*16384
  __hip_bfloat16* embT = Wf3T + 3 * 16384;      // 256*64
  __hip_bfloat16* w1T = embT + 16384;           // 256*64
  __hip_bfloat16* w2T = w1T + 16384;            // 256*256
  __hip_bfloat16* w3T = w2T + 65536;            // 128*256

  __hip_bfloat16* Xb = (__hip_bfloat16*)X;      // N x 256
  __hip_bfloat16* xwtb = (__hip_bfloat16*)L;    // N x 64 (emb input)
  __hip_bfloat16* Qb16 = (__hip_bfloat16*)Qb;   // N x 256 / N x 64 bf16 Q
  __hip_bfloat16* KVb = (__hip_bfloat16*)Kb;    // N x 512 / N x 128
  __hip_bfloat16* Hd1 = (__hip_bfloat16*)Kb;    // GCN ping/pong
  __hip_bfloat16* G1 = (__hip_bfloat16*)Vb;
  __hip_bfloat16* Y1 = (__hip_bfloat16*)Kb;
  __hip_bfloat16* Hd2 = (__hip_bfloat16*)Vb;
  __hip_bfloat16* Y2b = (__hip_bfloat16*)Kb;
  __hip_bfloat16* Hd3 = (__hip_bfloat16*)Vb;
  float* VFD = L;

  const int TB = 256;

  // ---- weight folds (f32) + transposes to bf16 WT[n][k] ----
  gemm_fold6_kernel<<<dim3(4, 4, 6), TB, 0, stream>>>(cw_lin_w, cw_q_w, cw_k_w, cw_v_w, Wf6);
  bias_fold6_kernel<<<6, TB, 0, stream>>>(cw_lin_b, cw_q_w, cw_k_w, cw_v_w, cw_q_b, cw_k_b,
                                          cw_v_b, bf6);
  gemm3_kernel<false><<<dim3(4, 1, 3), TB, 0, stream>>>(
      c3_lin_w, c3_q_w, c3_k_w, c3_v_w, nullptr, nullptr, nullptr,
      Wf3, Wf3 + 16384, Wf3 + 32768, 256, 64, 64);
  bias_fold3_kernel<<<3, 64, 0, stream>>>(c3_lin_b, c3_q_w, c3_k_w, c3_v_w, c3_q_b, c3_k_b,
                                          c3_v_b, bf3);
  transpose_bf16_kernel<<<dim3(cdiv_h(65536, TB), 1, 6), TB, 0, stream>>>(Wf6, WfT6, 256, 256);
  transpose_bf16_kernel<<<dim3(cdiv_h(16384, TB), 1, 3), TB, 0, stream>>>(Wf3, Wf3T, 256, 64);
  transpose_bf16_kernel<<<dim3(cdiv_h(16384, TB), 1, 1), TB, 0, stream>>>(emb_w, embT, 64, 256);
  transpose_bf16_kernel<<<dim3(cdiv_h(16384, TB), 1, 1), TB, 0, stream>>>(gcn_w1, w1T, 64, 256);
  transpose_bf16_kernel<<<dim3(cdiv_h(65536, TB), 1, 1), TB, 0, stream>>>(gcn_w2, w2T, 256, 256);
  transpose_bf16_kernel<<<dim3(cdiv_h(32768, TB), 1, 1), TB, 0, stream>>>(gcn_w3, w3T, 256, 128);

  // ---- CSR build (both graphs); reuse cur_* as temporary deg ----
  fill_i_kernel<<<32, TB, 0, stream>>>(cur_wt, 0, N);
  fill_i_kernel<<<32, TB, 0, stream>>>(cur_df, 0, N);
  hist_kernel<<<cdiv_h(E, TB), TB, 0, stream>>>(dst_wt, cur_wt, E);
  hist_kernel<<<cdiv_h(E, TB), TB, 0, stream>>>(dst_df, cur_df, E);
  scan_kernel<<<1, 1024, 0, stream>>>(cur_wt, rp_wt, cur_wt, N);
  scan_kernel<<<1, 1024, 0, stream>>>(cur_df, rp_df, cur_df, N);
  fill_adj_kernel<<<cdiv_h(E, TB), TB, 0, stream>>>(src_wt, dst_wt, cur_wt, adj_wt, E);
  fill_adj_kernel<<<cdiv_h(E, TB), TB, 0, stream>>>(src_df, dst_df, cur_df, adj_df, E);
  dis_kernel<<<cdiv_h(N, TB), TB, 0, stream>>>(rp_df, DIS, N);

  const int MT = N / 16;  // 375 row-tiles
  // ---- WT branch ----
  f2b_kernel<<<cdiv_h(N * 64, TB), TB, 0, stream>>>(x_wt, xwtb, N * 64);
  mfma_gemm_kernel<0><<<dim3(MT, 4), TB, 0, stream>>>(xwtb, embT, emb_b, nullptr, nullptr,
                                                      Xb, N, 64, 256);
  const float isd32 = 0.17677669529663687f;  // 1/sqrt(32)
  const float isd8 = 0.35355339059327373f;   // 1/sqrt(8)
  for (int l = 0; l < 2; ++l) {
    mfma_gemm_kernel<3><<<dim3(MT, 4, 3), TB, 0, stream>>>(
        Xb, WfT6 + (size_t)l * 3 * 65536, bf6 + l * 768, nullptr, (float*)Qb16, KVb,
        N, 256, 256);
    conv_mfma_kernel<<<N, TB, 0, stream>>>(Qb16, KVb, rp_wt, adj_wt, cw_bias + l * 8,
                                           Xb, isd32);
  }
  // conv3 (256 -> 64), lin folded into QKV (bf16 Q + K|Vt interleaved)
  mfma_gemm_kernel<4><<<dim3(MT, 1, 3), TB, 0, stream>>>(Xb, Wf3T, bf3, nullptr,
                                                         (float*)Qb16, KVb, N, 256, 64);
  conv3_mfma_kernel<<<N, TB, 0, stream>>>(Qb16, KVb, rp_wt, adj_wt, c3_bias, X3, isd8);

  fill_f_kernel<<<8, TB, 0, stream>>>(SEG, 0.f, 2064);
  segsum_x3_pe_kernel<<<120, TB, 0, stream>>>(X3, b_wt, sum_x3, sum_pe, cnt_wt, N);

  // ---- diff branch (GCN); dis[src] folded into bf16 rows ----
  xd_scale_bf16_kernel<<<cdiv_h(N * 64, TB), TB, 0, stream>>>(x_diff, DIS, Hd1, N * 64);
  gcn_gather5_kernel<64, false, false, true><<<N, TB, 0, stream>>>(Hd1, rp_df, adj_df, DIS,
                                                                   nullptr, G1, N);
  mfma_gemm_kernel<0><<<dim3(MT, 4), TB, 0, stream>>>(G1, w1T, gcn_b1, nullptr, nullptr,
                                                      Y1, N, 64, 256);
  mfma_gemm_kernel<1><<<dim3(MT, 4), TB, 0, stream>>>(Y1, w2T, nullptr, DIS, nullptr,
                                                      Hd2, N, 256, 256);
  gcn_gather5_kernel<256, true, true, true><<<N, TB, 0, stream>>>(Hd2, rp_df, adj_df, DIS,
                                                                  gcn_b2, Y2b, N);
  mfma_gemm_kernel<1><<<dim3(MT, 2), TB, 0, stream>>>(Y2b, w3T, nullptr, DIS, nullptr,
                                                      Hd3, N, 256, 128);
  gcn_gather5_kernel<128, true, false, false><<<N, TB, 0, stream>>>(Hd3, rp_df, adj_df, DIS,
                                                                    gcn_b3, VFD, N);
  segsum_vfd_kernel<<<120, TB, 0, stream>>>(VFD, b_df, sum_vfd, cnt_df, N);

  // ---- head ----
  head_kernel<<<8, TB, 0, stream>>>(sum_x3, sum_pe, cnt_wt, sum_vfd, cnt_df, sft_w, sft_b,
                                    gru_wih, gru_bih, gru_bhh, mlp_w1, mlp_b1, mlp_w2,
                                    mlp_b2, mlp_w3, mlp_b3, pred_w, pred_b, (float*)d_out);
}

// Round 12
// 412.190 us; speedup vs baseline: 7.1288x; 1.0181x over previous
//
#include <hip/hip_runtime.h>
#include <hip/hip_bf16.h>

// ---------------------------------------------------------------------------
// ProteinGraphConv (3x CustomConv edge-attention) + GCN diff branch + GRU/MLP
// head. Round 12: mfma_gemm re-tiled — wave computes 64 rows x 16 cols
// (4 row-tiles share one B-frag; loads/MFMA 2.0 -> 1.25), K templated so the
// K-loop fully unrolls (was VGPR=12, MfmaUtil 2%, pure latency serialization).
// Everything else unchanged from Round 11.
// N=6000, E=200000, HID=256, GH=64, H=8, B=8.
// ---------------------------------------------------------------------------

static inline int cdiv_h(int a, int b) { return (a + b - 1) / b; }

typedef __attribute__((ext_vector_type(8))) short bf16x8_t;
typedef __attribute__((ext_vector_type(4))) float f32x4_t;

__device__ __forceinline__ float bf16lo(uint32_t w) { return __uint_as_float(w << 16); }
__device__ __forceinline__ float bf16hi(uint32_t w) { return __uint_as_float(w & 0xffff0000u); }
__device__ __forceinline__ unsigned short f2bu(float f) {
  __hip_bfloat16 h = __float2bfloat16(f);
  return *reinterpret_cast<unsigned short*>(&h);
}
__device__ __forceinline__ uint32_t pk_bf16(float a, float b) {
  return (uint32_t)f2bu(a) | ((uint32_t)f2bu(b) << 16);
}

__global__ void fill_f_kernel(float* __restrict__ p, float v, int n) {
  int stride = gridDim.x * blockDim.x;
  for (int i = blockIdx.x * blockDim.x + threadIdx.x; i < n; i += stride) p[i] = v;
}
__global__ void fill_i_kernel(int* __restrict__ p, int v, int n) {
  int stride = gridDim.x * blockDim.x;
  for (int i = blockIdx.x * blockDim.x + threadIdx.x; i < n; i += stride) p[i] = v;
}
__global__ void f2b_kernel(const float* __restrict__ in, __hip_bfloat16* __restrict__ out, int n) {
  int i = blockIdx.x * blockDim.x + threadIdx.x;
  if (i < n) out[i] = __float2bfloat16(in[i]);
}

// ---------------- CSR build ----------------
__global__ void hist_kernel(const int* __restrict__ dst, int* __restrict__ deg, int E) {
  int i = blockIdx.x * blockDim.x + threadIdx.x;
  if (i < E) atomicAdd(&deg[dst[i]], 1);
}

__global__ void scan_kernel(const int* __restrict__ deg, int* __restrict__ rowptr,
                            int* __restrict__ cursor, int N) {
  __shared__ int part[1024];
  const int t = threadIdx.x;
  const int chunk = (N + 1023) / 1024;
  const int base0 = t * chunk;
  int s = 0;
  for (int i = 0; i < chunk; ++i) {
    int idx = base0 + i;
    if (idx < N) s += deg[idx];
  }
  part[t] = s;
  __syncthreads();
  for (int off = 1; off < 1024; off <<= 1) {
    int v = (t >= off) ? part[t - off] : 0;
    __syncthreads();
    part[t] += v;
    __syncthreads();
  }
  int run = (t == 0) ? 0 : part[t - 1];
  for (int i = 0; i < chunk; ++i) {
    int idx = base0 + i;
    if (idx < N) {
      rowptr[idx] = run;
      cursor[idx] = run;
      run += deg[idx];
    }
  }
  if (t == 1023) rowptr[N] = part[1023];
}

__global__ void fill_adj_kernel(const int* __restrict__ src, const int* __restrict__ dst,
                                int* __restrict__ cursor, int* __restrict__ adj, int E) {
  int i = blockIdx.x * blockDim.x + threadIdx.x;
  if (i < E) {
    int p = atomicAdd(&cursor[dst[i]], 1);
    adj[p] = src[i];
  }
}

__global__ void dis_kernel(const int* __restrict__ rowptr, float* __restrict__ dis, int N) {
  int i = blockIdx.x * blockDim.x + threadIdx.x;
  if (i < N) dis[i] = rsqrtf((float)(rowptr[i + 1] - rowptr[i] + 1));
}

// Xd = bf16(x * dis[row])   (C = 64)
__global__ void xd_scale_bf16_kernel(const float* __restrict__ x, const float* __restrict__ dis,
                                     __hip_bfloat16* __restrict__ out, int n) {
  int i = blockIdx.x * blockDim.x + threadIdx.x;
  if (i < n) out[i] = __float2bfloat16(x[i] * dis[i >> 6]);
}

// WT[z][n][k] = bf16(W[z][k][n])
__global__ void transpose_bf16_kernel(const float* __restrict__ W,
                                      __hip_bfloat16* __restrict__ WT, int K, int N) {
  const size_t zoff = (size_t)blockIdx.z * K * N;
  int idx = blockIdx.x * blockDim.x + threadIdx.x;
  if (idx < K * N) {
    int k = idx / N, n = idx % N;
    WT[zoff + (size_t)n * K + k] = __float2bfloat16(W[zoff + idx]);
  }
}

// ---------------- MFMA GEMM: C = A(bf16 MxK) @ WT(bf16 [N][K])^T ------------
// Wave computes 64 rows x 16 cols: 4 row-tiles reuse one B-frag per K-step.
// Block = 4 waves = 64 rows x 64 cols. KC is compile-time (loop fully
// unrolls). EPI: 0 = +bias, relu -> bf16 ; 1 = *rsc[m] -> bf16 ;
// 3 = QKV D=32 (z0 bf16 Q, z1 K, z2 V transposed (n&31)*8+(n>>5)) ;
// 4 = QKV D=8 (z0 bf16 Q, z1 K, z2 V transposed (n&7)*8+(n>>3))
template <int KC, int EPI>
__global__ __launch_bounds__(256) void mfma_gemm_kernel(
    const __hip_bfloat16* __restrict__ A, const __hip_bfloat16* __restrict__ WT,
    const float* __restrict__ bias, const float* __restrict__ rsc,
    float* __restrict__ outF, __hip_bfloat16* __restrict__ outB,
    int M, int N) {
  const int tid = threadIdx.x, w = tid >> 6, lane = tid & 63;
  int z = 0;
  const __hip_bfloat16* Wz = WT;
  const float* bz = bias;
  if (EPI >= 3) {
    z = blockIdx.z;
    Wz = WT + (size_t)z * KC * N;
    bz = bias + (size_t)z * N;
  }
  const int row0 = blockIdx.x * 64;
  const int col0 = blockIdx.y * 64 + w * 16;
  if (col0 >= N) return;
  const int r = lane & 15, kb = lane >> 4;
  f32x4_t acc[4];
#pragma unroll
  for (int i = 0; i < 4; ++i) acc[i] = (f32x4_t){0.f, 0.f, 0.f, 0.f};
  const __hip_bfloat16* bp = Wz + (size_t)(col0 + r) * KC + kb * 8;
  const __hip_bfloat16* ap[4];
#pragma unroll
  for (int i = 0; i < 4; ++i) {
    int rr = row0 + i * 16 + r;
    if (rr > M - 1) rr = M - 1;  // clamp (stores guarded below)
    ap[i] = A + (size_t)rr * KC + kb * 8;
  }
#pragma unroll
  for (int k0 = 0; k0 < KC; k0 += 32) {
    bf16x8_t bv = *(const bf16x8_t*)(bp + k0);
#pragma unroll
    for (int i = 0; i < 4; ++i) {
      bf16x8_t av = *(const bf16x8_t*)(ap[i] + k0);
      acc[i] = __builtin_amdgcn_mfma_f32_16x16x32_bf16(av, bv, acc[i], 0, 0, 0);
    }
  }
  const int n = col0 + r;
#pragma unroll
  for (int i = 0; i < 4; ++i) {
#pragma unroll
    for (int j = 0; j < 4; ++j) {
      const int m = row0 + i * 16 + kb * 4 + j;
      if (m >= M) continue;
      float v = acc[i][j];
      if (EPI == 0) {
        v += bias[n];
        outB[(size_t)m * N + n] = __float2bfloat16(fmaxf(v, 0.f));
      } else if (EPI == 1) {
        v *= rsc[m];
        outB[(size_t)m * N + n] = __float2bfloat16(v);
      } else if (EPI == 3) {
        v += bz[n];
        if (z == 0)
          ((__hip_bfloat16*)outF)[(size_t)m * N + n] = __float2bfloat16(v);
        else if (z == 1)
          outB[(size_t)m * 2 * N + n] = __float2bfloat16(v);
        else
          outB[(size_t)m * 2 * N + N + (size_t)(n & 31) * 8 + (n >> 5)] = __float2bfloat16(v);
      } else {
        v += bz[n];
        if (z == 0)
          ((__hip_bfloat16*)outF)[(size_t)m * N + n] = __float2bfloat16(v);
        else if (z == 1)
          outB[(size_t)m * 2 * N + n] = __float2bfloat16(v);
        else
          outB[(size_t)m * 2 * N + N + (size_t)(n & 7) * 8 + (n >> 3)] = __float2bfloat16(v);
      }
    }
  }
}

// ---------------- f32 fold GEMMs (one-time weight prep) ----------------
template <bool BIAS>
__global__ void gemm3_kernel(const float* __restrict__ A, const float* __restrict__ W0,
                             const float* __restrict__ W1, const float* __restrict__ W2,
                             const float* __restrict__ b0, const float* __restrict__ b1,
                             const float* __restrict__ b2, float* __restrict__ C0,
                             float* __restrict__ C1, float* __restrict__ C2,
                             int M, int K, int N) {
  const int z = blockIdx.z;
  const float* W = (z == 0) ? W0 : (z == 1) ? W1 : W2;
  const float* bias = (z == 0) ? b0 : (z == 1) ? b1 : b2;
  float* C = (z == 0) ? C0 : (z == 1) ? C1 : C2;
  __shared__ float As[16][64];
  __shared__ float Bs[16][64];
  const int tx = threadIdx.x;
  const int m0 = blockIdx.x * 64, n0 = blockIdx.y * 64;
  const int tm = (tx & 15) * 4, tn = (tx >> 4) * 4;
  float acc[4][4] = {};
  for (int k0 = 0; k0 < K; k0 += 16) {
    {
      int m = tx >> 2, kq = (tx & 3) * 4;
      float4 av = make_float4(0.f, 0.f, 0.f, 0.f);
      if (m0 + m < M) av = *(const float4*)(A + (size_t)(m0 + m) * K + (k0 + kq));
      As[kq + 0][m] = av.x; As[kq + 1][m] = av.y;
      As[kq + 2][m] = av.z; As[kq + 3][m] = av.w;
      int kk = tx >> 4, nq = (tx & 15) * 4;
      *(float4*)&Bs[kk][nq] = *(const float4*)(W + (size_t)(k0 + kk) * N + (n0 + nq));
    }
    __syncthreads();
#pragma unroll
    for (int k = 0; k < 16; ++k) {
      float4 a4 = *(const float4*)&As[k][tm];
      float4 b4 = *(const float4*)&Bs[k][tn];
      float av[4] = {a4.x, a4.y, a4.z, a4.w};
      float bv[4] = {b4.x, b4.y, b4.z, b4.w};
#pragma unroll
      for (int i = 0; i < 4; ++i)
#pragma unroll
        for (int j = 0; j < 4; ++j) acc[i][j] += av[i] * bv[j];
    }
    __syncthreads();
  }
#pragma unroll
  for (int i = 0; i < 4; ++i) {
    int m = m0 + tm + i;
    if (m >= M) continue;
#pragma unroll
    for (int j = 0; j < 4; ++j) {
      float v = acc[i][j];
      int n = n0 + tn + j;
      if (BIAS) v += bias[n];
      C[(size_t)m * N + n] = v;
    }
  }
}

// Wf6[z=3l+j] = cw_lin_w[l] @ {q,k,v}w[l]   (grid 4x4x6)
__global__ void gemm_fold6_kernel(const float* __restrict__ lin_w, const float* __restrict__ qw,
                                  const float* __restrict__ kw, const float* __restrict__ vw,
                                  float* __restrict__ Wf) {
  const int z = blockIdx.z, l = z / 3, j = z % 3;
  const float* A = lin_w + (size_t)l * 65536;
  const float* W = ((j == 0) ? qw : (j == 1) ? kw : vw) + (size_t)l * 65536;
  float* C = Wf + (size_t)z * 65536;
  __shared__ float As[16][64];
  __shared__ float Bs[16][64];
  const int tx = threadIdx.x;
  const int m0 = blockIdx.x * 64, n0 = blockIdx.y * 64;
  const int tm = (tx & 15) * 4, tn = (tx >> 4) * 4;
  float acc[4][4] = {};
  for (int k0 = 0; k0 < 256; k0 += 16) {
    {
      int m = tx >> 2, kq = (tx & 3) * 4;
      float4 av = *(const float4*)(A + (size_t)(m0 + m) * 256 + (k0 + kq));
      As[kq + 0][m] = av.x; As[kq + 1][m] = av.y;
      As[kq + 2][m] = av.z; As[kq + 3][m] = av.w;
      int kk = tx >> 4, nq = (tx & 15) * 4;
      *(float4*)&Bs[kk][nq] = *(const float4*)(W + (size_t)(k0 + kk) * 256 + (n0 + nq));
    }
    __syncthreads();
#pragma unroll
    for (int k = 0; k < 16; ++k) {
      float4 a4 = *(const float4*)&As[k][tm];
      float4 b4 = *(const float4*)&Bs[k][tn];
      float av[4] = {a4.x, a4.y, a4.z, a4.w};
      float bv[4] = {b4.x, b4.y, b4.z, b4.w};
#pragma unroll
      for (int i = 0; i < 4; ++i)
#pragma unroll
        for (int j2 = 0; j2 < 4; ++j2) acc[i][j2] += av[i] * bv[j2];
    }
    __syncthreads();
  }
#pragma unroll
  for (int i = 0; i < 4; ++i)
#pragma unroll
    for (int j2 = 0; j2 < 4; ++j2)
      C[(size_t)(m0 + tm + i) * 256 + (n0 + tn + j2)] = acc[i][j2];
}

__global__ void bias_fold6_kernel(const float* __restrict__ lin_b, const float* __restrict__ qw,
                                  const float* __restrict__ kw, const float* __restrict__ vw,
                                  const float* __restrict__ qb, const float* __restrict__ kb,
                                  const float* __restrict__ vb, float* __restrict__ bf) {
  const int z = blockIdx.x, l = z / 3, j = z % 3, c = threadIdx.x;
  const float* W = ((j == 0) ? qw : (j == 1) ? kw : vw) + (size_t)l * 65536;
  const float* b = ((j == 0) ? qb : (j == 1) ? kb : vb) + l * 256;
  const float* lb = lin_b + l * 256;
  float acc = b[c];
  for (int k = 0; k < 256; ++k) acc += lb[k] * W[k * 256 + c];
  bf[z * 256 + c] = acc;
}

__global__ void bias_fold3_kernel(const float* __restrict__ lin_b, const float* __restrict__ qw,
                                  const float* __restrict__ kw, const float* __restrict__ vw,
                                  const float* __restrict__ qb, const float* __restrict__ kb,
                                  const float* __restrict__ vb, float* __restrict__ bf) {
  const int j = blockIdx.x, c = threadIdx.x;
  const float* W = (j == 0) ? qw : (j == 1) ? kw : vw;
  const float* b = (j == 0) ? qb : (j == 1) ? kb : vb;
  float acc = b[c];
  for (int k = 0; k < 64; ++k) acc += lin_b[k] * W[k * 64 + c];
  bf[j * 64 + c] = acc;
}

// ---------------- CustomConv D=32 — full MFMA path --------------------------
__global__ __launch_bounds__(256) void conv_mfma_kernel(
    const __hip_bfloat16* __restrict__ Qn, const __hip_bfloat16* __restrict__ KV,
    const int* __restrict__ rowptr, const int* __restrict__ adj,
    const float* __restrict__ abias, __hip_bfloat16* __restrict__ Xout,
    float inv_sqrt_d) {
  __shared__ __align__(16) unsigned short sKV[4][2048];  // 4 edges x 512 halfs
  __shared__ __align__(16) unsigned short sP[4][640];    // 16 rows x 40 halfs
  __shared__ float sR[4][256];
  const int tid = threadIdx.x, w = tid >> 6, lane = tid & 63;
  const int n = blockIdx.x;
  const int c = lane & 15, kb = lane >> 4;

  const bf16x8_t qf = *(const bf16x8_t*)(Qn + (size_t)n * 256 + (size_t)(c & 7) * 32 + kb * 8);
  const float bh = abias[c & 7];

  unsigned short* myKV = sKV[w];
  unsigned short* myP = sP[w];
  f32x4_t acc0 = {0.f, 0.f, 0.f, 0.f};
  f32x4_t acc1 = {0.f, 0.f, 0.f, 0.f};
  const f32x4_t z4 = {0.f, 0.f, 0.f, 0.f};

  const int s0 = rowptr[n], t0 = rowptr[n + 1];
  auto ld = [&](int idx) -> uint4 {
    if (idx < t0) return *(const uint4*)(KV + (size_t)adj[idx] * 512 + (lane << 3));
    return make_uint4(0u, 0u, 0u, 0u);
  };
  int i = s0 + w * 4;
  uint4 kv0, kv1, kv2, kv3;
  if (i < t0) {
    kv0 = ld(i); kv1 = ld(i + 1); kv2 = ld(i + 2); kv3 = ld(i + 3);
  }
  for (; i < t0; i += 16) {
    *(uint4*)(myKV + 0 + (lane << 3)) = kv0;
    *(uint4*)(myKV + 512 + (lane << 3)) = kv1;
    *(uint4*)(myKV + 1024 + (lane << 3)) = kv2;
    *(uint4*)(myKV + 1536 + (lane << 3)) = kv3;
    const int i2 = i + 16;
    if (i2 < t0) {
      kv0 = ld(i2); kv1 = ld(i2 + 1); kv2 = ld(i2 + 2); kv3 = ld(i2 + 3);
    }
    __builtin_amdgcn_wave_barrier();
    const int aoff = (c >> 3) * 512 + (c & 7) * 32 + kb * 8;
    bf16x8_t a0 = *(const bf16x8_t*)(myKV + aoff);
    bf16x8_t a1 = *(const bf16x8_t*)(myKV + 1024 + aoff);
    f32x4_t S0 = __builtin_amdgcn_mfma_f32_16x16x32_bf16(a0, qf, z4, 0, 0, 0);
    f32x4_t S1 = __builtin_amdgcn_mfma_f32_16x16x32_bf16(a1, qf, z4, 0, 0, 0);
    float p0[4], p1[4];
    {
      float sv[4];
#pragma unroll
      for (int j = 0; j < 4; ++j) sv[j] = S0[j] * inv_sqrt_d + bh;
      float m = fmaxf(fmaxf(sv[0], sv[1]), fmaxf(sv[2], sv[3]));
      m = fmaxf(m, __shfl_xor(m, 16));
      float sum = 0.f;
#pragma unroll
      for (int j = 0; j < 4; ++j) { p0[j] = __expf(sv[j] - m); sum += p0[j]; }
      sum += __shfl_xor(sum, 16);
      float rs = 1.f / sum;
#pragma unroll
      for (int j = 0; j < 4; ++j) p0[j] *= rs;
    }
    {
      float sv[4];
#pragma unroll
      for (int j = 0; j < 4; ++j) sv[j] = S1[j] * inv_sqrt_d + bh;
      float m = fmaxf(fmaxf(sv[0], sv[1]), fmaxf(sv[2], sv[3]));
      m = fmaxf(m, __shfl_xor(m, 16));
      float sum = 0.f;
#pragma unroll
      for (int j = 0; j < 4; ++j) { p1[j] = __expf(sv[j] - m); sum += p1[j]; }
      sum += __shfl_xor(sum, 16);
      float rs = 1.f / sum;
#pragma unroll
      for (int j = 0; j < 4; ++j) p1[j] *= rs;
    }
    *(uint32_t*)(myP + c * 40 + kb * 4) = pk_bf16(p0[0], p0[1]);
    *(uint32_t*)(myP + c * 40 + kb * 4 + 2) = pk_bf16(p0[2], p0[3]);
    *(uint32_t*)(myP + c * 40 + 16 + kb * 4) = pk_bf16(p1[0], p1[1]);
    *(uint32_t*)(myP + c * 40 + 16 + kb * 4 + 2) = pk_bf16(p1[2], p1[3]);
    __builtin_amdgcn_wave_barrier();
    bf16x8_t pa = *(const bf16x8_t*)(myP + c * 40 + kb * 8);
    bf16x8_t vb0 = *(const bf16x8_t*)(myKV + kb * 512 + 256 + c * 8);
    bf16x8_t vb1 = *(const bf16x8_t*)(myKV + kb * 512 + 256 + (c + 16) * 8);
    acc0 = __builtin_amdgcn_mfma_f32_16x16x32_bf16(pa, vb0, acc0, 0, 0, 0);
    acc1 = __builtin_amdgcn_mfma_f32_16x16x32_bf16(pa, vb1, acc1, 0, 0, 0);
    __builtin_amdgcn_wave_barrier();
  }
  if (kb < 2) {
#pragma unroll
    for (int j = 0; j < 4; ++j) {
      int h = kb * 4 + j;
      sR[w][h * 32 + c] = acc0[j];
      sR[w][h * 32 + 16 + c] = acc1[j];
    }
  }
  __syncthreads();
  for (int cc = tid; cc < 256; cc += 256) {
    float v = sR[0][cc] + sR[1][cc] + sR[2][cc] + sR[3][cc];
    Xout[(size_t)n * 256 + cc] = __float2bfloat16(fmaxf(v, 0.f));
  }
}

// ---------------- CustomConv D=8 (conv3) — MFMA path ------------------------
__global__ __launch_bounds__(256) void conv3_mfma_kernel(
    const __hip_bfloat16* __restrict__ Qn, const __hip_bfloat16* __restrict__ KV,
    const int* __restrict__ rowptr, const int* __restrict__ adj,
    const float* __restrict__ abias, float* __restrict__ Xout, float inv_sqrt_d) {
  __shared__ __align__(16) unsigned short sKV[4][544];  // 4 edges x 136 halfs
  __shared__ __align__(16) unsigned short sP[4][320];   // 8 rows x 40 halfs
  __shared__ float sR[4][64];
  const int tid = threadIdx.x, w = tid >> 6, lane = tid & 63;
  const int n = blockIdx.x;
  const int c = lane & 15, kb = lane >> 4;

  bf16x8_t qf = {};
  if (kb == 0) qf = *(const bf16x8_t*)(Qn + (size_t)n * 64 + (size_t)(c & 7) * 8);
  const float bh = abias[c & 7];

  unsigned short* myKV = sKV[w];
  unsigned short* myP = sP[w];
  f32x4_t acc = {0.f, 0.f, 0.f, 0.f};
  const f32x4_t z4 = {0.f, 0.f, 0.f, 0.f};

  const int s0 = rowptr[n], t0 = rowptr[n + 1];
  auto ld = [&](int idx) -> uint4 {
    if (idx < t0) return *(const uint4*)(KV + (size_t)adj[idx] * 128 + (c << 3));
    return make_uint4(0u, 0u, 0u, 0u);
  };
  int i = s0 + w * 4;
  uint4 kvst = make_uint4(0u, 0u, 0u, 0u);
  if (i < t0) kvst = ld(i + kb);
  for (; i < t0; i += 16) {
    *(uint4*)(myKV + kb * 136 + (c << 3)) = kvst;
    kvst = ld(i + 16 + kb);
    __builtin_amdgcn_wave_barrier();
    bf16x8_t a0 = {}, a1 = {};
    if (kb == 0) {
      a0 = *(const bf16x8_t*)(myKV + (c >> 3) * 136 + (c & 7) * 8);
      a1 = *(const bf16x8_t*)(myKV + (2 + (c >> 3)) * 136 + (c & 7) * 8);
    }
    f32x4_t S0 = __builtin_amdgcn_mfma_f32_16x16x32_bf16(a0, qf, z4, 0, 0, 0);
    f32x4_t S1 = __builtin_amdgcn_mfma_f32_16x16x32_bf16(a1, qf, z4, 0, 0, 0);
    float p0[4], p1[4];
    {
      float sv[4];
#pragma unroll
      for (int j = 0; j < 4; ++j) sv[j] = S0[j] * inv_sqrt_d + bh;
      float m = fmaxf(fmaxf(sv[0], sv[1]), fmaxf(sv[2], sv[3]));
      m = fmaxf(m, __shfl_xor(m, 16));
      float sum = 0.f;
#pragma unroll
      for (int j = 0; j < 4; ++j) { p0[j] = __expf(sv[j] - m); sum += p0[j]; }
      sum += __shfl_xor(sum, 16);
      float rs = 1.f / sum;
#pragma unroll
      for (int j = 0; j < 4; ++j) p0[j] *= rs;
    }
    {
      float sv[4];
#pragma unroll
      for (int j = 0; j < 4; ++j) sv[j] = S1[j] * inv_sqrt_d + bh;
      float m = fmaxf(fmaxf(sv[0], sv[1]), fmaxf(sv[2], sv[3]));
      m = fmaxf(m, __shfl_xor(m, 16));
      float sum = 0.f;
#pragma unroll
      for (int j = 0; j < 4; ++j) { p1[j] = __expf(sv[j] - m); sum += p1[j]; }
      sum += __shfl_xor(sum, 16);
      float rs = 1.f / sum;
#pragma unroll
      for (int j = 0; j < 4; ++j) p1[j] *= rs;
    }
    if (c < 8) {
      const int k0 = (kb >> 1) * 8 + (kb & 1) * 4;
      *(uint32_t*)(myP + c * 40 + k0) = pk_bf16(p0[0], p0[1]);
      *(uint32_t*)(myP + c * 40 + k0 + 2) = pk_bf16(p0[2], p0[3]);
      *(uint32_t*)(myP + c * 40 + 16 + k0) = pk_bf16(p1[0], p1[1]);
      *(uint32_t*)(myP + c * 40 + 16 + k0 + 2) = pk_bf16(p1[2], p1[3]);
    }
    __builtin_amdgcn_wave_barrier();
    bf16x8_t pa = *(const bf16x8_t*)(myP + (c & 7) * 40 + kb * 8);
    bf16x8_t vb = {};
    if (c < 8) vb = *(const bf16x8_t*)(myKV + kb * 136 + 64 + c * 8);
    acc = __builtin_amdgcn_mfma_f32_16x16x32_bf16(pa, vb, acc, 0, 0, 0);
    __builtin_amdgcn_wave_barrier();
  }
  if (kb < 2 && c < 8) {
#pragma unroll
    for (int j = 0; j < 4; ++j) sR[w][(kb * 4 + j) * 8 + c] = acc[j];
  }
  __syncthreads();
  if (tid < 64) {
    float v = sR[0][tid] + sR[1][tid] + sR[2][tid] + sR[3][tid];
    Xout[(size_t)n * 64 + tid] = fmaxf(v, 0.f);
  }
}

// ---------------- GCN propagate via dst-CSR gather, bf16 rows ---------------
template <int C, bool BIAS, bool RELU, bool OBF>
__global__ __launch_bounds__(256) void gcn_gather5_kernel(
    const __hip_bfloat16* __restrict__ Hd, const int* __restrict__ rowptr,
    const int* __restrict__ adj, const float* __restrict__ dis,
    const float* __restrict__ bias, void* __restrict__ O, int Nn) {
  constexpr int EPL = C / 64;  // 4, 2, 1
  __shared__ float sR[4][C];
  const int tid = threadIdx.x, w = tid >> 6, lane = tid & 63;
  const int n = blockIdx.x;
  float acc[EPL] = {};
  const int s = rowptr[n], t = rowptr[n + 1];
  int i = s + w;
  int vs = (i < t) ? adj[i] : 0;
  if constexpr (EPL == 4) {
    uint2 u = (i < t) ? *(const uint2*)(Hd + (size_t)vs * C + lane * 4) : make_uint2(0u, 0u);
    while (i < t) {
      const int i2 = i + 4;
      const int vs2 = (i2 < t) ? adj[i2] : 0;
      uint2 un = (i2 < t) ? *(const uint2*)(Hd + (size_t)vs2 * C + lane * 4) : make_uint2(0u, 0u);
      acc[0] += bf16lo(u.x); acc[1] += bf16hi(u.x);
      acc[2] += bf16lo(u.y); acc[3] += bf16hi(u.y);
      u = un; i = i2; vs = vs2;
    }
  } else if constexpr (EPL == 2) {
    uint32_t u = (i < t) ? *(const uint32_t*)(Hd + (size_t)vs * C + lane * 2) : 0u;
    while (i < t) {
      const int i2 = i + 4;
      const int vs2 = (i2 < t) ? adj[i2] : 0;
      uint32_t un = (i2 < t) ? *(const uint32_t*)(Hd + (size_t)vs2 * C + lane * 2) : 0u;
      acc[0] += bf16lo(u); acc[1] += bf16hi(u);
      u = un; i = i2; vs = vs2;
    }
  } else {
    unsigned short u = (i < t) ? *(const unsigned short*)(Hd + (size_t)vs * C + lane) : 0;
    while (i < t) {
      const int i2 = i + 4;
      const int vs2 = (i2 < t) ? adj[i2] : 0;
      unsigned short un = (i2 < t) ? *(const unsigned short*)(Hd + (size_t)vs2 * C + lane) : 0;
      acc[0] += bf16lo((uint32_t)u);
      u = un; i = i2; vs = vs2;
    }
  }
  if (w == 0) {
    const __hip_bfloat16* hn = Hd + (size_t)n * C;
#pragma unroll
    for (int j = 0; j < EPL; ++j)
      acc[j] += bf16lo((uint32_t)*(const unsigned short*)(hn + lane * EPL + j));
  }
#pragma unroll
  for (int j = 0; j < EPL; ++j) sR[w][lane * EPL + j] = acc[j];
  __syncthreads();
  const float dn = dis[n];
  for (int c = tid; c < C; c += 256) {
    float v = (sR[0][c] + sR[1][c] + sR[2][c] + sR[3][c]) * dn;
    if (BIAS) v += bias[c];
    if (RELU) v = fmaxf(v, 0.f);
    if (OBF)
      ((__hip_bfloat16*)O)[(size_t)n * C + c] = __float2bfloat16(v);
    else
      ((float*)O)[(size_t)n * C + c] = v;
  }
}

// ---------------- segment sums (grid-stride, 120 blocks) ----------------
__global__ void segsum_x3_pe_kernel(const float* __restrict__ X3, const int* __restrict__ batch,
                                    float* __restrict__ sum_x3, float* __restrict__ sum_pe,
                                    float* __restrict__ cnt, int N) {
  __shared__ float lx[512], lp[512], lc[8];
  const int tid = threadIdx.x;
  for (int i = tid; i < 512; i += 256) { lx[i] = 0.f; lp[i] = 0.f; }
  if (tid < 8) lc[tid] = 0.f;
  __syncthreads();
  const int stride = gridDim.x * 256;
  for (int i = blockIdx.x * 256 + tid; i < N * 64; i += stride) {
    int n = i >> 6, c = i & 63;
    int b = batch[n];
    atomicAdd(&lx[(b << 6) + c], X3[i]);
    const float F = -0.14391156831f;  // -ln(10000)/64
    float arg = (float)n * __expf(F * (float)(c & ~1));
    atomicAdd(&lp[(b << 6) + c], (c & 1) ? __cosf(arg) : __sinf(arg));
    if (c == 0) atomicAdd(&lc[b], 1.f);
  }
  __syncthreads();
  for (int j = tid; j < 512; j += 256) {
    if (lx[j] != 0.f) atomicAdd(&sum_x3[j], lx[j]);
    if (lp[j] != 0.f) atomicAdd(&sum_pe[j], lp[j]);
  }
  if (tid < 8 && lc[tid] != 0.f) atomicAdd(&cnt[tid], lc[tid]);
}

__global__ void segsum_vfd_kernel(const float* __restrict__ VFD, const int* __restrict__ batch,
                                  float* __restrict__ sum_vfd, float* __restrict__ cnt, int N) {
  __shared__ float lv[1024], lc[8];
  const int tid = threadIdx.x;
  for (int i = tid; i < 1024; i += 256) lv[i] = 0.f;
  if (tid < 8) lc[tid] = 0.f;
  __syncthreads();
  const int stride = gridDim.x * 256;
  for (int i = blockIdx.x * 256 + tid; i < N * 128; i += stride) {
    int n = i >> 7, c = i & 127;
    int b = batch[n];
    atomicAdd(&lv[(b << 7) + c], VFD[i]);
    if (c == 0) atomicAdd(&lc[b], 1.f);
  }
  __syncthreads();
  for (int j = tid; j < 1024; j += 256) {
    if (lv[j] != 0.f) atomicAdd(&sum_vfd[j], lv[j]);
  }
  if (tid < 8 && lc[tid] != 0.f) atomicAdd(&cnt[tid], lc[tid]);
}

// ---------------- head: 8 blocks (one per batch), K-split dot products ------
__global__ __launch_bounds__(256) void head_kernel(
    const float* __restrict__ sum_x3, const float* __restrict__ sum_pe,
    const float* __restrict__ cnt_wt, const float* __restrict__ sum_vfd,
    const float* __restrict__ cnt_df, const float* __restrict__ sft_w,
    const float* __restrict__ sft_b, const float* __restrict__ gru_wih,
    const float* __restrict__ gru_bih, const float* __restrict__ gru_bhh,
    const float* __restrict__ mlp_w1, const float* __restrict__ mlp_b1,
    const float* __restrict__ mlp_w2, const float* __restrict__ mlp_b2,
    const float* __restrict__ mlp_w3, const float* __restrict__ mlp_b3,
    const float* __restrict__ pred_w, const float* __restrict__ pred_b,
    float* __restrict__ out) {
  const int b = blockIdx.x;  // batch row
  const int tid = threadIdx.x;
  __shared__ float sf0[64], sf1[64], sfr[64];
  __shared__ float hcat[256];
  __shared__ float m1[128], m2[128], m3[128];
  __shared__ float part4[4][64];
  __shared__ float part2[2][128];
  __shared__ float gi[192];
  __shared__ float rsum[4];

  const float cw = fmaxf(cnt_wt[b], 1.f), cd = fmaxf(cnt_df[b], 1.f);
  if (tid < 64) sf0[tid] = sum_x3[(b << 6) + tid] / cw;
  __syncthreads();
  {
    const int c = tid & 63, q = tid >> 6;
    float acc = 0.f;
#pragma unroll
    for (int k = q * 16; k < q * 16 + 16; ++k) acc += sf0[k] * sft_w[k * 64 + c];
    part4[q][c] = acc;
  }
  __syncthreads();
  if (tid < 64)
    sf1[tid] = fmaxf(part4[0][tid] + part4[1][tid] + part4[2][tid] + part4[3][tid] +
                         sft_b[tid], 0.f);
  __syncthreads();
  if (tid < 192) {
    float acc = gru_bih[tid];
    const float* wr = gru_wih + tid * 64;
#pragma unroll 8
    for (int k = 0; k < 64; ++k) acc += sf1[k] * wr[k];
    gi[tid] = acc;
  }
  __syncthreads();
  if (tid < 64) {
    float r = 1.f / (1.f + __expf(-(gi[tid] + gru_bhh[tid])));
    float z = 1.f / (1.f + __expf(-(gi[64 + tid] + gru_bhh[64 + tid])));
    float ng = tanhf(gi[128 + tid] + r * gru_bhh[128 + tid]);
    sfr[tid] = (1.f - z) * ng;
  }
  __syncthreads();
  {
    const int c = tid;
    float v;
    if (c < 64)
      v = (sum_x3[(b << 6) + c] + sum_pe[(b << 6) + c]) / cw;
    else if (c < 128)
      v = sfr[c - 64];
    else
      v = sum_vfd[(b << 7) + (c - 128)] / cd;
    hcat[c] = v;
  }
  __syncthreads();
  {
    const int c = tid & 127, h = tid >> 7;
    float acc = 0.f;
#pragma unroll 8
    for (int k = h * 128; k < h * 128 + 128; ++k) acc += hcat[k] * mlp_w1[k * 128 + c];
    part2[h][c] = acc;
  }
  __syncthreads();
  if (tid < 128) m1[tid] = fmaxf(part2[0][tid] + part2[1][tid] + mlp_b1[tid], 0.f);
  __syncthreads();
  {
    const int c = tid & 127, h = tid >> 7;
    float acc = 0.f;
#pragma unroll 8
    for (int k = h * 64; k < h * 64 + 64; ++k) acc += m1[k] * mlp_w2[k * 128 + c];
    part2[h][c] = acc;
  }
  __syncthreads();
  if (tid < 128) m2[tid] = fmaxf(part2[0][tid] + part2[1][tid] + mlp_b2[tid], 0.f);
  __syncthreads();
  {
    const int c = tid & 127, h = tid >> 7;
    float acc = 0.f;
#pragma unroll 8
    for (int k = h * 64; k < h * 64 + 64; ++k) acc += m2[k] * mlp_w3[k * 128 + c];
    part2[h][c] = acc;
  }
  __syncthreads();
  if (tid < 128) m3[tid] = part2[0][tid] + part2[1][tid] + mlp_b3[tid];
  __syncthreads();
  if (tid < 128) {
    float p = m3[tid] * pred_w[tid];
    p += __shfl_down(p, 32);
    p += __shfl_down(p, 16);
    p += __shfl_down(p, 8);
    p += __shfl_down(p, 4);
    p += __shfl_down(p, 2);
    p += __shfl_down(p, 1);
    if ((tid & 63) == 0) rsum[tid >> 6] = p;
  }
  __syncthreads();
  if (tid == 0) out[b] = rsum[0] + rsum[1] + pred_b[0];
}

// ---------------------------------------------------------------------------
extern "C" void kernel_launch(void* const* d_in, const int* in_sizes, int n_in,
                              void* d_out, int out_size, void* d_ws, size_t ws_size,
                              hipStream_t stream) {
  const float* x_wt = (const float*)d_in[0];
  const float* x_diff = (const float*)d_in[1];
  const int* ei_wt = (const int*)d_in[2];
  const int* ei_df = (const int*)d_in[3];
  const int* b_wt = (const int*)d_in[4];
  const int* b_df = (const int*)d_in[5];
  const float* emb_w = (const float*)d_in[6];
  const float* emb_b = (const float*)d_in[7];
  const float* cw_lin_w = (const float*)d_in[8];
  const float* cw_lin_b = (const float*)d_in[9];
  const float* cw_q_w = (const float*)d_in[10];
  const float* cw_q_b = (const float*)d_in[11];
  const float* cw_k_w = (const float*)d_in[12];
  const float* cw_k_b = (const float*)d_in[13];
  const float* cw_v_w = (const float*)d_in[14];
  const float* cw_v_b = (const float*)d_in[15];
  const float* cw_bias = (const float*)d_in[16];
  const float* c3_lin_w = (const float*)d_in[17];
  const float* c3_lin_b = (const float*)d_in[18];
  const float* c3_q_w = (const float*)d_in[19];
  const float* c3_q_b = (const float*)d_in[20];
  const float* c3_k_w = (const float*)d_in[21];
  const float* c3_k_b = (const float*)d_in[22];
  const float* c3_v_w = (const float*)d_in[23];
  const float* c3_v_b = (const float*)d_in[24];
  const float* c3_bias = (const float*)d_in[25];
  const float* sft_w = (const float*)d_in[26];
  const float* sft_b = (const float*)d_in[27];
  const float* gru_wih = (const float*)d_in[28];
  const float* gru_bih = (const float*)d_in[30];
  const float* gru_bhh = (const float*)d_in[31];
  const float* gcn_w1 = (const float*)d_in[32];
  const float* gcn_b1 = (const float*)d_in[33];
  const float* gcn_w2 = (const float*)d_in[34];
  const float* gcn_b2 = (const float*)d_in[35];
  const float* gcn_w3 = (const float*)d_in[36];
  const float* gcn_b3 = (const float*)d_in[37];
  const float* mlp_w1 = (const float*)d_in[38];
  const float* mlp_b1 = (const float*)d_in[39];
  const float* mlp_w2 = (const float*)d_in[40];
  const float* mlp_b2 = (const float*)d_in[41];
  const float* mlp_w3 = (const float*)d_in[42];
  const float* mlp_b3 = (const float*)d_in[43];
  const float* pred_w = (const float*)d_in[44];
  const float* pred_b = (const float*)d_in[45];

  const int N = in_sizes[0] / 64;  // 6000
  const int E = in_sizes[2] / 2;   // 200000
  const int* src_wt = ei_wt;
  const int* dst_wt = ei_wt + E;
  const int* src_df = ei_df;
  const int* dst_df = ei_df + E;

  // ---- workspace layout ----
  float* ws = (float*)d_ws;
  const size_t fN256 = (size_t)N * 256;
  float* X = ws;
  float* L = ws + 1 * fN256;
  float* Qb = ws + 2 * fN256;
  float* Kb = ws + 3 * fN256;
  float* Vb = ws + 4 * fN256;
  float* X3 = ws + 5 * fN256;          // (N,64) f32
  float* DIS = X3 + (size_t)N * 64;    // (N)
  float* SEG = DIS + (((size_t)N + 63) / 64) * 64;
  float* sum_x3 = SEG;                 // 512
  float* sum_pe = SEG + 512;           // 512
  float* cnt_wt = SEG + 1024;          // 8
  float* sum_vfd = SEG + 1032;         // 1024
  float* cnt_df = SEG + 2056;          // 8
  int* ip = (int*)(SEG + 2064 + 16);
  int* rp_wt = ip;                     // N+1
  int* cur_wt = rp_wt + (N + 1);       // N
  int* adj_wt = cur_wt + N;            // E
  int* rp_df = adj_wt + E;             // N+1
  int* cur_df = rp_df + (N + 1);       // N
  int* adj_df = cur_df + N;            // E
  float* Wf6 = (float*)((((uintptr_t)(adj_df + E)) + 63) & ~(uintptr_t)63);  // 6*65536 f32
  float* bf6 = Wf6 + 6 * 65536;        // 6*256
  float* Wf3 = bf6 + 6 * 256;          // 3*16384 f32
  float* bf3 = Wf3 + 3 * 16384;        // 3*64
  __hip_bfloat16* wb = (__hip_bfloat16*)((((uintptr_t)(bf3 + 3 * 64)) + 63) & ~(uintptr_t)63);
  __hip_bfloat16* WfT6 = wb;                    // 6*65536
  __hip_bfloat16* Wf3T = WfT6 + 6 * 65536;      // 3*16384
  __hip_bfloat16* embT = Wf3T + 3 * 16384;      // 256*64
  __hip_bfloat16* w1T = embT + 16384;           // 256*64
  __hip_bfloat16* w2T = w1T + 16384;            // 256*256
  __hip_bfloat16* w3T = w2T + 65536;            // 128*256

  __hip_bfloat16* Xb = (__hip_bfloat16*)X;      // N x 256
  __hip_bfloat16* xwtb = (__hip_bfloat16*)L;    // N x 64 (emb input)
  __hip_bfloat16* Qb16 = (__hip_bfloat16*)Qb;   // N x 256 / N x 64 bf16 Q
  __hip_bfloat16* KVb = (__hip_bfloat16*)Kb;    // N x 512 / N x 128
  __hip_bfloat16* Hd1 = (__hip_bfloat16*)Kb;    // GCN ping/pong
  __hip_bfloat16* G1 = (__hip_bfloat16*)Vb;
  __hip_bfloat16* Y1 = (__hip_bfloat16*)Kb;
  __hip_bfloat16* Hd2 = (__hip_bfloat16*)Vb;
  __hip_bfloat16* Y2b = (__hip_bfloat16*)Kb;
  __hip_bfloat16* Hd3 = (__hip_bfloat16*)Vb;
  float* VFD = L;

  const int TB = 256;

  // ---- weight folds (f32) + transposes to bf16 WT[n][k] ----
  gemm_fold6_kernel<<<dim3(4, 4, 6), TB, 0, stream>>>(cw_lin_w, cw_q_w, cw_k_w, cw_v_w, Wf6);
  bias_fold6_kernel<<<6, TB, 0, stream>>>(cw_lin_b, cw_q_w, cw_k_w, cw_v_w, cw_q_b, cw_k_b,
                                          cw_v_b, bf6);
  gemm3_kernel<false><<<dim3(4, 1, 3), TB, 0, stream>>>(
      c3_lin_w, c3_q_w, c3_k_w, c3_v_w, nullptr, nullptr, nullptr,
      Wf3, Wf3 + 16384, Wf3 + 32768, 256, 64, 64);
  bias_fold3_kernel<<<3, 64, 0, stream>>>(c3_lin_b, c3_q_w, c3_k_w, c3_v_w, c3_q_b, c3_k_b,
                                          c3_v_b, bf3);
  transpose_bf16_kernel<<<dim3(cdiv_h(65536, TB), 1, 6), TB, 0, stream>>>(Wf6, WfT6, 256, 256);
  transpose_bf16_kernel<<<dim3(cdiv_h(16384, TB), 1, 3), TB, 0, stream>>>(Wf3, Wf3T, 256, 64);
  transpose_bf16_kernel<<<dim3(cdiv_h(16384, TB), 1, 1), TB, 0, stream>>>(emb_w, embT, 64, 256);
  transpose_bf16_kernel<<<dim3(cdiv_h(16384, TB), 1, 1), TB, 0, stream>>>(gcn_w1, w1T, 64, 256);
  transpose_bf16_kernel<<<dim3(cdiv_h(65536, TB), 1, 1), TB, 0, stream>>>(gcn_w2, w2T, 256, 256);
  transpose_bf16_kernel<<<dim3(cdiv_h(32768, TB), 1, 1), TB, 0, stream>>>(gcn_w3, w3T, 256, 128);

  // ---- CSR build (both graphs); reuse cur_* as temporary deg ----
  fill_i_kernel<<<32, TB, 0, stream>>>(cur_wt, 0, N);
  fill_i_kernel<<<32, TB, 0, stream>>>(cur_df, 0, N);
  hist_kernel<<<cdiv_h(E, TB), TB, 0, stream>>>(dst_wt, cur_wt, E);
  hist_kernel<<<cdiv_h(E, TB), TB, 0, stream>>>(dst_df, cur_df, E);
  scan_kernel<<<1, 1024, 0, stream>>>(cur_wt, rp_wt, cur_wt, N);
  scan_kernel<<<1, 1024, 0, stream>>>(cur_df, rp_df, cur_df, N);
  fill_adj_kernel<<<cdiv_h(E, TB), TB, 0, stream>>>(src_wt, dst_wt, cur_wt, adj_wt, E);
  fill_adj_kernel<<<cdiv_h(E, TB), TB, 0, stream>>>(src_df, dst_df, cur_df, adj_df, E);
  dis_kernel<<<cdiv_h(N, TB), TB, 0, stream>>>(rp_df, DIS, N);

  const int MT64 = cdiv_h(N, 64);  // 94 row-tiles
  // ---- WT branch ----
  f2b_kernel<<<cdiv_h(N * 64, TB), TB, 0, stream>>>(x_wt, xwtb, N * 64);
  mfma_gemm_kernel<64, 0><<<dim3(MT64, 4), TB, 0, stream>>>(xwtb, embT, emb_b, nullptr,
                                                            nullptr, Xb, N, 256);
  const float isd32 = 0.17677669529663687f;  // 1/sqrt(32)
  const float isd8 = 0.35355339059327373f;   // 1/sqrt(8)
  for (int l = 0; l < 2; ++l) {
    mfma_gemm_kernel<256, 3><<<dim3(MT64, 4, 3), TB, 0, stream>>>(
        Xb, WfT6 + (size_t)l * 3 * 65536, bf6 + l * 768, nullptr, (float*)Qb16, KVb, N, 256);
    conv_mfma_kernel<<<N, TB, 0, stream>>>(Qb16, KVb, rp_wt, adj_wt, cw_bias + l * 8,
                                           Xb, isd32);
  }
  // conv3 (256 -> 64), lin folded into QKV (bf16 Q + K|Vt interleaved)
  mfma_gemm_kernel<256, 4><<<dim3(MT64, 1, 3), TB, 0, stream>>>(Xb, Wf3T, bf3, nullptr,
                                                                (float*)Qb16, KVb, N, 64);
  conv3_mfma_kernel<<<N, TB, 0, stream>>>(Qb16, KVb, rp_wt, adj_wt, c3_bias, X3, isd8);

  fill_f_kernel<<<8, TB, 0, stream>>>(SEG, 0.f, 2064);
  segsum_x3_pe_kernel<<<120, TB, 0, stream>>>(X3, b_wt, sum_x3, sum_pe, cnt_wt, N);

  // ---- diff branch (GCN); dis[src] folded into bf16 rows ----
  xd_scale_bf16_kernel<<<cdiv_h(N * 64, TB), TB, 0, stream>>>(x_diff, DIS, Hd1, N * 64);
  gcn_gather5_kernel<64, false, false, true><<<N, TB, 0, stream>>>(Hd1, rp_df, adj_df, DIS,
                                                                   nullptr, G1, N);
  mfma_gemm_kernel<64, 0><<<dim3(MT64, 4), TB, 0, stream>>>(G1, w1T, gcn_b1, nullptr,
                                                            nullptr, Y1, N, 256);
  mfma_gemm_kernel<256, 1><<<dim3(MT64, 4), TB, 0, stream>>>(Y1, w2T, nullptr, DIS,
                                                             nullptr, Hd2, N, 256);
  gcn_gather5_kernel<256, true, true, true><<<N, TB, 0, stream>>>(Hd2, rp_df, adj_df, DIS,
                                                                  gcn_b2, Y2b, N);
  mfma_gemm_kernel<256, 1><<<dim3(MT64, 2), TB, 0, stream>>>(Y2b, w3T, nullptr, DIS,
                                                             nullptr, Hd3, N, 128);
  gcn_gather5_kernel<128, true, false, false><<<N, TB, 0, stream>>>(Hd3, rp_df, adj_df, DIS,
                                                                    gcn_b3, VFD, N);
  segsum_vfd_kernel<<<120, TB, 0, stream>>>(VFD, b_df, sum_vfd, cnt_df, N);

  // ---- head ----
  head_kernel<<<8, TB, 0, stream>>>(sum_x3, sum_pe, cnt_wt, sum_vfd, cnt_df, sft_w, sft_b,
                                    gru_wih, gru_bih, gru_bhh, mlp_w1, mlp_b1, mlp_w2,
                                    mlp_b2, mlp_w3, mlp_b3, pred_w, pred_b, (float*)d_out);
}